// Round 4
// baseline (803.670 us; speedup 1.0000x reference)
//
#include <hip/hip_runtime.h>
#include <math.h>

#define T_LEN 2048
#define HIDN  2048
#define HKN   16
#define DKN   96
#define HVN   16
#define DVN   192
#define KDIMN 1536
#define VDIMN 3072
#define QKVD  6144   // q(1536)+k(1536)+v(3072)
#define CHUNKN 64
#define NCHUNK 32
#define EPSF 1e-6f

typedef __attribute__((ext_vector_type(8))) short short8;
typedef __attribute__((ext_vector_type(4))) float f32x4;

__device__ __forceinline__ unsigned short f2bf(float f) {
    unsigned int u = __float_as_uint(f);
    unsigned int r = (u + 0x7FFFu + ((u >> 16) & 1u)) >> 16;
    return (unsigned short)r;
}
__device__ __forceinline__ float siluf(float x) { return x / (1.f + expf(-x)); }

__device__ __forceinline__ void gld_lds16(const void* g, void* l) {
    __builtin_amdgcn_global_load_lds((const __attribute__((address_space(1))) unsigned int*)g,
                                     (__attribute__((address_space(3))) unsigned int*)l, 16, 0, 0);
}

// ---------------- cast f32 -> bf16 (4/thread) ----------------
__global__ void cast_f32_bf16(const float* __restrict__ in, unsigned short* __restrict__ out, int n) {
    int i = (blockIdx.x * blockDim.x + threadIdx.x) * 4;
    if (i >= n) return;
    float4 v = *(const float4*)(in + i);
    ushort4 o;
    o.x = f2bf(v.x); o.y = f2bf(v.y); o.z = f2bf(v.z); o.w = f2bf(v.w);
    *(ushort4*)(out + i) = o;
}

// ---------------- transpose + cast: W[K][N] -> Wt[N][K] bf16 ----------------
__global__ void transpose_cast(const float* __restrict__ W, unsigned short* __restrict__ Wt,
                               int K, int N) {
    __shared__ float tile[64][65];
    int k0 = blockIdx.y * 64, n0 = blockIdx.x * 64;
    int tx = threadIdx.x, ty = threadIdx.y; // (64,4)
    for (int r = ty; r < 64; r += 4) tile[r][tx] = W[(size_t)(k0 + r) * N + n0 + tx];
    __syncthreads();
    for (int r = ty; r < 64; r += 4) Wt[(size_t)(n0 + r) * K + k0 + tx] = f2bf(tile[tx][r]);
}

// ---------------- bf16 MFMA GEMM: C[M][N] f32 = A[M][K] @ Bt[N][K]^T ----------------
__global__ __launch_bounds__(256) void gemm_bt(const unsigned short* __restrict__ A,
                                               const unsigned short* __restrict__ Bt,
                                               float* __restrict__ C, int M, int N, int K) {
    __shared__ __align__(16) unsigned short As[128 * 32];
    __shared__ __align__(16) unsigned short Bs[128 * 32];
    int tid = threadIdx.x;
    int wave = tid >> 6, lane = tid & 63;
    int bm = blockIdx.y, bn = blockIdx.x;
    f32x4 acc[4][4] = {};
    int wr = wave >> 1, wc = wave & 1;
    int rstage = wave * 32 + (lane >> 2);
    int cstage = (lane & 3) * 8;
    const size_t a_row0 = (size_t)bm * 128;
    const size_t b_row0 = (size_t)bn * 128;
    int row_a[4], row_b[4];
#pragma unroll
    for (int i = 0; i < 4; ++i) {
        row_a[i] = wr * 64 + i * 16 + (lane & 15);
        row_b[i] = wc * 64 + i * 16 + (lane & 15);
    }
    int koff = (lane >> 4) * 8;
    unsigned short* as_base = As + wave * 1024;
    unsigned short* bs_base = Bs + wave * 1024;
    for (int k0 = 0; k0 < K; k0 += 32) {
        const unsigned short* ga = A + (a_row0 + rstage) * (size_t)K + k0 + cstage;
        const unsigned short* gb = Bt + (b_row0 + rstage) * (size_t)K + k0 + cstage;
        gld_lds16(ga, as_base);
        gld_lds16(ga + (size_t)16 * K, as_base + 512);
        gld_lds16(gb, bs_base);
        gld_lds16(gb + (size_t)16 * K, bs_base + 512);
        __syncthreads();
        short8 af[4], bfr[4];
#pragma unroll
        for (int mi = 0; mi < 4; ++mi) af[mi] = *(const short8*)(As + row_a[mi] * 32 + koff);
#pragma unroll
        for (int ni = 0; ni < 4; ++ni) bfr[ni] = *(const short8*)(Bs + row_b[ni] * 32 + koff);
#pragma unroll
        for (int mi = 0; mi < 4; ++mi)
#pragma unroll
            for (int ni = 0; ni < 4; ++ni)
                acc[mi][ni] = __builtin_amdgcn_mfma_f32_16x16x32_bf16(af[mi], bfr[ni], acc[mi][ni], 0, 0, 0);
        __syncthreads();
    }
#pragma unroll
    for (int mi = 0; mi < 4; ++mi) {
        int rbase = bm * 128 + wr * 64 + mi * 16 + (lane >> 4) * 4;
#pragma unroll
        for (int ni = 0; ni < 4; ++ni) {
            int col = bn * 128 + wc * 64 + ni * 16 + (lane & 15);
#pragma unroll
            for (int j = 0; j < 4; ++j)
                C[(size_t)(rbase + j) * N + col] = acc[mi][ni][j];
        }
    }
}

// ---------------- causal depthwise conv(K=4) + SiLU ----------------
__global__ void conv_silu(const float* __restrict__ pre, int ldp,
                          const float* __restrict__ wconv, float* __restrict__ out, int C) {
    int c = blockIdx.x * blockDim.x + threadIdx.x;
    int t = blockIdx.y;
    if (c >= C) return;
    const float* wc4 = wconv + (size_t)c * 4;
    float acc = 0.f;
    if (t >= 3) acc += pre[(size_t)(t - 3) * ldp + c] * wc4[0];
    if (t >= 2) acc += pre[(size_t)(t - 2) * ldp + c] * wc4[1];
    if (t >= 1) acc += pre[(size_t)(t - 1) * ldp + c] * wc4[2];
    acc += pre[(size_t)t * ldp + c] * wc4[3];
    out[(size_t)t * C + c] = siluf(acc);
}

// ---------------- beta / g projections (f32, exact) ----------------
__global__ __launch_bounds__(256) void beta_g(const float* __restrict__ X,
                                              const float* __restrict__ Wb, const float* __restrict__ Wa,
                                              const float* __restrict__ A_log, const float* __restrict__ dtb,
                                              float* __restrict__ bvec, float* __restrict__ gvec) {
    int t = blockIdx.x;
    int tid = threadIdx.x;
    int s = tid >> 5, c = tid & 31;
    float acc = 0.f;
    const float* xr = X + (size_t)t * HIDN;
    for (int k = s; k < HIDN; k += 8) {
        float xv = xr[k];
        float wv = (c < 16) ? Wb[(size_t)k * 16 + c] : Wa[(size_t)k * 16 + (c - 16)];
        acc += xv * wv;
    }
    __shared__ float red[8][32];
    red[s][c] = acc;
    __syncthreads();
    if (s == 0) {
        float tot = 0.f;
#pragma unroll
        for (int i = 0; i < 8; ++i) tot += red[i][c];
        if (c < 16) {
            bvec[(size_t)t * 16 + c] = 2.f / (1.f + expf(-tot));
        } else {
            int hh = c - 16;
            float a = tot + dtb[hh];
            float sp = (a > 20.f) ? a : log1pf(expf(a));
            gvec[(size_t)t * 16 + hh] = -expf(A_log[hh]) * sp;
        }
    }
}

// ---------------- phase 1 (MFMA): per (chunk, head) WY-transform prep ----------------
__global__ __launch_bounds__(256) void phase1_mfma(
    const float* __restrict__ qpost, const float* __restrict__ kpost,
    const float* __restrict__ vpost, const float* __restrict__ gvec,
    const float* __restrict__ bvec,
    float* __restrict__ u_ws, float* __restrict__ w_ws,
    float* __restrict__ qg_ws, float* __restrict__ kd_ws,
    float* __restrict__ at_ws, float* __restrict__ gl_ws) {
    int n = blockIdx.x, h = blockIdx.y;
    int t0 = n * CHUNKN;
    int tid = threadIdx.x;
    int wave = tid >> 6, lane = tid & 63;
    size_t base = (size_t)(h * NCHUNK + n);

    __shared__ __align__(16) unsigned short QKb[128 * 104];
    __shared__ __align__(16) unsigned short Ab[64 * 104];
    __shared__ __align__(16) unsigned short Atb[64 * 104];
    __shared__ __align__(16) unsigned short Pb[64 * 104];
    __shared__ __align__(16) unsigned short Ptb[64 * 104];
    __shared__ float Pf[64 * 68];
    __shared__ __align__(16) unsigned short RHSw[96 * 72];
    __shared__ __align__(16) unsigned short RHSv[192 * 72];
    __shared__ float gr_s[64], gc_s[64], be_s[64];

    if (tid < 64) {
        gr_s[tid] = gvec[(size_t)(t0 + tid) * HVN + h];
        be_s[tid] = bvec[(size_t)(t0 + tid) * HVN + h];
    }
    __syncthreads();
    if (tid < 64) {
        float sacc = 0.f;
        for (int j = 0; j <= tid; ++j) sacc += gr_s[j];
        gc_s[tid] = sacc;
    }
    __syncthreads();
    float gl = gc_s[63];

    int r = tid >> 2, sub = tid & 3;
    {
        const float* kp = kpost + (size_t)(t0 + r) * KDIMN + h * DKN + sub * 24;
        float kreg[24];
        float ss = 0.f;
#pragma unroll
        for (int i = 0; i < 6; ++i) {
            float4 v = *(const float4*)(kp + i * 4);
            kreg[i * 4 + 0] = v.x; kreg[i * 4 + 1] = v.y; kreg[i * 4 + 2] = v.z; kreg[i * 4 + 3] = v.w;
            ss += v.x * v.x + v.y * v.y + v.z * v.z + v.w * v.w;
        }
        ss += __shfl_xor(ss, 1, 64);
        ss += __shfl_xor(ss, 2, 64);
        float nrm = rsqrtf(ss + EPSF);
        float gcr = gc_s[r];
        float egl = expf(gl - gcr);
        float ebg = be_s[r] * expf(gcr);
        float* kdp = kd_ws + base * (64 * 96) + r * 96 + sub * 24;
#pragma unroll
        for (int i = 0; i < 24; ++i) {
            float kn = kreg[i] * nrm;
            QKb[r * 104 + sub * 24 + i] = f2bf(kn);
            kdp[i] = kn * egl;
            RHSw[(sub * 24 + i) * 72 + r] = f2bf(kn * ebg);
        }
    }
    {
        const float* qp = qpost + (size_t)(t0 + r) * KDIMN + h * DKN + sub * 24;
        float qreg[24];
        float ss = 0.f;
#pragma unroll
        for (int i = 0; i < 6; ++i) {
            float4 v = *(const float4*)(qp + i * 4);
            qreg[i * 4 + 0] = v.x; qreg[i * 4 + 1] = v.y; qreg[i * 4 + 2] = v.z; qreg[i * 4 + 3] = v.w;
            ss += v.x * v.x + v.y * v.y + v.z * v.z + v.w * v.w;
        }
        ss += __shfl_xor(ss, 1, 64);
        ss += __shfl_xor(ss, 2, 64);
        float nrm = rsqrtf(ss + EPSF) * 0.10206207261596577f;
        float eg = expf(gc_s[r]);
        float* qgp = qg_ws + base * (64 * 96) + r * 96 + sub * 24;
#pragma unroll
        for (int i = 0; i < 24; ++i) {
            float qn = qreg[i] * nrm;
            QKb[(64 + r) * 104 + sub * 24 + i] = f2bf(qn);
            qgp[i] = qn * eg;
        }
    }
    {
        const float* vp = vpost + (size_t)(t0 + r) * VDIMN + h * DVN + sub * 48;
        float ber = be_s[r];
#pragma unroll
        for (int i = 0; i < 12; ++i) {
            float4 v = *(const float4*)(vp + i * 4);
            int d = sub * 48 + i * 4;
            RHSv[(d + 0) * 72 + r] = f2bf(v.x * ber);
            RHSv[(d + 1) * 72 + r] = f2bf(v.y * ber);
            RHSv[(d + 2) * 72 + r] = f2bf(v.z * ber);
            RHSv[(d + 3) * 72 + r] = f2bf(v.w * ber);
        }
    }
    __syncthreads();

    {
        f32x4 acc1[2][4] = {};
#pragma unroll
        for (int ks = 0; ks < 3; ++ks) {
            int ko = ks * 32 + (lane >> 4) * 8;
            short8 af[2], bfv[4];
#pragma unroll
            for (int rt2 = 0; rt2 < 2; ++rt2)
                af[rt2] = *(const short8*)&QKb[(wave * 32 + rt2 * 16 + (lane & 15)) * 104 + ko];
#pragma unroll
            for (int ct = 0; ct < 4; ++ct)
                bfv[ct] = *(const short8*)&QKb[(ct * 16 + (lane & 15)) * 104 + ko];
#pragma unroll
            for (int rt2 = 0; rt2 < 2; ++rt2)
#pragma unroll
                for (int ct = 0; ct < 4; ++ct)
                    acc1[rt2][ct] = __builtin_amdgcn_mfma_f32_16x16x32_bf16(af[rt2], bfv[ct], acc1[rt2][ct], 0, 0, 0);
        }
#pragma unroll
        for (int rt2 = 0; rt2 < 2; ++rt2)
#pragma unroll
            for (int ct = 0; ct < 4; ++ct)
#pragma unroll
                for (int j = 0; j < 4; ++j) {
                    int rr = wave * 32 + rt2 * 16 + (lane >> 4) * 4 + j;
                    int cc = ct * 16 + (lane & 15);
                    float val = acc1[rt2][ct][j];
                    if (rr < 64) {
                        float av = (rr > cc) ? -be_s[rr] * expf(gc_s[rr] - gc_s[cc]) * val : 0.f;
                        unsigned short ab = f2bf(av);
                        Ab[rr * 104 + cc] = ab;
                        Atb[cc * 104 + rr] = ab;
                        float pv = (rr == cc) ? 1.f : av;
                        Pf[rr * 68 + cc] = pv;
                        unsigned short pb = f2bf(pv);
                        Pb[rr * 104 + cc] = pb;
                        Ptb[cc * 104 + rr] = pb;
                    } else {
                        int ar = rr - 64;
                        float av = (ar >= cc) ? expf(gc_s[ar] - gc_s[cc]) * val : 0.f;
                        at_ws[base * (64 * 64) + ar * 64 + cc] = av;
                    }
                }
    }
    __syncthreads();

#pragma unroll 1
    for (int lev = 0; lev < 5; ++lev) {
        f32x4 d[4] = {};
#pragma unroll
        for (int ks = 0; ks < 2; ++ks) {
            int ko = ks * 32 + (lane >> 4) * 8;
            short8 a0 = *(const short8*)&Ab[(wave * 16 + (lane & 15)) * 104 + ko];
#pragma unroll
            for (int ct = 0; ct < 4; ++ct) {
                short8 b0 = *(const short8*)&Atb[(ct * 16 + (lane & 15)) * 104 + ko];
                d[ct] = __builtin_amdgcn_mfma_f32_16x16x32_bf16(a0, b0, d[ct], 0, 0, 0);
            }
        }
        __syncthreads();
#pragma unroll
        for (int ct = 0; ct < 4; ++ct)
#pragma unroll
            for (int j = 0; j < 4; ++j) {
                int rr = wave * 16 + (lane >> 4) * 4 + j;
                int cc = ct * 16 + (lane & 15);
                unsigned short hb = f2bf(d[ct][j]);
                Ab[rr * 104 + cc] = hb;
                Atb[cc * 104 + rr] = hb;
            }
        __syncthreads();
        f32x4 e[4];
#pragma unroll
        for (int ct = 0; ct < 4; ++ct)
#pragma unroll
            for (int j = 0; j < 4; ++j)
                e[ct][j] = Pf[(wave * 16 + (lane >> 4) * 4 + j) * 68 + ct * 16 + (lane & 15)];
#pragma unroll
        for (int ks = 0; ks < 2; ++ks) {
            int ko = ks * 32 + (lane >> 4) * 8;
            short8 a0 = *(const short8*)&Ab[(wave * 16 + (lane & 15)) * 104 + ko];
#pragma unroll
            for (int ct = 0; ct < 4; ++ct) {
                short8 b0 = *(const short8*)&Ptb[(ct * 16 + (lane & 15)) * 104 + ko];
                e[ct] = __builtin_amdgcn_mfma_f32_16x16x32_bf16(a0, b0, e[ct], 0, 0, 0);
            }
        }
        __syncthreads();
#pragma unroll
        for (int ct = 0; ct < 4; ++ct)
#pragma unroll
            for (int j = 0; j < 4; ++j) {
                int rr = wave * 16 + (lane >> 4) * 4 + j;
                int cc = ct * 16 + (lane & 15);
                float pv = e[ct][j];
                Pf[rr * 68 + cc] = pv;
                unsigned short pb = f2bf(pv);
                Pb[rr * 104 + cc] = pb;
                Ptb[cc * 104 + rr] = pb;
            }
        __syncthreads();
    }

#pragma unroll 1
    for (int i = 0; i < 18; ++i) {
        int id = wave * 18 + i;
        int rt = id & 3, ct = id >> 2;
        f32x4 o4 = {};
#pragma unroll
        for (int ks = 0; ks < 2; ++ks) {
            int ko = ks * 32 + (lane >> 4) * 8;
            short8 a0 = *(const short8*)&Pb[(rt * 16 + (lane & 15)) * 104 + ko];
            short8 b0 = (ct < 12)
                ? *(const short8*)&RHSv[(ct * 16 + (lane & 15)) * 72 + ko]
                : *(const short8*)&RHSw[((ct - 12) * 16 + (lane & 15)) * 72 + ko];
            o4 = __builtin_amdgcn_mfma_f32_16x16x32_bf16(a0, b0, o4, 0, 0, 0);
        }
#pragma unroll
        for (int j = 0; j < 4; ++j) {
            int rr = rt * 16 + (lane >> 4) * 4 + j;
            int nn = ct * 16 + (lane & 15);
            if (ct < 12) u_ws[base * (64 * 192) + rr * 192 + nn] = o4[j];
            else         w_ws[base * (64 * 96) + rr * 96 + (nn - 192)] = o4[j];
        }
    }
    if (tid == 0) gl_ws[base] = gl;
}

// ---------------- phase 2a: sequential recurrence (register-tiled + prefetch + XCD-swizzle) ----------------
// 1D grid of 192: bid = sl*16 + h  ->  bid%8 == h%8 (all 12 slices of a head on one XCD's L2).
// thread decode: ks = tid&3 (k-split), cg = (tid>>2)&3 (4-col group), rg = tid>>4 (row/d group)
__global__ __launch_bounds__(256) void phase2a(const float* __restrict__ u_ws, const float* __restrict__ w_ws,
                                               const float* __restrict__ kd_ws, const float* __restrict__ gl_ws,
                                               float* __restrict__ vn_ws, float* __restrict__ s_ws) {
    int bid = blockIdx.x;
    int sl = bid >> 4, h = bid & 15;
    int c0 = sl * 16;
    int tid = threadIdx.x;
    int ks = tid & 3, cg = (tid >> 2) & 3, rg = tid >> 4;
    int cc = cg * 4;
    __shared__ float w_s[64 * 100];   // stride 100 (float4-aligned)
    __shared__ float kd_s[64 * 101];  // stride 101 (scalar-staged, conflict-free reads)
    __shared__ float S_s[96 * 20];
    __shared__ float vn_s[64 * 20];

    float4 w6[6], k6[6];
    float4 ucur, unext;
    int myrow = rg * 4 + ks;          // m1 output row / u row
    int d0g = rg * 6;                 // m2 d-rows

    // prologue: prefetch chunk 0
    {
        size_t b0 = (size_t)(h * NCHUNK);
        const float4* wp = (const float4*)(w_ws + b0 * (64 * 96));
        const float4* kp = (const float4*)(kd_ws + b0 * (64 * 96));
#pragma unroll
        for (int j = 0; j < 6; ++j) { w6[j] = wp[j * 256 + tid]; k6[j] = kp[j * 256 + tid]; }
        ucur = *(const float4*)(u_ws + b0 * (64 * 192) + (size_t)myrow * 192 + c0 + cc);
    }
    f32x4 Sreg[6];
#pragma unroll
    for (int dd = 0; dd < 6; ++dd) Sreg[dd] = (f32x4){0.f, 0.f, 0.f, 0.f};
    for (int idx = tid; idx < 96 * 20; idx += 256) S_s[idx] = 0.f;
    __syncthreads();

    for (int n = 0; n < NCHUNK; ++n) {
        size_t base = (size_t)(h * NCHUNK + n);
        float egl = expf(gl_ws[base]);
        float* sp = s_ws + base * (96 * 192);
        float* vnp = vn_ws + base * (64 * 192);

        // store pre-chunk state S_n (old Sreg); ks-lanes hold copies, ks<2 write 3 d-rows each
        if (ks < 2) {
#pragma unroll
            for (int m = 0; m < 3; ++m) {
                int dd = ks * 3 + m;
                *(f32x4*)(sp + (size_t)(d0g + dd) * 192 + c0 + cc) = Sreg[dd];
            }
        }
        // stage regs -> LDS
#pragma unroll
        for (int j = 0; j < 6; ++j) {
            int f = j * 256 + tid;
            int rr = f / 24, c4 = (f % 24) * 4;
            *(float4*)&w_s[rr * 100 + c4] = w6[j];
            kd_s[rr * 101 + c4 + 0] = k6[j].x;
            kd_s[rr * 101 + c4 + 1] = k6[j].y;
            kd_s[rr * 101 + c4 + 2] = k6[j].z;
            kd_s[rr * 101 + c4 + 3] = k6[j].w;
        }
        // issue prefetch for chunk n+1 (latency hidden under m1+m2)
        if (n + 1 < NCHUNK) {
            const float4* wp2 = (const float4*)(w_ws + (base + 1) * (64 * 96));
            const float4* kp2 = (const float4*)(kd_ws + (base + 1) * (64 * 96));
#pragma unroll
            for (int j = 0; j < 6; ++j) { w6[j] = wp2[j * 256 + tid]; k6[j] = kp2[j * 256 + tid]; }
            unext = *(const float4*)(u_ws + (base + 1) * (64 * 192) + (size_t)myrow * 192 + c0 + cc);
        }
        __syncthreads();

        // m1: acc[i][c] = sum_d w[rg*4+i][d] * S[d][cc+c], d over ks-interleaved quarters
        f32x4 acc[4] = {};
#pragma unroll
        for (int s = 0; s < 6; ++s) {
            int d0 = s * 16 + ks * 4;
            float4 sv0 = *(const float4*)&S_s[(d0 + 0) * 20 + cc];
            float4 sv1 = *(const float4*)&S_s[(d0 + 1) * 20 + cc];
            float4 sv2 = *(const float4*)&S_s[(d0 + 2) * 20 + cc];
            float4 sv3 = *(const float4*)&S_s[(d0 + 3) * 20 + cc];
#pragma unroll
            for (int i = 0; i < 4; ++i) {
                float4 wv = *(const float4*)&w_s[(rg * 4 + i) * 100 + d0];
                acc[i][0] += wv.x * sv0.x + wv.y * sv1.x + wv.z * sv2.x + wv.w * sv3.x;
                acc[i][1] += wv.x * sv0.y + wv.y * sv1.y + wv.z * sv2.y + wv.w * sv3.y;
                acc[i][2] += wv.x * sv0.z + wv.y * sv1.z + wv.z * sv2.z + wv.w * sv3.z;
                acc[i][3] += wv.x * sv0.w + wv.y * sv1.w + wv.z * sv2.w + wv.w * sv3.w;
            }
        }
        // reduce-scatter over ks: lane ks ends owning row rg*4+ks
        {
            bool h2 = (ks & 2) != 0, h1 = (ks & 1) != 0;
            f32x4 p0 = h2 ? acc[2] : acc[0];
            f32x4 q0 = h2 ? acc[0] : acc[2];
            f32x4 p1 = h2 ? acc[3] : acc[1];
            f32x4 q1 = h2 ? acc[1] : acc[3];
#pragma unroll
            for (int c = 0; c < 4; ++c) {
                p0[c] += __shfl_xor(q0[c], 2, 64);
                p1[c] += __shfl_xor(q1[c], 2, 64);
            }
            f32x4 rv = h1 ? p1 : p0;
            f32x4 q2 = h1 ? p0 : p1;
#pragma unroll
            for (int c = 0; c < 4; ++c) rv[c] += __shfl_xor(q2[c], 1, 64);
            float4 vn4 = make_float4(ucur.x - rv[0], ucur.y - rv[1], ucur.z - rv[2], ucur.w - rv[3]);
            *(float4*)&vn_s[myrow * 20 + cc] = vn4;
            *(float4*)(vnp + (size_t)myrow * 192 + c0 + cc) = vn4;
        }
        ucur = unext;
        __syncthreads();

        // m2: Snew[d0g..d0g+5][cc..cc+3] = egl*S + sum_r kd[r][d]*vn[r][c], r ks-interleaved
        f32x4 a2[6] = {};
#pragma unroll
        for (int s = 0; s < 16; ++s) {
            int r = s * 4 + ks;
            float4 vv = *(const float4*)&vn_s[r * 20 + cc];
            const float* kdr = &kd_s[r * 101 + d0g];
#pragma unroll
            for (int dd = 0; dd < 6; ++dd) {
                float kv = kdr[dd];
                a2[dd][0] += kv * vv.x; a2[dd][1] += kv * vv.y;
                a2[dd][2] += kv * vv.z; a2[dd][3] += kv * vv.w;
            }
        }
#pragma unroll
        for (int dd = 0; dd < 6; ++dd)
#pragma unroll
            for (int c = 0; c < 4; ++c) {
                float v = a2[dd][c];
                v += __shfl_xor(v, 1, 64);
                v += __shfl_xor(v, 2, 64);
                Sreg[dd][c] = egl * Sreg[dd][c] + v;
            }
        if (ks < 2) {
#pragma unroll
            for (int m = 0; m < 3; ++m) {
                int dd = ks * 3 + m;
                *(f32x4*)&S_s[(d0g + dd) * 20 + cc] = Sreg[dd];
            }
        }
        __syncthreads();
    }
}

// ---------------- phase 2b: parallel o = qg@S_n + at@vn ----------------
__global__ __launch_bounds__(384) void phase2b(const float* __restrict__ qg_ws, const float* __restrict__ at_ws,
                                               const float* __restrict__ s_ws, const float* __restrict__ vn_ws,
                                               float* __restrict__ o_ws) {
    int n = blockIdx.x;
    int h = blockIdx.y >> 1, ch = blockIdx.y & 1;
    int tid = threadIdx.x;
    int rg = tid / 24, cg = tid % 24;
    __shared__ float qg_s[64][100];
    __shared__ float at_s[64][68];
    size_t base = (size_t)(h * NCHUNK + n);
    const float* qgp = qg_ws + base * (64 * 96);
    const float* ap  = at_ws + base * (64 * 64);
    const float* sp  = s_ws + base * (96 * 192) + ch * 96;
    const float* vnp = vn_ws + base * (64 * 192) + ch * 96;
    for (int f = tid; f < 1536; f += 384) {
        int rr = f / 24, cc = (f % 24) * 4;
        *(float4*)&qg_s[rr][cc] = ((const float4*)qgp)[f];
    }
    for (int f = tid; f < 1024; f += 384) {
        int rr = f / 16, cc = (f % 16) * 4;
        *(float4*)&at_s[rr][cc] = ((const float4*)ap)[f];
    }
    __syncthreads();
    float acc00=0,acc01=0,acc02=0,acc03=0, acc10=0,acc11=0,acc12=0,acc13=0;
    float acc20=0,acc21=0,acc22=0,acc23=0, acc30=0,acc31=0,acc32=0,acc33=0;
    int r0 = rg * 4, cc0 = cg * 4;
#pragma unroll 4
    for (int k = 0; k < 96; ++k) {
        float4 b = *(const float4*)(sp + (size_t)k * 192 + cc0);
        float a0 = qg_s[r0][k], a1 = qg_s[r0 + 1][k], a2 = qg_s[r0 + 2][k], a3 = qg_s[r0 + 3][k];
        acc00 += a0 * b.x; acc01 += a0 * b.y; acc02 += a0 * b.z; acc03 += a0 * b.w;
        acc10 += a1 * b.x; acc11 += a1 * b.y; acc12 += a1 * b.z; acc13 += a1 * b.w;
        acc20 += a2 * b.x; acc21 += a2 * b.y; acc22 += a2 * b.z; acc23 += a2 * b.w;
        acc30 += a3 * b.x; acc31 += a3 * b.y; acc32 += a3 * b.z; acc33 += a3 * b.w;
    }
#pragma unroll 4
    for (int j = 0; j < 64; ++j) {
        float4 b = *(const float4*)(vnp + (size_t)j * 192 + cc0);
        float a0 = at_s[r0][j], a1 = at_s[r0 + 1][j], a2 = at_s[r0 + 2][j], a3 = at_s[r0 + 3][j];
        acc00 += a0 * b.x; acc01 += a0 * b.y; acc02 += a0 * b.z; acc03 += a0 * b.w;
        acc10 += a1 * b.x; acc11 += a1 * b.y; acc12 += a1 * b.z; acc13 += a1 * b.w;
        acc20 += a2 * b.x; acc21 += a2 * b.y; acc22 += a2 * b.z; acc23 += a2 * b.w;
        acc30 += a3 * b.x; acc31 += a3 * b.y; acc32 += a3 * b.z; acc33 += a3 * b.w;
    }
    int t0 = n * CHUNKN;
    size_t ob = (size_t)(t0 + r0) * VDIMN + h * DVN + ch * 96 + cc0;
    *(float4*)(o_ws + ob)             = make_float4(acc00, acc01, acc02, acc03);
    *(float4*)(o_ws + ob + VDIMN)     = make_float4(acc10, acc11, acc12, acc13);
    *(float4*)(o_ws + ob + 2 * VDIMN) = make_float4(acc20, acc21, acc22, acc23);
    *(float4*)(o_ws + ob + 3 * VDIMN) = make_float4(acc30, acc31, acc32, acc33);
}

// ---------------- gate (SiLU) + RMSNorm -> bf16 ----------------
__global__ __launch_bounds__(64) void gate_norm(const float* __restrict__ o_ws, const float* __restrict__ Cgate,
                                                const float* __restrict__ nw, unsigned short* __restrict__ obf) {
    int b = blockIdx.x;
    int t = b >> 4, h = b & 15;
    int lane = threadIdx.x;
    float x[3];
    float ss = 0.f;
    size_t ob = (size_t)t * VDIMN + h * DVN;
    for (int j = 0; j < 3; ++j) {
        int d = j * 64 + lane;
        float ov = o_ws[ob + d];
        float gv = Cgate[ob + d];
        float xv = ov * siluf(gv);
        x[j] = xv;
        ss += xv * xv;
    }
    for (int off = 32; off > 0; off >>= 1) ss += __shfl_xor(ss, off, 64);
    float r = rsqrtf(ss * (1.f / 192.f) + EPSF);
    for (int j = 0; j < 3; ++j) {
        int d = j * 64 + lane;
        obf[ob + d] = f2bf(x[j] * r * nw[d]);
    }
}

extern "C" void kernel_launch(void* const* d_in, const int* in_sizes, int n_in,
                              void* d_out, int out_size, void* d_ws, size_t ws_size,
                              hipStream_t stream) {
    (void)in_sizes; (void)n_in; (void)out_size;
    const float* X    = (const float*)d_in[0];
    const float* Wq   = (const float*)d_in[1];
    const float* Wk   = (const float*)d_in[2];
    const float* Wv   = (const float*)d_in[3];
    const float* Wb   = (const float*)d_in[4];
    const float* Wa   = (const float*)d_in[5];
    const float* Wg   = (const float*)d_in[6];
    const float* Wo   = (const float*)d_in[7];
    const float* cq   = (const float*)d_in[8];
    const float* ck   = (const float*)d_in[9];
    const float* cv   = (const float*)d_in[10];
    const float* Alog = (const float*)d_in[11];
    const float* dtb  = (const float*)d_in[12];
    const float* nw   = (const float*)d_in[13];

    const size_t OFF_XBF   = 0;
    const size_t OFF_WALLT = 8388608;
    const size_t OFF_WOT   = 46137344;
    const size_t OFF_CQKV  = 58720256;
    const size_t OFF_CGATE = 109051904;
    const size_t OFF_QPOST = 134217728;
    const size_t OFF_KPOST = 146800640;
    const size_t OFF_VPOST = 159383552;
    const size_t OFF_GVEC  = 184549376;
    const size_t OFF_BVEC  = 184680448;
    const size_t OFF_GL    = 184811520;
    const size_t OFF_U     = 184819712;
    const size_t OFF_W     = 209985536;
    const size_t OFF_QG    = 222568448;
    const size_t OFF_KD    = 235151360;
    const size_t OFF_AT    = OFF_XBF;
    const size_t OFF_S     = OFF_CQKV;
    const size_t OFF_O     = OFF_QPOST;
    const size_t OFF_OBF   = OFF_VPOST;
    const size_t NEEDED    = 247734272;
    if (ws_size < NEEDED) return;

    char* ws = (char*)d_ws;
    unsigned short* Xbf   = (unsigned short*)(ws + OFF_XBF);
    unsigned short* WallT = (unsigned short*)(ws + OFF_WALLT);
    unsigned short* WoT   = (unsigned short*)(ws + OFF_WOT);
    float* Cqkv  = (float*)(ws + OFF_CQKV);
    float* Cgate = (float*)(ws + OFF_CGATE);
    float* qpost = (float*)(ws + OFF_QPOST);
    float* kpost = (float*)(ws + OFF_KPOST);
    float* vpost = (float*)(ws + OFF_VPOST);
    float* gvec  = (float*)(ws + OFF_GVEC);
    float* bvec  = (float*)(ws + OFF_BVEC);
    float* gl_ws = (float*)(ws + OFF_GL);
    float* u_ws  = (float*)(ws + OFF_U);
    float* w_ws  = (float*)(ws + OFF_W);
    float* qg_ws = (float*)(ws + OFF_QG);
    float* kd_ws = (float*)(ws + OFF_KD);
    float* at_ws = (float*)(ws + OFF_AT);
    float* s_ws  = (float*)(ws + OFF_S);
    float* o_ws  = (float*)(ws + OFF_O);
    unsigned short* obf = (unsigned short*)(ws + OFF_OBF);

    cast_f32_bf16<<<4096, 256, 0, stream>>>(X, Xbf, 2048 * 2048);
    dim3 tb(64, 4);
    transpose_cast<<<dim3(1536 / 64, 2048 / 64), tb, 0, stream>>>(Wq, WallT, 2048, 1536);
    transpose_cast<<<dim3(1536 / 64, 2048 / 64), tb, 0, stream>>>(Wk, WallT + (size_t)1536 * 2048, 2048, 1536);
    transpose_cast<<<dim3(3072 / 64, 2048 / 64), tb, 0, stream>>>(Wv, WallT + (size_t)3072 * 2048, 2048, 3072);
    transpose_cast<<<dim3(3072 / 64, 2048 / 64), tb, 0, stream>>>(Wg, WallT + (size_t)6144 * 2048, 2048, 3072);
    transpose_cast<<<dim3(2048 / 64, 3072 / 64), tb, 0, stream>>>(Wo, WoT, 3072, 2048);

    gemm_bt<<<dim3(QKVD / 128, 2048 / 128), 256, 0, stream>>>(Xbf, WallT, Cqkv, 2048, QKVD, 2048);
    gemm_bt<<<dim3(VDIMN / 128, 2048 / 128), 256, 0, stream>>>(Xbf, WallT + (size_t)QKVD * 2048, Cgate, 2048, VDIMN, 2048);

    conv_silu<<<dim3(6, T_LEN), 256, 0, stream>>>(Cqkv + 0, QKVD, cq, qpost, KDIMN);
    conv_silu<<<dim3(6, T_LEN), 256, 0, stream>>>(Cqkv + 1536, QKVD, ck, kpost, KDIMN);
    conv_silu<<<dim3(12, T_LEN), 256, 0, stream>>>(Cqkv + 3072, QKVD, cv, vpost, VDIMN);
    beta_g<<<T_LEN, 256, 0, stream>>>(X, Wb, Wa, Alog, dtb, bvec, gvec);

    phase1_mfma<<<dim3(NCHUNK, HVN), 256, 0, stream>>>(qpost, kpost, vpost, gvec, bvec,
                                                       u_ws, w_ws, qg_ws, kd_ws, at_ws, gl_ws);
    phase2a<<<192, 256, 0, stream>>>(u_ws, w_ws, kd_ws, gl_ws, u_ws, s_ws);
    phase2b<<<dim3(NCHUNK, HVN * 2), 384, 0, stream>>>(qg_ws, at_ws, s_ws, u_ws, o_ws);

    gate_norm<<<T_LEN * HVN, 64, 0, stream>>>(o_ws, Cgate, nw, obf);

    gemm_bt<<<dim3(2048 / 128, 2048 / 128), 256, 0, stream>>>(obf, WoT, (float*)d_out, 2048, 2048, 3072);
}

// Round 5
// 736.142 us; speedup vs baseline: 1.0917x; 1.0917x over previous
//
#include <hip/hip_runtime.h>
#include <math.h>

#define T_LEN 2048
#define HIDN  2048
#define HKN   16
#define DKN   96
#define HVN   16
#define DVN   192
#define KDIMN 1536
#define VDIMN 3072
#define QKVD  6144   // q(1536)+k(1536)+v(3072)
#define CHUNKN 64
#define NCHUNK 32
#define EPSF 1e-6f

typedef __attribute__((ext_vector_type(8))) short short8;
typedef __attribute__((ext_vector_type(4))) float f32x4;

__device__ __forceinline__ unsigned short f2bf(float f) {
    unsigned int u = __float_as_uint(f);
    unsigned int r = (u + 0x7FFFu + ((u >> 16) & 1u)) >> 16;
    return (unsigned short)r;
}
__device__ __forceinline__ float siluf(float x) { return x / (1.f + expf(-x)); }

__device__ __forceinline__ void gld_lds16(const void* g, void* l) {
    __builtin_amdgcn_global_load_lds((const __attribute__((address_space(1))) unsigned int*)g,
                                     (__attribute__((address_space(3))) unsigned int*)l, 16, 0, 0);
}

// ---------------- cast f32 -> bf16 (4/thread) ----------------
__global__ void cast_f32_bf16(const float* __restrict__ in, unsigned short* __restrict__ out, int n) {
    int i = (blockIdx.x * blockDim.x + threadIdx.x) * 4;
    if (i >= n) return;
    float4 v = *(const float4*)(in + i);
    ushort4 o;
    o.x = f2bf(v.x); o.y = f2bf(v.y); o.z = f2bf(v.z); o.w = f2bf(v.w);
    *(ushort4*)(out + i) = o;
}

// ---------------- transpose + cast: W[K][N] -> Wt[N][K] bf16 ----------------
__global__ void transpose_cast(const float* __restrict__ W, unsigned short* __restrict__ Wt,
                               int K, int N) {
    __shared__ float tile[64][65];
    int k0 = blockIdx.y * 64, n0 = blockIdx.x * 64;
    int tx = threadIdx.x, ty = threadIdx.y; // (64,4)
    for (int r = ty; r < 64; r += 4) tile[r][tx] = W[(size_t)(k0 + r) * N + n0 + tx];
    __syncthreads();
    for (int r = ty; r < 64; r += 4) Wt[(size_t)(n0 + r) * K + k0 + tx] = f2bf(tile[tx][r]);
}

// ---------------- bf16 MFMA GEMM: C[M][N] f32 = A[M][K] @ Bt[N][K]^T ----------------
__global__ __launch_bounds__(256) void gemm_bt(const unsigned short* __restrict__ A,
                                               const unsigned short* __restrict__ Bt,
                                               float* __restrict__ C, int M, int N, int K) {
    __shared__ __align__(16) unsigned short As[128 * 32];
    __shared__ __align__(16) unsigned short Bs[128 * 32];
    int tid = threadIdx.x;
    int wave = tid >> 6, lane = tid & 63;
    int bm = blockIdx.y, bn = blockIdx.x;
    f32x4 acc[4][4] = {};
    int wr = wave >> 1, wc = wave & 1;
    int rstage = wave * 32 + (lane >> 2);
    int cstage = (lane & 3) * 8;
    const size_t a_row0 = (size_t)bm * 128;
    const size_t b_row0 = (size_t)bn * 128;
    int row_a[4], row_b[4];
#pragma unroll
    for (int i = 0; i < 4; ++i) {
        row_a[i] = wr * 64 + i * 16 + (lane & 15);
        row_b[i] = wc * 64 + i * 16 + (lane & 15);
    }
    int koff = (lane >> 4) * 8;
    unsigned short* as_base = As + wave * 1024;
    unsigned short* bs_base = Bs + wave * 1024;
    for (int k0 = 0; k0 < K; k0 += 32) {
        const unsigned short* ga = A + (a_row0 + rstage) * (size_t)K + k0 + cstage;
        const unsigned short* gb = Bt + (b_row0 + rstage) * (size_t)K + k0 + cstage;
        gld_lds16(ga, as_base);
        gld_lds16(ga + (size_t)16 * K, as_base + 512);
        gld_lds16(gb, bs_base);
        gld_lds16(gb + (size_t)16 * K, bs_base + 512);
        __syncthreads();
        short8 af[4], bfr[4];
#pragma unroll
        for (int mi = 0; mi < 4; ++mi) af[mi] = *(const short8*)(As + row_a[mi] * 32 + koff);
#pragma unroll
        for (int ni = 0; ni < 4; ++ni) bfr[ni] = *(const short8*)(Bs + row_b[ni] * 32 + koff);
#pragma unroll
        for (int mi = 0; mi < 4; ++mi)
#pragma unroll
            for (int ni = 0; ni < 4; ++ni)
                acc[mi][ni] = __builtin_amdgcn_mfma_f32_16x16x32_bf16(af[mi], bfr[ni], acc[mi][ni], 0, 0, 0);
        __syncthreads();
    }
#pragma unroll
    for (int mi = 0; mi < 4; ++mi) {
        int rbase = bm * 128 + wr * 64 + mi * 16 + (lane >> 4) * 4;
#pragma unroll
        for (int ni = 0; ni < 4; ++ni) {
            int col = bn * 128 + wc * 64 + ni * 16 + (lane & 15);
#pragma unroll
            for (int j = 0; j < 4; ++j)
                C[(size_t)(rbase + j) * N + col] = acc[mi][ni][j];
        }
    }
}

// ---------------- causal depthwise conv(K=4) + SiLU ----------------
__global__ void conv_silu(const float* __restrict__ pre, int ldp,
                          const float* __restrict__ wconv, float* __restrict__ out, int C) {
    int c = blockIdx.x * blockDim.x + threadIdx.x;
    int t = blockIdx.y;
    if (c >= C) return;
    const float* wc4 = wconv + (size_t)c * 4;
    float acc = 0.f;
    if (t >= 3) acc += pre[(size_t)(t - 3) * ldp + c] * wc4[0];
    if (t >= 2) acc += pre[(size_t)(t - 2) * ldp + c] * wc4[1];
    if (t >= 1) acc += pre[(size_t)(t - 1) * ldp + c] * wc4[2];
    acc += pre[(size_t)t * ldp + c] * wc4[3];
    out[(size_t)t * C + c] = siluf(acc);
}

// ---------------- beta / g projections (f32, exact) ----------------
__global__ __launch_bounds__(256) void beta_g(const float* __restrict__ X,
                                              const float* __restrict__ Wb, const float* __restrict__ Wa,
                                              const float* __restrict__ A_log, const float* __restrict__ dtb,
                                              float* __restrict__ bvec, float* __restrict__ gvec) {
    int t = blockIdx.x;
    int tid = threadIdx.x;
    int s = tid >> 5, c = tid & 31;
    float acc = 0.f;
    const float* xr = X + (size_t)t * HIDN;
    for (int k = s; k < HIDN; k += 8) {
        float xv = xr[k];
        float wv = (c < 16) ? Wb[(size_t)k * 16 + c] : Wa[(size_t)k * 16 + (c - 16)];
        acc += xv * wv;
    }
    __shared__ float red[8][32];
    red[s][c] = acc;
    __syncthreads();
    if (s == 0) {
        float tot = 0.f;
#pragma unroll
        for (int i = 0; i < 8; ++i) tot += red[i][c];
        if (c < 16) {
            bvec[(size_t)t * 16 + c] = 2.f / (1.f + expf(-tot));
        } else {
            int hh = c - 16;
            float a = tot + dtb[hh];
            float sp = (a > 20.f) ? a : log1pf(expf(a));
            gvec[(size_t)t * 16 + hh] = -expf(A_log[hh]) * sp;
        }
    }
}

// ---------------- phase 1 (MFMA): per (chunk, head) WY-transform prep ----------------
__global__ __launch_bounds__(256) void phase1_mfma(
    const float* __restrict__ qpost, const float* __restrict__ kpost,
    const float* __restrict__ vpost, const float* __restrict__ gvec,
    const float* __restrict__ bvec,
    float* __restrict__ u_ws, float* __restrict__ w_ws,
    float* __restrict__ qg_ws, float* __restrict__ kd_ws,
    float* __restrict__ at_ws, float* __restrict__ gl_ws) {
    int n = blockIdx.x, h = blockIdx.y;
    int t0 = n * CHUNKN;
    int tid = threadIdx.x;
    int wave = tid >> 6, lane = tid & 63;
    size_t base = (size_t)(h * NCHUNK + n);

    __shared__ __align__(16) unsigned short QKb[128 * 104];
    __shared__ __align__(16) unsigned short Ab[64 * 104];
    __shared__ __align__(16) unsigned short Atb[64 * 104];
    __shared__ __align__(16) unsigned short Pb[64 * 104];
    __shared__ __align__(16) unsigned short Ptb[64 * 104];
    __shared__ float Pf[64 * 68];
    __shared__ __align__(16) unsigned short RHSw[96 * 72];
    __shared__ __align__(16) unsigned short RHSv[192 * 72];
    __shared__ float gr_s[64], gc_s[64], be_s[64];

    if (tid < 64) {
        gr_s[tid] = gvec[(size_t)(t0 + tid) * HVN + h];
        be_s[tid] = bvec[(size_t)(t0 + tid) * HVN + h];
    }
    __syncthreads();
    if (tid < 64) {
        float sacc = 0.f;
        for (int j = 0; j <= tid; ++j) sacc += gr_s[j];
        gc_s[tid] = sacc;
    }
    __syncthreads();
    float gl = gc_s[63];

    int r = tid >> 2, sub = tid & 3;
    {
        const float* kp = kpost + (size_t)(t0 + r) * KDIMN + h * DKN + sub * 24;
        float kreg[24];
        float ss = 0.f;
#pragma unroll
        for (int i = 0; i < 6; ++i) {
            float4 v = *(const float4*)(kp + i * 4);
            kreg[i * 4 + 0] = v.x; kreg[i * 4 + 1] = v.y; kreg[i * 4 + 2] = v.z; kreg[i * 4 + 3] = v.w;
            ss += v.x * v.x + v.y * v.y + v.z * v.z + v.w * v.w;
        }
        ss += __shfl_xor(ss, 1, 64);
        ss += __shfl_xor(ss, 2, 64);
        float nrm = rsqrtf(ss + EPSF);
        float gcr = gc_s[r];
        float egl = expf(gl - gcr);
        float ebg = be_s[r] * expf(gcr);
        float* kdp = kd_ws + base * (64 * 96) + r * 96 + sub * 24;
#pragma unroll
        for (int i = 0; i < 24; ++i) {
            float kn = kreg[i] * nrm;
            QKb[r * 104 + sub * 24 + i] = f2bf(kn);
            kdp[i] = kn * egl;
            RHSw[(sub * 24 + i) * 72 + r] = f2bf(kn * ebg);
        }
    }
    {
        const float* qp = qpost + (size_t)(t0 + r) * KDIMN + h * DKN + sub * 24;
        float qreg[24];
        float ss = 0.f;
#pragma unroll
        for (int i = 0; i < 6; ++i) {
            float4 v = *(const float4*)(qp + i * 4);
            qreg[i * 4 + 0] = v.x; qreg[i * 4 + 1] = v.y; qreg[i * 4 + 2] = v.z; qreg[i * 4 + 3] = v.w;
            ss += v.x * v.x + v.y * v.y + v.z * v.z + v.w * v.w;
        }
        ss += __shfl_xor(ss, 1, 64);
        ss += __shfl_xor(ss, 2, 64);
        float nrm = rsqrtf(ss + EPSF) * 0.10206207261596577f;
        float eg = expf(gc_s[r]);
        float* qgp = qg_ws + base * (64 * 96) + r * 96 + sub * 24;
#pragma unroll
        for (int i = 0; i < 24; ++i) {
            float qn = qreg[i] * nrm;
            QKb[(64 + r) * 104 + sub * 24 + i] = f2bf(qn);
            qgp[i] = qn * eg;
        }
    }
    {
        const float* vp = vpost + (size_t)(t0 + r) * VDIMN + h * DVN + sub * 48;
        float ber = be_s[r];
#pragma unroll
        for (int i = 0; i < 12; ++i) {
            float4 v = *(const float4*)(vp + i * 4);
            int d = sub * 48 + i * 4;
            RHSv[(d + 0) * 72 + r] = f2bf(v.x * ber);
            RHSv[(d + 1) * 72 + r] = f2bf(v.y * ber);
            RHSv[(d + 2) * 72 + r] = f2bf(v.z * ber);
            RHSv[(d + 3) * 72 + r] = f2bf(v.w * ber);
        }
    }
    __syncthreads();

    {
        f32x4 acc1[2][4] = {};
#pragma unroll
        for (int ks = 0; ks < 3; ++ks) {
            int ko = ks * 32 + (lane >> 4) * 8;
            short8 af[2], bfv[4];
#pragma unroll
            for (int rt2 = 0; rt2 < 2; ++rt2)
                af[rt2] = *(const short8*)&QKb[(wave * 32 + rt2 * 16 + (lane & 15)) * 104 + ko];
#pragma unroll
            for (int ct = 0; ct < 4; ++ct)
                bfv[ct] = *(const short8*)&QKb[(ct * 16 + (lane & 15)) * 104 + ko];
#pragma unroll
            for (int rt2 = 0; rt2 < 2; ++rt2)
#pragma unroll
                for (int ct = 0; ct < 4; ++ct)
                    acc1[rt2][ct] = __builtin_amdgcn_mfma_f32_16x16x32_bf16(af[rt2], bfv[ct], acc1[rt2][ct], 0, 0, 0);
        }
#pragma unroll
        for (int rt2 = 0; rt2 < 2; ++rt2)
#pragma unroll
            for (int ct = 0; ct < 4; ++ct)
#pragma unroll
                for (int j = 0; j < 4; ++j) {
                    int rr = wave * 32 + rt2 * 16 + (lane >> 4) * 4 + j;
                    int cc = ct * 16 + (lane & 15);
                    float val = acc1[rt2][ct][j];
                    if (rr < 64) {
                        float av = (rr > cc) ? -be_s[rr] * expf(gc_s[rr] - gc_s[cc]) * val : 0.f;
                        unsigned short ab = f2bf(av);
                        Ab[rr * 104 + cc] = ab;
                        Atb[cc * 104 + rr] = ab;
                        float pv = (rr == cc) ? 1.f : av;
                        Pf[rr * 68 + cc] = pv;
                        unsigned short pb = f2bf(pv);
                        Pb[rr * 104 + cc] = pb;
                        Ptb[cc * 104 + rr] = pb;
                    } else {
                        int ar = rr - 64;
                        float av = (ar >= cc) ? expf(gc_s[ar] - gc_s[cc]) * val : 0.f;
                        at_ws[base * (64 * 64) + ar * 64 + cc] = av;
                    }
                }
    }
    __syncthreads();

#pragma unroll 1
    for (int lev = 0; lev < 5; ++lev) {
        f32x4 d[4] = {};
#pragma unroll
        for (int ks = 0; ks < 2; ++ks) {
            int ko = ks * 32 + (lane >> 4) * 8;
            short8 a0 = *(const short8*)&Ab[(wave * 16 + (lane & 15)) * 104 + ko];
#pragma unroll
            for (int ct = 0; ct < 4; ++ct) {
                short8 b0 = *(const short8*)&Atb[(ct * 16 + (lane & 15)) * 104 + ko];
                d[ct] = __builtin_amdgcn_mfma_f32_16x16x32_bf16(a0, b0, d[ct], 0, 0, 0);
            }
        }
        __syncthreads();
#pragma unroll
        for (int ct = 0; ct < 4; ++ct)
#pragma unroll
            for (int j = 0; j < 4; ++j) {
                int rr = wave * 16 + (lane >> 4) * 4 + j;
                int cc = ct * 16 + (lane & 15);
                unsigned short hb = f2bf(d[ct][j]);
                Ab[rr * 104 + cc] = hb;
                Atb[cc * 104 + rr] = hb;
            }
        __syncthreads();
        f32x4 e[4];
#pragma unroll
        for (int ct = 0; ct < 4; ++ct)
#pragma unroll
            for (int j = 0; j < 4; ++j)
                e[ct][j] = Pf[(wave * 16 + (lane >> 4) * 4 + j) * 68 + ct * 16 + (lane & 15)];
#pragma unroll
        for (int ks = 0; ks < 2; ++ks) {
            int ko = ks * 32 + (lane >> 4) * 8;
            short8 a0 = *(const short8*)&Ab[(wave * 16 + (lane & 15)) * 104 + ko];
#pragma unroll
            for (int ct = 0; ct < 4; ++ct) {
                short8 b0 = *(const short8*)&Ptb[(ct * 16 + (lane & 15)) * 104 + ko];
                e[ct] = __builtin_amdgcn_mfma_f32_16x16x32_bf16(a0, b0, e[ct], 0, 0, 0);
            }
        }
        __syncthreads();
#pragma unroll
        for (int ct = 0; ct < 4; ++ct)
#pragma unroll
            for (int j = 0; j < 4; ++j) {
                int rr = wave * 16 + (lane >> 4) * 4 + j;
                int cc = ct * 16 + (lane & 15);
                float pv = e[ct][j];
                Pf[rr * 68 + cc] = pv;
                unsigned short pb = f2bf(pv);
                Pb[rr * 104 + cc] = pb;
                Ptb[cc * 104 + rr] = pb;
            }
        __syncthreads();
    }

#pragma unroll 1
    for (int i = 0; i < 18; ++i) {
        int id = wave * 18 + i;
        int rt = id & 3, ct = id >> 2;
        f32x4 o4 = {};
#pragma unroll
        for (int ks = 0; ks < 2; ++ks) {
            int ko = ks * 32 + (lane >> 4) * 8;
            short8 a0 = *(const short8*)&Pb[(rt * 16 + (lane & 15)) * 104 + ko];
            short8 b0 = (ct < 12)
                ? *(const short8*)&RHSv[(ct * 16 + (lane & 15)) * 72 + ko]
                : *(const short8*)&RHSw[((ct - 12) * 16 + (lane & 15)) * 72 + ko];
            o4 = __builtin_amdgcn_mfma_f32_16x16x32_bf16(a0, b0, o4, 0, 0, 0);
        }
#pragma unroll
        for (int j = 0; j < 4; ++j) {
            int rr = rt * 16 + (lane >> 4) * 4 + j;
            int nn = ct * 16 + (lane & 15);
            if (ct < 12) u_ws[base * (64 * 192) + rr * 192 + nn] = o4[j];
            else         w_ws[base * (64 * 96) + rr * 96 + (nn - 192)] = o4[j];
        }
    }
    if (tid == 0) gl_ws[base] = gl;
}

// ---------------- phase 2a: sequential recurrence (round-3 compute + 1D XCD grid + reg prefetch) ----------------
// 1D grid of 192: bid = sl*16 + h -> bid%8 == h%8 (all 12 slice-blocks of a head on one XCD's L2).
__global__ __launch_bounds__(256) void phase2a(const float* __restrict__ u_ws, const float* __restrict__ w_ws,
                                               const float* __restrict__ kd_ws, const float* __restrict__ gl_ws,
                                               float* __restrict__ vn_ws, float* __restrict__ s_ws) {
    int bid = blockIdx.x;
    int sl = bid >> 4, h = bid & 15;
    int c0 = sl * 16;
    int tid = threadIdx.x;
    __shared__ float w_s[64][100];
    __shared__ float kd_s[64][100];
    __shared__ float S_s[96][20];
    __shared__ float vn_s[64][20];
    int r1 = tid >> 2, dg = tid & 3;
    int d2 = tid % 96, cq = tid / 96;
    bool act2 = tid < 192;
    float Sreg[8];
#pragma unroll
    for (int j = 0; j < 8; ++j) Sreg[j] = 0.f;
    for (int idx = tid; idx < 96 * 20; idx += 256) (&S_s[0][0])[idx] = 0.f;

    // prologue: prefetch chunk 0 into registers
    float4 wst[6], kst[6], u4;
    {
        size_t b0 = (size_t)(h * NCHUNK);
        const float4* wp = (const float4*)(w_ws + b0 * (64 * 96));
        const float4* kp = (const float4*)(kd_ws + b0 * (64 * 96));
#pragma unroll
        for (int j = 0; j < 6; ++j) { wst[j] = wp[j * 256 + tid]; kst[j] = kp[j * 256 + tid]; }
        u4 = *(const float4*)(u_ws + b0 * (64 * 192) + (size_t)r1 * 192 + c0 + dg * 4);
    }
    __syncthreads();

    for (int n = 0; n < NCHUNK; ++n) {
        size_t base = (size_t)(h * NCHUNK + n);
        float* vnp = vn_ws + base * (64 * 192);
        float* sp = s_ws + base * (96 * 192);
        float egl = expf(gl_ws[base]);
        float4 ucur = u4;
        // store pre-chunk state S_n
        if (act2) {
            *(float4*)(sp + (size_t)d2 * 192 + c0 + cq * 8)     = *(float4*)&Sreg[0];
            *(float4*)(sp + (size_t)d2 * 192 + c0 + cq * 8 + 4) = *(float4*)&Sreg[4];
        }
        // stage regs -> LDS (chunk n)
#pragma unroll
        for (int j = 0; j < 6; ++j) {
            int f = j * 256 + tid;
            int rr = f / 24, cc4 = (f % 24) * 4;
            *(float4*)&w_s[rr][cc4] = wst[j];
            *(float4*)&kd_s[rr][cc4] = kst[j];
        }
        // issue prefetch for chunk n+1 (latency hides under m1+m2)
        if (n + 1 < NCHUNK) {
            const float4* wp2 = (const float4*)(w_ws + (base + 1) * (64 * 96));
            const float4* kp2 = (const float4*)(kd_ws + (base + 1) * (64 * 96));
#pragma unroll
            for (int j = 0; j < 6; ++j) { wst[j] = wp2[j * 256 + tid]; kst[j] = kp2[j * 256 + tid]; }
            u4 = *(const float4*)(u_ws + (base + 1) * (64 * 192) + (size_t)r1 * 192 + c0 + dg * 4);
        }
        __syncthreads();
        // m1: partial sums over d = 4i+dg
        float acc[16];
#pragma unroll
        for (int c = 0; c < 16; ++c) acc[c] = 0.f;
        for (int i = 0; i < 24; ++i) {
            int d = i * 4 + dg;
            float wv = w_s[r1][d];
            float4 s0 = *(const float4*)&S_s[d][0];
            float4 s1 = *(const float4*)&S_s[d][4];
            float4 s2 = *(const float4*)&S_s[d][8];
            float4 s3 = *(const float4*)&S_s[d][12];
            acc[0] += wv * s0.x; acc[1] += wv * s0.y; acc[2] += wv * s0.z; acc[3] += wv * s0.w;
            acc[4] += wv * s1.x; acc[5] += wv * s1.y; acc[6] += wv * s1.z; acc[7] += wv * s1.w;
            acc[8] += wv * s2.x; acc[9] += wv * s2.y; acc[10] += wv * s2.z; acc[11] += wv * s2.w;
            acc[12] += wv * s3.x; acc[13] += wv * s3.y; acc[14] += wv * s3.z; acc[15] += wv * s3.w;
        }
        // reduce-scatter over dg: lane dg ends with cols dg*4..dg*4+3
        bool hi2 = (dg & 2) != 0, hi1 = (dg & 1) != 0;
        float half8[8], fin[4];
#pragma unroll
        for (int j = 0; j < 8; ++j) {
            float mine = hi2 ? acc[8 + j] : acc[j];
            float yours = hi2 ? acc[j] : acc[8 + j];
            half8[j] = mine + __shfl_xor(yours, 2, 64);
        }
#pragma unroll
        for (int j = 0; j < 4; ++j) {
            float mine = hi1 ? half8[4 + j] : half8[j];
            float yours = hi1 ? half8[j] : half8[4 + j];
            fin[j] = mine + __shfl_xor(yours, 1, 64);
        }
        float4 vn4;
        vn4.x = ucur.x - fin[0]; vn4.y = ucur.y - fin[1]; vn4.z = ucur.z - fin[2]; vn4.w = ucur.w - fin[3];
        *(float4*)&vn_s[r1][dg * 4] = vn4;
        *(float4*)(vnp + (size_t)r1 * 192 + c0 + dg * 4) = vn4;
        __syncthreads();
        // m2: Snew = egl*S + kd^T @ vnew
        if (act2) {
            float a2[8];
#pragma unroll
            for (int j = 0; j < 8; ++j) a2[j] = 0.f;
            for (int rr = 0; rr < 64; ++rr) {
                float kv = kd_s[rr][d2];
                float4 v0 = *(const float4*)&vn_s[rr][cq * 8];
                float4 v1 = *(const float4*)&vn_s[rr][cq * 8 + 4];
                a2[0] += kv * v0.x; a2[1] += kv * v0.y; a2[2] += kv * v0.z; a2[3] += kv * v0.w;
                a2[4] += kv * v1.x; a2[5] += kv * v1.y; a2[6] += kv * v1.z; a2[7] += kv * v1.w;
            }
#pragma unroll
            for (int j = 0; j < 8; ++j) Sreg[j] = egl * Sreg[j] + a2[j];
            *(float4*)&S_s[d2][cq * 8] = *(float4*)&Sreg[0];
            *(float4*)&S_s[d2][cq * 8 + 4] = *(float4*)&Sreg[4];
        }
        __syncthreads();
    }
}

// ---------------- phase 2b: parallel o = qg@S_n + at@vn ----------------
__global__ __launch_bounds__(384) void phase2b(const float* __restrict__ qg_ws, const float* __restrict__ at_ws,
                                               const float* __restrict__ s_ws, const float* __restrict__ vn_ws,
                                               float* __restrict__ o_ws) {
    int n = blockIdx.x;
    int h = blockIdx.y >> 1, ch = blockIdx.y & 1;
    int tid = threadIdx.x;
    int rg = tid / 24, cg = tid % 24;
    __shared__ float qg_s[64][100];
    __shared__ float at_s[64][68];
    size_t base = (size_t)(h * NCHUNK + n);
    const float* qgp = qg_ws + base * (64 * 96);
    const float* ap  = at_ws + base * (64 * 64);
    const float* sp  = s_ws + base * (96 * 192) + ch * 96;
    const float* vnp = vn_ws + base * (64 * 192) + ch * 96;
    for (int f = tid; f < 1536; f += 384) {
        int rr = f / 24, cc = (f % 24) * 4;
        *(float4*)&qg_s[rr][cc] = ((const float4*)qgp)[f];
    }
    for (int f = tid; f < 1024; f += 384) {
        int rr = f / 16, cc = (f % 16) * 4;
        *(float4*)&at_s[rr][cc] = ((const float4*)ap)[f];
    }
    __syncthreads();
    float acc00=0,acc01=0,acc02=0,acc03=0, acc10=0,acc11=0,acc12=0,acc13=0;
    float acc20=0,acc21=0,acc22=0,acc23=0, acc30=0,acc31=0,acc32=0,acc33=0;
    int r0 = rg * 4, cc0 = cg * 4;
#pragma unroll 4
    for (int k = 0; k < 96; ++k) {
        float4 b = *(const float4*)(sp + (size_t)k * 192 + cc0);
        float a0 = qg_s[r0][k], a1 = qg_s[r0 + 1][k], a2 = qg_s[r0 + 2][k], a3 = qg_s[r0 + 3][k];
        acc00 += a0 * b.x; acc01 += a0 * b.y; acc02 += a0 * b.z; acc03 += a0 * b.w;
        acc10 += a1 * b.x; acc11 += a1 * b.y; acc12 += a1 * b.z; acc13 += a1 * b.w;
        acc20 += a2 * b.x; acc21 += a2 * b.y; acc22 += a2 * b.z; acc23 += a2 * b.w;
        acc30 += a3 * b.x; acc31 += a3 * b.y; acc32 += a3 * b.z; acc33 += a3 * b.w;
    }
#pragma unroll 4
    for (int j = 0; j < 64; ++j) {
        float4 b = *(const float4*)(vnp + (size_t)j * 192 + cc0);
        float a0 = at_s[r0][j], a1 = at_s[r0 + 1][j], a2 = at_s[r0 + 2][j], a3 = at_s[r0 + 3][j];
        acc00 += a0 * b.x; acc01 += a0 * b.y; acc02 += a0 * b.z; acc03 += a0 * b.w;
        acc10 += a1 * b.x; acc11 += a1 * b.y; acc12 += a1 * b.z; acc13 += a1 * b.w;
        acc20 += a2 * b.x; acc21 += a2 * b.y; acc22 += a2 * b.z; acc23 += a2 * b.w;
        acc30 += a3 * b.x; acc31 += a3 * b.y; acc32 += a3 * b.z; acc33 += a3 * b.w;
    }
    int t0 = n * CHUNKN;
    size_t ob = (size_t)(t0 + r0) * VDIMN + h * DVN + ch * 96 + cc0;
    *(float4*)(o_ws + ob)             = make_float4(acc00, acc01, acc02, acc03);
    *(float4*)(o_ws + ob + VDIMN)     = make_float4(acc10, acc11, acc12, acc13);
    *(float4*)(o_ws + ob + 2 * VDIMN) = make_float4(acc20, acc21, acc22, acc23);
    *(float4*)(o_ws + ob + 3 * VDIMN) = make_float4(acc30, acc31, acc32, acc33);
}

// ---------------- gate (SiLU) + RMSNorm -> bf16 ----------------
__global__ __launch_bounds__(64) void gate_norm(const float* __restrict__ o_ws, const float* __restrict__ Cgate,
                                                const float* __restrict__ nw, unsigned short* __restrict__ obf) {
    int b = blockIdx.x;
    int t = b >> 4, h = b & 15;
    int lane = threadIdx.x;
    float x[3];
    float ss = 0.f;
    size_t ob = (size_t)t * VDIMN + h * DVN;
    for (int j = 0; j < 3; ++j) {
        int d = j * 64 + lane;
        float ov = o_ws[ob + d];
        float gv = Cgate[ob + d];
        float xv = ov * siluf(gv);
        x[j] = xv;
        ss += xv * xv;
    }
    for (int off = 32; off > 0; off >>= 1) ss += __shfl_xor(ss, off, 64);
    float r = rsqrtf(ss * (1.f / 192.f) + EPSF);
    for (int j = 0; j < 3; ++j) {
        int d = j * 64 + lane;
        obf[ob + d] = f2bf(x[j] * r * nw[d]);
    }
}

extern "C" void kernel_launch(void* const* d_in, const int* in_sizes, int n_in,
                              void* d_out, int out_size, void* d_ws, size_t ws_size,
                              hipStream_t stream) {
    (void)in_sizes; (void)n_in; (void)out_size;
    const float* X    = (const float*)d_in[0];
    const float* Wq   = (const float*)d_in[1];
    const float* Wk   = (const float*)d_in[2];
    const float* Wv   = (const float*)d_in[3];
    const float* Wb   = (const float*)d_in[4];
    const float* Wa   = (const float*)d_in[5];
    const float* Wg   = (const float*)d_in[6];
    const float* Wo   = (const float*)d_in[7];
    const float* cq   = (const float*)d_in[8];
    const float* ck   = (const float*)d_in[9];
    const float* cv   = (const float*)d_in[10];
    const float* Alog = (const float*)d_in[11];
    const float* dtb  = (const float*)d_in[12];
    const float* nw   = (const float*)d_in[13];

    const size_t OFF_XBF   = 0;
    const size_t OFF_WALLT = 8388608;
    const size_t OFF_WOT   = 46137344;
    const size_t OFF_CQKV  = 58720256;
    const size_t OFF_CGATE = 109051904;
    const size_t OFF_QPOST = 134217728;
    const size_t OFF_KPOST = 146800640;
    const size_t OFF_VPOST = 159383552;
    const size_t OFF_GVEC  = 184549376;
    const size_t OFF_BVEC  = 184680448;
    const size_t OFF_GL    = 184811520;
    const size_t OFF_U     = 184819712;
    const size_t OFF_W     = 209985536;
    const size_t OFF_QG    = 222568448;
    const size_t OFF_KD    = 235151360;
    const size_t OFF_AT    = OFF_XBF;
    const size_t OFF_S     = OFF_CQKV;
    const size_t OFF_O     = OFF_QPOST;
    const size_t OFF_OBF   = OFF_VPOST;
    const size_t NEEDED    = 247734272;
    if (ws_size < NEEDED) return;

    char* ws = (char*)d_ws;
    unsigned short* Xbf   = (unsigned short*)(ws + OFF_XBF);
    unsigned short* WallT = (unsigned short*)(ws + OFF_WALLT);
    unsigned short* WoT   = (unsigned short*)(ws + OFF_WOT);
    float* Cqkv  = (float*)(ws + OFF_CQKV);
    float* Cgate = (float*)(ws + OFF_CGATE);
    float* qpost = (float*)(ws + OFF_QPOST);
    float* kpost = (float*)(ws + OFF_KPOST);
    float* vpost = (float*)(ws + OFF_VPOST);
    float* gvec  = (float*)(ws + OFF_GVEC);
    float* bvec  = (float*)(ws + OFF_BVEC);
    float* gl_ws = (float*)(ws + OFF_GL);
    float* u_ws  = (float*)(ws + OFF_U);
    float* w_ws  = (float*)(ws + OFF_W);
    float* qg_ws = (float*)(ws + OFF_QG);
    float* kd_ws = (float*)(ws + OFF_KD);
    float* at_ws = (float*)(ws + OFF_AT);
    float* s_ws  = (float*)(ws + OFF_S);
    float* o_ws  = (float*)(ws + OFF_O);
    unsigned short* obf = (unsigned short*)(ws + OFF_OBF);

    cast_f32_bf16<<<4096, 256, 0, stream>>>(X, Xbf, 2048 * 2048);
    dim3 tb(64, 4);
    transpose_cast<<<dim3(1536 / 64, 2048 / 64), tb, 0, stream>>>(Wq, WallT, 2048, 1536);
    transpose_cast<<<dim3(1536 / 64, 2048 / 64), tb, 0, stream>>>(Wk, WallT + (size_t)1536 * 2048, 2048, 1536);
    transpose_cast<<<dim3(3072 / 64, 2048 / 64), tb, 0, stream>>>(Wv, WallT + (size_t)3072 * 2048, 2048, 3072);
    transpose_cast<<<dim3(3072 / 64, 2048 / 64), tb, 0, stream>>>(Wg, WallT + (size_t)6144 * 2048, 2048, 3072);
    transpose_cast<<<dim3(2048 / 64, 3072 / 64), tb, 0, stream>>>(Wo, WoT, 3072, 2048);

    gemm_bt<<<dim3(QKVD / 128, 2048 / 128), 256, 0, stream>>>(Xbf, WallT, Cqkv, 2048, QKVD, 2048);
    gemm_bt<<<dim3(VDIMN / 128, 2048 / 128), 256, 0, stream>>>(Xbf, WallT + (size_t)QKVD * 2048, Cgate, 2048, VDIMN, 2048);

    conv_silu<<<dim3(6, T_LEN), 256, 0, stream>>>(Cqkv + 0, QKVD, cq, qpost, KDIMN);
    conv_silu<<<dim3(6, T_LEN), 256, 0, stream>>>(Cqkv + 1536, QKVD, ck, kpost, KDIMN);
    conv_silu<<<dim3(12, T_LEN), 256, 0, stream>>>(Cqkv + 3072, QKVD, cv, vpost, VDIMN);
    beta_g<<<T_LEN, 256, 0, stream>>>(X, Wb, Wa, Alog, dtb, bvec, gvec);

    phase1_mfma<<<dim3(NCHUNK, HVN), 256, 0, stream>>>(qpost, kpost, vpost, gvec, bvec,
                                                       u_ws, w_ws, qg_ws, kd_ws, at_ws, gl_ws);
    phase2a<<<192, 256, 0, stream>>>(u_ws, w_ws, kd_ws, gl_ws, u_ws, s_ws);
    phase2b<<<dim3(NCHUNK, HVN * 2), 384, 0, stream>>>(qg_ws, at_ws, s_ws, u_ws, o_ws);

    gate_norm<<<T_LEN * HVN, 64, 0, stream>>>(o_ws, Cgate, nw, obf);

    gemm_bt<<<dim3(2048 / 128, 2048 / 128), 256, 0, stream>>>(obf, WoT, (float*)d_out, 2048, 2048, 3072);
}

// Round 6
// 721.067 us; speedup vs baseline: 1.1146x; 1.0209x over previous
//
#include <hip/hip_runtime.h>
#include <math.h>

#define T_LEN 2048
#define HIDN  2048
#define HKN   16
#define DKN   96
#define HVN   16
#define DVN   192
#define KDIMN 1536
#define VDIMN 3072
#define QKVD  6144   // q(1536)+k(1536)+v(3072)
#define CHUNKN 64
#define NCHUNK 32
#define EPSF 1e-6f

typedef __attribute__((ext_vector_type(8))) short short8;
typedef __attribute__((ext_vector_type(4))) float f32x4;

__device__ __forceinline__ unsigned short f2bf(float f) {
    unsigned int u = __float_as_uint(f);
    unsigned int r = (u + 0x7FFFu + ((u >> 16) & 1u)) >> 16;
    return (unsigned short)r;
}
__device__ __forceinline__ float siluf(float x) { return x / (1.f + expf(-x)); }

__device__ __forceinline__ void gld_lds16(const void* g, void* l) {
    __builtin_amdgcn_global_load_lds((const __attribute__((address_space(1))) unsigned int*)g,
                                     (__attribute__((address_space(3))) unsigned int*)l, 16, 0, 0);
}

// ---------------- cast f32 -> bf16 (4/thread) ----------------
__global__ void cast_f32_bf16(const float* __restrict__ in, unsigned short* __restrict__ out, int n) {
    int i = (blockIdx.x * blockDim.x + threadIdx.x) * 4;
    if (i >= n) return;
    float4 v = *(const float4*)(in + i);
    ushort4 o;
    o.x = f2bf(v.x); o.y = f2bf(v.y); o.z = f2bf(v.z); o.w = f2bf(v.w);
    *(ushort4*)(out + i) = o;
}

// ---------------- transpose + cast: W[K][N] -> Wt[N][K] bf16 ----------------
__global__ void transpose_cast(const float* __restrict__ W, unsigned short* __restrict__ Wt,
                               int K, int N) {
    __shared__ float tile[64][65];
    int k0 = blockIdx.y * 64, n0 = blockIdx.x * 64;
    int tx = threadIdx.x, ty = threadIdx.y; // (64,4)
    for (int r = ty; r < 64; r += 4) tile[r][tx] = W[(size_t)(k0 + r) * N + n0 + tx];
    __syncthreads();
    for (int r = ty; r < 64; r += 4) Wt[(size_t)(n0 + r) * K + k0 + tx] = f2bf(tile[tx][r]);
}

// ---------------- bf16 MFMA GEMM: C[M][N] f32 = A[M][K] @ Bt[N][K]^T ----------------
__global__ __launch_bounds__(256) void gemm_bt(const unsigned short* __restrict__ A,
                                               const unsigned short* __restrict__ Bt,
                                               float* __restrict__ C, int M, int N, int K) {
    __shared__ __align__(16) unsigned short As[128 * 32];
    __shared__ __align__(16) unsigned short Bs[128 * 32];
    int tid = threadIdx.x;
    int wave = tid >> 6, lane = tid & 63;
    int bm = blockIdx.y, bn = blockIdx.x;
    f32x4 acc[4][4] = {};
    int wr = wave >> 1, wc = wave & 1;
    int rstage = wave * 32 + (lane >> 2);
    int cstage = (lane & 3) * 8;
    const size_t a_row0 = (size_t)bm * 128;
    const size_t b_row0 = (size_t)bn * 128;
    int row_a[4], row_b[4];
#pragma unroll
    for (int i = 0; i < 4; ++i) {
        row_a[i] = wr * 64 + i * 16 + (lane & 15);
        row_b[i] = wc * 64 + i * 16 + (lane & 15);
    }
    int koff = (lane >> 4) * 8;
    unsigned short* as_base = As + wave * 1024;
    unsigned short* bs_base = Bs + wave * 1024;
    for (int k0 = 0; k0 < K; k0 += 32) {
        const unsigned short* ga = A + (a_row0 + rstage) * (size_t)K + k0 + cstage;
        const unsigned short* gb = Bt + (b_row0 + rstage) * (size_t)K + k0 + cstage;
        gld_lds16(ga, as_base);
        gld_lds16(ga + (size_t)16 * K, as_base + 512);
        gld_lds16(gb, bs_base);
        gld_lds16(gb + (size_t)16 * K, bs_base + 512);
        __syncthreads();
        short8 af[4], bfr[4];
#pragma unroll
        for (int mi = 0; mi < 4; ++mi) af[mi] = *(const short8*)(As + row_a[mi] * 32 + koff);
#pragma unroll
        for (int ni = 0; ni < 4; ++ni) bfr[ni] = *(const short8*)(Bs + row_b[ni] * 32 + koff);
#pragma unroll
        for (int mi = 0; mi < 4; ++mi)
#pragma unroll
            for (int ni = 0; ni < 4; ++ni)
                acc[mi][ni] = __builtin_amdgcn_mfma_f32_16x16x32_bf16(af[mi], bfr[ni], acc[mi][ni], 0, 0, 0);
        __syncthreads();
    }
#pragma unroll
    for (int mi = 0; mi < 4; ++mi) {
        int rbase = bm * 128 + wr * 64 + mi * 16 + (lane >> 4) * 4;
#pragma unroll
        for (int ni = 0; ni < 4; ++ni) {
            int col = bn * 128 + wc * 64 + ni * 16 + (lane & 15);
#pragma unroll
            for (int j = 0; j < 4; ++j)
                C[(size_t)(rbase + j) * N + col] = acc[mi][ni][j];
        }
    }
}

// ---------------- causal depthwise conv(K=4) + SiLU ----------------
__global__ void conv_silu(const float* __restrict__ pre, int ldp,
                          const float* __restrict__ wconv, float* __restrict__ out, int C) {
    int c = blockIdx.x * blockDim.x + threadIdx.x;
    int t = blockIdx.y;
    if (c >= C) return;
    const float* wc4 = wconv + (size_t)c * 4;
    float acc = 0.f;
    if (t >= 3) acc += pre[(size_t)(t - 3) * ldp + c] * wc4[0];
    if (t >= 2) acc += pre[(size_t)(t - 2) * ldp + c] * wc4[1];
    if (t >= 1) acc += pre[(size_t)(t - 1) * ldp + c] * wc4[2];
    acc += pre[(size_t)t * ldp + c] * wc4[3];
    out[(size_t)t * C + c] = siluf(acc);
}

// ---------------- beta / g projections (f32, exact) ----------------
__global__ __launch_bounds__(256) void beta_g(const float* __restrict__ X,
                                              const float* __restrict__ Wb, const float* __restrict__ Wa,
                                              const float* __restrict__ A_log, const float* __restrict__ dtb,
                                              float* __restrict__ bvec, float* __restrict__ gvec) {
    int t = blockIdx.x;
    int tid = threadIdx.x;
    int s = tid >> 5, c = tid & 31;
    float acc = 0.f;
    const float* xr = X + (size_t)t * HIDN;
    for (int k = s; k < HIDN; k += 8) {
        float xv = xr[k];
        float wv = (c < 16) ? Wb[(size_t)k * 16 + c] : Wa[(size_t)k * 16 + (c - 16)];
        acc += xv * wv;
    }
    __shared__ float red[8][32];
    red[s][c] = acc;
    __syncthreads();
    if (s == 0) {
        float tot = 0.f;
#pragma unroll
        for (int i = 0; i < 8; ++i) tot += red[i][c];
        if (c < 16) {
            bvec[(size_t)t * 16 + c] = 2.f / (1.f + expf(-tot));
        } else {
            int hh = c - 16;
            float a = tot + dtb[hh];
            float sp = (a > 20.f) ? a : log1pf(expf(a));
            gvec[(size_t)t * 16 + hh] = -expf(A_log[hh]) * sp;
        }
    }
}

// ---------------- phase 1 (MFMA): per (chunk, head) WY-transform prep ----------------
__global__ __launch_bounds__(256) void phase1_mfma(
    const float* __restrict__ qpost, const float* __restrict__ kpost,
    const float* __restrict__ vpost, const float* __restrict__ gvec,
    const float* __restrict__ bvec,
    float* __restrict__ u_ws, float* __restrict__ w_ws,
    float* __restrict__ qg_ws, float* __restrict__ kd_ws,
    float* __restrict__ at_ws, float* __restrict__ gl_ws) {
    int n = blockIdx.x, h = blockIdx.y;
    int t0 = n * CHUNKN;
    int tid = threadIdx.x;
    int wave = tid >> 6, lane = tid & 63;
    size_t base = (size_t)(h * NCHUNK + n);

    __shared__ __align__(16) unsigned short QKb[128 * 104];
    __shared__ __align__(16) unsigned short Ab[64 * 104];
    __shared__ __align__(16) unsigned short Atb[64 * 104];
    __shared__ __align__(16) unsigned short Pb[64 * 104];
    __shared__ __align__(16) unsigned short Ptb[64 * 104];
    __shared__ float Pf[64 * 68];
    __shared__ __align__(16) unsigned short RHSw[96 * 72];
    __shared__ __align__(16) unsigned short RHSv[192 * 72];
    __shared__ float gr_s[64], gc_s[64], be_s[64];

    if (tid < 64) {
        gr_s[tid] = gvec[(size_t)(t0 + tid) * HVN + h];
        be_s[tid] = bvec[(size_t)(t0 + tid) * HVN + h];
    }
    __syncthreads();
    if (tid < 64) {
        float sacc = 0.f;
        for (int j = 0; j <= tid; ++j) sacc += gr_s[j];
        gc_s[tid] = sacc;
    }
    __syncthreads();
    float gl = gc_s[63];

    int r = tid >> 2, sub = tid & 3;
    {
        const float* kp = kpost + (size_t)(t0 + r) * KDIMN + h * DKN + sub * 24;
        float kreg[24];
        float ss = 0.f;
#pragma unroll
        for (int i = 0; i < 6; ++i) {
            float4 v = *(const float4*)(kp + i * 4);
            kreg[i * 4 + 0] = v.x; kreg[i * 4 + 1] = v.y; kreg[i * 4 + 2] = v.z; kreg[i * 4 + 3] = v.w;
            ss += v.x * v.x + v.y * v.y + v.z * v.z + v.w * v.w;
        }
        ss += __shfl_xor(ss, 1, 64);
        ss += __shfl_xor(ss, 2, 64);
        float nrm = rsqrtf(ss + EPSF);
        float gcr = gc_s[r];
        float egl = expf(gl - gcr);
        float ebg = be_s[r] * expf(gcr);
        float* kdp = kd_ws + base * (64 * 96) + r * 96 + sub * 24;
#pragma unroll
        for (int i = 0; i < 24; ++i) {
            float kn = kreg[i] * nrm;
            QKb[r * 104 + sub * 24 + i] = f2bf(kn);
            kdp[i] = kn * egl;
            RHSw[(sub * 24 + i) * 72 + r] = f2bf(kn * ebg);
        }
    }
    {
        const float* qp = qpost + (size_t)(t0 + r) * KDIMN + h * DKN + sub * 24;
        float qreg[24];
        float ss = 0.f;
#pragma unroll
        for (int i = 0; i < 6; ++i) {
            float4 v = *(const float4*)(qp + i * 4);
            qreg[i * 4 + 0] = v.x; qreg[i * 4 + 1] = v.y; qreg[i * 4 + 2] = v.z; qreg[i * 4 + 3] = v.w;
            ss += v.x * v.x + v.y * v.y + v.z * v.z + v.w * v.w;
        }
        ss += __shfl_xor(ss, 1, 64);
        ss += __shfl_xor(ss, 2, 64);
        float nrm = rsqrtf(ss + EPSF) * 0.10206207261596577f;
        float eg = expf(gc_s[r]);
        float* qgp = qg_ws + base * (64 * 96) + r * 96 + sub * 24;
#pragma unroll
        for (int i = 0; i < 24; ++i) {
            float qn = qreg[i] * nrm;
            QKb[(64 + r) * 104 + sub * 24 + i] = f2bf(qn);
            qgp[i] = qn * eg;
        }
    }
    {
        const float* vp = vpost + (size_t)(t0 + r) * VDIMN + h * DVN + sub * 48;
        float ber = be_s[r];
#pragma unroll
        for (int i = 0; i < 12; ++i) {
            float4 v = *(const float4*)(vp + i * 4);
            int d = sub * 48 + i * 4;
            RHSv[(d + 0) * 72 + r] = f2bf(v.x * ber);
            RHSv[(d + 1) * 72 + r] = f2bf(v.y * ber);
            RHSv[(d + 2) * 72 + r] = f2bf(v.z * ber);
            RHSv[(d + 3) * 72 + r] = f2bf(v.w * ber);
        }
    }
    __syncthreads();

    {
        f32x4 acc1[2][4] = {};
#pragma unroll
        for (int ks = 0; ks < 3; ++ks) {
            int ko = ks * 32 + (lane >> 4) * 8;
            short8 af[2], bfv[4];
#pragma unroll
            for (int rt2 = 0; rt2 < 2; ++rt2)
                af[rt2] = *(const short8*)&QKb[(wave * 32 + rt2 * 16 + (lane & 15)) * 104 + ko];
#pragma unroll
            for (int ct = 0; ct < 4; ++ct)
                bfv[ct] = *(const short8*)&QKb[(ct * 16 + (lane & 15)) * 104 + ko];
#pragma unroll
            for (int rt2 = 0; rt2 < 2; ++rt2)
#pragma unroll
                for (int ct = 0; ct < 4; ++ct)
                    acc1[rt2][ct] = __builtin_amdgcn_mfma_f32_16x16x32_bf16(af[rt2], bfv[ct], acc1[rt2][ct], 0, 0, 0);
        }
#pragma unroll
        for (int rt2 = 0; rt2 < 2; ++rt2)
#pragma unroll
            for (int ct = 0; ct < 4; ++ct)
#pragma unroll
                for (int j = 0; j < 4; ++j) {
                    int rr = wave * 32 + rt2 * 16 + (lane >> 4) * 4 + j;
                    int cc = ct * 16 + (lane & 15);
                    float val = acc1[rt2][ct][j];
                    if (rr < 64) {
                        float av = (rr > cc) ? -be_s[rr] * expf(gc_s[rr] - gc_s[cc]) * val : 0.f;
                        unsigned short ab = f2bf(av);
                        Ab[rr * 104 + cc] = ab;
                        Atb[cc * 104 + rr] = ab;
                        float pv = (rr == cc) ? 1.f : av;
                        Pf[rr * 68 + cc] = pv;
                        unsigned short pb = f2bf(pv);
                        Pb[rr * 104 + cc] = pb;
                        Ptb[cc * 104 + rr] = pb;
                    } else {
                        int ar = rr - 64;
                        float av = (ar >= cc) ? expf(gc_s[ar] - gc_s[cc]) * val : 0.f;
                        at_ws[base * (64 * 64) + ar * 64 + cc] = av;
                    }
                }
    }
    __syncthreads();

#pragma unroll 1
    for (int lev = 0; lev < 5; ++lev) {
        f32x4 d[4] = {};
#pragma unroll
        for (int ks = 0; ks < 2; ++ks) {
            int ko = ks * 32 + (lane >> 4) * 8;
            short8 a0 = *(const short8*)&Ab[(wave * 16 + (lane & 15)) * 104 + ko];
#pragma unroll
            for (int ct = 0; ct < 4; ++ct) {
                short8 b0 = *(const short8*)&Atb[(ct * 16 + (lane & 15)) * 104 + ko];
                d[ct] = __builtin_amdgcn_mfma_f32_16x16x32_bf16(a0, b0, d[ct], 0, 0, 0);
            }
        }
        __syncthreads();
#pragma unroll
        for (int ct = 0; ct < 4; ++ct)
#pragma unroll
            for (int j = 0; j < 4; ++j) {
                int rr = wave * 16 + (lane >> 4) * 4 + j;
                int cc = ct * 16 + (lane & 15);
                unsigned short hb = f2bf(d[ct][j]);
                Ab[rr * 104 + cc] = hb;
                Atb[cc * 104 + rr] = hb;
            }
        __syncthreads();
        f32x4 e[4];
#pragma unroll
        for (int ct = 0; ct < 4; ++ct)
#pragma unroll
            for (int j = 0; j < 4; ++j)
                e[ct][j] = Pf[(wave * 16 + (lane >> 4) * 4 + j) * 68 + ct * 16 + (lane & 15)];
#pragma unroll
        for (int ks = 0; ks < 2; ++ks) {
            int ko = ks * 32 + (lane >> 4) * 8;
            short8 a0 = *(const short8*)&Ab[(wave * 16 + (lane & 15)) * 104 + ko];
#pragma unroll
            for (int ct = 0; ct < 4; ++ct) {
                short8 b0 = *(const short8*)&Ptb[(ct * 16 + (lane & 15)) * 104 + ko];
                e[ct] = __builtin_amdgcn_mfma_f32_16x16x32_bf16(a0, b0, e[ct], 0, 0, 0);
            }
        }
        __syncthreads();
#pragma unroll
        for (int ct = 0; ct < 4; ++ct)
#pragma unroll
            for (int j = 0; j < 4; ++j) {
                int rr = wave * 16 + (lane >> 4) * 4 + j;
                int cc = ct * 16 + (lane & 15);
                float pv = e[ct][j];
                Pf[rr * 68 + cc] = pv;
                unsigned short pb = f2bf(pv);
                Pb[rr * 104 + cc] = pb;
                Ptb[cc * 104 + rr] = pb;
            }
        __syncthreads();
    }

#pragma unroll 1
    for (int i = 0; i < 18; ++i) {
        int id = wave * 18 + i;
        int rt = id & 3, ct = id >> 2;
        f32x4 o4 = {};
#pragma unroll
        for (int ks = 0; ks < 2; ++ks) {
            int ko = ks * 32 + (lane >> 4) * 8;
            short8 a0 = *(const short8*)&Pb[(rt * 16 + (lane & 15)) * 104 + ko];
            short8 b0 = (ct < 12)
                ? *(const short8*)&RHSv[(ct * 16 + (lane & 15)) * 72 + ko]
                : *(const short8*)&RHSw[((ct - 12) * 16 + (lane & 15)) * 72 + ko];
            o4 = __builtin_amdgcn_mfma_f32_16x16x32_bf16(a0, b0, o4, 0, 0, 0);
        }
#pragma unroll
        for (int j = 0; j < 4; ++j) {
            int rr = rt * 16 + (lane >> 4) * 4 + j;
            int nn = ct * 16 + (lane & 15);
            if (ct < 12) u_ws[base * (64 * 192) + rr * 192 + nn] = o4[j];
            else         w_ws[base * (64 * 96) + rr * 96 + (nn - 192)] = o4[j];
        }
    }
    if (tid == 0) gl_ws[base] = gl;
}

// ---------------- tprep: T_n = e^gl I - kd^T w (bf16), Ct = u^T kd (f32) ----------------
__global__ __launch_bounds__(256) void tprep(const float* __restrict__ u_ws, const float* __restrict__ w_ws,
                                             const float* __restrict__ kd_ws, const float* __restrict__ gl_ws,
                                             float* __restrict__ Ct, unsigned short* __restrict__ Tn) {
    int n = blockIdx.x, h = blockIdx.y;
    size_t base = (size_t)(h * NCHUNK + n);
    int tid = threadIdx.x, wave = tid >> 6, lane = tid & 63;
    __shared__ __align__(16) unsigned short kdT[96 * 72];
    __shared__ __align__(16) unsigned short wT[96 * 72];
    __shared__ __align__(16) unsigned short uT[192 * 72];
    const float* kdp = kd_ws + base * (64 * 96);
    const float* wp  = w_ws + base * (64 * 96);
    const float* up  = u_ws + base * (64 * 192);
    for (int f = tid; f < 1536; f += 256) {
        int t = f / 24, c4 = (f % 24) * 4;
        float4 kv = *(const float4*)(kdp + t * 96 + c4);
        float4 wv = *(const float4*)(wp + t * 96 + c4);
        kdT[(c4 + 0) * 72 + t] = f2bf(kv.x); kdT[(c4 + 1) * 72 + t] = f2bf(kv.y);
        kdT[(c4 + 2) * 72 + t] = f2bf(kv.z); kdT[(c4 + 3) * 72 + t] = f2bf(kv.w);
        wT[(c4 + 0) * 72 + t] = f2bf(wv.x); wT[(c4 + 1) * 72 + t] = f2bf(wv.y);
        wT[(c4 + 2) * 72 + t] = f2bf(wv.z); wT[(c4 + 3) * 72 + t] = f2bf(wv.w);
    }
    for (int f = tid; f < 3072; f += 256) {
        int t = f / 48, c4 = (f % 48) * 4;
        float4 uv = *(const float4*)(up + t * 192 + c4);
        uT[(c4 + 0) * 72 + t] = f2bf(uv.x); uT[(c4 + 1) * 72 + t] = f2bf(uv.y);
        uT[(c4 + 2) * 72 + t] = f2bf(uv.z); uT[(c4 + 3) * 72 + t] = f2bf(uv.w);
    }
    __syncthreads();
    float egl = expf(gl_ws[base]);
#pragma unroll 1
    for (int q = 0; q < 27; ++q) {
        int id = wave * 27 + q;
        f32x4 acc = {};
        if (id < 36) {
            int jt = id / 6, kt = id % 6;
#pragma unroll
            for (int ks = 0; ks < 2; ++ks) {
                int ko = ks * 32 + (lane >> 4) * 8;
                short8 a0 = *(const short8*)&kdT[(jt * 16 + (lane & 15)) * 72 + ko];
                short8 b0 = *(const short8*)&wT[(kt * 16 + (lane & 15)) * 72 + ko];
                acc = __builtin_amdgcn_mfma_f32_16x16x32_bf16(a0, b0, acc, 0, 0, 0);
            }
#pragma unroll
            for (int r = 0; r < 4; ++r) {
                int j = jt * 16 + (lane >> 4) * 4 + r;
                int k = kt * 16 + (lane & 15);
                float val = -acc[r];
                if (j == k) val += egl;
                Tn[base * 9216 + j * 96 + k] = f2bf(val);
            }
        } else {
            int cid = id - 36;
            int it = cid / 6, jt = cid % 6;
#pragma unroll
            for (int ks = 0; ks < 2; ++ks) {
                int ko = ks * 32 + (lane >> 4) * 8;
                short8 a0 = *(const short8*)&uT[(it * 16 + (lane & 15)) * 72 + ko];
                short8 b0 = *(const short8*)&kdT[(jt * 16 + (lane & 15)) * 72 + ko];
                acc = __builtin_amdgcn_mfma_f32_16x16x32_bf16(a0, b0, acc, 0, 0, 0);
            }
#pragma unroll
            for (int r = 0; r < 4; ++r)
                Ct[base * 18432 + (size_t)(it * 16 + (lane >> 4) * 4 + r) * 96 + jt * 16 + (lane & 15)] = acc[r];
        }
    }
}

// ---------------- mscan: St_{n+1} = St_n @ T_n^T + Ct_n, 1 block/head, MFMA ----------------
__global__ __launch_bounds__(256) void mscan(const float* __restrict__ Ct, const unsigned short* __restrict__ Tn,
                                             float* __restrict__ s_ws) {
    int h = blockIdx.x;
    int tid = threadIdx.x, wave = tid >> 6, lane = tid & 63;
    __shared__ __align__(16) unsigned short St[192 * 104];
    __shared__ __align__(16) unsigned short Tb[2][96 * 104];
    for (int i = tid; i < 192 * 104; i += 256) St[i] = 0;
    {
        const unsigned short* tp = Tn + (size_t)(h * NCHUNK) * 9216;
        for (int f = tid; f < 2304; f += 256) {
            int rr = f / 24, c4 = (f % 24) * 4;
            *(ushort4*)&Tb[0][rr * 104 + c4] = *(const ushort4*)(tp + rr * 96 + c4);
        }
    }
    f32x4 acc[3][6] = {};
    int i0w = wave * 48;
    __syncthreads();
#pragma unroll 1
    for (int n = 0; n < NCHUNK; ++n) {
        size_t base = (size_t)(h * NCHUNK + n);
        if (n + 1 < NCHUNK) {
            const unsigned short* tp = Tn + (base + 1) * 9216;
            unsigned short* dst = &Tb[(n + 1) & 1][0];
            for (int f = tid; f < 2304; f += 256) {
                int rr = f / 24, c4 = (f % 24) * 4;
                *(ushort4*)&dst[rr * 104 + c4] = *(const ushort4*)(tp + rr * 96 + c4);
            }
        }
        float* sp = s_ws + base * 18432;
        const float* cp = Ct + base * 18432;
        const unsigned short* tb = &Tb[n & 1][0];
        // store S_pre (acc), re-init acc from Ct
#pragma unroll
        for (int it = 0; it < 3; ++it)
#pragma unroll
            for (int jt = 0; jt < 6; ++jt) {
                int irow = i0w + it * 16 + (lane >> 4) * 4;
                int j = jt * 16 + (lane & 15);
#pragma unroll
                for (int r = 0; r < 4; ++r) {
                    size_t off = (size_t)(irow + r) * 96 + j;
                    sp[off] = acc[it][jt][r];
                    acc[it][jt][r] = cp[off];
                }
            }
#pragma unroll
        for (int ks = 0; ks < 3; ++ks) {
            int ko = ks * 32 + (lane >> 4) * 8;
            short8 af[3], bfv[6];
#pragma unroll
            for (int it = 0; it < 3; ++it)
                af[it] = *(const short8*)&St[(i0w + it * 16 + (lane & 15)) * 104 + ko];
#pragma unroll
            for (int jt = 0; jt < 6; ++jt)
                bfv[jt] = *(const short8*)&tb[(jt * 16 + (lane & 15)) * 104 + ko];
#pragma unroll
            for (int it = 0; it < 3; ++it)
#pragma unroll
                for (int jt = 0; jt < 6; ++jt)
                    acc[it][jt] = __builtin_amdgcn_mfma_f32_16x16x32_bf16(af[it], bfv[jt], acc[it][jt], 0, 0, 0);
        }
        // write S_{n+1} bf16 to St (wave-local rows)
#pragma unroll
        for (int it = 0; it < 3; ++it)
#pragma unroll
            for (int jt = 0; jt < 6; ++jt)
#pragma unroll
                for (int r = 0; r < 4; ++r)
                    St[(i0w + it * 16 + (lane >> 4) * 4 + r) * 104 + jt * 16 + (lane & 15)] = f2bf(acc[it][jt][r]);
        __syncthreads();
    }
}

// ---------------- phase2b (MFMA): vnT = uT + St@(-w)^T ; oT = St@qg^T + vnT@at^T ----------------
#define P2_ST 0
#define P2_W  39936
#define P2_QG 53248
#define P2_AT 66560
#define P2_U  75776
#define P2_VN 125952
__global__ __launch_bounds__(256) void phase2b_mfma(const float* __restrict__ s_ws, const float* __restrict__ w_ws,
                                                    const float* __restrict__ qg_ws, const float* __restrict__ at_ws,
                                                    const float* __restrict__ u_ws, float* __restrict__ o_ws) {
    __shared__ __align__(16) char LB[153600];
    unsigned short* StB = (unsigned short*)(LB + P2_ST);
    unsigned short* wB  = (unsigned short*)(LB + P2_W);
    unsigned short* qgB = (unsigned short*)(LB + P2_QG);
    unsigned short* atB = (unsigned short*)(LB + P2_AT);
    float* uF           = (float*)(LB + P2_U);
    unsigned short* vnB = (unsigned short*)(LB + P2_VN);
    int n = blockIdx.x, h = blockIdx.y;
    size_t base = (size_t)(h * NCHUNK + n);
    int tid = threadIdx.x, wave = tid >> 6, lane = tid & 63;
    int i0w = wave * 48;
    // stage St (f32 -> bf16)
    {
        const float* sp = s_ws + base * 18432;
        for (int f = tid; f < 4608; f += 256) {
            int i = f / 24, c4 = (f % 24) * 4;
            float4 v = *(const float4*)(sp + i * 96 + c4);
            ushort4 o4; o4.x = f2bf(v.x); o4.y = f2bf(v.y); o4.z = f2bf(v.z); o4.w = f2bf(v.w);
            *(ushort4*)&StB[i * 104 + c4] = o4;
        }
    }
    // stage -w, qg
    {
        const float* wp = w_ws + base * 6144;
        const float* qp = qg_ws + base * 6144;
        for (int f = tid; f < 1536; f += 256) {
            int t = f / 24, c4 = (f % 24) * 4;
            float4 wv = *(const float4*)(wp + t * 96 + c4);
            float4 qv = *(const float4*)(qp + t * 96 + c4);
            ushort4 ow; ow.x = f2bf(-wv.x); ow.y = f2bf(-wv.y); ow.z = f2bf(-wv.z); ow.w = f2bf(-wv.w);
            ushort4 oq; oq.x = f2bf(qv.x); oq.y = f2bf(qv.y); oq.z = f2bf(qv.z); oq.w = f2bf(qv.w);
            *(ushort4*)&wB[t * 104 + c4] = ow;
            *(ushort4*)&qgB[t * 104 + c4] = oq;
        }
    }
    // stage at
    {
        const float* ap = at_ws + base * 4096;
        for (int f = tid; f < 1024; f += 256) {
            int t = f / 16, c4 = (f % 16) * 4;
            float4 av = *(const float4*)(ap + t * 64 + c4);
            ushort4 oa; oa.x = f2bf(av.x); oa.y = f2bf(av.y); oa.z = f2bf(av.z); oa.w = f2bf(av.w);
            *(ushort4*)&atB[t * 72 + c4] = oa;
        }
    }
    // stage u f32
    {
        const float* up = u_ws + base * 12288;
        for (int f = tid; f < 3072; f += 256) {
            int t = f / 48, c4 = (f % 48) * 4;
            *(float4*)&uF[t * 196 + c4] = *(const float4*)(up + t * 192 + c4);
        }
    }
    __syncthreads();
    // product 1: vnT[i][j] = u[j][i] + sum_k St[i][k]*(-w)[j][k]
    {
        f32x4 acc[3][4];
#pragma unroll
        for (int it = 0; it < 3; ++it)
#pragma unroll
            for (int jt = 0; jt < 4; ++jt)
#pragma unroll
                for (int r = 0; r < 4; ++r)
                    acc[it][jt][r] = uF[(jt * 16 + (lane & 15)) * 196 + i0w + it * 16 + (lane >> 4) * 4 + r];
#pragma unroll
        for (int ks = 0; ks < 3; ++ks) {
            int ko = ks * 32 + (lane >> 4) * 8;
            short8 af[3], bfv[4];
#pragma unroll
            for (int it = 0; it < 3; ++it)
                af[it] = *(const short8*)&StB[(i0w + it * 16 + (lane & 15)) * 104 + ko];
#pragma unroll
            for (int jt = 0; jt < 4; ++jt)
                bfv[jt] = *(const short8*)&wB[(jt * 16 + (lane & 15)) * 104 + ko];
#pragma unroll
            for (int it = 0; it < 3; ++it)
#pragma unroll
                for (int jt = 0; jt < 4; ++jt)
                    acc[it][jt] = __builtin_amdgcn_mfma_f32_16x16x32_bf16(af[it], bfv[jt], acc[it][jt], 0, 0, 0);
        }
#pragma unroll
        for (int it = 0; it < 3; ++it)
#pragma unroll
            for (int jt = 0; jt < 4; ++jt)
#pragma unroll
                for (int r = 0; r < 4; ++r)
                    vnB[(i0w + it * 16 + (lane >> 4) * 4 + r) * 72 + jt * 16 + (lane & 15)] = f2bf(acc[it][jt][r]);
    }
    // product 2: oT = St@qg^T + vnT@at^T
    f32x4 acc2[3][4] = {};
#pragma unroll
    for (int ks = 0; ks < 3; ++ks) {
        int ko = ks * 32 + (lane >> 4) * 8;
        short8 af[3], bfv[4];
#pragma unroll
        for (int it = 0; it < 3; ++it)
            af[it] = *(const short8*)&StB[(i0w + it * 16 + (lane & 15)) * 104 + ko];
#pragma unroll
        for (int jt = 0; jt < 4; ++jt)
            bfv[jt] = *(const short8*)&qgB[(jt * 16 + (lane & 15)) * 104 + ko];
#pragma unroll
        for (int it = 0; it < 3; ++it)
#pragma unroll
            for (int jt = 0; jt < 4; ++jt)
                acc2[it][jt] = __builtin_amdgcn_mfma_f32_16x16x32_bf16(af[it], bfv[jt], acc2[it][jt], 0, 0, 0);
    }
#pragma unroll
    for (int ks = 0; ks < 2; ++ks) {
        int ko = ks * 32 + (lane >> 4) * 8;
        short8 af[3], bfv[4];
#pragma unroll
        for (int it = 0; it < 3; ++it)
            af[it] = *(const short8*)&vnB[(i0w + it * 16 + (lane & 15)) * 72 + ko];
#pragma unroll
        for (int jt = 0; jt < 4; ++jt)
            bfv[jt] = *(const short8*)&atB[(jt * 16 + (lane & 15)) * 72 + ko];
#pragma unroll
        for (int it = 0; it < 3; ++it)
#pragma unroll
            for (int jt = 0; jt < 4; ++jt)
                acc2[it][jt] = __builtin_amdgcn_mfma_f32_16x16x32_bf16(af[it], bfv[jt], acc2[it][jt], 0, 0, 0);
    }
    __syncthreads(); // all MFMA reads of StB/wB/qgB done before oF overwrite
    float* oF = (float*)(LB + 0); // [192][68]
#pragma unroll
    for (int it = 0; it < 3; ++it)
#pragma unroll
        for (int jt = 0; jt < 4; ++jt)
#pragma unroll
            for (int r = 0; r < 4; ++r)
                oF[(i0w + it * 16 + (lane >> 4) * 4 + r) * 68 + jt * 16 + (lane & 15)] = acc2[it][jt][r];
    __syncthreads();
    int t0 = n * CHUNKN;
    for (int f = tid; f < 3072; f += 256) {
        int t = f / 48, c4 = (f % 48) * 4;
        float4 ov;
        ov.x = oF[(c4 + 0) * 68 + t];
        ov.y = oF[(c4 + 1) * 68 + t];
        ov.z = oF[(c4 + 2) * 68 + t];
        ov.w = oF[(c4 + 3) * 68 + t];
        *(float4*)(o_ws + (size_t)(t0 + t) * VDIMN + h * DVN + c4) = ov;
    }
}

// ---------------- gate (SiLU) + RMSNorm -> bf16 ----------------
__global__ __launch_bounds__(64) void gate_norm(const float* __restrict__ o_ws, const float* __restrict__ Cgate,
                                                const float* __restrict__ nw, unsigned short* __restrict__ obf) {
    int b = blockIdx.x;
    int t = b >> 4, h = b & 15;
    int lane = threadIdx.x;
    float x[3];
    float ss = 0.f;
    size_t ob = (size_t)t * VDIMN + h * DVN;
    for (int j = 0; j < 3; ++j) {
        int d = j * 64 + lane;
        float ov = o_ws[ob + d];
        float gv = Cgate[ob + d];
        float xv = ov * siluf(gv);
        x[j] = xv;
        ss += xv * xv;
    }
    for (int off = 32; off > 0; off >>= 1) ss += __shfl_xor(ss, off, 64);
    float r = rsqrtf(ss * (1.f / 192.f) + EPSF);
    for (int j = 0; j < 3; ++j) {
        int d = j * 64 + lane;
        obf[ob + d] = f2bf(x[j] * r * nw[d]);
    }
}

extern "C" void kernel_launch(void* const* d_in, const int* in_sizes, int n_in,
                              void* d_out, int out_size, void* d_ws, size_t ws_size,
                              hipStream_t stream) {
    (void)in_sizes; (void)n_in; (void)out_size;
    const float* X    = (const float*)d_in[0];
    const float* Wq   = (const float*)d_in[1];
    const float* Wk   = (const float*)d_in[2];
    const float* Wv   = (const float*)d_in[3];
    const float* Wb   = (const float*)d_in[4];
    const float* Wa   = (const float*)d_in[5];
    const float* Wg   = (const float*)d_in[6];
    const float* Wo   = (const float*)d_in[7];
    const float* cq   = (const float*)d_in[8];
    const float* ck   = (const float*)d_in[9];
    const float* cv   = (const float*)d_in[10];
    const float* Alog = (const float*)d_in[11];
    const float* dtb  = (const float*)d_in[12];
    const float* nw   = (const float*)d_in[13];

    const size_t OFF_XBF   = 0;                     // 8.39 MB; aliased by at_ws after gemms
    const size_t OFF_WALLT = 8388608;               // 37.7 MB; aliased by o_ws + obf after gemms
    const size_t OFF_WOT   = 46137344;              // 12.6 MB (live to end)
    const size_t OFF_CQKV  = 58720256;              // 50.3 MB; aliased by Ct + Tn after conv
    const size_t OFF_CGATE = 109051904;             // 25.2 MB (live to gate_norm)
    const size_t OFF_QPOST = 134217728;             // qpost/kpost/vpost 50.3 MB; aliased by s_ws after phase1
    const size_t OFF_KPOST = 146800640;
    const size_t OFF_VPOST = 159383552;
    const size_t OFF_GVEC  = 184549376;
    const size_t OFF_BVEC  = 184680448;
    const size_t OFF_GL    = 184811520;
    const size_t OFF_U     = 184819712;             // 25.2 MB
    const size_t OFF_W     = 209985536;             // 12.6 MB
    const size_t OFF_QG    = 222568448;             // 12.6 MB
    const size_t OFF_KD    = 235151360;             // 12.6 MB -> end 247,734,272
    const size_t OFF_AT    = OFF_XBF;               // 8.39 MB exact
    const size_t OFF_CT    = OFF_CQKV;              // 37.7 MB
    const size_t OFF_TN    = OFF_CQKV + 37748736;   // 9.44 MB -> ends 105.9 MB < CGATE
    const size_t OFF_S     = OFF_QPOST;             // 37.7 MB -> ends 171.97 MB < GVEC
    const size_t OFF_O     = OFF_WALLT;             // 25.2 MB
    const size_t OFF_OBF   = OFF_WALLT + 25165824;  // 12.6 MB -> ends at WOT
    const size_t NEEDED    = 247734272;
    if (ws_size < NEEDED) return;

    char* ws = (char*)d_ws;
    unsigned short* Xbf   = (unsigned short*)(ws + OFF_XBF);
    unsigned short* WallT = (unsigned short*)(ws + OFF_WALLT);
    unsigned short* WoT   = (unsigned short*)(ws + OFF_WOT);
    float* Cqkv  = (float*)(ws + OFF_CQKV);
    float* Cgate = (float*)(ws + OFF_CGATE);
    float* qpost = (float*)(ws + OFF_QPOST);
    float* kpost = (float*)(ws + OFF_KPOST);
    float* vpost = (float*)(ws + OFF_VPOST);
    float* gvec  = (float*)(ws + OFF_GVEC);
    float* bvec  = (float*)(ws + OFF_BVEC);
    float* gl_ws = (float*)(ws + OFF_GL);
    float* u_ws  = (float*)(ws + OFF_U);
    float* w_ws  = (float*)(ws + OFF_W);
    float* qg_ws = (float*)(ws + OFF_QG);
    float* kd_ws = (float*)(ws + OFF_KD);
    float* at_ws = (float*)(ws + OFF_AT);
    float* Ct    = (float*)(ws + OFF_CT);
    unsigned short* Tn = (unsigned short*)(ws + OFF_TN);
    float* s_ws  = (float*)(ws + OFF_S);
    float* o_ws  = (float*)(ws + OFF_O);
    unsigned short* obf = (unsigned short*)(ws + OFF_OBF);

    cast_f32_bf16<<<4096, 256, 0, stream>>>(X, Xbf, 2048 * 2048);
    dim3 tb(64, 4);
    transpose_cast<<<dim3(1536 / 64, 2048 / 64), tb, 0, stream>>>(Wq, WallT, 2048, 1536);
    transpose_cast<<<dim3(1536 / 64, 2048 / 64), tb, 0, stream>>>(Wk, WallT + (size_t)1536 * 2048, 2048, 1536);
    transpose_cast<<<dim3(3072 / 64, 2048 / 64), tb, 0, stream>>>(Wv, WallT + (size_t)3072 * 2048, 2048, 3072);
    transpose_cast<<<dim3(3072 / 64, 2048 / 64), tb, 0, stream>>>(Wg, WallT + (size_t)6144 * 2048, 2048, 3072);
    transpose_cast<<<dim3(2048 / 64, 3072 / 64), tb, 0, stream>>>(Wo, WoT, 3072, 2048);

    gemm_bt<<<dim3(QKVD / 128, 2048 / 128), 256, 0, stream>>>(Xbf, WallT, Cqkv, 2048, QKVD, 2048);
    gemm_bt<<<dim3(VDIMN / 128, 2048 / 128), 256, 0, stream>>>(Xbf, WallT + (size_t)QKVD * 2048, Cgate, 2048, VDIMN, 2048);

    conv_silu<<<dim3(6, T_LEN), 256, 0, stream>>>(Cqkv + 0, QKVD, cq, qpost, KDIMN);
    conv_silu<<<dim3(6, T_LEN), 256, 0, stream>>>(Cqkv + 1536, QKVD, ck, kpost, KDIMN);
    conv_silu<<<dim3(12, T_LEN), 256, 0, stream>>>(Cqkv + 3072, QKVD, cv, vpost, VDIMN);
    beta_g<<<T_LEN, 256, 0, stream>>>(X, Wb, Wa, Alog, dtb, bvec, gvec);

    phase1_mfma<<<dim3(NCHUNK, HVN), 256, 0, stream>>>(qpost, kpost, vpost, gvec, bvec,
                                                       u_ws, w_ws, qg_ws, kd_ws, at_ws, gl_ws);
    tprep<<<dim3(NCHUNK, HVN), 256, 0, stream>>>(u_ws, w_ws, kd_ws, gl_ws, Ct, Tn);
    mscan<<<HVN, 256, 0, stream>>>(Ct, Tn, s_ws);
    phase2b_mfma<<<dim3(NCHUNK, HVN), 256, 0, stream>>>(s_ws, w_ws, qg_ws, at_ws, u_ws, o_ws);

    gate_norm<<<T_LEN * HVN, 64, 0, stream>>>(o_ws, Cgate, nw, obf);

    gemm_bt<<<dim3(2048 / 128, 2048 / 128), 256, 0, stream>>>(obf, WoT, (float*)d_out, 2048, 2048, 3072);
}

// Round 7
// 599.510 us; speedup vs baseline: 1.3405x; 1.2028x over previous
//
#include <hip/hip_runtime.h>
#include <math.h>

#define T_LEN 2048
#define HIDN  2048
#define HKN   16
#define DKN   96
#define HVN   16
#define DVN   192
#define KDIMN 1536
#define VDIMN 3072
#define QKVD  6144   // q(1536)+k(1536)+v(3072)
#define CHUNKN 64
#define NCHUNK 32
#define EPSF 1e-6f
#define TN_STRIDE 10240   // ushorts per (chunk,head) Tn record: 96 rows * 104 + pad -> 20480 B (20 x 1024B)

typedef __attribute__((ext_vector_type(8))) short short8;
typedef __attribute__((ext_vector_type(4))) float f32x4;

__device__ __forceinline__ unsigned short f2bf(float f) {
    unsigned int u = __float_as_uint(f);
    unsigned int r = (u + 0x7FFFu + ((u >> 16) & 1u)) >> 16;
    return (unsigned short)r;
}
__device__ __forceinline__ float siluf(float x) { return x / (1.f + expf(-x)); }

__device__ __forceinline__ void gld_lds16(const void* g, void* l) {
    __builtin_amdgcn_global_load_lds((const __attribute__((address_space(1))) unsigned int*)g,
                                     (__attribute__((address_space(3))) unsigned int*)l, 16, 0, 0);
}

// ---------------- cast f32 -> bf16 (4/thread) ----------------
__global__ void cast_f32_bf16(const float* __restrict__ in, unsigned short* __restrict__ out, int n) {
    int i = (blockIdx.x * blockDim.x + threadIdx.x) * 4;
    if (i >= n) return;
    float4 v = *(const float4*)(in + i);
    ushort4 o;
    o.x = f2bf(v.x); o.y = f2bf(v.y); o.z = f2bf(v.z); o.w = f2bf(v.w);
    *(ushort4*)(out + i) = o;
}

// ---------------- transpose + cast: W[K][N] -> Wt[N][K] bf16 ----------------
__global__ void transpose_cast(const float* __restrict__ W, unsigned short* __restrict__ Wt,
                               int K, int N) {
    __shared__ float tile[64][65];
    int k0 = blockIdx.y * 64, n0 = blockIdx.x * 64;
    int tx = threadIdx.x, ty = threadIdx.y; // (64,4)
    for (int r = ty; r < 64; r += 4) tile[r][tx] = W[(size_t)(k0 + r) * N + n0 + tx];
    __syncthreads();
    for (int r = ty; r < 64; r += 4) Wt[(size_t)(n0 + r) * K + k0 + tx] = f2bf(tile[tx][r]);
}

// ---------------- bf16 MFMA GEMM: C[M][N] f32 = A[M][K] @ Bt[N][K]^T ----------------
__global__ __launch_bounds__(256) void gemm_bt(const unsigned short* __restrict__ A,
                                               const unsigned short* __restrict__ Bt,
                                               float* __restrict__ C, int M, int N, int K) {
    __shared__ __align__(16) unsigned short As[128 * 32];
    __shared__ __align__(16) unsigned short Bs[128 * 32];
    int tid = threadIdx.x;
    int wave = tid >> 6, lane = tid & 63;
    int bm = blockIdx.y, bn = blockIdx.x;
    f32x4 acc[4][4] = {};
    int wr = wave >> 1, wc = wave & 1;
    int rstage = wave * 32 + (lane >> 2);
    int cstage = (lane & 3) * 8;
    const size_t a_row0 = (size_t)bm * 128;
    const size_t b_row0 = (size_t)bn * 128;
    int row_a[4], row_b[4];
#pragma unroll
    for (int i = 0; i < 4; ++i) {
        row_a[i] = wr * 64 + i * 16 + (lane & 15);
        row_b[i] = wc * 64 + i * 16 + (lane & 15);
    }
    int koff = (lane >> 4) * 8;
    unsigned short* as_base = As + wave * 1024;
    unsigned short* bs_base = Bs + wave * 1024;
    for (int k0 = 0; k0 < K; k0 += 32) {
        const unsigned short* ga = A + (a_row0 + rstage) * (size_t)K + k0 + cstage;
        const unsigned short* gb = Bt + (b_row0 + rstage) * (size_t)K + k0 + cstage;
        gld_lds16(ga, as_base);
        gld_lds16(ga + (size_t)16 * K, as_base + 512);
        gld_lds16(gb, bs_base);
        gld_lds16(gb + (size_t)16 * K, bs_base + 512);
        __syncthreads();
        short8 af[4], bfr[4];
#pragma unroll
        for (int mi = 0; mi < 4; ++mi) af[mi] = *(const short8*)(As + row_a[mi] * 32 + koff);
#pragma unroll
        for (int ni = 0; ni < 4; ++ni) bfr[ni] = *(const short8*)(Bs + row_b[ni] * 32 + koff);
#pragma unroll
        for (int mi = 0; mi < 4; ++mi)
#pragma unroll
            for (int ni = 0; ni < 4; ++ni)
                acc[mi][ni] = __builtin_amdgcn_mfma_f32_16x16x32_bf16(af[mi], bfr[ni], acc[mi][ni], 0, 0, 0);
        __syncthreads();
    }
#pragma unroll
    for (int mi = 0; mi < 4; ++mi) {
        int rbase = bm * 128 + wr * 64 + mi * 16 + (lane >> 4) * 4;
#pragma unroll
        for (int ni = 0; ni < 4; ++ni) {
            int col = bn * 128 + wc * 64 + ni * 16 + (lane & 15);
#pragma unroll
            for (int j = 0; j < 4; ++j)
                C[(size_t)(rbase + j) * N + col] = acc[mi][ni][j];
        }
    }
}

// ---------------- causal depthwise conv(K=4) + SiLU ----------------
__global__ void conv_silu(const float* __restrict__ pre, int ldp,
                          const float* __restrict__ wconv, float* __restrict__ out, int C) {
    int c = blockIdx.x * blockDim.x + threadIdx.x;
    int t = blockIdx.y;
    if (c >= C) return;
    const float* wc4 = wconv + (size_t)c * 4;
    float acc = 0.f;
    if (t >= 3) acc += pre[(size_t)(t - 3) * ldp + c] * wc4[0];
    if (t >= 2) acc += pre[(size_t)(t - 2) * ldp + c] * wc4[1];
    if (t >= 1) acc += pre[(size_t)(t - 1) * ldp + c] * wc4[2];
    acc += pre[(size_t)t * ldp + c] * wc4[3];
    out[(size_t)t * C + c] = siluf(acc);
}

// ---------------- beta / g projections (f32, exact) ----------------
__global__ __launch_bounds__(256) void beta_g(const float* __restrict__ X,
                                              const float* __restrict__ Wb, const float* __restrict__ Wa,
                                              const float* __restrict__ A_log, const float* __restrict__ dtb,
                                              float* __restrict__ bvec, float* __restrict__ gvec) {
    int t = blockIdx.x;
    int tid = threadIdx.x;
    int s = tid >> 5, c = tid & 31;
    float acc = 0.f;
    const float* xr = X + (size_t)t * HIDN;
    for (int k = s; k < HIDN; k += 8) {
        float xv = xr[k];
        float wv = (c < 16) ? Wb[(size_t)k * 16 + c] : Wa[(size_t)k * 16 + (c - 16)];
        acc += xv * wv;
    }
    __shared__ float red[8][32];
    red[s][c] = acc;
    __syncthreads();
    if (s == 0) {
        float tot = 0.f;
#pragma unroll
        for (int i = 0; i < 8; ++i) tot += red[i][c];
        if (c < 16) {
            bvec[(size_t)t * 16 + c] = 2.f / (1.f + expf(-tot));
        } else {
            int hh = c - 16;
            float a = tot + dtb[hh];
            float sp = (a > 20.f) ? a : log1pf(expf(a));
            gvec[(size_t)t * 16 + hh] = -expf(A_log[hh]) * sp;
        }
    }
}

// ---------------- phase 1 (MFMA): per (chunk, head) WY-transform prep ----------------
__global__ __launch_bounds__(256) void phase1_mfma(
    const float* __restrict__ qpost, const float* __restrict__ kpost,
    const float* __restrict__ vpost, const float* __restrict__ gvec,
    const float* __restrict__ bvec,
    float* __restrict__ u_ws, float* __restrict__ w_ws,
    float* __restrict__ qg_ws, float* __restrict__ kd_ws,
    float* __restrict__ at_ws, float* __restrict__ gl_ws) {
    int n = blockIdx.x, h = blockIdx.y;
    int t0 = n * CHUNKN;
    int tid = threadIdx.x;
    int wave = tid >> 6, lane = tid & 63;
    size_t base = (size_t)(h * NCHUNK + n);

    __shared__ __align__(16) unsigned short QKb[128 * 104];
    __shared__ __align__(16) unsigned short Ab[64 * 104];
    __shared__ __align__(16) unsigned short Atb[64 * 104];
    __shared__ __align__(16) unsigned short Pb[64 * 104];
    __shared__ __align__(16) unsigned short Ptb[64 * 104];
    __shared__ float Pf[64 * 68];
    __shared__ __align__(16) unsigned short RHSw[96 * 72];
    __shared__ __align__(16) unsigned short RHSv[192 * 72];
    __shared__ float gr_s[64], gc_s[64], be_s[64];

    if (tid < 64) {
        gr_s[tid] = gvec[(size_t)(t0 + tid) * HVN + h];
        be_s[tid] = bvec[(size_t)(t0 + tid) * HVN + h];
    }
    __syncthreads();
    if (tid < 64) {
        float sacc = 0.f;
        for (int j = 0; j <= tid; ++j) sacc += gr_s[j];
        gc_s[tid] = sacc;
    }
    __syncthreads();
    float gl = gc_s[63];

    int r = tid >> 2, sub = tid & 3;
    {
        const float* kp = kpost + (size_t)(t0 + r) * KDIMN + h * DKN + sub * 24;
        float kreg[24];
        float ss = 0.f;
#pragma unroll
        for (int i = 0; i < 6; ++i) {
            float4 v = *(const float4*)(kp + i * 4);
            kreg[i * 4 + 0] = v.x; kreg[i * 4 + 1] = v.y; kreg[i * 4 + 2] = v.z; kreg[i * 4 + 3] = v.w;
            ss += v.x * v.x + v.y * v.y + v.z * v.z + v.w * v.w;
        }
        ss += __shfl_xor(ss, 1, 64);
        ss += __shfl_xor(ss, 2, 64);
        float nrm = rsqrtf(ss + EPSF);
        float gcr = gc_s[r];
        float egl = expf(gl - gcr);
        float ebg = be_s[r] * expf(gcr);
        float* kdp = kd_ws + base * (64 * 96) + r * 96 + sub * 24;
#pragma unroll
        for (int i = 0; i < 24; ++i) {
            float kn = kreg[i] * nrm;
            QKb[r * 104 + sub * 24 + i] = f2bf(kn);
            kdp[i] = kn * egl;
            RHSw[(sub * 24 + i) * 72 + r] = f2bf(kn * ebg);
        }
    }
    {
        const float* qp = qpost + (size_t)(t0 + r) * KDIMN + h * DKN + sub * 24;
        float qreg[24];
        float ss = 0.f;
#pragma unroll
        for (int i = 0; i < 6; ++i) {
            float4 v = *(const float4*)(qp + i * 4);
            qreg[i * 4 + 0] = v.x; qreg[i * 4 + 1] = v.y; qreg[i * 4 + 2] = v.z; qreg[i * 4 + 3] = v.w;
            ss += v.x * v.x + v.y * v.y + v.z * v.z + v.w * v.w;
        }
        ss += __shfl_xor(ss, 1, 64);
        ss += __shfl_xor(ss, 2, 64);
        float nrm = rsqrtf(ss + EPSF) * 0.10206207261596577f;
        float eg = expf(gc_s[r]);
        float* qgp = qg_ws + base * (64 * 96) + r * 96 + sub * 24;
#pragma unroll
        for (int i = 0; i < 24; ++i) {
            float qn = qreg[i] * nrm;
            QKb[(64 + r) * 104 + sub * 24 + i] = f2bf(qn);
            qgp[i] = qn * eg;
        }
    }
    {
        const float* vp = vpost + (size_t)(t0 + r) * VDIMN + h * DVN + sub * 48;
        float ber = be_s[r];
#pragma unroll
        for (int i = 0; i < 12; ++i) {
            float4 v = *(const float4*)(vp + i * 4);
            int d = sub * 48 + i * 4;
            RHSv[(d + 0) * 72 + r] = f2bf(v.x * ber);
            RHSv[(d + 1) * 72 + r] = f2bf(v.y * ber);
            RHSv[(d + 2) * 72 + r] = f2bf(v.z * ber);
            RHSv[(d + 3) * 72 + r] = f2bf(v.w * ber);
        }
    }
    __syncthreads();

    {
        f32x4 acc1[2][4] = {};
#pragma unroll
        for (int ks = 0; ks < 3; ++ks) {
            int ko = ks * 32 + (lane >> 4) * 8;
            short8 af[2], bfv[4];
#pragma unroll
            for (int rt2 = 0; rt2 < 2; ++rt2)
                af[rt2] = *(const short8*)&QKb[(wave * 32 + rt2 * 16 + (lane & 15)) * 104 + ko];
#pragma unroll
            for (int ct = 0; ct < 4; ++ct)
                bfv[ct] = *(const short8*)&QKb[(ct * 16 + (lane & 15)) * 104 + ko];
#pragma unroll
            for (int rt2 = 0; rt2 < 2; ++rt2)
#pragma unroll
                for (int ct = 0; ct < 4; ++ct)
                    acc1[rt2][ct] = __builtin_amdgcn_mfma_f32_16x16x32_bf16(af[rt2], bfv[ct], acc1[rt2][ct], 0, 0, 0);
        }
#pragma unroll
        for (int rt2 = 0; rt2 < 2; ++rt2)
#pragma unroll
            for (int ct = 0; ct < 4; ++ct)
#pragma unroll
                for (int j = 0; j < 4; ++j) {
                    int rr = wave * 32 + rt2 * 16 + (lane >> 4) * 4 + j;
                    int cc = ct * 16 + (lane & 15);
                    float val = acc1[rt2][ct][j];
                    if (rr < 64) {
                        float av = (rr > cc) ? -be_s[rr] * expf(gc_s[rr] - gc_s[cc]) * val : 0.f;
                        unsigned short ab = f2bf(av);
                        Ab[rr * 104 + cc] = ab;
                        Atb[cc * 104 + rr] = ab;
                        float pv = (rr == cc) ? 1.f : av;
                        Pf[rr * 68 + cc] = pv;
                        unsigned short pb = f2bf(pv);
                        Pb[rr * 104 + cc] = pb;
                        Ptb[cc * 104 + rr] = pb;
                    } else {
                        int ar = rr - 64;
                        float av = (ar >= cc) ? expf(gc_s[ar] - gc_s[cc]) * val : 0.f;
                        at_ws[base * (64 * 64) + ar * 64 + cc] = av;
                    }
                }
    }
    __syncthreads();

#pragma unroll 1
    for (int lev = 0; lev < 5; ++lev) {
        f32x4 d[4] = {};
#pragma unroll
        for (int ks = 0; ks < 2; ++ks) {
            int ko = ks * 32 + (lane >> 4) * 8;
            short8 a0 = *(const short8*)&Ab[(wave * 16 + (lane & 15)) * 104 + ko];
#pragma unroll
            for (int ct = 0; ct < 4; ++ct) {
                short8 b0 = *(const short8*)&Atb[(ct * 16 + (lane & 15)) * 104 + ko];
                d[ct] = __builtin_amdgcn_mfma_f32_16x16x32_bf16(a0, b0, d[ct], 0, 0, 0);
            }
        }
        __syncthreads();
#pragma unroll
        for (int ct = 0; ct < 4; ++ct)
#pragma unroll
            for (int j = 0; j < 4; ++j) {
                int rr = wave * 16 + (lane >> 4) * 4 + j;
                int cc = ct * 16 + (lane & 15);
                unsigned short hb = f2bf(d[ct][j]);
                Ab[rr * 104 + cc] = hb;
                Atb[cc * 104 + rr] = hb;
            }
        __syncthreads();
        f32x4 e[4];
#pragma unroll
        for (int ct = 0; ct < 4; ++ct)
#pragma unroll
            for (int j = 0; j < 4; ++j)
                e[ct][j] = Pf[(wave * 16 + (lane >> 4) * 4 + j) * 68 + ct * 16 + (lane & 15)];
#pragma unroll
        for (int ks = 0; ks < 2; ++ks) {
            int ko = ks * 32 + (lane >> 4) * 8;
            short8 a0 = *(const short8*)&Ab[(wave * 16 + (lane & 15)) * 104 + ko];
#pragma unroll
            for (int ct = 0; ct < 4; ++ct) {
                short8 b0 = *(const short8*)&Ptb[(ct * 16 + (lane & 15)) * 104 + ko];
                e[ct] = __builtin_amdgcn_mfma_f32_16x16x32_bf16(a0, b0, e[ct], 0, 0, 0);
            }
        }
        __syncthreads();
#pragma unroll
        for (int ct = 0; ct < 4; ++ct)
#pragma unroll
            for (int j = 0; j < 4; ++j) {
                int rr = wave * 16 + (lane >> 4) * 4 + j;
                int cc = ct * 16 + (lane & 15);
                float pv = e[ct][j];
                Pf[rr * 68 + cc] = pv;
                unsigned short pb = f2bf(pv);
                Pb[rr * 104 + cc] = pb;
                Ptb[cc * 104 + rr] = pb;
            }
        __syncthreads();
    }

#pragma unroll 1
    for (int i = 0; i < 18; ++i) {
        int id = wave * 18 + i;
        int rt = id & 3, ct = id >> 2;
        f32x4 o4 = {};
#pragma unroll
        for (int ks = 0; ks < 2; ++ks) {
            int ko = ks * 32 + (lane >> 4) * 8;
            short8 a0 = *(const short8*)&Pb[(rt * 16 + (lane & 15)) * 104 + ko];
            short8 b0 = (ct < 12)
                ? *(const short8*)&RHSv[(ct * 16 + (lane & 15)) * 72 + ko]
                : *(const short8*)&RHSw[((ct - 12) * 16 + (lane & 15)) * 72 + ko];
            o4 = __builtin_amdgcn_mfma_f32_16x16x32_bf16(a0, b0, o4, 0, 0, 0);
        }
#pragma unroll
        for (int j = 0; j < 4; ++j) {
            int rr = rt * 16 + (lane >> 4) * 4 + j;
            int nn = ct * 16 + (lane & 15);
            if (ct < 12) u_ws[base * (64 * 192) + rr * 192 + nn] = o4[j];
            else         w_ws[base * (64 * 96) + rr * 96 + (nn - 192)] = o4[j];
        }
    }
    if (tid == 0) gl_ws[base] = gl;
}

// ---------------- tprep: T_n = e^gl I - kd^T w (bf16, stride-104 padded), Ct = u^T kd (f32) ----------------
__global__ __launch_bounds__(256) void tprep(const float* __restrict__ u_ws, const float* __restrict__ w_ws,
                                             const float* __restrict__ kd_ws, const float* __restrict__ gl_ws,
                                             float* __restrict__ Ct, unsigned short* __restrict__ Tn) {
    int n = blockIdx.x, h = blockIdx.y;
    size_t base = (size_t)(h * NCHUNK + n);
    int tid = threadIdx.x, wave = tid >> 6, lane = tid & 63;
    __shared__ __align__(16) unsigned short kdT[96 * 72];
    __shared__ __align__(16) unsigned short wT[96 * 72];
    __shared__ __align__(16) unsigned short uT[192 * 72];
    const float* kdp = kd_ws + base * (64 * 96);
    const float* wp  = w_ws + base * (64 * 96);
    const float* up  = u_ws + base * (64 * 192);
    for (int f = tid; f < 1536; f += 256) {
        int t = f / 24, c4 = (f % 24) * 4;
        float4 kv = *(const float4*)(kdp + t * 96 + c4);
        float4 wv = *(const float4*)(wp + t * 96 + c4);
        kdT[(c4 + 0) * 72 + t] = f2bf(kv.x); kdT[(c4 + 1) * 72 + t] = f2bf(kv.y);
        kdT[(c4 + 2) * 72 + t] = f2bf(kv.z); kdT[(c4 + 3) * 72 + t] = f2bf(kv.w);
        wT[(c4 + 0) * 72 + t] = f2bf(wv.x); wT[(c4 + 1) * 72 + t] = f2bf(wv.y);
        wT[(c4 + 2) * 72 + t] = f2bf(wv.z); wT[(c4 + 3) * 72 + t] = f2bf(wv.w);
    }
    for (int f = tid; f < 3072; f += 256) {
        int t = f / 48, c4 = (f % 48) * 4;
        float4 uv = *(const float4*)(up + t * 192 + c4);
        uT[(c4 + 0) * 72 + t] = f2bf(uv.x); uT[(c4 + 1) * 72 + t] = f2bf(uv.y);
        uT[(c4 + 2) * 72 + t] = f2bf(uv.z); uT[(c4 + 3) * 72 + t] = f2bf(uv.w);
    }
    __syncthreads();
    float egl = expf(gl_ws[base]);
#pragma unroll 1
    for (int q = 0; q < 27; ++q) {
        int id = wave * 27 + q;
        f32x4 acc = {};
        if (id < 36) {
            int jt = id / 6, kt = id % 6;
#pragma unroll
            for (int ks = 0; ks < 2; ++ks) {
                int ko = ks * 32 + (lane >> 4) * 8;
                short8 a0 = *(const short8*)&kdT[(jt * 16 + (lane & 15)) * 72 + ko];
                short8 b0 = *(const short8*)&wT[(kt * 16 + (lane & 15)) * 72 + ko];
                acc = __builtin_amdgcn_mfma_f32_16x16x32_bf16(a0, b0, acc, 0, 0, 0);
            }
#pragma unroll
            for (int r = 0; r < 4; ++r) {
                int j = jt * 16 + (lane >> 4) * 4 + r;
                int k = kt * 16 + (lane & 15);
                float val = -acc[r];
                if (j == k) val += egl;
                Tn[base * TN_STRIDE + j * 104 + k] = f2bf(val);
            }
        } else {
            int cid = id - 36;
            int it = cid / 6, jt = cid % 6;
#pragma unroll
            for (int ks = 0; ks < 2; ++ks) {
                int ko = ks * 32 + (lane >> 4) * 8;
                short8 a0 = *(const short8*)&uT[(it * 16 + (lane & 15)) * 72 + ko];
                short8 b0 = *(const short8*)&kdT[(jt * 16 + (lane & 15)) * 72 + ko];
                acc = __builtin_amdgcn_mfma_f32_16x16x32_bf16(a0, b0, acc, 0, 0, 0);
            }
#pragma unroll
            for (int r = 0; r < 4; ++r)
                Ct[base * 18432 + (size_t)(it * 16 + (lane >> 4) * 4 + r) * 96 + jt * 16 + (lane & 15)] = acc[r];
        }
    }
}

// ---------------- mscan: St_{n+1} = St_n @ T_n^T + Ct_n ----------------
// grid (4 rowgroups of 48 dv-rows, 16 heads) x 128 threads (2 waves).
// Ct/Tn double-buffered into LDS via global_load_lds issued at step start (latency hidden under MFMA).
__global__ __launch_bounds__(128) void mscan(const float* __restrict__ Ct, const unsigned short* __restrict__ Tn,
                                             float* __restrict__ s_ws) {
    int rg = blockIdx.x, h = blockIdx.y;
    int tid = threadIdx.x, wave = tid >> 6, lane = tid & 63;
    __shared__ __align__(16) unsigned short St[48 * 104];    // 9984 B, bf16 state (shared A-operand)
    __shared__ __align__(16) unsigned short TnB[2][TN_STRIDE]; // 2 x 20480 B
    __shared__ __align__(16) float CtB[2][48 * 96];          // 2 x 18432 B
    for (int i = tid; i < 48 * 104; i += 128) St[i] = 0;

    // prologue: load chunk 0 into buffer 0
    {
        const float* cp = Ct + (size_t)(h * NCHUNK) * 18432 + rg * (48 * 96);
        const unsigned short* tp = Tn + (size_t)(h * NCHUNK) * TN_STRIDE;
#pragma unroll
        for (int q = 0; q < 9; ++q) {
            size_t o = (size_t)(wave * 9 + q) * 1024 + lane * 16;
            gld_lds16((const char*)cp + o, (char*)&CtB[0][0] + (size_t)(wave * 9 + q) * 1024);
        }
#pragma unroll
        for (int q = 0; q < 10; ++q) {
            size_t o = (size_t)(wave * 10 + q) * 1024 + lane * 16;
            gld_lds16((const char*)tp + o, (char*)&TnB[0][0] + (size_t)(wave * 10 + q) * 1024);
        }
    }
    f32x4 acc[3][3] = {};   // S state f32: rows it*16+(lane>>4)*4+r, cols wave*48+jt*16+(lane&15)
    int colw = wave * 48;
    __syncthreads();        // drains prologue loads

#pragma unroll 1
    for (int n = 0; n < NCHUNK; ++n) {
        size_t base = (size_t)(h * NCHUNK + n);
        int cur = n & 1;
        // issue prefetch for chunk n+1 into buffer cur^1 (completes by end-of-step barrier)
        if (n + 1 < NCHUNK) {
            const float* cp = Ct + (base + 1) * 18432 + rg * (48 * 96);
            const unsigned short* tp = Tn + (base + 1) * TN_STRIDE;
#pragma unroll
            for (int q = 0; q < 9; ++q) {
                size_t o = (size_t)(wave * 9 + q) * 1024 + lane * 16;
                gld_lds16((const char*)cp + o, (char*)&CtB[cur ^ 1][0] + (size_t)(wave * 9 + q) * 1024);
            }
#pragma unroll
            for (int q = 0; q < 10; ++q) {
                size_t o = (size_t)(wave * 10 + q) * 1024 + lane * 16;
                gld_lds16((const char*)tp + o, (char*)&TnB[cur ^ 1][0] + (size_t)(wave * 10 + q) * 1024);
            }
        }
        // store S_pre (fire-and-forget) and re-init acc from Ct
        float* sp = s_ws + base * 18432 + rg * (48 * 96);
#pragma unroll
        for (int it = 0; it < 3; ++it)
#pragma unroll
            for (int jt = 0; jt < 3; ++jt) {
                int irow = it * 16 + (lane >> 4) * 4;
                int col = colw + jt * 16 + (lane & 15);
#pragma unroll
                for (int r = 0; r < 4; ++r) {
                    sp[(size_t)(irow + r) * 96 + col] = acc[it][jt][r];
                    acc[it][jt][r] = CtB[cur][(irow + r) * 96 + col];
                }
            }
        // MFMA: acc += St @ Tn^T
#pragma unroll
        for (int ks = 0; ks < 3; ++ks) {
            int ko = ks * 32 + (lane >> 4) * 8;
            short8 af[3], bfv[3];
#pragma unroll
            for (int it = 0; it < 3; ++it)
                af[it] = *(const short8*)&St[(it * 16 + (lane & 15)) * 104 + ko];
#pragma unroll
            for (int jt = 0; jt < 3; ++jt)
                bfv[jt] = *(const short8*)&TnB[cur][(colw + jt * 16 + (lane & 15)) * 104 + ko];
#pragma unroll
            for (int it = 0; it < 3; ++it)
#pragma unroll
                for (int jt = 0; jt < 3; ++jt)
                    acc[it][jt] = __builtin_amdgcn_mfma_f32_16x16x32_bf16(af[it], bfv[jt], acc[it][jt], 0, 0, 0);
        }
        __syncthreads();    // St reads done in both waves before overwrite
        // write S_{n+1} bf16 to St
#pragma unroll
        for (int it = 0; it < 3; ++it)
#pragma unroll
            for (int jt = 0; jt < 3; ++jt)
#pragma unroll
                for (int r = 0; r < 4; ++r)
                    St[(it * 16 + (lane >> 4) * 4 + r) * 104 + colw + jt * 16 + (lane & 15)] = f2bf(acc[it][jt][r]);
        __syncthreads();    // St writes visible + prefetch loads drained
    }
}

// ---------------- phase2b (MFMA): vnT = uT + St@(-w)^T ; oT = St@qg^T + vnT@at^T ----------------
#define P2_ST 0
#define P2_W  39936
#define P2_QG 53248
#define P2_AT 66560
#define P2_U  75776
#define P2_VN 125952
__global__ __launch_bounds__(256) void phase2b_mfma(const float* __restrict__ s_ws, const float* __restrict__ w_ws,
                                                    const float* __restrict__ qg_ws, const float* __restrict__ at_ws,
                                                    const float* __restrict__ u_ws, float* __restrict__ o_ws) {
    __shared__ __align__(16) char LB[153600];
    unsigned short* StB = (unsigned short*)(LB + P2_ST);
    unsigned short* wB  = (unsigned short*)(LB + P2_W);
    unsigned short* qgB = (unsigned short*)(LB + P2_QG);
    unsigned short* atB = (unsigned short*)(LB + P2_AT);
    float* uF           = (float*)(LB + P2_U);
    unsigned short* vnB = (unsigned short*)(LB + P2_VN);
    int n = blockIdx.x, h = blockIdx.y;
    size_t base = (size_t)(h * NCHUNK + n);
    int tid = threadIdx.x, wave = tid >> 6, lane = tid & 63;
    int i0w = wave * 48;
    {
        const float* sp = s_ws + base * 18432;
        for (int f = tid; f < 4608; f += 256) {
            int i = f / 24, c4 = (f % 24) * 4;
            float4 v = *(const float4*)(sp + i * 96 + c4);
            ushort4 o4; o4.x = f2bf(v.x); o4.y = f2bf(v.y); o4.z = f2bf(v.z); o4.w = f2bf(v.w);
            *(ushort4*)&StB[i * 104 + c4] = o4;
        }
    }
    {
        const float* wp = w_ws + base * 6144;
        const float* qp = qg_ws + base * 6144;
        for (int f = tid; f < 1536; f += 256) {
            int t = f / 24, c4 = (f % 24) * 4;
            float4 wv = *(const float4*)(wp + t * 96 + c4);
            float4 qv = *(const float4*)(qp + t * 96 + c4);
            ushort4 ow; ow.x = f2bf(-wv.x); ow.y = f2bf(-wv.y); ow.z = f2bf(-wv.z); ow.w = f2bf(-wv.w);
            ushort4 oq; oq.x = f2bf(qv.x); oq.y = f2bf(qv.y); oq.z = f2bf(qv.z); oq.w = f2bf(qv.w);
            *(ushort4*)&wB[t * 104 + c4] = ow;
            *(ushort4*)&qgB[t * 104 + c4] = oq;
        }
    }
    {
        const float* ap = at_ws + base * 4096;
        for (int f = tid; f < 1024; f += 256) {
            int t = f / 16, c4 = (f % 16) * 4;
            float4 av = *(const float4*)(ap + t * 64 + c4);
            ushort4 oa; oa.x = f2bf(av.x); oa.y = f2bf(av.y); oa.z = f2bf(av.z); oa.w = f2bf(av.w);
            *(ushort4*)&atB[t * 72 + c4] = oa;
        }
    }
    {
        const float* up = u_ws + base * 12288;
        for (int f = tid; f < 3072; f += 256) {
            int t = f / 48, c4 = (f % 48) * 4;
            *(float4*)&uF[t * 196 + c4] = *(const float4*)(up + t * 192 + c4);
        }
    }
    __syncthreads();
    {
        f32x4 acc[3][4];
#pragma unroll
        for (int it = 0; it < 3; ++it)
#pragma unroll
            for (int jt = 0; jt < 4; ++jt)
#pragma unroll
                for (int r = 0; r < 4; ++r)
                    acc[it][jt][r] = uF[(jt * 16 + (lane & 15)) * 196 + i0w + it * 16 + (lane >> 4) * 4 + r];
#pragma unroll
        for (int ks = 0; ks < 3; ++ks) {
            int ko = ks * 32 + (lane >> 4) * 8;
            short8 af[3], bfv[4];
#pragma unroll
            for (int it = 0; it < 3; ++it)
                af[it] = *(const short8*)&StB[(i0w + it * 16 + (lane & 15)) * 104 + ko];
#pragma unroll
            for (int jt = 0; jt < 4; ++jt)
                bfv[jt] = *(const short8*)&wB[(jt * 16 + (lane & 15)) * 104 + ko];
#pragma unroll
            for (int it = 0; it < 3; ++it)
#pragma unroll
                for (int jt = 0; jt < 4; ++jt)
                    acc[it][jt] = __builtin_amdgcn_mfma_f32_16x16x32_bf16(af[it], bfv[jt], acc[it][jt], 0, 0, 0);
        }
#pragma unroll
        for (int it = 0; it < 3; ++it)
#pragma unroll
            for (int jt = 0; jt < 4; ++jt)
#pragma unroll
                for (int r = 0; r < 4; ++r)
                    vnB[(i0w + it * 16 + (lane >> 4) * 4 + r) * 72 + jt * 16 + (lane & 15)] = f2bf(acc[it][jt][r]);
    }
    f32x4 acc2[3][4] = {};
#pragma unroll
    for (int ks = 0; ks < 3; ++ks) {
        int ko = ks * 32 + (lane >> 4) * 8;
        short8 af[3], bfv[4];
#pragma unroll
        for (int it = 0; it < 3; ++it)
            af[it] = *(const short8*)&StB[(i0w + it * 16 + (lane & 15)) * 104 + ko];
#pragma unroll
        for (int jt = 0; jt < 4; ++jt)
            bfv[jt] = *(const short8*)&qgB[(jt * 16 + (lane & 15)) * 104 + ko];
#pragma unroll
        for (int it = 0; it < 3; ++it)
#pragma unroll
            for (int jt = 0; jt < 4; ++jt)
                acc2[it][jt] = __builtin_amdgcn_mfma_f32_16x16x32_bf16(af[it], bfv[jt], acc2[it][jt], 0, 0, 0);
    }
#pragma unroll
    for (int ks = 0; ks < 2; ++ks) {
        int ko = ks * 32 + (lane >> 4) * 8;
        short8 af[3], bfv[4];
#pragma unroll
        for (int it = 0; it < 3; ++it)
            af[it] = *(const short8*)&vnB[(i0w + it * 16 + (lane & 15)) * 72 + ko];
#pragma unroll
        for (int jt = 0; jt < 4; ++jt)
            bfv[jt] = *(const short8*)&atB[(jt * 16 + (lane & 15)) * 72 + ko];
#pragma unroll
        for (int it = 0; it < 3; ++it)
#pragma unroll
            for (int jt = 0; jt < 4; ++jt)
                acc2[it][jt] = __builtin_amdgcn_mfma_f32_16x16x32_bf16(af[it], bfv[jt], acc2[it][jt], 0, 0, 0);
    }
    __syncthreads();
    float* oF = (float*)(LB + 0); // [192][68]
#pragma unroll
    for (int it = 0; it < 3; ++it)
#pragma unroll
        for (int jt = 0; jt < 4; ++jt)
#pragma unroll
            for (int r = 0; r < 4; ++r)
                oF[(i0w + it * 16 + (lane >> 4) * 4 + r) * 68 + jt * 16 + (lane & 15)] = acc2[it][jt][r];
    __syncthreads();
    int t0 = n * CHUNKN;
    for (int f = tid; f < 3072; f += 256) {
        int t = f / 48, c4 = (f % 48) * 4;
        float4 ov;
        ov.x = oF[(c4 + 0) * 68 + t];
        ov.y = oF[(c4 + 1) * 68 + t];
        ov.z = oF[(c4 + 2) * 68 + t];
        ov.w = oF[(c4 + 3) * 68 + t];
        *(float4*)(o_ws + (size_t)(t0 + t) * VDIMN + h * DVN + c4) = ov;
    }
}

// ---------------- gate (SiLU) + RMSNorm -> bf16 ----------------
__global__ __launch_bounds__(64) void gate_norm(const float* __restrict__ o_ws, const float* __restrict__ Cgate,
                                                const float* __restrict__ nw, unsigned short* __restrict__ obf) {
    int b = blockIdx.x;
    int t = b >> 4, h = b & 15;
    int lane = threadIdx.x;
    float x[3];
    float ss = 0.f;
    size_t ob = (size_t)t * VDIMN + h * DVN;
    for (int j = 0; j < 3; ++j) {
        int d = j * 64 + lane;
        float ov = o_ws[ob + d];
        float gv = Cgate[ob + d];
        float xv = ov * siluf(gv);
        x[j] = xv;
        ss += xv * xv;
    }
    for (int off = 32; off > 0; off >>= 1) ss += __shfl_xor(ss, off, 64);
    float r = rsqrtf(ss * (1.f / 192.f) + EPSF);
    for (int j = 0; j < 3; ++j) {
        int d = j * 64 + lane;
        obf[ob + d] = f2bf(x[j] * r * nw[d]);
    }
}

extern "C" void kernel_launch(void* const* d_in, const int* in_sizes, int n_in,
                              void* d_out, int out_size, void* d_ws, size_t ws_size,
                              hipStream_t stream) {
    (void)in_sizes; (void)n_in; (void)out_size;
    const float* X    = (const float*)d_in[0];
    const float* Wq   = (const float*)d_in[1];
    const float* Wk   = (const float*)d_in[2];
    const float* Wv   = (const float*)d_in[3];
    const float* Wb   = (const float*)d_in[4];
    const float* Wa   = (const float*)d_in[5];
    const float* Wg   = (const float*)d_in[6];
    const float* Wo   = (const float*)d_in[7];
    const float* cq   = (const float*)d_in[8];
    const float* ck   = (const float*)d_in[9];
    const float* cv   = (const float*)d_in[10];
    const float* Alog = (const float*)d_in[11];
    const float* dtb  = (const float*)d_in[12];
    const float* nw   = (const float*)d_in[13];

    const size_t OFF_XBF   = 0;                     // 8.39 MB; aliased by at_ws after gemms
    const size_t OFF_WALLT = 8388608;               // 37.7 MB; aliased by o_ws + obf after gemms
    const size_t OFF_WOT   = 46137344;              // 12.6 MB (live to end)
    const size_t OFF_CQKV  = 58720256;              // 50.3 MB; aliased by Ct + Tn after conv
    const size_t OFF_CGATE = 109051904;             // 25.2 MB (live to gate_norm)
    const size_t OFF_QPOST = 134217728;             // qpost/kpost/vpost 50.3 MB; aliased by s_ws after phase1
    const size_t OFF_KPOST = 146800640;
    const size_t OFF_VPOST = 159383552;
    const size_t OFF_GVEC  = 184549376;
    const size_t OFF_BVEC  = 184680448;
    const size_t OFF_GL    = 184811520;
    const size_t OFF_U     = 184819712;             // 25.2 MB
    const size_t OFF_W     = 209985536;             // 12.6 MB
    const size_t OFF_QG    = 222568448;             // 12.6 MB
    const size_t OFF_KD    = 235151360;             // 12.6 MB -> end 247,734,272
    const size_t OFF_AT    = OFF_XBF;               // 8.39 MB exact
    const size_t OFF_CT    = OFF_CQKV;              // 37.7 MB
    const size_t OFF_TN    = OFF_CQKV + 37748736;   // 512*10240*2 = 10.49 MB -> ends 106.95 MB < CGATE
    const size_t OFF_S     = OFF_QPOST;             // 37.7 MB -> ends 171.97 MB < GVEC
    const size_t OFF_O     = OFF_WALLT;             // 25.2 MB
    const size_t OFF_OBF   = OFF_WALLT + 25165824;  // 12.6 MB -> ends at WOT
    const size_t NEEDED    = 247734272;
    if (ws_size < NEEDED) return;

    char* ws = (char*)d_ws;
    unsigned short* Xbf   = (unsigned short*)(ws + OFF_XBF);
    unsigned short* WallT = (unsigned short*)(ws + OFF_WALLT);
    unsigned short* WoT   = (unsigned short*)(ws + OFF_WOT);
    float* Cqkv  = (float*)(ws + OFF_CQKV);
    float* Cgate = (float*)(ws + OFF_CGATE);
    float* qpost = (float*)(ws + OFF_QPOST);
    float* kpost = (float*)(ws + OFF_KPOST);
    float* vpost = (float*)(ws + OFF_VPOST);
    float* gvec  = (float*)(ws + OFF_GVEC);
    float* bvec  = (float*)(ws + OFF_BVEC);
    float* gl_ws = (float*)(ws + OFF_GL);
    float* u_ws  = (float*)(ws + OFF_U);
    float* w_ws  = (float*)(ws + OFF_W);
    float* qg_ws = (float*)(ws + OFF_QG);
    float* kd_ws = (float*)(ws + OFF_KD);
    float* at_ws = (float*)(ws + OFF_AT);
    float* Ct    = (float*)(ws + OFF_CT);
    unsigned short* Tn = (unsigned short*)(ws + OFF_TN);
    float* s_ws  = (float*)(ws + OFF_S);
    float* o_ws  = (float*)(ws + OFF_O);
    unsigned short* obf = (unsigned short*)(ws + OFF_OBF);

    cast_f32_bf16<<<4096, 256, 0, stream>>>(X, Xbf, 2048 * 2048);
    dim3 tb(64, 4);
    transpose_cast<<<dim3(1536 / 64, 2048 / 64), tb, 0, stream>>>(Wq, WallT, 2048, 1536);
    transpose_cast<<<dim3(1536 / 64, 2048 / 64), tb, 0, stream>>>(Wk, WallT + (size_t)1536 * 2048, 2048, 1536);
    transpose_cast<<<dim3(3072 / 64, 2048 / 64), tb, 0, stream>>>(Wv, WallT + (size_t)3072 * 2048, 2048, 3072);
    transpose_cast<<<dim3(3072 / 64, 2048 / 64), tb, 0, stream>>>(Wg, WallT + (size_t)6144 * 2048, 2048, 3072);
    transpose_cast<<<dim3(2048 / 64, 3072 / 64), tb, 0, stream>>>(Wo, WoT, 3072, 2048);

    gemm_bt<<<dim3(QKVD / 128, 2048 / 128), 256, 0, stream>>>(Xbf, WallT, Cqkv, 2048, QKVD, 2048);
    gemm_bt<<<dim3(VDIMN / 128, 2048 / 128), 256, 0, stream>>>(Xbf, WallT + (size_t)QKVD * 2048, Cgate, 2048, VDIMN, 2048);

    conv_silu<<<dim3(6, T_LEN), 256, 0, stream>>>(Cqkv + 0, QKVD, cq, qpost, KDIMN);
    conv_silu<<<dim3(6, T_LEN), 256, 0, stream>>>(Cqkv + 1536, QKVD, ck, kpost, KDIMN);
    conv_silu<<<dim3(12, T_LEN), 256, 0, stream>>>(Cqkv + 3072, QKVD, cv, vpost, VDIMN);
    beta_g<<<T_LEN, 256, 0, stream>>>(X, Wb, Wa, Alog, dtb, bvec, gvec);

    phase1_mfma<<<dim3(NCHUNK, HVN), 256, 0, stream>>>(qpost, kpost, vpost, gvec, bvec,
                                                       u_ws, w_ws, qg_ws, kd_ws, at_ws, gl_ws);
    tprep<<<dim3(NCHUNK, HVN), 256, 0, stream>>>(u_ws, w_ws, kd_ws, gl_ws, Ct, Tn);
    mscan<<<dim3(4, HVN), 128, 0, stream>>>(Ct, Tn, s_ws);
    phase2b_mfma<<<dim3(NCHUNK, HVN), 256, 0, stream>>>(s_ws, w_ws, qg_ws, at_ws, u_ws, o_ws);

    gate_norm<<<T_LEN * HVN, 64, 0, stream>>>(o_ws, Cgate, nw, obf);

    gemm_bt<<<dim3(2048 / 128, 2048 / 128), 256, 0, stream>>>(obf, WoT, (float*)d_out, 2048, 2048, 3072);
}

// Round 8
// 537.972 us; speedup vs baseline: 1.4939x; 1.1144x over previous
//
#include <hip/hip_runtime.h>
#include <math.h>

#define T_LEN 2048
#define HIDN  2048
#define HKN   16
#define DKN   96
#define HVN   16
#define DVN   192
#define KDIMN 1536
#define VDIMN 3072
#define QKVD  6144   // q(1536)+k(1536)+v(3072)
#define CHUNKN 64
#define NCHUNK 32
#define EPSF 1e-6f
#define TN_STRIDE 10240   // ushorts per (chunk,head) Tn record: 96 rows * 104 + pad -> 20480 B (20 x 1024B)

typedef __attribute__((ext_vector_type(8))) short short8;
typedef __attribute__((ext_vector_type(4))) float f32x4;

__device__ __forceinline__ unsigned short f2bf(float f) {
    unsigned int u = __float_as_uint(f);
    unsigned int r = (u + 0x7FFFu + ((u >> 16) & 1u)) >> 16;
    return (unsigned short)r;
}
__device__ __forceinline__ float siluf(float x) { return x / (1.f + expf(-x)); }

__device__ __forceinline__ void gld_lds16(const void* g, void* l) {
    __builtin_amdgcn_global_load_lds((const __attribute__((address_space(1))) unsigned int*)g,
                                     (__attribute__((address_space(3))) unsigned int*)l, 16, 0, 0);
}

// ---------------- cast f32 -> bf16 (4/thread) ----------------
__global__ void cast_f32_bf16(const float* __restrict__ in, unsigned short* __restrict__ out, int n) {
    int i = (blockIdx.x * blockDim.x + threadIdx.x) * 4;
    if (i >= n) return;
    float4 v = *(const float4*)(in + i);
    ushort4 o;
    o.x = f2bf(v.x); o.y = f2bf(v.y); o.z = f2bf(v.z); o.w = f2bf(v.w);
    *(ushort4*)(out + i) = o;
}

// ---------------- transpose + cast: W[K][N] -> Wt[N][K] bf16 ----------------
__global__ void transpose_cast(const float* __restrict__ W, unsigned short* __restrict__ Wt,
                               int K, int N) {
    __shared__ float tile[64][65];
    int k0 = blockIdx.y * 64, n0 = blockIdx.x * 64;
    int tx = threadIdx.x, ty = threadIdx.y; // (64,4)
    for (int r = ty; r < 64; r += 4) tile[r][tx] = W[(size_t)(k0 + r) * N + n0 + tx];
    __syncthreads();
    for (int r = ty; r < 64; r += 4) Wt[(size_t)(n0 + r) * K + k0 + tx] = f2bf(tile[tx][r]);
}

// ---------------- bf16 MFMA GEMM: C[M][N] f32 = A[M][K] @ Bt[N][K]^T ----------------
__global__ __launch_bounds__(256) void gemm_bt(const unsigned short* __restrict__ A,
                                               const unsigned short* __restrict__ Bt,
                                               float* __restrict__ C, int M, int N, int K) {
    __shared__ __align__(16) unsigned short As[128 * 32];
    __shared__ __align__(16) unsigned short Bs[128 * 32];
    int tid = threadIdx.x;
    int wave = tid >> 6, lane = tid & 63;
    int bm = blockIdx.y, bn = blockIdx.x;
    f32x4 acc[4][4] = {};
    int wr = wave >> 1, wc = wave & 1;
    int rstage = wave * 32 + (lane >> 2);
    int cstage = (lane & 3) * 8;
    const size_t a_row0 = (size_t)bm * 128;
    const size_t b_row0 = (size_t)bn * 128;
    int row_a[4], row_b[4];
#pragma unroll
    for (int i = 0; i < 4; ++i) {
        row_a[i] = wr * 64 + i * 16 + (lane & 15);
        row_b[i] = wc * 64 + i * 16 + (lane & 15);
    }
    int koff = (lane >> 4) * 8;
    unsigned short* as_base = As + wave * 1024;
    unsigned short* bs_base = Bs + wave * 1024;
    for (int k0 = 0; k0 < K; k0 += 32) {
        const unsigned short* ga = A + (a_row0 + rstage) * (size_t)K + k0 + cstage;
        const unsigned short* gb = Bt + (b_row0 + rstage) * (size_t)K + k0 + cstage;
        gld_lds16(ga, as_base);
        gld_lds16(ga + (size_t)16 * K, as_base + 512);
        gld_lds16(gb, bs_base);
        gld_lds16(gb + (size_t)16 * K, bs_base + 512);
        __syncthreads();
        short8 af[4], bfr[4];
#pragma unroll
        for (int mi = 0; mi < 4; ++mi) af[mi] = *(const short8*)(As + row_a[mi] * 32 + koff);
#pragma unroll
        for (int ni = 0; ni < 4; ++ni) bfr[ni] = *(const short8*)(Bs + row_b[ni] * 32 + koff);
#pragma unroll
        for (int mi = 0; mi < 4; ++mi)
#pragma unroll
            for (int ni = 0; ni < 4; ++ni)
                acc[mi][ni] = __builtin_amdgcn_mfma_f32_16x16x32_bf16(af[mi], bfr[ni], acc[mi][ni], 0, 0, 0);
        __syncthreads();
    }
#pragma unroll
    for (int mi = 0; mi < 4; ++mi) {
        int rbase = bm * 128 + wr * 64 + mi * 16 + (lane >> 4) * 4;
#pragma unroll
        for (int ni = 0; ni < 4; ++ni) {
            int col = bn * 128 + wc * 64 + ni * 16 + (lane & 15);
#pragma unroll
            for (int j = 0; j < 4; ++j)
                C[(size_t)(rbase + j) * N + col] = acc[mi][ni][j];
        }
    }
}

// ---------------- causal depthwise conv(K=4) + SiLU ----------------
__global__ void conv_silu(const float* __restrict__ pre, int ldp,
                          const float* __restrict__ wconv, float* __restrict__ out, int C) {
    int c = blockIdx.x * blockDim.x + threadIdx.x;
    int t = blockIdx.y;
    if (c >= C) return;
    const float* wc4 = wconv + (size_t)c * 4;
    float acc = 0.f;
    if (t >= 3) acc += pre[(size_t)(t - 3) * ldp + c] * wc4[0];
    if (t >= 2) acc += pre[(size_t)(t - 2) * ldp + c] * wc4[1];
    if (t >= 1) acc += pre[(size_t)(t - 1) * ldp + c] * wc4[2];
    acc += pre[(size_t)t * ldp + c] * wc4[3];
    out[(size_t)t * C + c] = siluf(acc);
}

// ---------------- beta / g projections (f32, vectorized) ----------------
// grid 2048 (one block per t), 256 threads: ks = tid>>3 (32 k-slices of stride-128 float4s),
// cg = tid&7 (cg<4 -> Wb col-group, cg>=4 -> Wa col-group). float4 loads on X and W.
__global__ __launch_bounds__(256) void beta_g(const float* __restrict__ X,
                                              const float* __restrict__ Wb, const float* __restrict__ Wa,
                                              const float* __restrict__ A_log, const float* __restrict__ dtb,
                                              float* __restrict__ bvec, float* __restrict__ gvec) {
    int t = blockIdx.x;
    int tid = threadIdx.x;
    int cg = tid & 7, ks = tid >> 3;
    int wave = tid >> 6, lane = tid & 63;
    const float* xr = X + (size_t)t * HIDN;
    const float* Wsel = (cg < 4) ? Wb : Wa;
    int cc = (cg & 3) * 4;
    float ax = 0.f, ay = 0.f, az = 0.f, aw = 0.f;
#pragma unroll 4
    for (int i = 0; i < 16; ++i) {
        int k = (ks + 32 * i) * 4;
        float4 xv = *(const float4*)(xr + k);
        float4 w0 = *(const float4*)(Wsel + (size_t)(k + 0) * 16 + cc);
        float4 w1 = *(const float4*)(Wsel + (size_t)(k + 1) * 16 + cc);
        float4 w2 = *(const float4*)(Wsel + (size_t)(k + 2) * 16 + cc);
        float4 w3 = *(const float4*)(Wsel + (size_t)(k + 3) * 16 + cc);
        ax += xv.x * w0.x + xv.y * w1.x + xv.z * w2.x + xv.w * w3.x;
        ay += xv.x * w0.y + xv.y * w1.y + xv.z * w2.y + xv.w * w3.y;
        az += xv.x * w0.z + xv.y * w1.z + xv.z * w2.z + xv.w * w3.z;
        aw += xv.x * w0.w + xv.y * w1.w + xv.z * w2.w + xv.w * w3.w;
    }
    // reduce over ks%8 (lane bits 3..5) via shuffles
#pragma unroll
    for (int off = 8; off <= 32; off <<= 1) {
        ax += __shfl_xor(ax, off, 64);
        ay += __shfl_xor(ay, off, 64);
        az += __shfl_xor(az, off, 64);
        aw += __shfl_xor(aw, off, 64);
    }
    __shared__ float red[4][8][4];
    if ((lane >> 3) == 0) {
        red[wave][cg][0] = ax; red[wave][cg][1] = ay;
        red[wave][cg][2] = az; red[wave][cg][3] = aw;
    }
    __syncthreads();
    if (tid < 8) {
        float tot[4];
#pragma unroll
        for (int j = 0; j < 4; ++j)
            tot[j] = red[0][tid][j] + red[1][tid][j] + red[2][tid][j] + red[3][tid][j];
        int c0 = (tid & 3) * 4;
        if (tid < 4) {
#pragma unroll
            for (int j = 0; j < 4; ++j)
                bvec[(size_t)t * 16 + c0 + j] = 2.f / (1.f + expf(-tot[j]));
        } else {
#pragma unroll
            for (int j = 0; j < 4; ++j) {
                float a = tot[j] + dtb[c0 + j];
                float sp = (a > 20.f) ? a : log1pf(expf(a));
                gvec[(size_t)t * 16 + c0 + j] = -expf(A_log[c0 + j]) * sp;
            }
        }
    }
}

// ---------------- phase 1 (MFMA): per (chunk, head) WY-transform prep ----------------
__global__ __launch_bounds__(256) void phase1_mfma(
    const float* __restrict__ qpost, const float* __restrict__ kpost,
    const float* __restrict__ vpost, const float* __restrict__ gvec,
    const float* __restrict__ bvec,
    float* __restrict__ u_ws, float* __restrict__ w_ws,
    float* __restrict__ qg_ws, float* __restrict__ kd_ws,
    float* __restrict__ at_ws, float* __restrict__ gl_ws) {
    int n = blockIdx.x, h = blockIdx.y;
    int t0 = n * CHUNKN;
    int tid = threadIdx.x;
    int wave = tid >> 6, lane = tid & 63;
    size_t base = (size_t)(h * NCHUNK + n);

    __shared__ __align__(16) unsigned short QKb[128 * 104];
    __shared__ __align__(16) unsigned short Ab[64 * 104];
    __shared__ __align__(16) unsigned short Atb[64 * 104];
    __shared__ __align__(16) unsigned short Pb[64 * 104];
    __shared__ __align__(16) unsigned short Ptb[64 * 104];
    __shared__ float Pf[64 * 68];
    __shared__ __align__(16) unsigned short RHSw[96 * 72];
    __shared__ __align__(16) unsigned short RHSv[192 * 72];
    __shared__ float gr_s[64], gc_s[64], be_s[64];

    if (tid < 64) {
        gr_s[tid] = gvec[(size_t)(t0 + tid) * HVN + h];
        be_s[tid] = bvec[(size_t)(t0 + tid) * HVN + h];
    }
    __syncthreads();
    if (tid < 64) {
        float sacc = 0.f;
        for (int j = 0; j <= tid; ++j) sacc += gr_s[j];
        gc_s[tid] = sacc;
    }
    __syncthreads();
    float gl = gc_s[63];

    int r = tid >> 2, sub = tid & 3;
    {
        const float* kp = kpost + (size_t)(t0 + r) * KDIMN + h * DKN + sub * 24;
        float kreg[24];
        float ss = 0.f;
#pragma unroll
        for (int i = 0; i < 6; ++i) {
            float4 v = *(const float4*)(kp + i * 4);
            kreg[i * 4 + 0] = v.x; kreg[i * 4 + 1] = v.y; kreg[i * 4 + 2] = v.z; kreg[i * 4 + 3] = v.w;
            ss += v.x * v.x + v.y * v.y + v.z * v.z + v.w * v.w;
        }
        ss += __shfl_xor(ss, 1, 64);
        ss += __shfl_xor(ss, 2, 64);
        float nrm = rsqrtf(ss + EPSF);
        float gcr = gc_s[r];
        float egl = expf(gl - gcr);
        float ebg = be_s[r] * expf(gcr);
        float* kdp = kd_ws + base * (64 * 96) + r * 96 + sub * 24;
#pragma unroll
        for (int i = 0; i < 24; ++i) {
            float kn = kreg[i] * nrm;
            QKb[r * 104 + sub * 24 + i] = f2bf(kn);
            kdp[i] = kn * egl;
            RHSw[(sub * 24 + i) * 72 + r] = f2bf(kn * ebg);
        }
    }
    {
        const float* qp = qpost + (size_t)(t0 + r) * KDIMN + h * DKN + sub * 24;
        float qreg[24];
        float ss = 0.f;
#pragma unroll
        for (int i = 0; i < 6; ++i) {
            float4 v = *(const float4*)(qp + i * 4);
            qreg[i * 4 + 0] = v.x; qreg[i * 4 + 1] = v.y; qreg[i * 4 + 2] = v.z; qreg[i * 4 + 3] = v.w;
            ss += v.x * v.x + v.y * v.y + v.z * v.z + v.w * v.w;
        }
        ss += __shfl_xor(ss, 1, 64);
        ss += __shfl_xor(ss, 2, 64);
        float nrm = rsqrtf(ss + EPSF) * 0.10206207261596577f;
        float eg = expf(gc_s[r]);
        float* qgp = qg_ws + base * (64 * 96) + r * 96 + sub * 24;
#pragma unroll
        for (int i = 0; i < 24; ++i) {
            float qn = qreg[i] * nrm;
            QKb[(64 + r) * 104 + sub * 24 + i] = f2bf(qn);
            qgp[i] = qn * eg;
        }
    }
    {
        const float* vp = vpost + (size_t)(t0 + r) * VDIMN + h * DVN + sub * 48;
        float ber = be_s[r];
#pragma unroll
        for (int i = 0; i < 12; ++i) {
            float4 v = *(const float4*)(vp + i * 4);
            int d = sub * 48 + i * 4;
            RHSv[(d + 0) * 72 + r] = f2bf(v.x * ber);
            RHSv[(d + 1) * 72 + r] = f2bf(v.y * ber);
            RHSv[(d + 2) * 72 + r] = f2bf(v.z * ber);
            RHSv[(d + 3) * 72 + r] = f2bf(v.w * ber);
        }
    }
    __syncthreads();

    {
        f32x4 acc1[2][4] = {};
#pragma unroll
        for (int ks = 0; ks < 3; ++ks) {
            int ko = ks * 32 + (lane >> 4) * 8;
            short8 af[2], bfv[4];
#pragma unroll
            for (int rt2 = 0; rt2 < 2; ++rt2)
                af[rt2] = *(const short8*)&QKb[(wave * 32 + rt2 * 16 + (lane & 15)) * 104 + ko];
#pragma unroll
            for (int ct = 0; ct < 4; ++ct)
                bfv[ct] = *(const short8*)&QKb[(ct * 16 + (lane & 15)) * 104 + ko];
#pragma unroll
            for (int rt2 = 0; rt2 < 2; ++rt2)
#pragma unroll
                for (int ct = 0; ct < 4; ++ct)
                    acc1[rt2][ct] = __builtin_amdgcn_mfma_f32_16x16x32_bf16(af[rt2], bfv[ct], acc1[rt2][ct], 0, 0, 0);
        }
#pragma unroll
        for (int rt2 = 0; rt2 < 2; ++rt2)
#pragma unroll
            for (int ct = 0; ct < 4; ++ct)
#pragma unroll
                for (int j = 0; j < 4; ++j) {
                    int rr = wave * 32 + rt2 * 16 + (lane >> 4) * 4 + j;
                    int cc = ct * 16 + (lane & 15);
                    float val = acc1[rt2][ct][j];
                    if (rr < 64) {
                        float av = (rr > cc) ? -be_s[rr] * expf(gc_s[rr] - gc_s[cc]) * val : 0.f;
                        unsigned short ab = f2bf(av);
                        Ab[rr * 104 + cc] = ab;
                        Atb[cc * 104 + rr] = ab;
                        float pv = (rr == cc) ? 1.f : av;
                        Pf[rr * 68 + cc] = pv;
                        unsigned short pb = f2bf(pv);
                        Pb[rr * 104 + cc] = pb;
                        Ptb[cc * 104 + rr] = pb;
                    } else {
                        int ar = rr - 64;
                        float av = (ar >= cc) ? expf(gc_s[ar] - gc_s[cc]) * val : 0.f;
                        at_ws[base * (64 * 64) + ar * 64 + cc] = av;
                    }
                }
    }
    __syncthreads();

#pragma unroll 1
    for (int lev = 0; lev < 5; ++lev) {
        f32x4 d[4] = {};
#pragma unroll
        for (int ks = 0; ks < 2; ++ks) {
            int ko = ks * 32 + (lane >> 4) * 8;
            short8 a0 = *(const short8*)&Ab[(wave * 16 + (lane & 15)) * 104 + ko];
#pragma unroll
            for (int ct = 0; ct < 4; ++ct) {
                short8 b0 = *(const short8*)&Atb[(ct * 16 + (lane & 15)) * 104 + ko];
                d[ct] = __builtin_amdgcn_mfma_f32_16x16x32_bf16(a0, b0, d[ct], 0, 0, 0);
            }
        }
        __syncthreads();
#pragma unroll
        for (int ct = 0; ct < 4; ++ct)
#pragma unroll
            for (int j = 0; j < 4; ++j) {
                int rr = wave * 16 + (lane >> 4) * 4 + j;
                int cc = ct * 16 + (lane & 15);
                unsigned short hb = f2bf(d[ct][j]);
                Ab[rr * 104 + cc] = hb;
                Atb[cc * 104 + rr] = hb;
            }
        __syncthreads();
        f32x4 e[4];
#pragma unroll
        for (int ct = 0; ct < 4; ++ct)
#pragma unroll
            for (int j = 0; j < 4; ++j)
                e[ct][j] = Pf[(wave * 16 + (lane >> 4) * 4 + j) * 68 + ct * 16 + (lane & 15)];
#pragma unroll
        for (int ks = 0; ks < 2; ++ks) {
            int ko = ks * 32 + (lane >> 4) * 8;
            short8 a0 = *(const short8*)&Ab[(wave * 16 + (lane & 15)) * 104 + ko];
#pragma unroll
            for (int ct = 0; ct < 4; ++ct) {
                short8 b0 = *(const short8*)&Ptb[(ct * 16 + (lane & 15)) * 104 + ko];
                e[ct] = __builtin_amdgcn_mfma_f32_16x16x32_bf16(a0, b0, e[ct], 0, 0, 0);
            }
        }
        __syncthreads();
#pragma unroll
        for (int ct = 0; ct < 4; ++ct)
#pragma unroll
            for (int j = 0; j < 4; ++j) {
                int rr = wave * 16 + (lane >> 4) * 4 + j;
                int cc = ct * 16 + (lane & 15);
                float pv = e[ct][j];
                Pf[rr * 68 + cc] = pv;
                unsigned short pb = f2bf(pv);
                Pb[rr * 104 + cc] = pb;
                Ptb[cc * 104 + rr] = pb;
            }
        __syncthreads();
    }

#pragma unroll 1
    for (int i = 0; i < 18; ++i) {
        int id = wave * 18 + i;
        int rt = id & 3, ct = id >> 2;
        f32x4 o4 = {};
#pragma unroll
        for (int ks = 0; ks < 2; ++ks) {
            int ko = ks * 32 + (lane >> 4) * 8;
            short8 a0 = *(const short8*)&Pb[(rt * 16 + (lane & 15)) * 104 + ko];
            short8 b0 = (ct < 12)
                ? *(const short8*)&RHSv[(ct * 16 + (lane & 15)) * 72 + ko]
                : *(const short8*)&RHSw[((ct - 12) * 16 + (lane & 15)) * 72 + ko];
            o4 = __builtin_amdgcn_mfma_f32_16x16x32_bf16(a0, b0, o4, 0, 0, 0);
        }
#pragma unroll
        for (int j = 0; j < 4; ++j) {
            int rr = rt * 16 + (lane >> 4) * 4 + j;
            int nn = ct * 16 + (lane & 15);
            if (ct < 12) u_ws[base * (64 * 192) + rr * 192 + nn] = o4[j];
            else         w_ws[base * (64 * 96) + rr * 96 + (nn - 192)] = o4[j];
        }
    }
    if (tid == 0) gl_ws[base] = gl;
}

// ---------------- tprep: T_n = e^gl I - kd^T w (bf16, stride-104 padded), Ct = u^T kd (f32) ----------------
__global__ __launch_bounds__(256) void tprep(const float* __restrict__ u_ws, const float* __restrict__ w_ws,
                                             const float* __restrict__ kd_ws, const float* __restrict__ gl_ws,
                                             float* __restrict__ Ct, unsigned short* __restrict__ Tn) {
    int n = blockIdx.x, h = blockIdx.y;
    size_t base = (size_t)(h * NCHUNK + n);
    int tid = threadIdx.x, wave = tid >> 6, lane = tid & 63;
    __shared__ __align__(16) unsigned short kdT[96 * 72];
    __shared__ __align__(16) unsigned short wT[96 * 72];
    __shared__ __align__(16) unsigned short uT[192 * 72];
    const float* kdp = kd_ws + base * (64 * 96);
    const float* wp  = w_ws + base * (64 * 96);
    const float* up  = u_ws + base * (64 * 192);
    for (int f = tid; f < 1536; f += 256) {
        int t = f / 24, c4 = (f % 24) * 4;
        float4 kv = *(const float4*)(kdp + t * 96 + c4);
        float4 wv = *(const float4*)(wp + t * 96 + c4);
        kdT[(c4 + 0) * 72 + t] = f2bf(kv.x); kdT[(c4 + 1) * 72 + t] = f2bf(kv.y);
        kdT[(c4 + 2) * 72 + t] = f2bf(kv.z); kdT[(c4 + 3) * 72 + t] = f2bf(kv.w);
        wT[(c4 + 0) * 72 + t] = f2bf(wv.x); wT[(c4 + 1) * 72 + t] = f2bf(wv.y);
        wT[(c4 + 2) * 72 + t] = f2bf(wv.z); wT[(c4 + 3) * 72 + t] = f2bf(wv.w);
    }
    for (int f = tid; f < 3072; f += 256) {
        int t = f / 48, c4 = (f % 48) * 4;
        float4 uv = *(const float4*)(up + t * 192 + c4);
        uT[(c4 + 0) * 72 + t] = f2bf(uv.x); uT[(c4 + 1) * 72 + t] = f2bf(uv.y);
        uT[(c4 + 2) * 72 + t] = f2bf(uv.z); uT[(c4 + 3) * 72 + t] = f2bf(uv.w);
    }
    __syncthreads();
    float egl = expf(gl_ws[base]);
#pragma unroll 1
    for (int q = 0; q < 27; ++q) {
        int id = wave * 27 + q;
        f32x4 acc = {};
        if (id < 36) {
            int jt = id / 6, kt = id % 6;
#pragma unroll
            for (int ks = 0; ks < 2; ++ks) {
                int ko = ks * 32 + (lane >> 4) * 8;
                short8 a0 = *(const short8*)&kdT[(jt * 16 + (lane & 15)) * 72 + ko];
                short8 b0 = *(const short8*)&wT[(kt * 16 + (lane & 15)) * 72 + ko];
                acc = __builtin_amdgcn_mfma_f32_16x16x32_bf16(a0, b0, acc, 0, 0, 0);
            }
#pragma unroll
            for (int r = 0; r < 4; ++r) {
                int j = jt * 16 + (lane >> 4) * 4 + r;
                int k = kt * 16 + (lane & 15);
                float val = -acc[r];
                if (j == k) val += egl;
                Tn[base * TN_STRIDE + j * 104 + k] = f2bf(val);
            }
        } else {
            int cid = id - 36;
            int it = cid / 6, jt = cid % 6;
#pragma unroll
            for (int ks = 0; ks < 2; ++ks) {
                int ko = ks * 32 + (lane >> 4) * 8;
                short8 a0 = *(const short8*)&uT[(it * 16 + (lane & 15)) * 72 + ko];
                short8 b0 = *(const short8*)&kdT[(jt * 16 + (lane & 15)) * 72 + ko];
                acc = __builtin_amdgcn_mfma_f32_16x16x32_bf16(a0, b0, acc, 0, 0, 0);
            }
#pragma unroll
            for (int r = 0; r < 4; ++r)
                Ct[base * 18432 + (size_t)(it * 16 + (lane >> 4) * 4 + r) * 96 + jt * 16 + (lane & 15)] = acc[r];
        }
    }
}

// ---------------- mscan: St_{n+1} = St_n @ T_n^T + Ct_n ----------------
// grid (4 rowgroups of 48 dv-rows, 16 heads) x 128 threads (2 waves).
__global__ __launch_bounds__(128) void mscan(const float* __restrict__ Ct, const unsigned short* __restrict__ Tn,
                                             float* __restrict__ s_ws) {
    int rg = blockIdx.x, h = blockIdx.y;
    int tid = threadIdx.x, wave = tid >> 6, lane = tid & 63;
    __shared__ __align__(16) unsigned short St[48 * 104];
    __shared__ __align__(16) unsigned short TnB[2][TN_STRIDE];
    __shared__ __align__(16) float CtB[2][48 * 96];
    for (int i = tid; i < 48 * 104; i += 128) St[i] = 0;

    {
        const float* cp = Ct + (size_t)(h * NCHUNK) * 18432 + rg * (48 * 96);
        const unsigned short* tp = Tn + (size_t)(h * NCHUNK) * TN_STRIDE;
#pragma unroll
        for (int q = 0; q < 9; ++q) {
            size_t o = (size_t)(wave * 9 + q) * 1024 + lane * 16;
            gld_lds16((const char*)cp + o, (char*)&CtB[0][0] + (size_t)(wave * 9 + q) * 1024);
        }
#pragma unroll
        for (int q = 0; q < 10; ++q) {
            size_t o = (size_t)(wave * 10 + q) * 1024 + lane * 16;
            gld_lds16((const char*)tp + o, (char*)&TnB[0][0] + (size_t)(wave * 10 + q) * 1024);
        }
    }
    f32x4 acc[3][3] = {};
    int colw = wave * 48;
    __syncthreads();

#pragma unroll 1
    for (int n = 0; n < NCHUNK; ++n) {
        size_t base = (size_t)(h * NCHUNK + n);
        int cur = n & 1;
        if (n + 1 < NCHUNK) {
            const float* cp = Ct + (base + 1) * 18432 + rg * (48 * 96);
            const unsigned short* tp = Tn + (base + 1) * TN_STRIDE;
#pragma unroll
            for (int q = 0; q < 9; ++q) {
                size_t o = (size_t)(wave * 9 + q) * 1024 + lane * 16;
                gld_lds16((const char*)cp + o, (char*)&CtB[cur ^ 1][0] + (size_t)(wave * 9 + q) * 1024);
            }
#pragma unroll
            for (int q = 0; q < 10; ++q) {
                size_t o = (size_t)(wave * 10 + q) * 1024 + lane * 16;
                gld_lds16((const char*)tp + o, (char*)&TnB[cur ^ 1][0] + (size_t)(wave * 10 + q) * 1024);
            }
        }
        float* sp = s_ws + base * 18432 + rg * (48 * 96);
#pragma unroll
        for (int it = 0; it < 3; ++it)
#pragma unroll
            for (int jt = 0; jt < 3; ++jt) {
                int irow = it * 16 + (lane >> 4) * 4;
                int col = colw + jt * 16 + (lane & 15);
#pragma unroll
                for (int r = 0; r < 4; ++r) {
                    sp[(size_t)(irow + r) * 96 + col] = acc[it][jt][r];
                    acc[it][jt][r] = CtB[cur][(irow + r) * 96 + col];
                }
            }
#pragma unroll
        for (int ks = 0; ks < 3; ++ks) {
            int ko = ks * 32 + (lane >> 4) * 8;
            short8 af[3], bfv[3];
#pragma unroll
            for (int it = 0; it < 3; ++it)
                af[it] = *(const short8*)&St[(it * 16 + (lane & 15)) * 104 + ko];
#pragma unroll
            for (int jt = 0; jt < 3; ++jt)
                bfv[jt] = *(const short8*)&TnB[cur][(colw + jt * 16 + (lane & 15)) * 104 + ko];
#pragma unroll
            for (int it = 0; it < 3; ++it)
#pragma unroll
                for (int jt = 0; jt < 3; ++jt)
                    acc[it][jt] = __builtin_amdgcn_mfma_f32_16x16x32_bf16(af[it], bfv[jt], acc[it][jt], 0, 0, 0);
        }
        __syncthreads();
#pragma unroll
        for (int it = 0; it < 3; ++it)
#pragma unroll
            for (int jt = 0; jt < 3; ++jt)
#pragma unroll
                for (int r = 0; r < 4; ++r)
                    St[(it * 16 + (lane >> 4) * 4 + r) * 104 + colw + jt * 16 + (lane & 15)] = f2bf(acc[it][jt][r]);
        __syncthreads();
    }
}

// ---------------- phase2b (MFMA): vnT = uT + St@(-w)^T ; oT = St@qg^T + vnT@at^T ----------------
#define P2_ST 0
#define P2_W  39936
#define P2_QG 53248
#define P2_AT 66560
#define P2_U  75776
#define P2_VN 125952
__global__ __launch_bounds__(256) void phase2b_mfma(const float* __restrict__ s_ws, const float* __restrict__ w_ws,
                                                    const float* __restrict__ qg_ws, const float* __restrict__ at_ws,
                                                    const float* __restrict__ u_ws, float* __restrict__ o_ws) {
    __shared__ __align__(16) char LB[153600];
    unsigned short* StB = (unsigned short*)(LB + P2_ST);
    unsigned short* wB  = (unsigned short*)(LB + P2_W);
    unsigned short* qgB = (unsigned short*)(LB + P2_QG);
    unsigned short* atB = (unsigned short*)(LB + P2_AT);
    float* uF           = (float*)(LB + P2_U);
    unsigned short* vnB = (unsigned short*)(LB + P2_VN);
    int n = blockIdx.x, h = blockIdx.y;
    size_t base = (size_t)(h * NCHUNK + n);
    int tid = threadIdx.x, wave = tid >> 6, lane = tid & 63;
    int i0w = wave * 48;
    {
        const float* sp = s_ws + base * 18432;
        for (int f = tid; f < 4608; f += 256) {
            int i = f / 24, c4 = (f % 24) * 4;
            float4 v = *(const float4*)(sp + i * 96 + c4);
            ushort4 o4; o4.x = f2bf(v.x); o4.y = f2bf(v.y); o4.z = f2bf(v.z); o4.w = f2bf(v.w);
            *(ushort4*)&StB[i * 104 + c4] = o4;
        }
    }
    {
        const float* wp = w_ws + base * 6144;
        const float* qp = qg_ws + base * 6144;
        for (int f = tid; f < 1536; f += 256) {
            int t = f / 24, c4 = (f % 24) * 4;
            float4 wv = *(const float4*)(wp + t * 96 + c4);
            float4 qv = *(const float4*)(qp + t * 96 + c4);
            ushort4 ow; ow.x = f2bf(-wv.x); ow.y = f2bf(-wv.y); ow.z = f2bf(-wv.z); ow.w = f2bf(-wv.w);
            ushort4 oq; oq.x = f2bf(qv.x); oq.y = f2bf(qv.y); oq.z = f2bf(qv.z); oq.w = f2bf(qv.w);
            *(ushort4*)&wB[t * 104 + c4] = ow;
            *(ushort4*)&qgB[t * 104 + c4] = oq;
        }
    }
    {
        const float* ap = at_ws + base * 4096;
        for (int f = tid; f < 1024; f += 256) {
            int t = f / 16, c4 = (f % 16) * 4;
            float4 av = *(const float4*)(ap + t * 64 + c4);
            ushort4 oa; oa.x = f2bf(av.x); oa.y = f2bf(av.y); oa.z = f2bf(av.z); oa.w = f2bf(av.w);
            *(ushort4*)&atB[t * 72 + c4] = oa;
        }
    }
    {
        const float* up = u_ws + base * 12288;
        for (int f = tid; f < 3072; f += 256) {
            int t = f / 48, c4 = (f % 48) * 4;
            *(float4*)&uF[t * 196 + c4] = *(const float4*)(up + t * 192 + c4);
        }
    }
    __syncthreads();
    {
        f32x4 acc[3][4];
#pragma unroll
        for (int it = 0; it < 3; ++it)
#pragma unroll
            for (int jt = 0; jt < 4; ++jt)
#pragma unroll
                for (int r = 0; r < 4; ++r)
                    acc[it][jt][r] = uF[(jt * 16 + (lane & 15)) * 196 + i0w + it * 16 + (lane >> 4) * 4 + r];
#pragma unroll
        for (int ks = 0; ks < 3; ++ks) {
            int ko = ks * 32 + (lane >> 4) * 8;
            short8 af[3], bfv[4];
#pragma unroll
            for (int it = 0; it < 3; ++it)
                af[it] = *(const short8*)&StB[(i0w + it * 16 + (lane & 15)) * 104 + ko];
#pragma unroll
            for (int jt = 0; jt < 4; ++jt)
                bfv[jt] = *(const short8*)&wB[(jt * 16 + (lane & 15)) * 104 + ko];
#pragma unroll
            for (int it = 0; it < 3; ++it)
#pragma unroll
                for (int jt = 0; jt < 4; ++jt)
                    acc[it][jt] = __builtin_amdgcn_mfma_f32_16x16x32_bf16(af[it], bfv[jt], acc[it][jt], 0, 0, 0);
        }
#pragma unroll
        for (int it = 0; it < 3; ++it)
#pragma unroll
            for (int jt = 0; jt < 4; ++jt)
#pragma unroll
                for (int r = 0; r < 4; ++r)
                    vnB[(i0w + it * 16 + (lane >> 4) * 4 + r) * 72 + jt * 16 + (lane & 15)] = f2bf(acc[it][jt][r]);
    }
    f32x4 acc2[3][4] = {};
#pragma unroll
    for (int ks = 0; ks < 3; ++ks) {
        int ko = ks * 32 + (lane >> 4) * 8;
        short8 af[3], bfv[4];
#pragma unroll
        for (int it = 0; it < 3; ++it)
            af[it] = *(const short8*)&StB[(i0w + it * 16 + (lane & 15)) * 104 + ko];
#pragma unroll
        for (int jt = 0; jt < 4; ++jt)
            bfv[jt] = *(const short8*)&qgB[(jt * 16 + (lane & 15)) * 104 + ko];
#pragma unroll
        for (int it = 0; it < 3; ++it)
#pragma unroll
            for (int jt = 0; jt < 4; ++jt)
                acc2[it][jt] = __builtin_amdgcn_mfma_f32_16x16x32_bf16(af[it], bfv[jt], acc2[it][jt], 0, 0, 0);
    }
#pragma unroll
    for (int ks = 0; ks < 2; ++ks) {
        int ko = ks * 32 + (lane >> 4) * 8;
        short8 af[3], bfv[4];
#pragma unroll
        for (int it = 0; it < 3; ++it)
            af[it] = *(const short8*)&vnB[(i0w + it * 16 + (lane & 15)) * 72 + ko];
#pragma unroll
        for (int jt = 0; jt < 4; ++jt)
            bfv[jt] = *(const short8*)&atB[(jt * 16 + (lane & 15)) * 72 + ko];
#pragma unroll
        for (int it = 0; it < 3; ++it)
#pragma unroll
            for (int jt = 0; jt < 4; ++jt)
                acc2[it][jt] = __builtin_amdgcn_mfma_f32_16x16x32_bf16(af[it], bfv[jt], acc2[it][jt], 0, 0, 0);
    }
    __syncthreads();
    float* oF = (float*)(LB + 0); // [192][68]
#pragma unroll
    for (int it = 0; it < 3; ++it)
#pragma unroll
        for (int jt = 0; jt < 4; ++jt)
#pragma unroll
            for (int r = 0; r < 4; ++r)
                oF[(i0w + it * 16 + (lane >> 4) * 4 + r) * 68 + jt * 16 + (lane & 15)] = acc2[it][jt][r];
    __syncthreads();
    int t0 = n * CHUNKN;
    for (int f = tid; f < 3072; f += 256) {
        int t = f / 48, c4 = (f % 48) * 4;
        float4 ov;
        ov.x = oF[(c4 + 0) * 68 + t];
        ov.y = oF[(c4 + 1) * 68 + t];
        ov.z = oF[(c4 + 2) * 68 + t];
        ov.w = oF[(c4 + 3) * 68 + t];
        *(float4*)(o_ws + (size_t)(t0 + t) * VDIMN + h * DVN + c4) = ov;
    }
}

// ---------------- gate (SiLU) + RMSNorm -> bf16 ----------------
__global__ __launch_bounds__(64) void gate_norm(const float* __restrict__ o_ws, const float* __restrict__ Cgate,
                                                const float* __restrict__ nw, unsigned short* __restrict__ obf) {
    int b = blockIdx.x;
    int t = b >> 4, h = b & 15;
    int lane = threadIdx.x;
    float x[3];
    float ss = 0.f;
    size_t ob = (size_t)t * VDIMN + h * DVN;
    for (int j = 0; j < 3; ++j) {
        int d = j * 64 + lane;
        float ov = o_ws[ob + d];
        float gv = Cgate[ob + d];
        float xv = ov * siluf(gv);
        x[j] = xv;
        ss += xv * xv;
    }
    for (int off = 32; off > 0; off >>= 1) ss += __shfl_xor(ss, off, 64);
    float r = rsqrtf(ss * (1.f / 192.f) + EPSF);
    for (int j = 0; j < 3; ++j) {
        int d = j * 64 + lane;
        obf[ob + d] = f2bf(x[j] * r * nw[d]);
    }
}

extern "C" void kernel_launch(void* const* d_in, const int* in_sizes, int n_in,
                              void* d_out, int out_size, void* d_ws, size_t ws_size,
                              hipStream_t stream) {
    (void)in_sizes; (void)n_in; (void)out_size;
    const float* X    = (const float*)d_in[0];
    const float* Wq   = (const float*)d_in[1];
    const float* Wk   = (const float*)d_in[2];
    const float* Wv   = (const float*)d_in[3];
    const float* Wb   = (const float*)d_in[4];
    const float* Wa   = (const float*)d_in[5];
    const float* Wg   = (const float*)d_in[6];
    const float* Wo   = (const float*)d_in[7];
    const float* cq   = (const float*)d_in[8];
    const float* ck   = (const float*)d_in[9];
    const float* cv   = (const float*)d_in[10];
    const float* Alog = (const float*)d_in[11];
    const float* dtb  = (const float*)d_in[12];
    const float* nw   = (const float*)d_in[13];

    const size_t OFF_XBF   = 0;
    const size_t OFF_WALLT = 8388608;
    const size_t OFF_WOT   = 46137344;
    const size_t OFF_CQKV  = 58720256;
    const size_t OFF_CGATE = 109051904;
    const size_t OFF_QPOST = 134217728;
    const size_t OFF_KPOST = 146800640;
    const size_t OFF_VPOST = 159383552;
    const size_t OFF_GVEC  = 184549376;
    const size_t OFF_BVEC  = 184680448;
    const size_t OFF_GL    = 184811520;
    const size_t OFF_U     = 184819712;
    const size_t OFF_W     = 209985536;
    const size_t OFF_QG    = 222568448;
    const size_t OFF_KD    = 235151360;
    const size_t OFF_AT    = OFF_XBF;
    const size_t OFF_CT    = OFF_CQKV;
    const size_t OFF_TN    = OFF_CQKV + 37748736;
    const size_t OFF_S     = OFF_QPOST;
    const size_t OFF_O     = OFF_WALLT;
    const size_t OFF_OBF   = OFF_WALLT + 25165824;
    const size_t NEEDED    = 247734272;
    if (ws_size < NEEDED) return;

    char* ws = (char*)d_ws;
    unsigned short* Xbf   = (unsigned short*)(ws + OFF_XBF);
    unsigned short* WallT = (unsigned short*)(ws + OFF_WALLT);
    unsigned short* WoT   = (unsigned short*)(ws + OFF_WOT);
    float* Cqkv  = (float*)(ws + OFF_CQKV);
    float* Cgate = (float*)(ws + OFF_CGATE);
    float* qpost = (float*)(ws + OFF_QPOST);
    float* kpost = (float*)(ws + OFF_KPOST);
    float* vpost = (float*)(ws + OFF_VPOST);
    float* gvec  = (float*)(ws + OFF_GVEC);
    float* bvec  = (float*)(ws + OFF_BVEC);
    float* gl_ws = (float*)(ws + OFF_GL);
    float* u_ws  = (float*)(ws + OFF_U);
    float* w_ws  = (float*)(ws + OFF_W);
    float* qg_ws = (float*)(ws + OFF_QG);
    float* kd_ws = (float*)(ws + OFF_KD);
    float* at_ws = (float*)(ws + OFF_AT);
    float* Ct    = (float*)(ws + OFF_CT);
    unsigned short* Tn = (unsigned short*)(ws + OFF_TN);
    float* s_ws  = (float*)(ws + OFF_S);
    float* o_ws  = (float*)(ws + OFF_O);
    unsigned short* obf = (unsigned short*)(ws + OFF_OBF);

    cast_f32_bf16<<<4096, 256, 0, stream>>>(X, Xbf, 2048 * 2048);
    dim3 tb(64, 4);
    transpose_cast<<<dim3(1536 / 64, 2048 / 64), tb, 0, stream>>>(Wq, WallT, 2048, 1536);
    transpose_cast<<<dim3(1536 / 64, 2048 / 64), tb, 0, stream>>>(Wk, WallT + (size_t)1536 * 2048, 2048, 1536);
    transpose_cast<<<dim3(3072 / 64, 2048 / 64), tb, 0, stream>>>(Wv, WallT + (size_t)3072 * 2048, 2048, 3072);
    transpose_cast<<<dim3(3072 / 64, 2048 / 64), tb, 0, stream>>>(Wg, WallT + (size_t)6144 * 2048, 2048, 3072);
    transpose_cast<<<dim3(2048 / 64, 3072 / 64), tb, 0, stream>>>(Wo, WoT, 3072, 2048);

    gemm_bt<<<dim3(QKVD / 128, 2048 / 128), 256, 0, stream>>>(Xbf, WallT, Cqkv, 2048, QKVD, 2048);
    gemm_bt<<<dim3(VDIMN / 128, 2048 / 128), 256, 0, stream>>>(Xbf, WallT + (size_t)QKVD * 2048, Cgate, 2048, VDIMN, 2048);

    conv_silu<<<dim3(6, T_LEN), 256, 0, stream>>>(Cqkv + 0, QKVD, cq, qpost, KDIMN);
    conv_silu<<<dim3(6, T_LEN), 256, 0, stream>>>(Cqkv + 1536, QKVD, ck, kpost, KDIMN);
    conv_silu<<<dim3(12, T_LEN), 256, 0, stream>>>(Cqkv + 3072, QKVD, cv, vpost, VDIMN);
    beta_g<<<T_LEN, 256, 0, stream>>>(X, Wb, Wa, Alog, dtb, bvec, gvec);

    phase1_mfma<<<dim3(NCHUNK, HVN), 256, 0, stream>>>(qpost, kpost, vpost, gvec, bvec,
                                                       u_ws, w_ws, qg_ws, kd_ws, at_ws, gl_ws);
    tprep<<<dim3(NCHUNK, HVN), 256, 0, stream>>>(u_ws, w_ws, kd_ws, gl_ws, Ct, Tn);
    mscan<<<dim3(4, HVN), 128, 0, stream>>>(Ct, Tn, s_ws);
    phase2b_mfma<<<dim3(NCHUNK, HVN), 256, 0, stream>>>(s_ws, w_ws, qg_ws, at_ws, u_ws, o_ws);

    gate_norm<<<T_LEN * HVN, 64, 0, stream>>>(o_ws, Cgate, nw, obf);

    gemm_bt<<<dim3(2048 / 128, 2048 / 128), 256, 0, stream>>>(obf, WoT, (float*)d_out, 2048, 2048, 3072);
}

// Round 9
// 509.427 us; speedup vs baseline: 1.5776x; 1.0560x over previous
//
#include <hip/hip_runtime.h>
#include <math.h>

#define T_LEN 2048
#define HIDN  2048
#define HKN   16
#define DKN   96
#define HVN   16
#define DVN   192
#define KDIMN 1536
#define VDIMN 3072
#define QKVD  6144   // q(1536)+k(1536)+v(3072)
#define CHUNKN 64
#define NCHUNK 32
#define EPSF 1e-6f
#define TN_STRIDE 10240   // ushorts per (chunk,head) Tn record: 96 rows * 104 + pad -> 20480 B

typedef __attribute__((ext_vector_type(8))) short short8;
typedef __attribute__((ext_vector_type(4))) float f32x4;

__device__ __forceinline__ unsigned short f2bf(float f) {
    unsigned int u = __float_as_uint(f);
    unsigned int r = (u + 0x7FFFu + ((u >> 16) & 1u)) >> 16;
    return (unsigned short)r;
}
__device__ __forceinline__ float siluf(float x) { return x / (1.f + expf(-x)); }

__device__ __forceinline__ void gld_lds16(const void* g, void* l) {
    __builtin_amdgcn_global_load_lds((const __attribute__((address_space(1))) unsigned int*)g,
                                     (__attribute__((address_space(3))) unsigned int*)l, 16, 0, 0);
}

// ---------------- cast f32 -> bf16 (4/thread) ----------------
__global__ void cast_f32_bf16(const float* __restrict__ in, unsigned short* __restrict__ out, int n) {
    int i = (blockIdx.x * blockDim.x + threadIdx.x) * 4;
    if (i >= n) return;
    float4 v = *(const float4*)(in + i);
    ushort4 o;
    o.x = f2bf(v.x); o.y = f2bf(v.y); o.z = f2bf(v.z); o.w = f2bf(v.w);
    *(ushort4*)(out + i) = o;
}

// ---------------- transpose + cast: W[K][N] -> Wt[N][K] bf16 ----------------
__global__ void transpose_cast(const float* __restrict__ W, unsigned short* __restrict__ Wt,
                               int K, int N) {
    __shared__ float tile[64][65];
    int k0 = blockIdx.y * 64, n0 = blockIdx.x * 64;
    int tx = threadIdx.x, ty = threadIdx.y; // (64,4)
    for (int r = ty; r < 64; r += 4) tile[r][tx] = W[(size_t)(k0 + r) * N + n0 + tx];
    __syncthreads();
    for (int r = ty; r < 64; r += 4) Wt[(size_t)(n0 + r) * K + k0 + tx] = f2bf(tile[tx][r]);
}

// ---------------- fused projection GEMM with N-split outputs ----------------
// C[M][*] = A[M][K] @ Bt[*][K]^T; blocks bn<nblk1 write C1 (ld1), else C2 (ld2).
__global__ __launch_bounds__(256) void gemm_bt2(const unsigned short* __restrict__ A,
                                                const unsigned short* __restrict__ Bt,
                                                float* __restrict__ C1, int ld1, int nblk1,
                                                float* __restrict__ C2, int ld2,
                                                int M, int K) {
    __shared__ __align__(16) unsigned short As[128 * 32];
    __shared__ __align__(16) unsigned short Bs[128 * 32];
    int tid = threadIdx.x;
    int wave = tid >> 6, lane = tid & 63;
    int bm = blockIdx.y, bn = blockIdx.x;
    f32x4 acc[4][4] = {};
    int wr = wave >> 1, wc = wave & 1;
    int rstage = wave * 32 + (lane >> 2);
    int cstage = (lane & 3) * 8;
    const size_t a_row0 = (size_t)bm * 128;
    const size_t b_row0 = (size_t)bn * 128;
    int row_a[4], row_b[4];
#pragma unroll
    for (int i = 0; i < 4; ++i) {
        row_a[i] = wr * 64 + i * 16 + (lane & 15);
        row_b[i] = wc * 64 + i * 16 + (lane & 15);
    }
    int koff = (lane >> 4) * 8;
    unsigned short* as_base = As + wave * 1024;
    unsigned short* bs_base = Bs + wave * 1024;
    for (int k0 = 0; k0 < K; k0 += 32) {
        const unsigned short* ga = A + (a_row0 + rstage) * (size_t)K + k0 + cstage;
        const unsigned short* gb = Bt + (b_row0 + rstage) * (size_t)K + k0 + cstage;
        gld_lds16(ga, as_base);
        gld_lds16(ga + (size_t)16 * K, as_base + 512);
        gld_lds16(gb, bs_base);
        gld_lds16(gb + (size_t)16 * K, bs_base + 512);
        __syncthreads();
        short8 af[4], bfr[4];
#pragma unroll
        for (int mi = 0; mi < 4; ++mi) af[mi] = *(const short8*)(As + row_a[mi] * 32 + koff);
#pragma unroll
        for (int ni = 0; ni < 4; ++ni) bfr[ni] = *(const short8*)(Bs + row_b[ni] * 32 + koff);
#pragma unroll
        for (int mi = 0; mi < 4; ++mi)
#pragma unroll
            for (int ni = 0; ni < 4; ++ni)
                acc[mi][ni] = __builtin_amdgcn_mfma_f32_16x16x32_bf16(af[mi], bfr[ni], acc[mi][ni], 0, 0, 0);
        __syncthreads();
    }
    float* Cout; int ldo, colb;
    if (bn < nblk1) { Cout = C1; ldo = ld1; colb = bn * 128; }
    else            { Cout = C2; ldo = ld2; colb = (bn - nblk1) * 128; }
#pragma unroll
    for (int mi = 0; mi < 4; ++mi) {
        int rbase = bm * 128 + wr * 64 + mi * 16 + (lane >> 4) * 4;
#pragma unroll
        for (int ni = 0; ni < 4; ++ni) {
            int col = colb + wc * 64 + ni * 16 + (lane & 15);
#pragma unroll
            for (int j = 0; j < 4; ++j)
                Cout[(size_t)(rbase + j) * ldo + col] = acc[mi][ni][j];
        }
    }
}

// ---------------- split-K GEMM (SPLIT=3): kz=0 -> C, kz>=1 -> Cp slabs ----------------
__global__ __launch_bounds__(256) void gemm_btk(const unsigned short* __restrict__ A,
                                                const unsigned short* __restrict__ Bt,
                                                float* __restrict__ C, float* __restrict__ Cp,
                                                int M, int N, int K) {
    __shared__ __align__(16) unsigned short As[128 * 32];
    __shared__ __align__(16) unsigned short Bs[128 * 32];
    int tid = threadIdx.x;
    int wave = tid >> 6, lane = tid & 63;
    int bm = blockIdx.y, bn = blockIdx.x, kz = blockIdx.z;
    int kchunk = K / 3;
    int kbeg = kz * kchunk, kend = kbeg + kchunk;
    f32x4 acc[4][4] = {};
    int wr = wave >> 1, wc = wave & 1;
    int rstage = wave * 32 + (lane >> 2);
    int cstage = (lane & 3) * 8;
    const size_t a_row0 = (size_t)bm * 128;
    const size_t b_row0 = (size_t)bn * 128;
    int row_a[4], row_b[4];
#pragma unroll
    for (int i = 0; i < 4; ++i) {
        row_a[i] = wr * 64 + i * 16 + (lane & 15);
        row_b[i] = wc * 64 + i * 16 + (lane & 15);
    }
    int koff = (lane >> 4) * 8;
    unsigned short* as_base = As + wave * 1024;
    unsigned short* bs_base = Bs + wave * 1024;
    for (int k0 = kbeg; k0 < kend; k0 += 32) {
        const unsigned short* ga = A + (a_row0 + rstage) * (size_t)K + k0 + cstage;
        const unsigned short* gb = Bt + (b_row0 + rstage) * (size_t)K + k0 + cstage;
        gld_lds16(ga, as_base);
        gld_lds16(ga + (size_t)16 * K, as_base + 512);
        gld_lds16(gb, bs_base);
        gld_lds16(gb + (size_t)16 * K, bs_base + 512);
        __syncthreads();
        short8 af[4], bfr[4];
#pragma unroll
        for (int mi = 0; mi < 4; ++mi) af[mi] = *(const short8*)(As + row_a[mi] * 32 + koff);
#pragma unroll
        for (int ni = 0; ni < 4; ++ni) bfr[ni] = *(const short8*)(Bs + row_b[ni] * 32 + koff);
#pragma unroll
        for (int mi = 0; mi < 4; ++mi)
#pragma unroll
            for (int ni = 0; ni < 4; ++ni)
                acc[mi][ni] = __builtin_amdgcn_mfma_f32_16x16x32_bf16(af[mi], bfr[ni], acc[mi][ni], 0, 0, 0);
        __syncthreads();
    }
    float* Cout = (kz == 0) ? C : (Cp + (size_t)(kz - 1) * M * N);
#pragma unroll
    for (int mi = 0; mi < 4; ++mi) {
        int rbase = bm * 128 + wr * 64 + mi * 16 + (lane >> 4) * 4;
#pragma unroll
        for (int ni = 0; ni < 4; ++ni) {
            int col = bn * 128 + wc * 64 + ni * 16 + (lane & 15);
#pragma unroll
            for (int j = 0; j < 4; ++j)
                Cout[(size_t)(rbase + j) * N + col] = acc[mi][ni][j];
        }
    }
}

// ---------------- addk: out += p0 + p1 (split-K fixup, deterministic) ----------------
__global__ void addk(float* __restrict__ out, const float* __restrict__ p, int n) {
    int i = (blockIdx.x * blockDim.x + threadIdx.x) * 4;
    if (i >= n) return;
    float4 a = *(const float4*)(out + i);
    float4 b = *(const float4*)(p + i);
    float4 c = *(const float4*)(p + n + i);
    a.x += b.x + c.x; a.y += b.y + c.y; a.z += b.z + c.z; a.w += b.w + c.w;
    *(float4*)(out + i) = a;
}

// ---------------- causal depthwise conv(K=4) + SiLU ----------------
__global__ void conv_silu(const float* __restrict__ pre, int ldp,
                          const float* __restrict__ wconv, float* __restrict__ out, int C) {
    int c = blockIdx.x * blockDim.x + threadIdx.x;
    int t = blockIdx.y;
    if (c >= C) return;
    const float* wc4 = wconv + (size_t)c * 4;
    float acc = 0.f;
    if (t >= 3) acc += pre[(size_t)(t - 3) * ldp + c] * wc4[0];
    if (t >= 2) acc += pre[(size_t)(t - 2) * ldp + c] * wc4[1];
    if (t >= 1) acc += pre[(size_t)(t - 1) * ldp + c] * wc4[2];
    acc += pre[(size_t)t * ldp + c] * wc4[3];
    out[(size_t)t * C + c] = siluf(acc);
}

// ---------------- beta / g projections (f32, vectorized) ----------------
__global__ __launch_bounds__(256) void beta_g(const float* __restrict__ X,
                                              const float* __restrict__ Wb, const float* __restrict__ Wa,
                                              const float* __restrict__ A_log, const float* __restrict__ dtb,
                                              float* __restrict__ bvec, float* __restrict__ gvec) {
    int t = blockIdx.x;
    int tid = threadIdx.x;
    int cg = tid & 7, ks = tid >> 3;
    int wave = tid >> 6, lane = tid & 63;
    const float* xr = X + (size_t)t * HIDN;
    const float* Wsel = (cg < 4) ? Wb : Wa;
    int cc = (cg & 3) * 4;
    float ax = 0.f, ay = 0.f, az = 0.f, aw = 0.f;
#pragma unroll 4
    for (int i = 0; i < 16; ++i) {
        int k = (ks + 32 * i) * 4;
        float4 xv = *(const float4*)(xr + k);
        float4 w0 = *(const float4*)(Wsel + (size_t)(k + 0) * 16 + cc);
        float4 w1 = *(const float4*)(Wsel + (size_t)(k + 1) * 16 + cc);
        float4 w2 = *(const float4*)(Wsel + (size_t)(k + 2) * 16 + cc);
        float4 w3 = *(const float4*)(Wsel + (size_t)(k + 3) * 16 + cc);
        ax += xv.x * w0.x + xv.y * w1.x + xv.z * w2.x + xv.w * w3.x;
        ay += xv.x * w0.y + xv.y * w1.y + xv.z * w2.y + xv.w * w3.y;
        az += xv.x * w0.z + xv.y * w1.z + xv.z * w2.z + xv.w * w3.z;
        aw += xv.x * w0.w + xv.y * w1.w + xv.z * w2.w + xv.w * w3.w;
    }
#pragma unroll
    for (int off = 8; off <= 32; off <<= 1) {
        ax += __shfl_xor(ax, off, 64);
        ay += __shfl_xor(ay, off, 64);
        az += __shfl_xor(az, off, 64);
        aw += __shfl_xor(aw, off, 64);
    }
    __shared__ float red[4][8][4];
    if ((lane >> 3) == 0) {
        red[wave][cg][0] = ax; red[wave][cg][1] = ay;
        red[wave][cg][2] = az; red[wave][cg][3] = aw;
    }
    __syncthreads();
    if (tid < 8) {
        float tot[4];
#pragma unroll
        for (int j = 0; j < 4; ++j)
            tot[j] = red[0][tid][j] + red[1][tid][j] + red[2][tid][j] + red[3][tid][j];
        int c0 = (tid & 3) * 4;
        if (tid < 4) {
#pragma unroll
            for (int j = 0; j < 4; ++j)
                bvec[(size_t)t * 16 + c0 + j] = 2.f / (1.f + expf(-tot[j]));
        } else {
#pragma unroll
            for (int j = 0; j < 4; ++j) {
                float a = tot[j] + dtb[c0 + j];
                float sp = (a > 20.f) ? a : log1pf(expf(a));
                gvec[(size_t)t * 16 + c0 + j] = -expf(A_log[c0 + j]) * sp;
            }
        }
    }
}

// ---------------- phase 1 (MFMA): per (chunk, head) WY-transform prep ----------------
__global__ __launch_bounds__(256) void phase1_mfma(
    const float* __restrict__ qpost, const float* __restrict__ kpost,
    const float* __restrict__ vpost, const float* __restrict__ gvec,
    const float* __restrict__ bvec,
    float* __restrict__ u_ws, float* __restrict__ w_ws,
    float* __restrict__ qg_ws, float* __restrict__ kd_ws,
    float* __restrict__ at_ws, float* __restrict__ gl_ws) {
    int n = blockIdx.x, h = blockIdx.y;
    int t0 = n * CHUNKN;
    int tid = threadIdx.x;
    int wave = tid >> 6, lane = tid & 63;
    size_t base = (size_t)(h * NCHUNK + n);

    __shared__ __align__(16) unsigned short QKb[128 * 104];
    __shared__ __align__(16) unsigned short Ab[64 * 104];
    __shared__ __align__(16) unsigned short Atb[64 * 104];
    __shared__ __align__(16) unsigned short Pb[64 * 104];
    __shared__ __align__(16) unsigned short Ptb[64 * 104];
    __shared__ float Pf[64 * 68];
    __shared__ __align__(16) unsigned short RHSw[96 * 72];
    __shared__ __align__(16) unsigned short RHSv[192 * 72];
    __shared__ float gr_s[64], gc_s[64], be_s[64];

    if (tid < 64) {
        gr_s[tid] = gvec[(size_t)(t0 + tid) * HVN + h];
        be_s[tid] = bvec[(size_t)(t0 + tid) * HVN + h];
    }
    __syncthreads();
    if (tid < 64) {
        float sacc = 0.f;
        for (int j = 0; j <= tid; ++j) sacc += gr_s[j];
        gc_s[tid] = sacc;
    }
    __syncthreads();
    float gl = gc_s[63];

    int r = tid >> 2, sub = tid & 3;
    {
        const float* kp = kpost + (size_t)(t0 + r) * KDIMN + h * DKN + sub * 24;
        float kreg[24];
        float ss = 0.f;
#pragma unroll
        for (int i = 0; i < 6; ++i) {
            float4 v = *(const float4*)(kp + i * 4);
            kreg[i * 4 + 0] = v.x; kreg[i * 4 + 1] = v.y; kreg[i * 4 + 2] = v.z; kreg[i * 4 + 3] = v.w;
            ss += v.x * v.x + v.y * v.y + v.z * v.z + v.w * v.w;
        }
        ss += __shfl_xor(ss, 1, 64);
        ss += __shfl_xor(ss, 2, 64);
        float nrm = rsqrtf(ss + EPSF);
        float gcr = gc_s[r];
        float egl = expf(gl - gcr);
        float ebg = be_s[r] * expf(gcr);
        float* kdp = kd_ws + base * (64 * 96) + r * 96 + sub * 24;
#pragma unroll
        for (int i = 0; i < 24; ++i) {
            float kn = kreg[i] * nrm;
            QKb[r * 104 + sub * 24 + i] = f2bf(kn);
            kdp[i] = kn * egl;
            RHSw[(sub * 24 + i) * 72 + r] = f2bf(kn * ebg);
        }
    }
    {
        const float* qp = qpost + (size_t)(t0 + r) * KDIMN + h * DKN + sub * 24;
        float qreg[24];
        float ss = 0.f;
#pragma unroll
        for (int i = 0; i < 6; ++i) {
            float4 v = *(const float4*)(qp + i * 4);
            qreg[i * 4 + 0] = v.x; qreg[i * 4 + 1] = v.y; qreg[i * 4 + 2] = v.z; qreg[i * 4 + 3] = v.w;
            ss += v.x * v.x + v.y * v.y + v.z * v.z + v.w * v.w;
        }
        ss += __shfl_xor(ss, 1, 64);
        ss += __shfl_xor(ss, 2, 64);
        float nrm = rsqrtf(ss + EPSF) * 0.10206207261596577f;
        float eg = expf(gc_s[r]);
        float* qgp = qg_ws + base * (64 * 96) + r * 96 + sub * 24;
#pragma unroll
        for (int i = 0; i < 24; ++i) {
            float qn = qreg[i] * nrm;
            QKb[(64 + r) * 104 + sub * 24 + i] = f2bf(qn);
            qgp[i] = qn * eg;
        }
    }
    {
        const float* vp = vpost + (size_t)(t0 + r) * VDIMN + h * DVN + sub * 48;
        float ber = be_s[r];
#pragma unroll
        for (int i = 0; i < 12; ++i) {
            float4 v = *(const float4*)(vp + i * 4);
            int d = sub * 48 + i * 4;
            RHSv[(d + 0) * 72 + r] = f2bf(v.x * ber);
            RHSv[(d + 1) * 72 + r] = f2bf(v.y * ber);
            RHSv[(d + 2) * 72 + r] = f2bf(v.z * ber);
            RHSv[(d + 3) * 72 + r] = f2bf(v.w * ber);
        }
    }
    __syncthreads();

    {
        f32x4 acc1[2][4] = {};
#pragma unroll
        for (int ks = 0; ks < 3; ++ks) {
            int ko = ks * 32 + (lane >> 4) * 8;
            short8 af[2], bfv[4];
#pragma unroll
            for (int rt2 = 0; rt2 < 2; ++rt2)
                af[rt2] = *(const short8*)&QKb[(wave * 32 + rt2 * 16 + (lane & 15)) * 104 + ko];
#pragma unroll
            for (int ct = 0; ct < 4; ++ct)
                bfv[ct] = *(const short8*)&QKb[(ct * 16 + (lane & 15)) * 104 + ko];
#pragma unroll
            for (int rt2 = 0; rt2 < 2; ++rt2)
#pragma unroll
                for (int ct = 0; ct < 4; ++ct)
                    acc1[rt2][ct] = __builtin_amdgcn_mfma_f32_16x16x32_bf16(af[rt2], bfv[ct], acc1[rt2][ct], 0, 0, 0);
        }
#pragma unroll
        for (int rt2 = 0; rt2 < 2; ++rt2)
#pragma unroll
            for (int ct = 0; ct < 4; ++ct)
#pragma unroll
                for (int j = 0; j < 4; ++j) {
                    int rr = wave * 32 + rt2 * 16 + (lane >> 4) * 4 + j;
                    int cc = ct * 16 + (lane & 15);
                    float val = acc1[rt2][ct][j];
                    if (rr < 64) {
                        float av = (rr > cc) ? -be_s[rr] * expf(gc_s[rr] - gc_s[cc]) * val : 0.f;
                        unsigned short ab = f2bf(av);
                        Ab[rr * 104 + cc] = ab;
                        Atb[cc * 104 + rr] = ab;
                        float pv = (rr == cc) ? 1.f : av;
                        Pf[rr * 68 + cc] = pv;
                        unsigned short pb = f2bf(pv);
                        Pb[rr * 104 + cc] = pb;
                        Ptb[cc * 104 + rr] = pb;
                    } else {
                        int ar = rr - 64;
                        float av = (ar >= cc) ? expf(gc_s[ar] - gc_s[cc]) * val : 0.f;
                        at_ws[base * (64 * 64) + ar * 64 + cc] = av;
                    }
                }
    }
    __syncthreads();

#pragma unroll 1
    for (int lev = 0; lev < 5; ++lev) {
        f32x4 d[4] = {};
#pragma unroll
        for (int ks = 0; ks < 2; ++ks) {
            int ko = ks * 32 + (lane >> 4) * 8;
            short8 a0 = *(const short8*)&Ab[(wave * 16 + (lane & 15)) * 104 + ko];
#pragma unroll
            for (int ct = 0; ct < 4; ++ct) {
                short8 b0 = *(const short8*)&Atb[(ct * 16 + (lane & 15)) * 104 + ko];
                d[ct] = __builtin_amdgcn_mfma_f32_16x16x32_bf16(a0, b0, d[ct], 0, 0, 0);
            }
        }
        __syncthreads();
#pragma unroll
        for (int ct = 0; ct < 4; ++ct)
#pragma unroll
            for (int j = 0; j < 4; ++j) {
                int rr = wave * 16 + (lane >> 4) * 4 + j;
                int cc = ct * 16 + (lane & 15);
                unsigned short hb = f2bf(d[ct][j]);
                Ab[rr * 104 + cc] = hb;
                Atb[cc * 104 + rr] = hb;
            }
        __syncthreads();
        f32x4 e[4];
#pragma unroll
        for (int ct = 0; ct < 4; ++ct)
#pragma unroll
            for (int j = 0; j < 4; ++j)
                e[ct][j] = Pf[(wave * 16 + (lane >> 4) * 4 + j) * 68 + ct * 16 + (lane & 15)];
#pragma unroll
        for (int ks = 0; ks < 2; ++ks) {
            int ko = ks * 32 + (lane >> 4) * 8;
            short8 a0 = *(const short8*)&Ab[(wave * 16 + (lane & 15)) * 104 + ko];
#pragma unroll
            for (int ct = 0; ct < 4; ++ct) {
                short8 b0 = *(const short8*)&Ptb[(ct * 16 + (lane & 15)) * 104 + ko];
                e[ct] = __builtin_amdgcn_mfma_f32_16x16x32_bf16(a0, b0, e[ct], 0, 0, 0);
            }
        }
        __syncthreads();
#pragma unroll
        for (int ct = 0; ct < 4; ++ct)
#pragma unroll
            for (int j = 0; j < 4; ++j) {
                int rr = wave * 16 + (lane >> 4) * 4 + j;
                int cc = ct * 16 + (lane & 15);
                float pv = e[ct][j];
                Pf[rr * 68 + cc] = pv;
                unsigned short pb = f2bf(pv);
                Pb[rr * 104 + cc] = pb;
                Ptb[cc * 104 + rr] = pb;
            }
        __syncthreads();
    }

#pragma unroll 1
    for (int i = 0; i < 18; ++i) {
        int id = wave * 18 + i;
        int rt = id & 3, ct = id >> 2;
        f32x4 o4 = {};
#pragma unroll
        for (int ks = 0; ks < 2; ++ks) {
            int ko = ks * 32 + (lane >> 4) * 8;
            short8 a0 = *(const short8*)&Pb[(rt * 16 + (lane & 15)) * 104 + ko];
            short8 b0 = (ct < 12)
                ? *(const short8*)&RHSv[(ct * 16 + (lane & 15)) * 72 + ko]
                : *(const short8*)&RHSw[((ct - 12) * 16 + (lane & 15)) * 72 + ko];
            o4 = __builtin_amdgcn_mfma_f32_16x16x32_bf16(a0, b0, o4, 0, 0, 0);
        }
#pragma unroll
        for (int j = 0; j < 4; ++j) {
            int rr = rt * 16 + (lane >> 4) * 4 + j;
            int nn = ct * 16 + (lane & 15);
            if (ct < 12) u_ws[base * (64 * 192) + rr * 192 + nn] = o4[j];
            else         w_ws[base * (64 * 96) + rr * 96 + (nn - 192)] = o4[j];
        }
    }
    if (tid == 0) gl_ws[base] = gl;
}

// ---------------- tprep: T_n = e^gl I - kd^T w (bf16, stride-104 padded), Ct = u^T kd (f32) ----------------
__global__ __launch_bounds__(256) void tprep(const float* __restrict__ u_ws, const float* __restrict__ w_ws,
                                             const float* __restrict__ kd_ws, const float* __restrict__ gl_ws,
                                             float* __restrict__ Ct, unsigned short* __restrict__ Tn) {
    int n = blockIdx.x, h = blockIdx.y;
    size_t base = (size_t)(h * NCHUNK + n);
    int tid = threadIdx.x, wave = tid >> 6, lane = tid & 63;
    __shared__ __align__(16) unsigned short kdT[96 * 72];
    __shared__ __align__(16) unsigned short wT[96 * 72];
    __shared__ __align__(16) unsigned short uT[192 * 72];
    const float* kdp = kd_ws + base * (64 * 96);
    const float* wp  = w_ws + base * (64 * 96);
    const float* up  = u_ws + base * (64 * 192);
    for (int f = tid; f < 1536; f += 256) {
        int t = f / 24, c4 = (f % 24) * 4;
        float4 kv = *(const float4*)(kdp + t * 96 + c4);
        float4 wv = *(const float4*)(wp + t * 96 + c4);
        kdT[(c4 + 0) * 72 + t] = f2bf(kv.x); kdT[(c4 + 1) * 72 + t] = f2bf(kv.y);
        kdT[(c4 + 2) * 72 + t] = f2bf(kv.z); kdT[(c4 + 3) * 72 + t] = f2bf(kv.w);
        wT[(c4 + 0) * 72 + t] = f2bf(wv.x); wT[(c4 + 1) * 72 + t] = f2bf(wv.y);
        wT[(c4 + 2) * 72 + t] = f2bf(wv.z); wT[(c4 + 3) * 72 + t] = f2bf(wv.w);
    }
    for (int f = tid; f < 3072; f += 256) {
        int t = f / 48, c4 = (f % 48) * 4;
        float4 uv = *(const float4*)(up + t * 192 + c4);
        uT[(c4 + 0) * 72 + t] = f2bf(uv.x); uT[(c4 + 1) * 72 + t] = f2bf(uv.y);
        uT[(c4 + 2) * 72 + t] = f2bf(uv.z); uT[(c4 + 3) * 72 + t] = f2bf(uv.w);
    }
    __syncthreads();
    float egl = expf(gl_ws[base]);
#pragma unroll 1
    for (int q = 0; q < 27; ++q) {
        int id = wave * 27 + q;
        f32x4 acc = {};
        if (id < 36) {
            int jt = id / 6, kt = id % 6;
#pragma unroll
            for (int ks = 0; ks < 2; ++ks) {
                int ko = ks * 32 + (lane >> 4) * 8;
                short8 a0 = *(const short8*)&kdT[(jt * 16 + (lane & 15)) * 72 + ko];
                short8 b0 = *(const short8*)&wT[(kt * 16 + (lane & 15)) * 72 + ko];
                acc = __builtin_amdgcn_mfma_f32_16x16x32_bf16(a0, b0, acc, 0, 0, 0);
            }
#pragma unroll
            for (int r = 0; r < 4; ++r) {
                int j = jt * 16 + (lane >> 4) * 4 + r;
                int k = kt * 16 + (lane & 15);
                float val = -acc[r];
                if (j == k) val += egl;
                Tn[base * TN_STRIDE + j * 104 + k] = f2bf(val);
            }
        } else {
            int cid = id - 36;
            int it = cid / 6, jt = cid % 6;
#pragma unroll
            for (int ks = 0; ks < 2; ++ks) {
                int ko = ks * 32 + (lane >> 4) * 8;
                short8 a0 = *(const short8*)&uT[(it * 16 + (lane & 15)) * 72 + ko];
                short8 b0 = *(const short8*)&kdT[(jt * 16 + (lane & 15)) * 72 + ko];
                acc = __builtin_amdgcn_mfma_f32_16x16x32_bf16(a0, b0, acc, 0, 0, 0);
            }
#pragma unroll
            for (int r = 0; r < 4; ++r)
                Ct[base * 18432 + (size_t)(it * 16 + (lane >> 4) * 4 + r) * 96 + jt * 16 + (lane & 15)] = acc[r];
        }
    }
}

// ---------------- mscan: St_{n+1} = St_n @ T_n^T + Ct_n ----------------
__global__ __launch_bounds__(128) void mscan(const float* __restrict__ Ct, const unsigned short* __restrict__ Tn,
                                             float* __restrict__ s_ws) {
    int rg = blockIdx.x, h = blockIdx.y;
    int tid = threadIdx.x, wave = tid >> 6, lane = tid & 63;
    __shared__ __align__(16) unsigned short St[48 * 104];
    __shared__ __align__(16) unsigned short TnB[2][TN_STRIDE];
    __shared__ __align__(16) float CtB[2][48 * 96];
    for (int i = tid; i < 48 * 104; i += 128) St[i] = 0;

    {
        const float* cp = Ct + (size_t)(h * NCHUNK) * 18432 + rg * (48 * 96);
        const unsigned short* tp = Tn + (size_t)(h * NCHUNK) * TN_STRIDE;
#pragma unroll
        for (int q = 0; q < 9; ++q) {
            size_t o = (size_t)(wave * 9 + q) * 1024 + lane * 16;
            gld_lds16((const char*)cp + o, (char*)&CtB[0][0] + (size_t)(wave * 9 + q) * 1024);
        }
#pragma unroll
        for (int q = 0; q < 10; ++q) {
            size_t o = (size_t)(wave * 10 + q) * 1024 + lane * 16;
            gld_lds16((const char*)tp + o, (char*)&TnB[0][0] + (size_t)(wave * 10 + q) * 1024);
        }
    }
    f32x4 acc[3][3] = {};
    int colw = wave * 48;
    __syncthreads();

#pragma unroll 1
    for (int n = 0; n < NCHUNK; ++n) {
        size_t base = (size_t)(h * NCHUNK + n);
        int cur = n & 1;
        if (n + 1 < NCHUNK) {
            const float* cp = Ct + (base + 1) * 18432 + rg * (48 * 96);
            const unsigned short* tp = Tn + (base + 1) * TN_STRIDE;
#pragma unroll
            for (int q = 0; q < 9; ++q) {
                size_t o = (size_t)(wave * 9 + q) * 1024 + lane * 16;
                gld_lds16((const char*)cp + o, (char*)&CtB[cur ^ 1][0] + (size_t)(wave * 9 + q) * 1024);
            }
#pragma unroll
            for (int q = 0; q < 10; ++q) {
                size_t o = (size_t)(wave * 10 + q) * 1024 + lane * 16;
                gld_lds16((const char*)tp + o, (char*)&TnB[cur ^ 1][0] + (size_t)(wave * 10 + q) * 1024);
            }
        }
        float* sp = s_ws + base * 18432 + rg * (48 * 96);
#pragma unroll
        for (int it = 0; it < 3; ++it)
#pragma unroll
            for (int jt = 0; jt < 3; ++jt) {
                int irow = it * 16 + (lane >> 4) * 4;
                int col = colw + jt * 16 + (lane & 15);
#pragma unroll
                for (int r = 0; r < 4; ++r) {
                    sp[(size_t)(irow + r) * 96 + col] = acc[it][jt][r];
                    acc[it][jt][r] = CtB[cur][(irow + r) * 96 + col];
                }
            }
#pragma unroll
        for (int ks = 0; ks < 3; ++ks) {
            int ko = ks * 32 + (lane >> 4) * 8;
            short8 af[3], bfv[3];
#pragma unroll
            for (int it = 0; it < 3; ++it)
                af[it] = *(const short8*)&St[(it * 16 + (lane & 15)) * 104 + ko];
#pragma unroll
            for (int jt = 0; jt < 3; ++jt)
                bfv[jt] = *(const short8*)&TnB[cur][(colw + jt * 16 + (lane & 15)) * 104 + ko];
#pragma unroll
            for (int it = 0; it < 3; ++it)
#pragma unroll
                for (int jt = 0; jt < 3; ++jt)
                    acc[it][jt] = __builtin_amdgcn_mfma_f32_16x16x32_bf16(af[it], bfv[jt], acc[it][jt], 0, 0, 0);
        }
        __syncthreads();
#pragma unroll
        for (int it = 0; it < 3; ++it)
#pragma unroll
            for (int jt = 0; jt < 3; ++jt)
#pragma unroll
                for (int r = 0; r < 4; ++r)
                    St[(it * 16 + (lane >> 4) * 4 + r) * 104 + colw + jt * 16 + (lane & 15)] = f2bf(acc[it][jt][r]);
        __syncthreads();
    }
}

// ---------------- phase2b (MFMA): vnT = uT + St@(-w)^T ; oT = St@qg^T + vnT@at^T ----------------
#define P2_ST 0
#define P2_W  39936
#define P2_QG 53248
#define P2_AT 66560
#define P2_U  75776
#define P2_VN 125952
__global__ __launch_bounds__(256) void phase2b_mfma(const float* __restrict__ s_ws, const float* __restrict__ w_ws,
                                                    const float* __restrict__ qg_ws, const float* __restrict__ at_ws,
                                                    const float* __restrict__ u_ws, float* __restrict__ o_ws) {
    __shared__ __align__(16) char LB[153600];
    unsigned short* StB = (unsigned short*)(LB + P2_ST);
    unsigned short* wB  = (unsigned short*)(LB + P2_W);
    unsigned short* qgB = (unsigned short*)(LB + P2_QG);
    unsigned short* atB = (unsigned short*)(LB + P2_AT);
    float* uF           = (float*)(LB + P2_U);
    unsigned short* vnB = (unsigned short*)(LB + P2_VN);
    int n = blockIdx.x, h = blockIdx.y;
    size_t base = (size_t)(h * NCHUNK + n);
    int tid = threadIdx.x, wave = tid >> 6, lane = tid & 63;
    int i0w = wave * 48;
    {
        const float* sp = s_ws + base * 18432;
        for (int f = tid; f < 4608; f += 256) {
            int i = f / 24, c4 = (f % 24) * 4;
            float4 v = *(const float4*)(sp + i * 96 + c4);
            ushort4 o4; o4.x = f2bf(v.x); o4.y = f2bf(v.y); o4.z = f2bf(v.z); o4.w = f2bf(v.w);
            *(ushort4*)&StB[i * 104 + c4] = o4;
        }
    }
    {
        const float* wp = w_ws + base * 6144;
        const float* qp = qg_ws + base * 6144;
        for (int f = tid; f < 1536; f += 256) {
            int t = f / 24, c4 = (f % 24) * 4;
            float4 wv = *(const float4*)(wp + t * 96 + c4);
            float4 qv = *(const float4*)(qp + t * 96 + c4);
            ushort4 ow; ow.x = f2bf(-wv.x); ow.y = f2bf(-wv.y); ow.z = f2bf(-wv.z); ow.w = f2bf(-wv.w);
            ushort4 oq; oq.x = f2bf(qv.x); oq.y = f2bf(qv.y); oq.z = f2bf(qv.z); oq.w = f2bf(qv.w);
            *(ushort4*)&wB[t * 104 + c4] = ow;
            *(ushort4*)&qgB[t * 104 + c4] = oq;
        }
    }
    {
        const float* ap = at_ws + base * 4096;
        for (int f = tid; f < 1024; f += 256) {
            int t = f / 16, c4 = (f % 16) * 4;
            float4 av = *(const float4*)(ap + t * 64 + c4);
            ushort4 oa; oa.x = f2bf(av.x); oa.y = f2bf(av.y); oa.z = f2bf(av.z); oa.w = f2bf(av.w);
            *(ushort4*)&atB[t * 72 + c4] = oa;
        }
    }
    {
        const float* up = u_ws + base * 12288;
        for (int f = tid; f < 3072; f += 256) {
            int t = f / 48, c4 = (f % 48) * 4;
            *(float4*)&uF[t * 196 + c4] = *(const float4*)(up + t * 192 + c4);
        }
    }
    __syncthreads();
    {
        f32x4 acc[3][4];
#pragma unroll
        for (int it = 0; it < 3; ++it)
#pragma unroll
            for (int jt = 0; jt < 4; ++jt)
#pragma unroll
                for (int r = 0; r < 4; ++r)
                    acc[it][jt][r] = uF[(jt * 16 + (lane & 15)) * 196 + i0w + it * 16 + (lane >> 4) * 4 + r];
#pragma unroll
        for (int ks = 0; ks < 3; ++ks) {
            int ko = ks * 32 + (lane >> 4) * 8;
            short8 af[3], bfv[4];
#pragma unroll
            for (int it = 0; it < 3; ++it)
                af[it] = *(const short8*)&StB[(i0w + it * 16 + (lane & 15)) * 104 + ko];
#pragma unroll
            for (int jt = 0; jt < 4; ++jt)
                bfv[jt] = *(const short8*)&wB[(jt * 16 + (lane & 15)) * 104 + ko];
#pragma unroll
            for (int it = 0; it < 3; ++it)
#pragma unroll
                for (int jt = 0; jt < 4; ++jt)
                    acc[it][jt] = __builtin_amdgcn_mfma_f32_16x16x32_bf16(af[it], bfv[jt], acc[it][jt], 0, 0, 0);
        }
#pragma unroll
        for (int it = 0; it < 3; ++it)
#pragma unroll
            for (int jt = 0; jt < 4; ++jt)
#pragma unroll
                for (int r = 0; r < 4; ++r)
                    vnB[(i0w + it * 16 + (lane >> 4) * 4 + r) * 72 + jt * 16 + (lane & 15)] = f2bf(acc[it][jt][r]);
    }
    f32x4 acc2[3][4] = {};
#pragma unroll
    for (int ks = 0; ks < 3; ++ks) {
        int ko = ks * 32 + (lane >> 4) * 8;
        short8 af[3], bfv[4];
#pragma unroll
        for (int it = 0; it < 3; ++it)
            af[it] = *(const short8*)&StB[(i0w + it * 16 + (lane & 15)) * 104 + ko];
#pragma unroll
        for (int jt = 0; jt < 4; ++jt)
            bfv[jt] = *(const short8*)&qgB[(jt * 16 + (lane & 15)) * 104 + ko];
#pragma unroll
        for (int it = 0; it < 3; ++it)
#pragma unroll
            for (int jt = 0; jt < 4; ++jt)
                acc2[it][jt] = __builtin_amdgcn_mfma_f32_16x16x32_bf16(af[it], bfv[jt], acc2[it][jt], 0, 0, 0);
    }
#pragma unroll
    for (int ks = 0; ks < 2; ++ks) {
        int ko = ks * 32 + (lane >> 4) * 8;
        short8 af[3], bfv[4];
#pragma unroll
        for (int it = 0; it < 3; ++it)
            af[it] = *(const short8*)&vnB[(i0w + it * 16 + (lane & 15)) * 72 + ko];
#pragma unroll
        for (int jt = 0; jt < 4; ++jt)
            bfv[jt] = *(const short8*)&atB[(jt * 16 + (lane & 15)) * 72 + ko];
#pragma unroll
        for (int it = 0; it < 3; ++it)
#pragma unroll
            for (int jt = 0; jt < 4; ++jt)
                acc2[it][jt] = __builtin_amdgcn_mfma_f32_16x16x32_bf16(af[it], bfv[jt], acc2[it][jt], 0, 0, 0);
    }
    __syncthreads();
    float* oF = (float*)(LB + 0); // [192][68]
#pragma unroll
    for (int it = 0; it < 3; ++it)
#pragma unroll
        for (int jt = 0; jt < 4; ++jt)
#pragma unroll
            for (int r = 0; r < 4; ++r)
                oF[(i0w + it * 16 + (lane >> 4) * 4 + r) * 68 + jt * 16 + (lane & 15)] = acc2[it][jt][r];
    __syncthreads();
    int t0 = n * CHUNKN;
    for (int f = tid; f < 3072; f += 256) {
        int t = f / 48, c4 = (f % 48) * 4;
        float4 ov;
        ov.x = oF[(c4 + 0) * 68 + t];
        ov.y = oF[(c4 + 1) * 68 + t];
        ov.z = oF[(c4 + 2) * 68 + t];
        ov.w = oF[(c4 + 3) * 68 + t];
        *(float4*)(o_ws + (size_t)(t0 + t) * VDIMN + h * DVN + c4) = ov;
    }
}

// ---------------- gate (SiLU) + RMSNorm -> bf16 ----------------
__global__ __launch_bounds__(64) void gate_norm(const float* __restrict__ o_ws, const float* __restrict__ Cgate,
                                                const float* __restrict__ nw, unsigned short* __restrict__ obf) {
    int b = blockIdx.x;
    int t = b >> 4, h = b & 15;
    int lane = threadIdx.x;
    float x[3];
    float ss = 0.f;
    size_t ob = (size_t)t * VDIMN + h * DVN;
    for (int j = 0; j < 3; ++j) {
        int d = j * 64 + lane;
        float ov = o_ws[ob + d];
        float gv = Cgate[ob + d];
        float xv = ov * siluf(gv);
        x[j] = xv;
        ss += xv * xv;
    }
    for (int off = 32; off > 0; off >>= 1) ss += __shfl_xor(ss, off, 64);
    float r = rsqrtf(ss * (1.f / 192.f) + EPSF);
    for (int j = 0; j < 3; ++j) {
        int d = j * 64 + lane;
        obf[ob + d] = f2bf(x[j] * r * nw[d]);
    }
}

extern "C" void kernel_launch(void* const* d_in, const int* in_sizes, int n_in,
                              void* d_out, int out_size, void* d_ws, size_t ws_size,
                              hipStream_t stream) {
    (void)in_sizes; (void)n_in; (void)out_size;
    const float* X    = (const float*)d_in[0];
    const float* Wq   = (const float*)d_in[1];
    const float* Wk   = (const float*)d_in[2];
    const float* Wv   = (const float*)d_in[3];
    const float* Wb   = (const float*)d_in[4];
    const float* Wa   = (const float*)d_in[5];
    const float* Wg   = (const float*)d_in[6];
    const float* Wo   = (const float*)d_in[7];
    const float* cq   = (const float*)d_in[8];
    const float* ck   = (const float*)d_in[9];
    const float* cv   = (const float*)d_in[10];
    const float* Alog = (const float*)d_in[11];
    const float* dtb  = (const float*)d_in[12];
    const float* nw   = (const float*)d_in[13];

    const size_t OFF_XBF   = 0;
    const size_t OFF_WALLT = 8388608;
    const size_t OFF_WOT   = 46137344;
    const size_t OFF_CQKV  = 58720256;
    const size_t OFF_CGATE = 109051904;
    const size_t OFF_QPOST = 134217728;
    const size_t OFF_KPOST = 146800640;
    const size_t OFF_VPOST = 159383552;
    const size_t OFF_GVEC  = 184549376;
    const size_t OFF_BVEC  = 184680448;
    const size_t OFF_GL    = 184811520;
    const size_t OFF_U     = 184819712;
    const size_t OFF_W     = 209985536;
    const size_t OFF_QG    = 222568448;
    const size_t OFF_KD    = 235151360;
    const size_t OFF_AT    = OFF_XBF;               // 8.39 MB exact (after proj gemm)
    const size_t OFF_CT    = OFF_CQKV;              // Ct 37.7 MB (after conv)
    const size_t OFF_TN    = OFF_CQKV + 37748736;   // Tn 10.5 MB
    const size_t OFF_S     = OFF_QPOST;             // s_ws 37.7 MB (after phase1)
    const size_t OFF_O     = OFF_WALLT;             // o_ws 25.2 MB (after gemms)
    const size_t OFF_OBF   = OFF_WALLT + 25165824;  // obf 12.6 MB
    const size_t OFF_OPART = OFF_CQKV;              // split-K partials 2x16.78=33.6 MB (after phase2b)
    const size_t NEEDED    = 247734272;
    if (ws_size < NEEDED) return;

    char* ws = (char*)d_ws;
    unsigned short* Xbf   = (unsigned short*)(ws + OFF_XBF);
    unsigned short* WallT = (unsigned short*)(ws + OFF_WALLT);
    unsigned short* WoT   = (unsigned short*)(ws + OFF_WOT);
    float* Cqkv  = (float*)(ws + OFF_CQKV);
    float* Cgate = (float*)(ws + OFF_CGATE);
    float* qpost = (float*)(ws + OFF_QPOST);
    float* kpost = (float*)(ws + OFF_KPOST);
    float* vpost = (float*)(ws + OFF_VPOST);
    float* gvec  = (float*)(ws + OFF_GVEC);
    float* bvec  = (float*)(ws + OFF_BVEC);
    float* gl_ws = (float*)(ws + OFF_GL);
    float* u_ws  = (float*)(ws + OFF_U);
    float* w_ws  = (float*)(ws + OFF_W);
    float* qg_ws = (float*)(ws + OFF_QG);
    float* kd_ws = (float*)(ws + OFF_KD);
    float* at_ws = (float*)(ws + OFF_AT);
    float* Ct    = (float*)(ws + OFF_CT);
    unsigned short* Tn = (unsigned short*)(ws + OFF_TN);
    float* s_ws  = (float*)(ws + OFF_S);
    float* o_ws  = (float*)(ws + OFF_O);
    unsigned short* obf = (unsigned short*)(ws + OFF_OBF);
    float* opart = (float*)(ws + OFF_OPART);

    cast_f32_bf16<<<4096, 256, 0, stream>>>(X, Xbf, 2048 * 2048);
    dim3 tb(64, 4);
    transpose_cast<<<dim3(1536 / 64, 2048 / 64), tb, 0, stream>>>(Wq, WallT, 2048, 1536);
    transpose_cast<<<dim3(1536 / 64, 2048 / 64), tb, 0, stream>>>(Wk, WallT + (size_t)1536 * 2048, 2048, 1536);
    transpose_cast<<<dim3(3072 / 64, 2048 / 64), tb, 0, stream>>>(Wv, WallT + (size_t)3072 * 2048, 2048, 3072);
    transpose_cast<<<dim3(3072 / 64, 2048 / 64), tb, 0, stream>>>(Wg, WallT + (size_t)6144 * 2048, 2048, 3072);
    transpose_cast<<<dim3(2048 / 64, 3072 / 64), tb, 0, stream>>>(Wo, WoT, 3072, 2048);

    // fused QKV + gate projection: 1152 blocks (4.5 blocks/CU)
    gemm_bt2<<<dim3(9216 / 128, 2048 / 128), 256, 0, stream>>>(Xbf, WallT,
                                                               Cqkv, QKVD, QKVD / 128,
                                                               Cgate, VDIMN, 2048, 2048);

    conv_silu<<<dim3(6, T_LEN), 256, 0, stream>>>(Cqkv + 0, QKVD, cq, qpost, KDIMN);
    conv_silu<<<dim3(6, T_LEN), 256, 0, stream>>>(Cqkv + 1536, QKVD, ck, kpost, KDIMN);
    conv_silu<<<dim3(12, T_LEN), 256, 0, stream>>>(Cqkv + 3072, QKVD, cv, vpost, VDIMN);
    beta_g<<<T_LEN, 256, 0, stream>>>(X, Wb, Wa, Alog, dtb, bvec, gvec);

    phase1_mfma<<<dim3(NCHUNK, HVN), 256, 0, stream>>>(qpost, kpost, vpost, gvec, bvec,
                                                       u_ws, w_ws, qg_ws, kd_ws, at_ws, gl_ws);
    tprep<<<dim3(NCHUNK, HVN), 256, 0, stream>>>(u_ws, w_ws, kd_ws, gl_ws, Ct, Tn);
    mscan<<<dim3(4, HVN), 128, 0, stream>>>(Ct, Tn, s_ws);
    phase2b_mfma<<<dim3(NCHUNK, HVN), 256, 0, stream>>>(s_ws, w_ws, qg_ws, at_ws, u_ws, o_ws);

    gate_norm<<<T_LEN * HVN, 64, 0, stream>>>(o_ws, Cgate, nw, obf);

    // output GEMM split-K=3 (768 blocks, 3/CU) + deterministic fixup
    gemm_btk<<<dim3(2048 / 128, 2048 / 128, 3), 256, 0, stream>>>(obf, WoT, (float*)d_out, opart,
                                                                  2048, 2048, 3072);
    addk<<<4096, 256, 0, stream>>>((float*)d_out, opart, 2048 * 2048);
}

// Round 10
// 486.854 us; speedup vs baseline: 1.6507x; 1.0464x over previous
//
#include <hip/hip_runtime.h>
#include <math.h>

#define T_LEN 2048
#define HIDN  2048
#define HKN   16
#define DKN   96
#define HVN   16
#define DVN   192
#define KDIMN 1536
#define VDIMN 3072
#define QKVD  6144   // q(1536)+k(1536)+v(3072)
#define CHUNKN 64
#define NCHUNK 32
#define EPSF 1e-6f
#define TN_STRIDE 10240   // ushorts per (chunk,head) Tn record: 96 rows * 104 + pad -> 20480 B

typedef __attribute__((ext_vector_type(8))) short short8;
typedef __attribute__((ext_vector_type(4))) float f32x4;

__device__ __forceinline__ unsigned short f2bf(float f) {
    unsigned int u = __float_as_uint(f);
    unsigned int r = (u + 0x7FFFu + ((u >> 16) & 1u)) >> 16;
    return (unsigned short)r;
}
__device__ __forceinline__ float bf2f(unsigned short u) {
    return __uint_as_float(((unsigned int)u) << 16);
}
__device__ __forceinline__ float siluf(float x) { return x / (1.f + expf(-x)); }

__device__ __forceinline__ void gld_lds16(const void* g, void* l) {
    __builtin_amdgcn_global_load_lds((const __attribute__((address_space(1))) unsigned int*)g,
                                     (__attribute__((address_space(3))) unsigned int*)l, 16, 0, 0);
}

// ---------------- cast f32 -> bf16 (4/thread) ----------------
__global__ void cast_f32_bf16(const float* __restrict__ in, unsigned short* __restrict__ out, int n) {
    int i = (blockIdx.x * blockDim.x + threadIdx.x) * 4;
    if (i >= n) return;
    float4 v = *(const float4*)(in + i);
    ushort4 o;
    o.x = f2bf(v.x); o.y = f2bf(v.y); o.z = f2bf(v.z); o.w = f2bf(v.w);
    *(ushort4*)(out + i) = o;
}

// ---------------- transpose + cast: W[K][N] -> Wt[N][K] bf16 ----------------
__global__ void transpose_cast(const float* __restrict__ W, unsigned short* __restrict__ Wt,
                               int K, int N) {
    __shared__ float tile[64][65];
    int k0 = blockIdx.y * 64, n0 = blockIdx.x * 64;
    int tx = threadIdx.x, ty = threadIdx.y; // (64,4)
    for (int r = ty; r < 64; r += 4) tile[r][tx] = W[(size_t)(k0 + r) * N + n0 + tx];
    __syncthreads();
    for (int r = ty; r < 64; r += 4) Wt[(size_t)(n0 + r) * K + k0 + tx] = f2bf(tile[tx][r]);
}

// ---------------- fused projection GEMM, 2-phase double-buffered LDS ----------------
// C = A @ Bt^T; blocks bn<nblk1 write C1 f32 (ld1), else C2 bf16 (ld2).
// T3-minimum pipeline: stage tile i+1 into buf^1 BEFORE computing tile i; one barrier/iter.
__global__ __launch_bounds__(256) void gemm_bt2(const unsigned short* __restrict__ A,
                                                const unsigned short* __restrict__ Bt,
                                                float* __restrict__ C1, int ld1, int nblk1,
                                                unsigned short* __restrict__ C2, int ld2,
                                                int M, int K) {
    __shared__ __align__(16) unsigned short As[2][128 * 32];
    __shared__ __align__(16) unsigned short Bs[2][128 * 32];
    int tid = threadIdx.x;
    int wave = tid >> 6, lane = tid & 63;
    int bm = blockIdx.y, bn = blockIdx.x;
    f32x4 acc[4][4] = {};
    int wr = wave >> 1, wc = wave & 1;
    int rstage = wave * 32 + (lane >> 2);
    int cstage = (lane & 3) * 8;
    const size_t a_row0 = (size_t)bm * 128;
    const size_t b_row0 = (size_t)bn * 128;
    const unsigned short* gaBase = A + (a_row0 + rstage) * (size_t)K + cstage;
    const unsigned short* gbBase = Bt + (b_row0 + rstage) * (size_t)K + cstage;
    int row_a[4], row_b[4];
#pragma unroll
    for (int i = 0; i < 4; ++i) {
        row_a[i] = wr * 64 + i * 16 + (lane & 15);
        row_b[i] = wc * 64 + i * 16 + (lane & 15);
    }
    int koff = (lane >> 4) * 8;
    int niter = K >> 5;
    {
        unsigned short* ab = &As[0][wave * 1024];
        unsigned short* bb = &Bs[0][wave * 1024];
        gld_lds16(gaBase, ab);
        gld_lds16(gaBase + (size_t)16 * K, ab + 512);
        gld_lds16(gbBase, bb);
        gld_lds16(gbBase + (size_t)16 * K, bb + 512);
    }
    __syncthreads();
    for (int i = 0; i < niter; ++i) {
        int cur = i & 1;
        if (i + 1 < niter) {
            int k0 = (i + 1) * 32;
            unsigned short* ab = &As[cur ^ 1][wave * 1024];
            unsigned short* bb = &Bs[cur ^ 1][wave * 1024];
            gld_lds16(gaBase + k0, ab);
            gld_lds16(gaBase + k0 + (size_t)16 * K, ab + 512);
            gld_lds16(gbBase + k0, bb);
            gld_lds16(gbBase + k0 + (size_t)16 * K, bb + 512);
        }
        short8 af[4], bfr[4];
#pragma unroll
        for (int mi = 0; mi < 4; ++mi) af[mi] = *(const short8*)&As[cur][row_a[mi] * 32 + koff];
#pragma unroll
        for (int ni = 0; ni < 4; ++ni) bfr[ni] = *(const short8*)&Bs[cur][row_b[ni] * 32 + koff];
#pragma unroll
        for (int mi = 0; mi < 4; ++mi)
#pragma unroll
            for (int ni = 0; ni < 4; ++ni)
                acc[mi][ni] = __builtin_amdgcn_mfma_f32_16x16x32_bf16(af[mi], bfr[ni], acc[mi][ni], 0, 0, 0);
        __syncthreads();   // vmcnt(0)+lgkmcnt(0)+barrier: next buffer staged, this buffer free
    }
    if (bn < nblk1) {
        int colb = bn * 128;
#pragma unroll
        for (int mi = 0; mi < 4; ++mi) {
            int rbase = bm * 128 + wr * 64 + mi * 16 + (lane >> 4) * 4;
#pragma unroll
            for (int ni = 0; ni < 4; ++ni) {
                int col = colb + wc * 64 + ni * 16 + (lane & 15);
#pragma unroll
                for (int j = 0; j < 4; ++j)
                    C1[(size_t)(rbase + j) * ld1 + col] = acc[mi][ni][j];
            }
        }
    } else {
        int colb = (bn - nblk1) * 128;
#pragma unroll
        for (int mi = 0; mi < 4; ++mi) {
            int rbase = bm * 128 + wr * 64 + mi * 16 + (lane >> 4) * 4;
#pragma unroll
            for (int ni = 0; ni < 4; ++ni) {
                int col = colb + wc * 64 + ni * 16 + (lane & 15);
#pragma unroll
                for (int j = 0; j < 4; ++j)
                    C2[(size_t)(rbase + j) * ld2 + col] = f2bf(acc[mi][ni][j]);
            }
        }
    }
}

// ---------------- split-K GEMM (SPLIT=3), 2-phase double-buffered LDS ----------------
__global__ __launch_bounds__(256) void gemm_btk(const unsigned short* __restrict__ A,
                                                const unsigned short* __restrict__ Bt,
                                                float* __restrict__ C, float* __restrict__ Cp,
                                                int M, int N, int K) {
    __shared__ __align__(16) unsigned short As[2][128 * 32];
    __shared__ __align__(16) unsigned short Bs[2][128 * 32];
    int tid = threadIdx.x;
    int wave = tid >> 6, lane = tid & 63;
    int bm = blockIdx.y, bn = blockIdx.x, kz = blockIdx.z;
    int kchunk = K / 3;
    int kbeg = kz * kchunk;
    f32x4 acc[4][4] = {};
    int wr = wave >> 1, wc = wave & 1;
    int rstage = wave * 32 + (lane >> 2);
    int cstage = (lane & 3) * 8;
    const size_t a_row0 = (size_t)bm * 128;
    const size_t b_row0 = (size_t)bn * 128;
    const unsigned short* gaBase = A + (a_row0 + rstage) * (size_t)K + kbeg + cstage;
    const unsigned short* gbBase = Bt + (b_row0 + rstage) * (size_t)K + kbeg + cstage;
    int row_a[4], row_b[4];
#pragma unroll
    for (int i = 0; i < 4; ++i) {
        row_a[i] = wr * 64 + i * 16 + (lane & 15);
        row_b[i] = wc * 64 + i * 16 + (lane & 15);
    }
    int koff = (lane >> 4) * 8;
    int niter = kchunk >> 5;
    {
        unsigned short* ab = &As[0][wave * 1024];
        unsigned short* bb = &Bs[0][wave * 1024];
        gld_lds16(gaBase, ab);
        gld_lds16(gaBase + (size_t)16 * K, ab + 512);
        gld_lds16(gbBase, bb);
        gld_lds16(gbBase + (size_t)16 * K, bb + 512);
    }
    __syncthreads();
    for (int i = 0; i < niter; ++i) {
        int cur = i & 1;
        if (i + 1 < niter) {
            int k0 = (i + 1) * 32;
            unsigned short* ab = &As[cur ^ 1][wave * 1024];
            unsigned short* bb = &Bs[cur ^ 1][wave * 1024];
            gld_lds16(gaBase + k0, ab);
            gld_lds16(gaBase + k0 + (size_t)16 * K, ab + 512);
            gld_lds16(gbBase + k0, bb);
            gld_lds16(gbBase + k0 + (size_t)16 * K, bb + 512);
        }
        short8 af[4], bfr[4];
#pragma unroll
        for (int mi = 0; mi < 4; ++mi) af[mi] = *(const short8*)&As[cur][row_a[mi] * 32 + koff];
#pragma unroll
        for (int ni = 0; ni < 4; ++ni) bfr[ni] = *(const short8*)&Bs[cur][row_b[ni] * 32 + koff];
#pragma unroll
        for (int mi = 0; mi < 4; ++mi)
#pragma unroll
            for (int ni = 0; ni < 4; ++ni)
                acc[mi][ni] = __builtin_amdgcn_mfma_f32_16x16x32_bf16(af[mi], bfr[ni], acc[mi][ni], 0, 0, 0);
        __syncthreads();
    }
    float* Cout = (kz == 0) ? C : (Cp + (size_t)(kz - 1) * M * N);
#pragma unroll
    for (int mi = 0; mi < 4; ++mi) {
        int rbase = bm * 128 + wr * 64 + mi * 16 + (lane >> 4) * 4;
#pragma unroll
        for (int ni = 0; ni < 4; ++ni) {
            int col = bn * 128 + wc * 64 + ni * 16 + (lane & 15);
#pragma unroll
            for (int j = 0; j < 4; ++j)
                Cout[(size_t)(rbase + j) * N + col] = acc[mi][ni][j];
        }
    }
}

// ---------------- addk: out += p0 + p1 (split-K fixup, deterministic) ----------------
__global__ void addk(float* __restrict__ out, const float* __restrict__ p, int n) {
    int i = (blockIdx.x * blockDim.x + threadIdx.x) * 4;
    if (i >= n) return;
    float4 a = *(const float4*)(out + i);
    float4 b = *(const float4*)(p + i);
    float4 c = *(const float4*)(p + n + i);
    a.x += b.x + c.x; a.y += b.y + c.y; a.z += b.z + c.z; a.w += b.w + c.w;
    *(float4*)(out + i) = a;
}

// ---------------- causal depthwise conv(K=4) + SiLU ----------------
__global__ void conv_silu(const float* __restrict__ pre, int ldp,
                          const float* __restrict__ wconv, float* __restrict__ out, int C) {
    int c = blockIdx.x * blockDim.x + threadIdx.x;
    int t = blockIdx.y;
    if (c >= C) return;
    const float* wc4 = wconv + (size_t)c * 4;
    float acc = 0.f;
    if (t >= 3) acc += pre[(size_t)(t - 3) * ldp + c] * wc4[0];
    if (t >= 2) acc += pre[(size_t)(t - 2) * ldp + c] * wc4[1];
    if (t >= 1) acc += pre[(size_t)(t - 1) * ldp + c] * wc4[2];
    acc += pre[(size_t)t * ldp + c] * wc4[3];
    out[(size_t)t * C + c] = siluf(acc);
}

// ---------------- beta / g projections (f32, vectorized) ----------------
__global__ __launch_bounds__(256) void beta_g(const float* __restrict__ X,
                                              const float* __restrict__ Wb, const float* __restrict__ Wa,
                                              const float* __restrict__ A_log, const float* __restrict__ dtb,
                                              float* __restrict__ bvec, float* __restrict__ gvec) {
    int t = blockIdx.x;
    int tid = threadIdx.x;
    int cg = tid & 7, ks = tid >> 3;
    int wave = tid >> 6, lane = tid & 63;
    const float* xr = X + (size_t)t * HIDN;
    const float* Wsel = (cg < 4) ? Wb : Wa;
    int cc = (cg & 3) * 4;
    float ax = 0.f, ay = 0.f, az = 0.f, aw = 0.f;
#pragma unroll 4
    for (int i = 0; i < 16; ++i) {
        int k = (ks + 32 * i) * 4;
        float4 xv = *(const float4*)(xr + k);
        float4 w0 = *(const float4*)(Wsel + (size_t)(k + 0) * 16 + cc);
        float4 w1 = *(const float4*)(Wsel + (size_t)(k + 1) * 16 + cc);
        float4 w2 = *(const float4*)(Wsel + (size_t)(k + 2) * 16 + cc);
        float4 w3 = *(const float4*)(Wsel + (size_t)(k + 3) * 16 + cc);
        ax += xv.x * w0.x + xv.y * w1.x + xv.z * w2.x + xv.w * w3.x;
        ay += xv.x * w0.y + xv.y * w1.y + xv.z * w2.y + xv.w * w3.y;
        az += xv.x * w0.z + xv.y * w1.z + xv.z * w2.z + xv.w * w3.z;
        aw += xv.x * w0.w + xv.y * w1.w + xv.z * w2.w + xv.w * w3.w;
    }
#pragma unroll
    for (int off = 8; off <= 32; off <<= 1) {
        ax += __shfl_xor(ax, off, 64);
        ay += __shfl_xor(ay, off, 64);
        az += __shfl_xor(az, off, 64);
        aw += __shfl_xor(aw, off, 64);
    }
    __shared__ float red[4][8][4];
    if ((lane >> 3) == 0) {
        red[wave][cg][0] = ax; red[wave][cg][1] = ay;
        red[wave][cg][2] = az; red[wave][cg][3] = aw;
    }
    __syncthreads();
    if (tid < 8) {
        float tot[4];
#pragma unroll
        for (int j = 0; j < 4; ++j)
            tot[j] = red[0][tid][j] + red[1][tid][j] + red[2][tid][j] + red[3][tid][j];
        int c0 = (tid & 3) * 4;
        if (tid < 4) {
#pragma unroll
            for (int j = 0; j < 4; ++j)
                bvec[(size_t)t * 16 + c0 + j] = 2.f / (1.f + expf(-tot[j]));
        } else {
#pragma unroll
            for (int j = 0; j < 4; ++j) {
                float a = tot[j] + dtb[c0 + j];
                float sp = (a > 20.f) ? a : log1pf(expf(a));
                gvec[(size_t)t * 16 + c0 + j] = -expf(A_log[c0 + j]) * sp;
            }
        }
    }
}

// ---------------- phase 1 (MFMA): per (chunk, head) WY-transform prep ----------------
__global__ __launch_bounds__(256) void phase1_mfma(
    const float* __restrict__ qpost, const float* __restrict__ kpost,
    const float* __restrict__ vpost, const float* __restrict__ gvec,
    const float* __restrict__ bvec,
    float* __restrict__ u_ws, float* __restrict__ w_ws,
    float* __restrict__ qg_ws, float* __restrict__ kd_ws,
    float* __restrict__ at_ws, float* __restrict__ gl_ws) {
    int n = blockIdx.x, h = blockIdx.y;
    int t0 = n * CHUNKN;
    int tid = threadIdx.x;
    int wave = tid >> 6, lane = tid & 63;
    size_t base = (size_t)(h * NCHUNK + n);

    __shared__ __align__(16) unsigned short QKb[128 * 104];
    __shared__ __align__(16) unsigned short Ab[64 * 104];
    __shared__ __align__(16) unsigned short Atb[64 * 104];
    __shared__ __align__(16) unsigned short Pb[64 * 104];
    __shared__ __align__(16) unsigned short Ptb[64 * 104];
    __shared__ float Pf[64 * 68];
    __shared__ __align__(16) unsigned short RHSw[96 * 72];
    __shared__ __align__(16) unsigned short RHSv[192 * 72];
    __shared__ float gr_s[64], gc_s[64], be_s[64];

    if (tid < 64) {
        gr_s[tid] = gvec[(size_t)(t0 + tid) * HVN + h];
        be_s[tid] = bvec[(size_t)(t0 + tid) * HVN + h];
    }
    __syncthreads();
    if (tid < 64) {
        float sacc = 0.f;
        for (int j = 0; j <= tid; ++j) sacc += gr_s[j];
        gc_s[tid] = sacc;
    }
    __syncthreads();
    float gl = gc_s[63];

    int r = tid >> 2, sub = tid & 3;
    {
        const float* kp = kpost + (size_t)(t0 + r) * KDIMN + h * DKN + sub * 24;
        float kreg[24];
        float ss = 0.f;
#pragma unroll
        for (int i = 0; i < 6; ++i) {
            float4 v = *(const float4*)(kp + i * 4);
            kreg[i * 4 + 0] = v.x; kreg[i * 4 + 1] = v.y; kreg[i * 4 + 2] = v.z; kreg[i * 4 + 3] = v.w;
            ss += v.x * v.x + v.y * v.y + v.z * v.z + v.w * v.w;
        }
        ss += __shfl_xor(ss, 1, 64);
        ss += __shfl_xor(ss, 2, 64);
        float nrm = rsqrtf(ss + EPSF);
        float gcr = gc_s[r];
        float egl = expf(gl - gcr);
        float ebg = be_s[r] * expf(gcr);
        float* kdp = kd_ws + base * (64 * 96) + r * 96 + sub * 24;
#pragma unroll
        for (int i = 0; i < 24; ++i) {
            float kn = kreg[i] * nrm;
            QKb[r * 104 + sub * 24 + i] = f2bf(kn);
            kdp[i] = kn * egl;
            RHSw[(sub * 24 + i) * 72 + r] = f2bf(kn * ebg);
        }
    }
    {
        const float* qp = qpost + (size_t)(t0 + r) * KDIMN + h * DKN + sub * 24;
        float qreg[24];
        float ss = 0.f;
#pragma unroll
        for (int i = 0; i < 6; ++i) {
            float4 v = *(const float4*)(qp + i * 4);
            qreg[i * 4 + 0] = v.x; qreg[i * 4 + 1] = v.y; qreg[i * 4 + 2] = v.z; qreg[i * 4 + 3] = v.w;
            ss += v.x * v.x + v.y * v.y + v.z * v.z + v.w * v.w;
        }
        ss += __shfl_xor(ss, 1, 64);
        ss += __shfl_xor(ss, 2, 64);
        float nrm = rsqrtf(ss + EPSF) * 0.10206207261596577f;
        float eg = expf(gc_s[r]);
        float* qgp = qg_ws + base * (64 * 96) + r * 96 + sub * 24;
#pragma unroll
        for (int i = 0; i < 24; ++i) {
            float qn = qreg[i] * nrm;
            QKb[(64 + r) * 104 + sub * 24 + i] = f2bf(qn);
            qgp[i] = qn * eg;
        }
    }
    {
        const float* vp = vpost + (size_t)(t0 + r) * VDIMN + h * DVN + sub * 48;
        float ber = be_s[r];
#pragma unroll
        for (int i = 0; i < 12; ++i) {
            float4 v = *(const float4*)(vp + i * 4);
            int d = sub * 48 + i * 4;
            RHSv[(d + 0) * 72 + r] = f2bf(v.x * ber);
            RHSv[(d + 1) * 72 + r] = f2bf(v.y * ber);
            RHSv[(d + 2) * 72 + r] = f2bf(v.z * ber);
            RHSv[(d + 3) * 72 + r] = f2bf(v.w * ber);
        }
    }
    __syncthreads();

    {
        f32x4 acc1[2][4] = {};
#pragma unroll
        for (int ks = 0; ks < 3; ++ks) {
            int ko = ks * 32 + (lane >> 4) * 8;
            short8 af[2], bfv[4];
#pragma unroll
            for (int rt2 = 0; rt2 < 2; ++rt2)
                af[rt2] = *(const short8*)&QKb[(wave * 32 + rt2 * 16 + (lane & 15)) * 104 + ko];
#pragma unroll
            for (int ct = 0; ct < 4; ++ct)
                bfv[ct] = *(const short8*)&QKb[(ct * 16 + (lane & 15)) * 104 + ko];
#pragma unroll
            for (int rt2 = 0; rt2 < 2; ++rt2)
#pragma unroll
                for (int ct = 0; ct < 4; ++ct)
                    acc1[rt2][ct] = __builtin_amdgcn_mfma_f32_16x16x32_bf16(af[rt2], bfv[ct], acc1[rt2][ct], 0, 0, 0);
        }
#pragma unroll
        for (int rt2 = 0; rt2 < 2; ++rt2)
#pragma unroll
            for (int ct = 0; ct < 4; ++ct)
#pragma unroll
                for (int j = 0; j < 4; ++j) {
                    int rr = wave * 32 + rt2 * 16 + (lane >> 4) * 4 + j;
                    int cc = ct * 16 + (lane & 15);
                    float val = acc1[rt2][ct][j];
                    if (rr < 64) {
                        float av = (rr > cc) ? -be_s[rr] * expf(gc_s[rr] - gc_s[cc]) * val : 0.f;
                        unsigned short ab = f2bf(av);
                        Ab[rr * 104 + cc] = ab;
                        Atb[cc * 104 + rr] = ab;
                        float pv = (rr == cc) ? 1.f : av;
                        Pf[rr * 68 + cc] = pv;
                        unsigned short pb = f2bf(pv);
                        Pb[rr * 104 + cc] = pb;
                        Ptb[cc * 104 + rr] = pb;
                    } else {
                        int ar = rr - 64;
                        float av = (ar >= cc) ? expf(gc_s[ar] - gc_s[cc]) * val : 0.f;
                        at_ws[base * (64 * 64) + ar * 64 + cc] = av;
                    }
                }
    }
    __syncthreads();

#pragma unroll 1
    for (int lev = 0; lev < 5; ++lev) {
        f32x4 d[4] = {};
#pragma unroll
        for (int ks = 0; ks < 2; ++ks) {
            int ko = ks * 32 + (lane >> 4) * 8;
            short8 a0 = *(const short8*)&Ab[(wave * 16 + (lane & 15)) * 104 + ko];
#pragma unroll
            for (int ct = 0; ct < 4; ++ct) {
                short8 b0 = *(const short8*)&Atb[(ct * 16 + (lane & 15)) * 104 + ko];
                d[ct] = __builtin_amdgcn_mfma_f32_16x16x32_bf16(a0, b0, d[ct], 0, 0, 0);
            }
        }
        __syncthreads();
#pragma unroll
        for (int ct = 0; ct < 4; ++ct)
#pragma unroll
            for (int j = 0; j < 4; ++j) {
                int rr = wave * 16 + (lane >> 4) * 4 + j;
                int cc = ct * 16 + (lane & 15);
                unsigned short hb = f2bf(d[ct][j]);
                Ab[rr * 104 + cc] = hb;
                Atb[cc * 104 + rr] = hb;
            }
        __syncthreads();
        f32x4 e[4];
#pragma unroll
        for (int ct = 0; ct < 4; ++ct)
#pragma unroll
            for (int j = 0; j < 4; ++j)
                e[ct][j] = Pf[(wave * 16 + (lane >> 4) * 4 + j) * 68 + ct * 16 + (lane & 15)];
#pragma unroll
        for (int ks = 0; ks < 2; ++ks) {
            int ko = ks * 32 + (lane >> 4) * 8;
            short8 a0 = *(const short8*)&Ab[(wave * 16 + (lane & 15)) * 104 + ko];
#pragma unroll
            for (int ct = 0; ct < 4; ++ct) {
                short8 b0 = *(const short8*)&Ptb[(ct * 16 + (lane & 15)) * 104 + ko];
                e[ct] = __builtin_amdgcn_mfma_f32_16x16x32_bf16(a0, b0, e[ct], 0, 0, 0);
            }
        }
        __syncthreads();
#pragma unroll
        for (int ct = 0; ct < 4; ++ct)
#pragma unroll
            for (int j = 0; j < 4; ++j) {
                int rr = wave * 16 + (lane >> 4) * 4 + j;
                int cc = ct * 16 + (lane & 15);
                float pv = e[ct][j];
                Pf[rr * 68 + cc] = pv;
                unsigned short pb = f2bf(pv);
                Pb[rr * 104 + cc] = pb;
                Ptb[cc * 104 + rr] = pb;
            }
        __syncthreads();
    }

#pragma unroll 1
    for (int i = 0; i < 18; ++i) {
        int id = wave * 18 + i;
        int rt = id & 3, ct = id >> 2;
        f32x4 o4 = {};
#pragma unroll
        for (int ks = 0; ks < 2; ++ks) {
            int ko = ks * 32 + (lane >> 4) * 8;
            short8 a0 = *(const short8*)&Pb[(rt * 16 + (lane & 15)) * 104 + ko];
            short8 b0 = (ct < 12)
                ? *(const short8*)&RHSv[(ct * 16 + (lane & 15)) * 72 + ko]
                : *(const short8*)&RHSw[((ct - 12) * 16 + (lane & 15)) * 72 + ko];
            o4 = __builtin_amdgcn_mfma_f32_16x16x32_bf16(a0, b0, o4, 0, 0, 0);
        }
#pragma unroll
        for (int j = 0; j < 4; ++j) {
            int rr = rt * 16 + (lane >> 4) * 4 + j;
            int nn = ct * 16 + (lane & 15);
            if (ct < 12) u_ws[base * (64 * 192) + rr * 192 + nn] = o4[j];
            else         w_ws[base * (64 * 96) + rr * 96 + (nn - 192)] = o4[j];
        }
    }
    if (tid == 0) gl_ws[base] = gl;
}

// ---------------- tprep: T_n = e^gl I - kd^T w (bf16, stride-104 padded), Ct = u^T kd (f32) ----------------
__global__ __launch_bounds__(256) void tprep(const float* __restrict__ u_ws, const float* __restrict__ w_ws,
                                             const float* __restrict__ kd_ws, const float* __restrict__ gl_ws,
                                             float* __restrict__ Ct, unsigned short* __restrict__ Tn) {
    int n = blockIdx.x, h = blockIdx.y;
    size_t base = (size_t)(h * NCHUNK + n);
    int tid = threadIdx.x, wave = tid >> 6, lane = tid & 63;
    __shared__ __align__(16) unsigned short kdT[96 * 72];
    __shared__ __align__(16) unsigned short wT[96 * 72];
    __shared__ __align__(16) unsigned short uT[192 * 72];
    const float* kdp = kd_ws + base * (64 * 96);
    const float* wp  = w_ws + base * (64 * 96);
    const float* up  = u_ws + base * (64 * 192);
    for (int f = tid; f < 1536; f += 256) {
        int t = f / 24, c4 = (f % 24) * 4;
        float4 kv = *(const float4*)(kdp + t * 96 + c4);
        float4 wv = *(const float4*)(wp + t * 96 + c4);
        kdT[(c4 + 0) * 72 + t] = f2bf(kv.x); kdT[(c4 + 1) * 72 + t] = f2bf(kv.y);
        kdT[(c4 + 2) * 72 + t] = f2bf(kv.z); kdT[(c4 + 3) * 72 + t] = f2bf(kv.w);
        wT[(c4 + 0) * 72 + t] = f2bf(wv.x); wT[(c4 + 1) * 72 + t] = f2bf(wv.y);
        wT[(c4 + 2) * 72 + t] = f2bf(wv.z); wT[(c4 + 3) * 72 + t] = f2bf(wv.w);
    }
    for (int f = tid; f < 3072; f += 256) {
        int t = f / 48, c4 = (f % 48) * 4;
        float4 uv = *(const float4*)(up + t * 192 + c4);
        uT[(c4 + 0) * 72 + t] = f2bf(uv.x); uT[(c4 + 1) * 72 + t] = f2bf(uv.y);
        uT[(c4 + 2) * 72 + t] = f2bf(uv.z); uT[(c4 + 3) * 72 + t] = f2bf(uv.w);
    }
    __syncthreads();
    float egl = expf(gl_ws[base]);
#pragma unroll 1
    for (int q = 0; q < 27; ++q) {
        int id = wave * 27 + q;
        f32x4 acc = {};
        if (id < 36) {
            int jt = id / 6, kt = id % 6;
#pragma unroll
            for (int ks = 0; ks < 2; ++ks) {
                int ko = ks * 32 + (lane >> 4) * 8;
                short8 a0 = *(const short8*)&kdT[(jt * 16 + (lane & 15)) * 72 + ko];
                short8 b0 = *(const short8*)&wT[(kt * 16 + (lane & 15)) * 72 + ko];
                acc = __builtin_amdgcn_mfma_f32_16x16x32_bf16(a0, b0, acc, 0, 0, 0);
            }
#pragma unroll
            for (int r = 0; r < 4; ++r) {
                int j = jt * 16 + (lane >> 4) * 4 + r;
                int k = kt * 16 + (lane & 15);
                float val = -acc[r];
                if (j == k) val += egl;
                Tn[base * TN_STRIDE + j * 104 + k] = f2bf(val);
            }
        } else {
            int cid = id - 36;
            int it = cid / 6, jt = cid % 6;
#pragma unroll
            for (int ks = 0; ks < 2; ++ks) {
                int ko = ks * 32 + (lane >> 4) * 8;
                short8 a0 = *(const short8*)&uT[(it * 16 + (lane & 15)) * 72 + ko];
                short8 b0 = *(const short8*)&kdT[(jt * 16 + (lane & 15)) * 72 + ko];
                acc = __builtin_amdgcn_mfma_f32_16x16x32_bf16(a0, b0, acc, 0, 0, 0);
            }
#pragma unroll
            for (int r = 0; r < 4; ++r)
                Ct[base * 18432 + (size_t)(it * 16 + (lane >> 4) * 4 + r) * 96 + jt * 16 + (lane & 15)] = acc[r];
        }
    }
}

// ---------------- mscan: St_{n+1} = St_n @ T_n^T + Ct_n ----------------
__global__ __launch_bounds__(128) void mscan(const float* __restrict__ Ct, const unsigned short* __restrict__ Tn,
                                             float* __restrict__ s_ws) {
    int rg = blockIdx.x, h = blockIdx.y;
    int tid = threadIdx.x, wave = tid >> 6, lane = tid & 63;
    __shared__ __align__(16) unsigned short St[48 * 104];
    __shared__ __align__(16) unsigned short TnB[2][TN_STRIDE];
    __shared__ __align__(16) float CtB[2][48 * 96];
    for (int i = tid; i < 48 * 104; i += 128) St[i] = 0;

    {
        const float* cp = Ct + (size_t)(h * NCHUNK) * 18432 + rg * (48 * 96);
        const unsigned short* tp = Tn + (size_t)(h * NCHUNK) * TN_STRIDE;
#pragma unroll
        for (int q = 0; q < 9; ++q) {
            size_t o = (size_t)(wave * 9 + q) * 1024 + lane * 16;
            gld_lds16((const char*)cp + o, (char*)&CtB[0][0] + (size_t)(wave * 9 + q) * 1024);
        }
#pragma unroll
        for (int q = 0; q < 10; ++q) {
            size_t o = (size_t)(wave * 10 + q) * 1024 + lane * 16;
            gld_lds16((const char*)tp + o, (char*)&TnB[0][0] + (size_t)(wave * 10 + q) * 1024);
        }
    }
    f32x4 acc[3][3] = {};
    int colw = wave * 48;
    __syncthreads();

#pragma unroll 1
    for (int n = 0; n < NCHUNK; ++n) {
        size_t base = (size_t)(h * NCHUNK + n);
        int cur = n & 1;
        if (n + 1 < NCHUNK) {
            const float* cp = Ct + (base + 1) * 18432 + rg * (48 * 96);
            const unsigned short* tp = Tn + (base + 1) * TN_STRIDE;
#pragma unroll
            for (int q = 0; q < 9; ++q) {
                size_t o = (size_t)(wave * 9 + q) * 1024 + lane * 16;
                gld_lds16((const char*)cp + o, (char*)&CtB[cur ^ 1][0] + (size_t)(wave * 9 + q) * 1024);
            }
#pragma unroll
            for (int q = 0; q < 10; ++q) {
                size_t o = (size_t)(wave * 10 + q) * 1024 + lane * 16;
                gld_lds16((const char*)tp + o, (char*)&TnB[cur ^ 1][0] + (size_t)(wave * 10 + q) * 1024);
            }
        }
        float* sp = s_ws + base * 18432 + rg * (48 * 96);
#pragma unroll
        for (int it = 0; it < 3; ++it)
#pragma unroll
            for (int jt = 0; jt < 3; ++jt) {
                int irow = it * 16 + (lane >> 4) * 4;
                int col = colw + jt * 16 + (lane & 15);
#pragma unroll
                for (int r = 0; r < 4; ++r) {
                    sp[(size_t)(irow + r) * 96 + col] = acc[it][jt][r];
                    acc[it][jt][r] = CtB[cur][(irow + r) * 96 + col];
                }
            }
#pragma unroll
        for (int ks = 0; ks < 3; ++ks) {
            int ko = ks * 32 + (lane >> 4) * 8;
            short8 af[3], bfv[3];
#pragma unroll
            for (int it = 0; it < 3; ++it)
                af[it] = *(const short8*)&St[(it * 16 + (lane & 15)) * 104 + ko];
#pragma unroll
            for (int jt = 0; jt < 3; ++jt)
                bfv[jt] = *(const short8*)&TnB[cur][(colw + jt * 16 + (lane & 15)) * 104 + ko];
#pragma unroll
            for (int it = 0; it < 3; ++it)
#pragma unroll
                for (int jt = 0; jt < 3; ++jt)
                    acc[it][jt] = __builtin_amdgcn_mfma_f32_16x16x32_bf16(af[it], bfv[jt], acc[it][jt], 0, 0, 0);
        }
        __syncthreads();
#pragma unroll
        for (int it = 0; it < 3; ++it)
#pragma unroll
            for (int jt = 0; jt < 3; ++jt)
#pragma unroll
                for (int r = 0; r < 4; ++r)
                    St[(it * 16 + (lane >> 4) * 4 + r) * 104 + colw + jt * 16 + (lane & 15)] = f2bf(acc[it][jt][r]);
        __syncthreads();
    }
}

// ---------------- phase2b (MFMA): vnT = uT + St@(-w)^T ; oT = St@qg^T + vnT@at^T ----------------
#define P2_ST 0
#define P2_W  39936
#define P2_QG 53248
#define P2_AT 66560
#define P2_U  75776
#define P2_VN 125952
__global__ __launch_bounds__(256) void phase2b_mfma(const float* __restrict__ s_ws, const float* __restrict__ w_ws,
                                                    const float* __restrict__ qg_ws, const float* __restrict__ at_ws,
                                                    const float* __restrict__ u_ws, float* __restrict__ o_ws) {
    __shared__ __align__(16) char LB[153600];
    unsigned short* StB = (unsigned short*)(LB + P2_ST);
    unsigned short* wB  = (unsigned short*)(LB + P2_W);
    unsigned short* qgB = (unsigned short*)(LB + P2_QG);
    unsigned short* atB = (unsigned short*)(LB + P2_AT);
    float* uF           = (float*)(LB + P2_U);
    unsigned short* vnB = (unsigned short*)(LB + P2_VN);
    int n = blockIdx.x, h = blockIdx.y;
    size_t base = (size_t)(h * NCHUNK + n);
    int tid = threadIdx.x, wave = tid >> 6, lane = tid & 63;
    int i0w = wave * 48;
    {
        const float* sp = s_ws + base * 18432;
        for (int f = tid; f < 4608; f += 256) {
            int i = f / 24, c4 = (f % 24) * 4;
            float4 v = *(const float4*)(sp + i * 96 + c4);
            ushort4 o4; o4.x = f2bf(v.x); o4.y = f2bf(v.y); o4.z = f2bf(v.z); o4.w = f2bf(v.w);
            *(ushort4*)&StB[i * 104 + c4] = o4;
        }
    }
    {
        const float* wp = w_ws + base * 6144;
        const float* qp = qg_ws + base * 6144;
        for (int f = tid; f < 1536; f += 256) {
            int t = f / 24, c4 = (f % 24) * 4;
            float4 wv = *(const float4*)(wp + t * 96 + c4);
            float4 qv = *(const float4*)(qp + t * 96 + c4);
            ushort4 ow; ow.x = f2bf(-wv.x); ow.y = f2bf(-wv.y); ow.z = f2bf(-wv.z); ow.w = f2bf(-wv.w);
            ushort4 oq; oq.x = f2bf(qv.x); oq.y = f2bf(qv.y); oq.z = f2bf(qv.z); oq.w = f2bf(qv.w);
            *(ushort4*)&wB[t * 104 + c4] = ow;
            *(ushort4*)&qgB[t * 104 + c4] = oq;
        }
    }
    {
        const float* ap = at_ws + base * 4096;
        for (int f = tid; f < 1024; f += 256) {
            int t = f / 16, c4 = (f % 16) * 4;
            float4 av = *(const float4*)(ap + t * 64 + c4);
            ushort4 oa; oa.x = f2bf(av.x); oa.y = f2bf(av.y); oa.z = f2bf(av.z); oa.w = f2bf(av.w);
            *(ushort4*)&atB[t * 72 + c4] = oa;
        }
    }
    {
        const float* up = u_ws + base * 12288;
        for (int f = tid; f < 3072; f += 256) {
            int t = f / 48, c4 = (f % 48) * 4;
            *(float4*)&uF[t * 196 + c4] = *(const float4*)(up + t * 192 + c4);
        }
    }
    __syncthreads();
    {
        f32x4 acc[3][4];
#pragma unroll
        for (int it = 0; it < 3; ++it)
#pragma unroll
            for (int jt = 0; jt < 4; ++jt)
#pragma unroll
                for (int r = 0; r < 4; ++r)
                    acc[it][jt][r] = uF[(jt * 16 + (lane & 15)) * 196 + i0w + it * 16 + (lane >> 4) * 4 + r];
#pragma unroll
        for (int ks = 0; ks < 3; ++ks) {
            int ko = ks * 32 + (lane >> 4) * 8;
            short8 af[3], bfv[4];
#pragma unroll
            for (int it = 0; it < 3; ++it)
                af[it] = *(const short8*)&StB[(i0w + it * 16 + (lane & 15)) * 104 + ko];
#pragma unroll
            for (int jt = 0; jt < 4; ++jt)
                bfv[jt] = *(const short8*)&wB[(jt * 16 + (lane & 15)) * 104 + ko];
#pragma unroll
            for (int it = 0; it < 3; ++it)
#pragma unroll
                for (int jt = 0; jt < 4; ++jt)
                    acc[it][jt] = __builtin_amdgcn_mfma_f32_16x16x32_bf16(af[it], bfv[jt], acc[it][jt], 0, 0, 0);
        }
#pragma unroll
        for (int it = 0; it < 3; ++it)
#pragma unroll
            for (int jt = 0; jt < 4; ++jt)
#pragma unroll
                for (int r = 0; r < 4; ++r)
                    vnB[(i0w + it * 16 + (lane >> 4) * 4 + r) * 72 + jt * 16 + (lane & 15)] = f2bf(acc[it][jt][r]);
    }
    f32x4 acc2[3][4] = {};
#pragma unroll
    for (int ks = 0; ks < 3; ++ks) {
        int ko = ks * 32 + (lane >> 4) * 8;
        short8 af[3], bfv[4];
#pragma unroll
        for (int it = 0; it < 3; ++it)
            af[it] = *(const short8*)&StB[(i0w + it * 16 + (lane & 15)) * 104 + ko];
#pragma unroll
        for (int jt = 0; jt < 4; ++jt)
            bfv[jt] = *(const short8*)&qgB[(jt * 16 + (lane & 15)) * 104 + ko];
#pragma unroll
        for (int it = 0; it < 3; ++it)
#pragma unroll
            for (int jt = 0; jt < 4; ++jt)
                acc2[it][jt] = __builtin_amdgcn_mfma_f32_16x16x32_bf16(af[it], bfv[jt], acc2[it][jt], 0, 0, 0);
    }
#pragma unroll
    for (int ks = 0; ks < 2; ++ks) {
        int ko = ks * 32 + (lane >> 4) * 8;
        short8 af[3], bfv[4];
#pragma unroll
        for (int it = 0; it < 3; ++it)
            af[it] = *(const short8*)&vnB[(i0w + it * 16 + (lane & 15)) * 72 + ko];
#pragma unroll
        for (int jt = 0; jt < 4; ++jt)
            bfv[jt] = *(const short8*)&atB[(jt * 16 + (lane & 15)) * 72 + ko];
#pragma unroll
        for (int it = 0; it < 3; ++it)
#pragma unroll
            for (int jt = 0; jt < 4; ++jt)
                acc2[it][jt] = __builtin_amdgcn_mfma_f32_16x16x32_bf16(af[it], bfv[jt], acc2[it][jt], 0, 0, 0);
    }
    __syncthreads();
    float* oF = (float*)(LB + 0); // [192][68]
#pragma unroll
    for (int it = 0; it < 3; ++it)
#pragma unroll
        for (int jt = 0; jt < 4; ++jt)
#pragma unroll
            for (int r = 0; r < 4; ++r)
                oF[(i0w + it * 16 + (lane >> 4) * 4 + r) * 68 + jt * 16 + (lane & 15)] = acc2[it][jt][r];
    __syncthreads();
    int t0 = n * CHUNKN;
    for (int f = tid; f < 3072; f += 256) {
        int t = f / 48, c4 = (f % 48) * 4;
        float4 ov;
        ov.x = oF[(c4 + 0) * 68 + t];
        ov.y = oF[(c4 + 1) * 68 + t];
        ov.z = oF[(c4 + 2) * 68 + t];
        ov.w = oF[(c4 + 3) * 68 + t];
        *(float4*)(o_ws + (size_t)(t0 + t) * VDIMN + h * DVN + c4) = ov;
    }
}

// ---------------- gate (SiLU) + RMSNorm -> bf16 (gate read as bf16) ----------------
__global__ __launch_bounds__(64) void gate_norm(const float* __restrict__ o_ws, const unsigned short* __restrict__ Cgate,
                                                const float* __restrict__ nw, unsigned short* __restrict__ obf) {
    int b = blockIdx.x;
    int t = b >> 4, h = b & 15;
    int lane = threadIdx.x;
    float x[3];
    float ss = 0.f;
    size_t ob = (size_t)t * VDIMN + h * DVN;
    for (int j = 0; j < 3; ++j) {
        int d = j * 64 + lane;
        float ov = o_ws[ob + d];
        float gv = bf2f(Cgate[ob + d]);
        float xv = ov * siluf(gv);
        x[j] = xv;
        ss += xv * xv;
    }
    for (int off = 32; off > 0; off >>= 1) ss += __shfl_xor(ss, off, 64);
    float r = rsqrtf(ss * (1.f / 192.f) + EPSF);
    for (int j = 0; j < 3; ++j) {
        int d = j * 64 + lane;
        obf[ob + d] = f2bf(x[j] * r * nw[d]);
    }
}

extern "C" void kernel_launch(void* const* d_in, const int* in_sizes, int n_in,
                              void* d_out, int out_size, void* d_ws, size_t ws_size,
                              hipStream_t stream) {
    (void)in_sizes; (void)n_in; (void)out_size;
    const float* X    = (const float*)d_in[0];
    const float* Wq   = (const float*)d_in[1];
    const float* Wk   = (const float*)d_in[2];
    const float* Wv   = (const float*)d_in[3];
    const float* Wb   = (const float*)d_in[4];
    const float* Wa   = (const float*)d_in[5];
    const float* Wg   = (const float*)d_in[6];
    const float* Wo   = (const float*)d_in[7];
    const float* cq   = (const float*)d_in[8];
    const float* ck   = (const float*)d_in[9];
    const float* cv   = (const float*)d_in[10];
    const float* Alog = (const float*)d_in[11];
    const float* dtb  = (const float*)d_in[12];
    const float* nw   = (const float*)d_in[13];

    const size_t OFF_XBF   = 0;
    const size_t OFF_WALLT = 8388608;
    const size_t OFF_WOT   = 46137344;
    const size_t OFF_CQKV  = 58720256;
    const size_t OFF_CGATE = 109051904;             // bf16 now: 12.6 MB used of 25.2 slot
    const size_t OFF_QPOST = 134217728;
    const size_t OFF_KPOST = 146800640;
    const size_t OFF_VPOST = 159383552;
    const size_t OFF_GVEC  = 184549376;
    const size_t OFF_BVEC  = 184680448;
    const size_t OFF_GL    = 184811520;
    const size_t OFF_U     = 184819712;
    const size_t OFF_W     = 209985536;
    const size_t OFF_QG    = 222568448;
    const size_t OFF_KD    = 235151360;
    const size_t OFF_AT    = OFF_XBF;               // after proj gemm
    const size_t OFF_CT    = OFF_CQKV;              // after conv
    const size_t OFF_TN    = OFF_CQKV + 37748736;
    const size_t OFF_S     = OFF_QPOST;             // after phase1
    const size_t OFF_O     = OFF_WALLT;             // after gemms
    const size_t OFF_OBF   = OFF_WALLT + 25165824;
    const size_t OFF_OPART = OFF_CQKV;              // after phase2b
    const size_t NEEDED    = 247734272;
    if (ws_size < NEEDED) return;

    char* ws = (char*)d_ws;
    unsigned short* Xbf   = (unsigned short*)(ws + OFF_XBF);
    unsigned short* WallT = (unsigned short*)(ws + OFF_WALLT);
    unsigned short* WoT   = (unsigned short*)(ws + OFF_WOT);
    float* Cqkv  = (float*)(ws + OFF_CQKV);
    unsigned short* Cgate = (unsigned short*)(ws + OFF_CGATE);
    float* qpost = (float*)(ws + OFF_QPOST);
    float* kpost = (float*)(ws + OFF_KPOST);
    float* vpost = (float*)(ws + OFF_VPOST);
    float* gvec  = (float*)(ws + OFF_GVEC);
    float* bvec  = (float*)(ws + OFF_BVEC);
    float* gl_ws = (float*)(ws + OFF_GL);
    float* u_ws  = (float*)(ws + OFF_U);
    float* w_ws  = (float*)(ws + OFF_W);
    float* qg_ws = (float*)(ws + OFF_QG);
    float* kd_ws = (float*)(ws + OFF_KD);
    float* at_ws = (float*)(ws + OFF_AT);
    float* Ct    = (float*)(ws + OFF_CT);
    unsigned short* Tn = (unsigned short*)(ws + OFF_TN);
    float* s_ws  = (float*)(ws + OFF_S);
    float* o_ws  = (float*)(ws + OFF_O);
    unsigned short* obf = (unsigned short*)(ws + OFF_OBF);
    float* opart = (float*)(ws + OFF_OPART);

    cast_f32_bf16<<<4096, 256, 0, stream>>>(X, Xbf, 2048 * 2048);
    dim3 tb(64, 4);
    transpose_cast<<<dim3(1536 / 64, 2048 / 64), tb, 0, stream>>>(Wq, WallT, 2048, 1536);
    transpose_cast<<<dim3(1536 / 64, 2048 / 64), tb, 0, stream>>>(Wk, WallT + (size_t)1536 * 2048, 2048, 1536);
    transpose_cast<<<dim3(3072 / 64, 2048 / 64), tb, 0, stream>>>(Wv, WallT + (size_t)3072 * 2048, 2048, 3072);
    transpose_cast<<<dim3(3072 / 64, 2048 / 64), tb, 0, stream>>>(Wg, WallT + (size_t)6144 * 2048, 2048, 3072);
    transpose_cast<<<dim3(2048 / 64, 3072 / 64), tb, 0, stream>>>(Wo, WoT, 3072, 2048);

    // fused QKV (f32) + gate (bf16) projection, 2-phase pipelined
    gemm_bt2<<<dim3(9216 / 128, 2048 / 128), 256, 0, stream>>>(Xbf, WallT,
                                                               Cqkv, QKVD, QKVD / 128,
                                                               Cgate, VDIMN, 2048, 2048);

    conv_silu<<<dim3(6, T_LEN), 256, 0, stream>>>(Cqkv + 0, QKVD, cq, qpost, KDIMN);
    conv_silu<<<dim3(6, T_LEN), 256, 0, stream>>>(Cqkv + 1536, QKVD, ck, kpost, KDIMN);
    conv_silu<<<dim3(12, T_LEN), 256, 0, stream>>>(Cqkv + 3072, QKVD, cv, vpost, VDIMN);
    beta_g<<<T_LEN, 256, 0, stream>>>(X, Wb, Wa, Alog, dtb, bvec, gvec);

    phase1_mfma<<<dim3(NCHUNK, HVN), 256, 0, stream>>>(qpost, kpost, vpost, gvec, bvec,
                                                       u_ws, w_ws, qg_ws, kd_ws, at_ws, gl_ws);
    tprep<<<dim3(NCHUNK, HVN), 256, 0, stream>>>(u_ws, w_ws, kd_ws, gl_ws, Ct, Tn);
    mscan<<<dim3(4, HVN), 128, 0, stream>>>(Ct, Tn, s_ws);
    phase2b_mfma<<<dim3(NCHUNK, HVN), 256, 0, stream>>>(s_ws, w_ws, qg_ws, at_ws, u_ws, o_ws);

    gate_norm<<<T_LEN * HVN, 64, 0, stream>>>(o_ws, Cgate, nw, obf);

    // output GEMM split-K=3 (2-phase pipelined) + deterministic fixup
    gemm_btk<<<dim3(2048 / 128, 2048 / 128, 3), 256, 0, stream>>>(obf, WoT, (float*)d_out, opart,
                                                                  2048, 2048, 3072);
    addk<<<4096, 256, 0, stream>>>((float*)d_out, opart, 2048 * 2048);
}

// Round 11
// 463.882 us; speedup vs baseline: 1.7325x; 1.0495x over previous
//
#include <hip/hip_runtime.h>
#include <math.h>

#define T_LEN 2048
#define HIDN  2048
#define HKN   16
#define DKN   96
#define HVN   16
#define DVN   192
#define KDIMN 1536
#define VDIMN 3072
#define QKVD  6144   // q(1536)+k(1536)+v(3072)
#define CHUNKN 64
#define NCHUNK 32
#define EPSF 1e-6f
#define TN_STRIDE 10240   // ushorts per (chunk,head) Tn record: 96 rows * 104 + pad -> 20480 B

typedef __attribute__((ext_vector_type(8))) short short8;
typedef __attribute__((ext_vector_type(4))) float f32x4;

__device__ __forceinline__ unsigned short f2bf(float f) {
    unsigned int u = __float_as_uint(f);
    unsigned int r = (u + 0x7FFFu + ((u >> 16) & 1u)) >> 16;
    return (unsigned short)r;
}
__device__ __forceinline__ float bf2f(unsigned short u) {
    return __uint_as_float(((unsigned int)u) << 16);
}
__device__ __forceinline__ float siluf(float x) { return x / (1.f + expf(-x)); }

__device__ __forceinline__ void gld_lds16(const void* g, void* l) {
    __builtin_amdgcn_global_load_lds((const __attribute__((address_space(1))) unsigned int*)g,
                                     (__attribute__((address_space(3))) unsigned int*)l, 16, 0, 0);
}

// ---------------- cast f32 -> bf16 (4/thread) ----------------
__global__ void cast_f32_bf16(const float* __restrict__ in, unsigned short* __restrict__ out, int n) {
    int i = (blockIdx.x * blockDim.x + threadIdx.x) * 4;
    if (i >= n) return;
    float4 v = *(const float4*)(in + i);
    ushort4 o;
    o.x = f2bf(v.x); o.y = f2bf(v.y); o.z = f2bf(v.z); o.w = f2bf(v.w);
    *(ushort4*)(out + i) = o;
}

// ---------------- transpose + cast: W[K][N] -> Wt[N][K] bf16 ----------------
__global__ void transpose_cast(const float* __restrict__ W, unsigned short* __restrict__ Wt,
                               int K, int N) {
    __shared__ float tile[64][65];
    int k0 = blockIdx.y * 64, n0 = blockIdx.x * 64;
    int tx = threadIdx.x, ty = threadIdx.y; // (64,4)
    for (int r = ty; r < 64; r += 4) tile[r][tx] = W[(size_t)(k0 + r) * N + n0 + tx];
    __syncthreads();
    for (int r = ty; r < 64; r += 4) Wt[(size_t)(n0 + r) * K + k0 + tx] = f2bf(tile[tx][r]);
}

// ---------------- fused projection GEMM, 2-phase double-buffered LDS ----------------
__global__ __launch_bounds__(256) void gemm_bt2(const unsigned short* __restrict__ A,
                                                const unsigned short* __restrict__ Bt,
                                                float* __restrict__ C1, int ld1, int nblk1,
                                                unsigned short* __restrict__ C2, int ld2,
                                                int M, int K) {
    __shared__ __align__(16) unsigned short As[2][128 * 32];
    __shared__ __align__(16) unsigned short Bs[2][128 * 32];
    int tid = threadIdx.x;
    int wave = tid >> 6, lane = tid & 63;
    int bm = blockIdx.y, bn = blockIdx.x;
    f32x4 acc[4][4] = {};
    int wr = wave >> 1, wc = wave & 1;
    int rstage = wave * 32 + (lane >> 2);
    int cstage = (lane & 3) * 8;
    const size_t a_row0 = (size_t)bm * 128;
    const size_t b_row0 = (size_t)bn * 128;
    const unsigned short* gaBase = A + (a_row0 + rstage) * (size_t)K + cstage;
    const unsigned short* gbBase = Bt + (b_row0 + rstage) * (size_t)K + cstage;
    int row_a[4], row_b[4];
#pragma unroll
    for (int i = 0; i < 4; ++i) {
        row_a[i] = wr * 64 + i * 16 + (lane & 15);
        row_b[i] = wc * 64 + i * 16 + (lane & 15);
    }
    int koff = (lane >> 4) * 8;
    int niter = K >> 5;
    {
        unsigned short* ab = &As[0][wave * 1024];
        unsigned short* bb = &Bs[0][wave * 1024];
        gld_lds16(gaBase, ab);
        gld_lds16(gaBase + (size_t)16 * K, ab + 512);
        gld_lds16(gbBase, bb);
        gld_lds16(gbBase + (size_t)16 * K, bb + 512);
    }
    __syncthreads();
    for (int i = 0; i < niter; ++i) {
        int cur = i & 1;
        if (i + 1 < niter) {
            int k0 = (i + 1) * 32;
            unsigned short* ab = &As[cur ^ 1][wave * 1024];
            unsigned short* bb = &Bs[cur ^ 1][wave * 1024];
            gld_lds16(gaBase + k0, ab);
            gld_lds16(gaBase + k0 + (size_t)16 * K, ab + 512);
            gld_lds16(gbBase + k0, bb);
            gld_lds16(gbBase + k0 + (size_t)16 * K, bb + 512);
        }
        short8 af[4], bfr[4];
#pragma unroll
        for (int mi = 0; mi < 4; ++mi) af[mi] = *(const short8*)&As[cur][row_a[mi] * 32 + koff];
#pragma unroll
        for (int ni = 0; ni < 4; ++ni) bfr[ni] = *(const short8*)&Bs[cur][row_b[ni] * 32 + koff];
#pragma unroll
        for (int mi = 0; mi < 4; ++mi)
#pragma unroll
            for (int ni = 0; ni < 4; ++ni)
                acc[mi][ni] = __builtin_amdgcn_mfma_f32_16x16x32_bf16(af[mi], bfr[ni], acc[mi][ni], 0, 0, 0);
        __syncthreads();
    }
    if (bn < nblk1) {
        int colb = bn * 128;
#pragma unroll
        for (int mi = 0; mi < 4; ++mi) {
            int rbase = bm * 128 + wr * 64 + mi * 16 + (lane >> 4) * 4;
#pragma unroll
            for (int ni = 0; ni < 4; ++ni) {
                int col = colb + wc * 64 + ni * 16 + (lane & 15);
#pragma unroll
                for (int j = 0; j < 4; ++j)
                    C1[(size_t)(rbase + j) * ld1 + col] = acc[mi][ni][j];
            }
        }
    } else {
        int colb = (bn - nblk1) * 128;
#pragma unroll
        for (int mi = 0; mi < 4; ++mi) {
            int rbase = bm * 128 + wr * 64 + mi * 16 + (lane >> 4) * 4;
#pragma unroll
            for (int ni = 0; ni < 4; ++ni) {
                int col = colb + wc * 64 + ni * 16 + (lane & 15);
#pragma unroll
                for (int j = 0; j < 4; ++j)
                    C2[(size_t)(rbase + j) * ld2 + col] = f2bf(acc[mi][ni][j]);
            }
        }
    }
}

// ---------------- split-K GEMM (SPLIT=3), 2-phase double-buffered LDS ----------------
__global__ __launch_bounds__(256) void gemm_btk(const unsigned short* __restrict__ A,
                                                const unsigned short* __restrict__ Bt,
                                                float* __restrict__ C, float* __restrict__ Cp,
                                                int M, int N, int K) {
    __shared__ __align__(16) unsigned short As[2][128 * 32];
    __shared__ __align__(16) unsigned short Bs[2][128 * 32];
    int tid = threadIdx.x;
    int wave = tid >> 6, lane = tid & 63;
    int bm = blockIdx.y, bn = blockIdx.x, kz = blockIdx.z;
    int kchunk = K / 3;
    int kbeg = kz * kchunk;
    f32x4 acc[4][4] = {};
    int wr = wave >> 1, wc = wave & 1;
    int rstage = wave * 32 + (lane >> 2);
    int cstage = (lane & 3) * 8;
    const size_t a_row0 = (size_t)bm * 128;
    const size_t b_row0 = (size_t)bn * 128;
    const unsigned short* gaBase = A + (a_row0 + rstage) * (size_t)K + kbeg + cstage;
    const unsigned short* gbBase = Bt + (b_row0 + rstage) * (size_t)K + kbeg + cstage;
    int row_a[4], row_b[4];
#pragma unroll
    for (int i = 0; i < 4; ++i) {
        row_a[i] = wr * 64 + i * 16 + (lane & 15);
        row_b[i] = wc * 64 + i * 16 + (lane & 15);
    }
    int koff = (lane >> 4) * 8;
    int niter = kchunk >> 5;
    {
        unsigned short* ab = &As[0][wave * 1024];
        unsigned short* bb = &Bs[0][wave * 1024];
        gld_lds16(gaBase, ab);
        gld_lds16(gaBase + (size_t)16 * K, ab + 512);
        gld_lds16(gbBase, bb);
        gld_lds16(gbBase + (size_t)16 * K, bb + 512);
    }
    __syncthreads();
    for (int i = 0; i < niter; ++i) {
        int cur = i & 1;
        if (i + 1 < niter) {
            int k0 = (i + 1) * 32;
            unsigned short* ab = &As[cur ^ 1][wave * 1024];
            unsigned short* bb = &Bs[cur ^ 1][wave * 1024];
            gld_lds16(gaBase + k0, ab);
            gld_lds16(gaBase + k0 + (size_t)16 * K, ab + 512);
            gld_lds16(gbBase + k0, bb);
            gld_lds16(gbBase + k0 + (size_t)16 * K, bb + 512);
        }
        short8 af[4], bfr[4];
#pragma unroll
        for (int mi = 0; mi < 4; ++mi) af[mi] = *(const short8*)&As[cur][row_a[mi] * 32 + koff];
#pragma unroll
        for (int ni = 0; ni < 4; ++ni) bfr[ni] = *(const short8*)&Bs[cur][row_b[ni] * 32 + koff];
#pragma unroll
        for (int mi = 0; mi < 4; ++mi)
#pragma unroll
            for (int ni = 0; ni < 4; ++ni)
                acc[mi][ni] = __builtin_amdgcn_mfma_f32_16x16x32_bf16(af[mi], bfr[ni], acc[mi][ni], 0, 0, 0);
        __syncthreads();
    }
    float* Cout = (kz == 0) ? C : (Cp + (size_t)(kz - 1) * M * N);
#pragma unroll
    for (int mi = 0; mi < 4; ++mi) {
        int rbase = bm * 128 + wr * 64 + mi * 16 + (lane >> 4) * 4;
#pragma unroll
        for (int ni = 0; ni < 4; ++ni) {
            int col = bn * 128 + wc * 64 + ni * 16 + (lane & 15);
#pragma unroll
            for (int j = 0; j < 4; ++j)
                Cout[(size_t)(rbase + j) * N + col] = acc[mi][ni][j];
        }
    }
}

// ---------------- addk: out += p0 + p1 (split-K fixup, deterministic) ----------------
__global__ void addk(float* __restrict__ out, const float* __restrict__ p, int n) {
    int i = (blockIdx.x * blockDim.x + threadIdx.x) * 4;
    if (i >= n) return;
    float4 a = *(const float4*)(out + i);
    float4 b = *(const float4*)(p + i);
    float4 c = *(const float4*)(p + n + i);
    a.x += b.x + c.x; a.y += b.y + c.y; a.z += b.z + c.z; a.w += b.w + c.w;
    *(float4*)(out + i) = a;
}

// ---------------- fused causal depthwise conv(K=4) + SiLU over q|k|v ----------------
__global__ void conv_silu_all(const float* __restrict__ pre,
                              const float* __restrict__ cq, const float* __restrict__ ck,
                              const float* __restrict__ cv, float* __restrict__ out) {
    int c = blockIdx.x * blockDim.x + threadIdx.x;   // 0..6143
    int t = blockIdx.y;
    const float* wc4 = (c < 1536) ? (cq + (size_t)c * 4)
                     : (c < 3072) ? (ck + (size_t)(c - 1536) * 4)
                                  : (cv + (size_t)(c - 3072) * 4);
    float acc = 0.f;
    if (t >= 3) acc += pre[(size_t)(t - 3) * QKVD + c] * wc4[0];
    if (t >= 2) acc += pre[(size_t)(t - 2) * QKVD + c] * wc4[1];
    if (t >= 1) acc += pre[(size_t)(t - 1) * QKVD + c] * wc4[2];
    acc += pre[(size_t)t * QKVD + c] * wc4[3];
    out[(size_t)t * QKVD + c] = siluf(acc);
}

// ---------------- beta / g projections (f32, vectorized) ----------------
__global__ __launch_bounds__(256) void beta_g(const float* __restrict__ X,
                                              const float* __restrict__ Wb, const float* __restrict__ Wa,
                                              const float* __restrict__ A_log, const float* __restrict__ dtb,
                                              float* __restrict__ bvec, float* __restrict__ gvec) {
    int t = blockIdx.x;
    int tid = threadIdx.x;
    int cg = tid & 7, ks = tid >> 3;
    int wave = tid >> 6, lane = tid & 63;
    const float* xr = X + (size_t)t * HIDN;
    const float* Wsel = (cg < 4) ? Wb : Wa;
    int cc = (cg & 3) * 4;
    float ax = 0.f, ay = 0.f, az = 0.f, aw = 0.f;
#pragma unroll 4
    for (int i = 0; i < 16; ++i) {
        int k = (ks + 32 * i) * 4;
        float4 xv = *(const float4*)(xr + k);
        float4 w0 = *(const float4*)(Wsel + (size_t)(k + 0) * 16 + cc);
        float4 w1 = *(const float4*)(Wsel + (size_t)(k + 1) * 16 + cc);
        float4 w2 = *(const float4*)(Wsel + (size_t)(k + 2) * 16 + cc);
        float4 w3 = *(const float4*)(Wsel + (size_t)(k + 3) * 16 + cc);
        ax += xv.x * w0.x + xv.y * w1.x + xv.z * w2.x + xv.w * w3.x;
        ay += xv.x * w0.y + xv.y * w1.y + xv.z * w2.y + xv.w * w3.y;
        az += xv.x * w0.z + xv.y * w1.z + xv.z * w2.z + xv.w * w3.z;
        aw += xv.x * w0.w + xv.y * w1.w + xv.z * w2.w + xv.w * w3.w;
    }
#pragma unroll
    for (int off = 8; off <= 32; off <<= 1) {
        ax += __shfl_xor(ax, off, 64);
        ay += __shfl_xor(ay, off, 64);
        az += __shfl_xor(az, off, 64);
        aw += __shfl_xor(aw, off, 64);
    }
    __shared__ float red[4][8][4];
    if ((lane >> 3) == 0) {
        red[wave][cg][0] = ax; red[wave][cg][1] = ay;
        red[wave][cg][2] = az; red[wave][cg][3] = aw;
    }
    __syncthreads();
    if (tid < 8) {
        float tot[4];
#pragma unroll
        for (int j = 0; j < 4; ++j)
            tot[j] = red[0][tid][j] + red[1][tid][j] + red[2][tid][j] + red[3][tid][j];
        int c0 = (tid & 3) * 4;
        if (tid < 4) {
#pragma unroll
            for (int j = 0; j < 4; ++j)
                bvec[(size_t)t * 16 + c0 + j] = 2.f / (1.f + expf(-tot[j]));
        } else {
#pragma unroll
            for (int j = 0; j < 4; ++j) {
                float a = tot[j] + dtb[c0 + j];
                float sp = (a > 20.f) ? a : log1pf(expf(a));
                gvec[(size_t)t * 16 + c0 + j] = -expf(A_log[c0 + j]) * sp;
            }
        }
    }
}

// ---------------- phase 1 (MFMA): WY-transform prep + fused tprep (Tn, Ct) ----------------
// LDS overlay: Ab/Atb/Ptb/Pf (dead after doubling) reused for kdT/wT/uT.
__global__ __launch_bounds__(256) void phase1_mfma(
    const float* __restrict__ qkv, const float* __restrict__ gvec,
    const float* __restrict__ bvec,
    float* __restrict__ u_ws, float* __restrict__ w_ws,
    float* __restrict__ qg_ws, float* __restrict__ at_ws,
    float* __restrict__ gl_ws, float* __restrict__ Ct,
    unsigned short* __restrict__ Tn) {
    int n = blockIdx.x, h = blockIdx.y;
    int t0 = n * CHUNKN;
    int tid = threadIdx.x;
    int wave = tid >> 6, lane = tid & 63;
    size_t base = (size_t)(h * NCHUNK + n);

    __shared__ __align__(16) char LB1[139776];
    unsigned short* QKb  = (unsigned short*)(LB1 + 0);        // 128*104
    unsigned short* Pb   = (unsigned short*)(LB1 + 26624);    // 64*104
    unsigned short* RHSw = (unsigned short*)(LB1 + 39936);    // 96*72
    unsigned short* RHSv = (unsigned short*)(LB1 + 53760);    // 192*72
    unsigned short* Ab   = (unsigned short*)(LB1 + 81408);    // 64*104
    unsigned short* Atb  = (unsigned short*)(LB1 + 94720);    // 64*104
    unsigned short* Ptb  = (unsigned short*)(LB1 + 108032);   // 64*104
    float*          Pf   = (float*)(LB1 + 121344);            // 64*68 -> 138752
    unsigned short* kdT  = (unsigned short*)(LB1 + 81408);    // overlay: 96*72
    unsigned short* wT   = (unsigned short*)(LB1 + 95232);    // overlay: 96*72
    unsigned short* uT   = (unsigned short*)(LB1 + 109056);   // overlay: 192*72
    float* gr_s = (float*)(LB1 + 138752);
    float* gc_s = gr_s + 64;
    float* be_s = gc_s + 64;
    float* egc  = be_s + 64;   // e^(gl - gc_t); ends 139776

    if (tid < 64) {
        gr_s[tid] = gvec[(size_t)(t0 + tid) * HVN + h];
        be_s[tid] = bvec[(size_t)(t0 + tid) * HVN + h];
    }
    __syncthreads();
    if (tid < 64) {
        float sacc = 0.f;
        for (int j = 0; j <= tid; ++j) sacc += gr_s[j];
        gc_s[tid] = sacc;
    }
    __syncthreads();
    float gl = gc_s[63];
    if (tid < 64) egc[tid] = expf(gl - gc_s[tid]);

    int r = tid >> 2, sub = tid & 3;
    {
        const float* kp = qkv + (size_t)(t0 + r) * QKVD + 1536 + h * DKN + sub * 24;
        float kreg[24];
        float ss = 0.f;
#pragma unroll
        for (int i = 0; i < 6; ++i) {
            float4 v = *(const float4*)(kp + i * 4);
            kreg[i * 4 + 0] = v.x; kreg[i * 4 + 1] = v.y; kreg[i * 4 + 2] = v.z; kreg[i * 4 + 3] = v.w;
            ss += v.x * v.x + v.y * v.y + v.z * v.z + v.w * v.w;
        }
        ss += __shfl_xor(ss, 1, 64);
        ss += __shfl_xor(ss, 2, 64);
        float nrm = rsqrtf(ss + EPSF);
        float gcr = gc_s[r];
        float ebg = be_s[r] * expf(gcr);
#pragma unroll
        for (int i = 0; i < 24; ++i) {
            float kn = kreg[i] * nrm;
            QKb[r * 104 + sub * 24 + i] = f2bf(kn);
            RHSw[(sub * 24 + i) * 72 + r] = f2bf(kn * ebg);
        }
    }
    {
        const float* qp = qkv + (size_t)(t0 + r) * QKVD + 0 + h * DKN + sub * 24;
        float qreg[24];
        float ss = 0.f;
#pragma unroll
        for (int i = 0; i < 6; ++i) {
            float4 v = *(const float4*)(qp + i * 4);
            qreg[i * 4 + 0] = v.x; qreg[i * 4 + 1] = v.y; qreg[i * 4 + 2] = v.z; qreg[i * 4 + 3] = v.w;
            ss += v.x * v.x + v.y * v.y + v.z * v.z + v.w * v.w;
        }
        ss += __shfl_xor(ss, 1, 64);
        ss += __shfl_xor(ss, 2, 64);
        float nrm = rsqrtf(ss + EPSF) * 0.10206207261596577f;
        float eg = expf(gc_s[r]);
        float* qgp = qg_ws + base * (64 * 96) + r * 96 + sub * 24;
#pragma unroll
        for (int i = 0; i < 24; ++i) {
            float qn = qreg[i] * nrm;
            QKb[(64 + r) * 104 + sub * 24 + i] = f2bf(qn);
            qgp[i] = qn * eg;
        }
    }
    {
        const float* vp = qkv + (size_t)(t0 + r) * QKVD + 3072 + h * DVN + sub * 48;
        float ber = be_s[r];
#pragma unroll
        for (int i = 0; i < 12; ++i) {
            float4 v = *(const float4*)(vp + i * 4);
            int d = sub * 48 + i * 4;
            RHSv[(d + 0) * 72 + r] = f2bf(v.x * ber);
            RHSv[(d + 1) * 72 + r] = f2bf(v.y * ber);
            RHSv[(d + 2) * 72 + r] = f2bf(v.z * ber);
            RHSv[(d + 3) * 72 + r] = f2bf(v.w * ber);
        }
    }
    __syncthreads();

    // MFMA1: [Kn;Qn] @ Kn^T -> A (rows<64) and attn (rows>=64)
    {
        f32x4 acc1[2][4] = {};
#pragma unroll
        for (int ks = 0; ks < 3; ++ks) {
            int ko = ks * 32 + (lane >> 4) * 8;
            short8 af[2], bfv[4];
#pragma unroll
            for (int rt2 = 0; rt2 < 2; ++rt2)
                af[rt2] = *(const short8*)&QKb[(wave * 32 + rt2 * 16 + (lane & 15)) * 104 + ko];
#pragma unroll
            for (int ct = 0; ct < 4; ++ct)
                bfv[ct] = *(const short8*)&QKb[(ct * 16 + (lane & 15)) * 104 + ko];
#pragma unroll
            for (int rt2 = 0; rt2 < 2; ++rt2)
#pragma unroll
                for (int ct = 0; ct < 4; ++ct)
                    acc1[rt2][ct] = __builtin_amdgcn_mfma_f32_16x16x32_bf16(af[rt2], bfv[ct], acc1[rt2][ct], 0, 0, 0);
        }
#pragma unroll
        for (int rt2 = 0; rt2 < 2; ++rt2)
#pragma unroll
            for (int ct = 0; ct < 4; ++ct)
#pragma unroll
                for (int j = 0; j < 4; ++j) {
                    int rr = wave * 32 + rt2 * 16 + (lane >> 4) * 4 + j;
                    int cc = ct * 16 + (lane & 15);
                    float val = acc1[rt2][ct][j];
                    if (rr < 64) {
                        float av = (rr > cc) ? -be_s[rr] * expf(gc_s[rr] - gc_s[cc]) * val : 0.f;
                        unsigned short ab = f2bf(av);
                        Ab[rr * 104 + cc] = ab;
                        Atb[cc * 104 + rr] = ab;
                        float pv = (rr == cc) ? 1.f : av;
                        Pf[rr * 68 + cc] = pv;
                        unsigned short pb = f2bf(pv);
                        Pb[rr * 104 + cc] = pb;
                        Ptb[cc * 104 + rr] = pb;
                    } else {
                        int ar = rr - 64;
                        float av = (ar >= cc) ? expf(gc_s[ar] - gc_s[cc]) * val : 0.f;
                        at_ws[base * (64 * 64) + ar * 64 + cc] = av;
                    }
                }
    }
    __syncthreads();

    // doubling: T = (I+A)(I+A^2)(I+A^4)(I+A^8)(I+A^16)(I+A^32)
#pragma unroll 1
    for (int lev = 0; lev < 5; ++lev) {
        f32x4 d[4] = {};
#pragma unroll
        for (int ks = 0; ks < 2; ++ks) {
            int ko = ks * 32 + (lane >> 4) * 8;
            short8 a0 = *(const short8*)&Ab[(wave * 16 + (lane & 15)) * 104 + ko];
#pragma unroll
            for (int ct = 0; ct < 4; ++ct) {
                short8 b0 = *(const short8*)&Atb[(ct * 16 + (lane & 15)) * 104 + ko];
                d[ct] = __builtin_amdgcn_mfma_f32_16x16x32_bf16(a0, b0, d[ct], 0, 0, 0);
            }
        }
        __syncthreads();
#pragma unroll
        for (int ct = 0; ct < 4; ++ct)
#pragma unroll
            for (int j = 0; j < 4; ++j) {
                int rr = wave * 16 + (lane >> 4) * 4 + j;
                int cc = ct * 16 + (lane & 15);
                unsigned short hb = f2bf(d[ct][j]);
                Ab[rr * 104 + cc] = hb;
                Atb[cc * 104 + rr] = hb;
            }
        __syncthreads();
        f32x4 e[4];
#pragma unroll
        for (int ct = 0; ct < 4; ++ct)
#pragma unroll
            for (int j = 0; j < 4; ++j)
                e[ct][j] = Pf[(wave * 16 + (lane >> 4) * 4 + j) * 68 + ct * 16 + (lane & 15)];
#pragma unroll
        for (int ks = 0; ks < 2; ++ks) {
            int ko = ks * 32 + (lane >> 4) * 8;
            short8 a0 = *(const short8*)&Ab[(wave * 16 + (lane & 15)) * 104 + ko];
#pragma unroll
            for (int ct = 0; ct < 4; ++ct) {
                short8 b0 = *(const short8*)&Ptb[(ct * 16 + (lane & 15)) * 104 + ko];
                e[ct] = __builtin_amdgcn_mfma_f32_16x16x32_bf16(a0, b0, e[ct], 0, 0, 0);
            }
        }
        __syncthreads();
#pragma unroll
        for (int ct = 0; ct < 4; ++ct)
#pragma unroll
            for (int j = 0; j < 4; ++j) {
                int rr = wave * 16 + (lane >> 4) * 4 + j;
                int cc = ct * 16 + (lane & 15);
                float pv = e[ct][j];
                Pf[rr * 68 + cc] = pv;
                unsigned short pb = f2bf(pv);
                Pb[rr * 104 + cc] = pb;
                Ptb[cc * 104 + rr] = pb;
            }
        __syncthreads();
    }
    // --- after this barrier Ab/Atb/Ptb/Pf are dead; overlay kdT/wT/uT ---

    // stage kdT[d][t] = bf16( kn[t][d] * e^(gl - gc_t) )
    for (int f = tid; f < 6144; f += 256) {
        int d = f >> 6, tt = f & 63;
        kdT[d * 72 + tt] = f2bf(bf2f(QKb[tt * 104 + d]) * egc[tt]);
    }

    // u/w = T @ [v*beta | k*beta*e^gc]; write u_ws/w_ws (f32) and uT/wT (bf16 transposed)
#pragma unroll 1
    for (int i = 0; i < 18; ++i) {
        int id = wave * 18 + i;
        int rt = id & 3, ct = id >> 2;
        f32x4 o4 = {};
#pragma unroll
        for (int ks = 0; ks < 2; ++ks) {
            int ko = ks * 32 + (lane >> 4) * 8;
            short8 a0 = *(const short8*)&Pb[(rt * 16 + (lane & 15)) * 104 + ko];
            short8 b0 = (ct < 12)
                ? *(const short8*)&RHSv[(ct * 16 + (lane & 15)) * 72 + ko]
                : *(const short8*)&RHSw[((ct - 12) * 16 + (lane & 15)) * 72 + ko];
            o4 = __builtin_amdgcn_mfma_f32_16x16x32_bf16(a0, b0, o4, 0, 0, 0);
        }
#pragma unroll
        for (int j = 0; j < 4; ++j) {
            int rr = rt * 16 + (lane >> 4) * 4 + j;
            int nn = ct * 16 + (lane & 15);
            if (ct < 12) {
                u_ws[base * (64 * 192) + rr * 192 + nn] = o4[j];
                uT[nn * 72 + rr] = f2bf(o4[j]);
            } else {
                w_ws[base * (64 * 96) + rr * 96 + (nn - 192)] = o4[j];
                wT[(nn - 192) * 72 + rr] = f2bf(o4[j]);
            }
        }
    }
    __syncthreads();

    // fused tprep: Tn = e^gl I - kd^T w (bf16, stride-104), Ct = u^T kd (f32)
    float eglv = expf(gl);
#pragma unroll 1
    for (int q = 0; q < 27; ++q) {
        int id = wave * 27 + q;
        f32x4 acc = {};
        if (id < 36) {
            int jt = id / 6, kt = id % 6;
#pragma unroll
            for (int ks = 0; ks < 2; ++ks) {
                int ko = ks * 32 + (lane >> 4) * 8;
                short8 a0 = *(const short8*)&kdT[(jt * 16 + (lane & 15)) * 72 + ko];
                short8 b0 = *(const short8*)&wT[(kt * 16 + (lane & 15)) * 72 + ko];
                acc = __builtin_amdgcn_mfma_f32_16x16x32_bf16(a0, b0, acc, 0, 0, 0);
            }
#pragma unroll
            for (int rr = 0; rr < 4; ++rr) {
                int j = jt * 16 + (lane >> 4) * 4 + rr;
                int k = kt * 16 + (lane & 15);
                float val = -acc[rr];
                if (j == k) val += eglv;
                Tn[base * TN_STRIDE + j * 104 + k] = f2bf(val);
            }
        } else {
            int cid = id - 36;
            int it = cid / 6, jt = cid % 6;
#pragma unroll
            for (int ks = 0; ks < 2; ++ks) {
                int ko = ks * 32 + (lane >> 4) * 8;
                short8 a0 = *(const short8*)&uT[(it * 16 + (lane & 15)) * 72 + ko];
                short8 b0 = *(const short8*)&kdT[(jt * 16 + (lane & 15)) * 72 + ko];
                acc = __builtin_amdgcn_mfma_f32_16x16x32_bf16(a0, b0, acc, 0, 0, 0);
            }
#pragma unroll
            for (int rr = 0; rr < 4; ++rr)
                Ct[base * 18432 + (size_t)(it * 16 + (lane >> 4) * 4 + rr) * 96 + jt * 16 + (lane & 15)] = acc[rr];
        }
    }
    if (tid == 0) gl_ws[base] = gl;
}

// ---------------- mscan: St_{n+1} = St_n @ T_n^T + Ct_n ----------------
__global__ __launch_bounds__(128) void mscan(const float* __restrict__ Ct, const unsigned short* __restrict__ Tn,
                                             float* __restrict__ s_ws) {
    int rg = blockIdx.x, h = blockIdx.y;
    int tid = threadIdx.x, wave = tid >> 6, lane = tid & 63;
    __shared__ __align__(16) unsigned short St[48 * 104];
    __shared__ __align__(16) unsigned short TnB[2][TN_STRIDE];
    __shared__ __align__(16) float CtB[2][48 * 96];
    for (int i = tid; i < 48 * 104; i += 128) St[i] = 0;

    {
        const float* cp = Ct + (size_t)(h * NCHUNK) * 18432 + rg * (48 * 96);
        const unsigned short* tp = Tn + (size_t)(h * NCHUNK) * TN_STRIDE;
#pragma unroll
        for (int q = 0; q < 9; ++q) {
            size_t o = (size_t)(wave * 9 + q) * 1024 + lane * 16;
            gld_lds16((const char*)cp + o, (char*)&CtB[0][0] + (size_t)(wave * 9 + q) * 1024);
        }
#pragma unroll
        for (int q = 0; q < 10; ++q) {
            size_t o = (size_t)(wave * 10 + q) * 1024 + lane * 16;
            gld_lds16((const char*)tp + o, (char*)&TnB[0][0] + (size_t)(wave * 10 + q) * 1024);
        }
    }
    f32x4 acc[3][3] = {};
    int colw = wave * 48;
    __syncthreads();

#pragma unroll 1
    for (int n = 0; n < NCHUNK; ++n) {
        size_t base = (size_t)(h * NCHUNK + n);
        int cur = n & 1;
        if (n + 1 < NCHUNK) {
            const float* cp = Ct + (base + 1) * 18432 + rg * (48 * 96);
            const unsigned short* tp = Tn + (base + 1) * TN_STRIDE;
#pragma unroll
            for (int q = 0; q < 9; ++q) {
                size_t o = (size_t)(wave * 9 + q) * 1024 + lane * 16;
                gld_lds16((const char*)cp + o, (char*)&CtB[cur ^ 1][0] + (size_t)(wave * 9 + q) * 1024);
            }
#pragma unroll
            for (int q = 0; q < 10; ++q) {
                size_t o = (size_t)(wave * 10 + q) * 1024 + lane * 16;
                gld_lds16((const char*)tp + o, (char*)&TnB[cur ^ 1][0] + (size_t)(wave * 10 + q) * 1024);
            }
        }
        float* sp = s_ws + base * 18432 + rg * (48 * 96);
#pragma unroll
        for (int it = 0; it < 3; ++it)
#pragma unroll
            for (int jt = 0; jt < 3; ++jt) {
                int irow = it * 16 + (lane >> 4) * 4;
                int col = colw + jt * 16 + (lane & 15);
#pragma unroll
                for (int r = 0; r < 4; ++r) {
                    sp[(size_t)(irow + r) * 96 + col] = acc[it][jt][r];
                    acc[it][jt][r] = CtB[cur][(irow + r) * 96 + col];
                }
            }
#pragma unroll
        for (int ks = 0; ks < 3; ++ks) {
            int ko = ks * 32 + (lane >> 4) * 8;
            short8 af[3], bfv[3];
#pragma unroll
            for (int it = 0; it < 3; ++it)
                af[it] = *(const short8*)&St[(it * 16 + (lane & 15)) * 104 + ko];
#pragma unroll
            for (int jt = 0; jt < 3; ++jt)
                bfv[jt] = *(const short8*)&TnB[cur][(colw + jt * 16 + (lane & 15)) * 104 + ko];
#pragma unroll
            for (int it = 0; it < 3; ++it)
#pragma unroll
                for (int jt = 0; jt < 3; ++jt)
                    acc[it][jt] = __builtin_amdgcn_mfma_f32_16x16x32_bf16(af[it], bfv[jt], acc[it][jt], 0, 0, 0);
        }
        __syncthreads();
#pragma unroll
        for (int it = 0; it < 3; ++it)
#pragma unroll
            for (int jt = 0; jt < 3; ++jt)
#pragma unroll
                for (int r = 0; r < 4; ++r)
                    St[(it * 16 + (lane >> 4) * 4 + r) * 104 + colw + jt * 16 + (lane & 15)] = f2bf(acc[it][jt][r]);
        __syncthreads();
    }
}

// ---------------- phase2b (MFMA) + fused gate/RMSNorm -> obf ----------------
#define P2_ST 0
#define P2_W  39936
#define P2_QG 53248
#define P2_AT 66560
#define P2_U  75776
#define P2_VN 125952
__global__ __launch_bounds__(256) void phase2b_mfma(const float* __restrict__ s_ws, const float* __restrict__ w_ws,
                                                    const float* __restrict__ qg_ws, const float* __restrict__ at_ws,
                                                    const float* __restrict__ u_ws,
                                                    const unsigned short* __restrict__ Cgate,
                                                    const float* __restrict__ nw,
                                                    unsigned short* __restrict__ obf) {
    __shared__ __align__(16) char LB[153600];
    unsigned short* StB = (unsigned short*)(LB + P2_ST);
    unsigned short* wB  = (unsigned short*)(LB + P2_W);
    unsigned short* qgB = (unsigned short*)(LB + P2_QG);
    unsigned short* atB = (unsigned short*)(LB + P2_AT);
    float* uF           = (float*)(LB + P2_U);
    unsigned short* vnB = (unsigned short*)(LB + P2_VN);
    int n = blockIdx.x, h = blockIdx.y;
    size_t base = (size_t)(h * NCHUNK + n);
    int tid = threadIdx.x, wave = tid >> 6, lane = tid & 63;
    int i0w = wave * 48;
    {
        const float* sp = s_ws + base * 18432;
        for (int f = tid; f < 4608; f += 256) {
            int i = f / 24, c4 = (f % 24) * 4;
            float4 v = *(const float4*)(sp + i * 96 + c4);
            ushort4 o4; o4.x = f2bf(v.x); o4.y = f2bf(v.y); o4.z = f2bf(v.z); o4.w = f2bf(v.w);
            *(ushort4*)&StB[i * 104 + c4] = o4;
        }
    }
    {
        const float* wp = w_ws + base * 6144;
        const float* qp = qg_ws + base * 6144;
        for (int f = tid; f < 1536; f += 256) {
            int t = f / 24, c4 = (f % 24) * 4;
            float4 wv = *(const float4*)(wp + t * 96 + c4);
            float4 qv = *(const float4*)(qp + t * 96 + c4);
            ushort4 ow; ow.x = f2bf(-wv.x); ow.y = f2bf(-wv.y); ow.z = f2bf(-wv.z); ow.w = f2bf(-wv.w);
            ushort4 oq; oq.x = f2bf(qv.x); oq.y = f2bf(qv.y); oq.z = f2bf(qv.z); oq.w = f2bf(qv.w);
            *(ushort4*)&wB[t * 104 + c4] = ow;
            *(ushort4*)&qgB[t * 104 + c4] = oq;
        }
    }
    {
        const float* ap = at_ws + base * 4096;
        for (int f = tid; f < 1024; f += 256) {
            int t = f / 16, c4 = (f % 16) * 4;
            float4 av = *(const float4*)(ap + t * 64 + c4);
            ushort4 oa; oa.x = f2bf(av.x); oa.y = f2bf(av.y); oa.z = f2bf(av.z); oa.w = f2bf(av.w);
            *(ushort4*)&atB[t * 72 + c4] = oa;
        }
    }
    {
        const float* up = u_ws + base * 12288;
        for (int f = tid; f < 3072; f += 256) {
            int t = f / 48, c4 = (f % 48) * 4;
            *(float4*)&uF[t * 196 + c4] = *(const float4*)(up + t * 192 + c4);
        }
    }
    __syncthreads();
    {
        f32x4 acc[3][4];
#pragma unroll
        for (int it = 0; it < 3; ++it)
#pragma unroll
            for (int jt = 0; jt < 4; ++jt)
#pragma unroll
                for (int r = 0; r < 4; ++r)
                    acc[it][jt][r] = uF[(jt * 16 + (lane & 15)) * 196 + i0w + it * 16 + (lane >> 4) * 4 + r];
#pragma unroll
        for (int ks = 0; ks < 3; ++ks) {
            int ko = ks * 32 + (lane >> 4) * 8;
            short8 af[3], bfv[4];
#pragma unroll
            for (int it = 0; it < 3; ++it)
                af[it] = *(const short8*)&StB[(i0w + it * 16 + (lane & 15)) * 104 + ko];
#pragma unroll
            for (int jt = 0; jt < 4; ++jt)
                bfv[jt] = *(const short8*)&wB[(jt * 16 + (lane & 15)) * 104 + ko];
#pragma unroll
            for (int it = 0; it < 3; ++it)
#pragma unroll
                for (int jt = 0; jt < 4; ++jt)
                    acc[it][jt] = __builtin_amdgcn_mfma_f32_16x16x32_bf16(af[it], bfv[jt], acc[it][jt], 0, 0, 0);
        }
#pragma unroll
        for (int it = 0; it < 3; ++it)
#pragma unroll
            for (int jt = 0; jt < 4; ++jt)
#pragma unroll
                for (int r = 0; r < 4; ++r)
                    vnB[(i0w + it * 16 + (lane >> 4) * 4 + r) * 72 + jt * 16 + (lane & 15)] = f2bf(acc[it][jt][r]);
    }
    f32x4 acc2[3][4] = {};
#pragma unroll
    for (int ks = 0; ks < 3; ++ks) {
        int ko = ks * 32 + (lane >> 4) * 8;
        short8 af[3], bfv[4];
#pragma unroll
        for (int it = 0; it < 3; ++it)
            af[it] = *(const short8*)&StB[(i0w + it * 16 + (lane & 15)) * 104 + ko];
#pragma unroll
        for (int jt = 0; jt < 4; ++jt)
            bfv[jt] = *(const short8*)&qgB[(jt * 16 + (lane & 15)) * 104 + ko];
#pragma unroll
        for (int it = 0; it < 3; ++it)
#pragma unroll
            for (int jt = 0; jt < 4; ++jt)
                acc2[it][jt] = __builtin_amdgcn_mfma_f32_16x16x32_bf16(af[it], bfv[jt], acc2[it][jt], 0, 0, 0);
    }
#pragma unroll
    for (int ks = 0; ks < 2; ++ks) {
        int ko = ks * 32 + (lane >> 4) * 8;
        short8 af[3], bfv[4];
#pragma unroll
        for (int it = 0; it < 3; ++it)
            af[it] = *(const short8*)&vnB[(i0w + it * 16 + (lane & 15)) * 72 + ko];
#pragma unroll
        for (int jt = 0; jt < 4; ++jt)
            bfv[jt] = *(const short8*)&atB[(jt * 16 + (lane & 15)) * 72 + ko];
#pragma unroll
        for (int it = 0; it < 3; ++it)
#pragma unroll
            for (int jt = 0; jt < 4; ++jt)
                acc2[it][jt] = __builtin_amdgcn_mfma_f32_16x16x32_bf16(af[it], bfv[jt], acc2[it][jt], 0, 0, 0);
    }
    __syncthreads();
    float* oF = (float*)(LB + 0); // [192][68] (StB region; dead)
#pragma unroll
    for (int it = 0; it < 3; ++it)
#pragma unroll
        for (int jt = 0; jt < 4; ++jt)
#pragma unroll
            for (int r = 0; r < 4; ++r)
                oF[(i0w + it * 16 + (lane >> 4) * 4 + r) * 68 + jt * 16 + (lane & 15)] = acc2[it][jt][r];
    __syncthreads();

    // fused gate (SiLU) + RMSNorm over dv=192 per t-column, write obf
    float* ssq = (float*)(LB + 131072);  // [64][4] (vnB region; dead)
    float* rno = (float*)(LB + 132096);  // [64]
    int jj = tid >> 2, qq = tid & 3;
    int t0 = n * CHUNKN;
    {
        const unsigned short* gp = Cgate + (size_t)(t0 + jj) * VDIMN + h * DVN + qq * 48;
        float ss = 0.f;
#pragma unroll 4
        for (int m = 0; m < 48; ++m) {
            int i = qq * 48 + m;
            float x = oF[i * 68 + jj];
            float g = bf2f(gp[m]);
            float xv = x * siluf(g);
            oF[i * 68 + jj] = xv;
            ss += xv * xv;
        }
        ssq[jj * 4 + qq] = ss;
    }
    __syncthreads();
    if (tid < 64) {
        float tot = ssq[tid * 4] + ssq[tid * 4 + 1] + ssq[tid * 4 + 2] + ssq[tid * 4 + 3];
        rno[tid] = rsqrtf(tot * (1.f / 192.f) + EPSF);
    }
    __syncthreads();
    {
        float rr2 = rno[jj];
        unsigned short* op = obf + (size_t)(t0 + jj) * VDIMN + h * DVN + qq * 48;
#pragma unroll 4
        for (int m = 0; m < 48; ++m) {
            int i = qq * 48 + m;
            op[m] = f2bf(oF[i * 68 + jj] * rr2 * nw[i]);
        }
    }
}

extern "C" void kernel_launch(void* const* d_in, const int* in_sizes, int n_in,
                              void* d_out, int out_size, void* d_ws, size_t ws_size,
                              hipStream_t stream) {
    (void)in_sizes; (void)n_in; (void)out_size;
    const float* X    = (const float*)d_in[0];
    const float* Wq   = (const float*)d_in[1];
    const float* Wk   = (const float*)d_in[2];
    const float* Wv   = (const float*)d_in[3];
    const float* Wb   = (const float*)d_in[4];
    const float* Wa   = (const float*)d_in[5];
    const float* Wg   = (const float*)d_in[6];
    const float* Wo   = (const float*)d_in[7];
    const float* cq   = (const float*)d_in[8];
    const float* ck   = (const float*)d_in[9];
    const float* cv   = (const float*)d_in[10];
    const float* Alog = (const float*)d_in[11];
    const float* dtb  = (const float*)d_in[12];
    const float* nw   = (const float*)d_in[13];

    const size_t OFF_XBF   = 0;
    const size_t OFF_WALLT = 8388608;
    const size_t OFF_WOT   = 46137344;
    const size_t OFF_CQKV  = 58720256;
    const size_t OFF_CGATE = 109051904;             // bf16 gate
    const size_t OFF_QPOST = 134217728;             // qkvpost fused [2048][6144] f32 (50.3 MB)
    const size_t OFF_GVEC  = 184549376;
    const size_t OFF_BVEC  = 184680448;
    const size_t OFF_GL    = 184811520;
    const size_t OFF_U     = 184819712;
    const size_t OFF_W     = 209985536;
    const size_t OFF_QG    = 222568448;
    const size_t OFF_KD    = 235151360;             // unused now
    const size_t OFF_AT    = OFF_XBF;               // after proj gemm
    const size_t OFF_CT    = OFF_CQKV;              // after conv (phase1 writes)
    const size_t OFF_TN    = OFF_CQKV + 37748736;
    const size_t OFF_S     = OFF_QPOST;             // after phase1
    const size_t OFF_OBF   = OFF_WALLT + 25165824;  // obf 12.6 MB (WallT dead after gemms)
    const size_t OFF_OPART = OFF_CQKV;              // after mscan/phase2b
    const size_t NEEDED    = 247734272;
    if (ws_size < NEEDED) return;

    char* ws = (char*)d_ws;
    unsigned short* Xbf   = (unsigned short*)(ws + OFF_XBF);
    unsigned short* WallT = (unsigned short*)(ws + OFF_WALLT);
    unsigned short* WoT   = (unsigned short*)(ws + OFF_WOT);
    float* Cqkv  = (float*)(ws + OFF_CQKV);
    unsigned short* Cgate = (unsigned short*)(ws + OFF_CGATE);
    float* qkvpost = (float*)(ws + OFF_QPOST);
    float* gvec  = (float*)(ws + OFF_GVEC);
    float* bvec  = (float*)(ws + OFF_BVEC);
    float* gl_ws = (float*)(ws + OFF_GL);
    float* u_ws  = (float*)(ws + OFF_U);
    float* w_ws  = (float*)(ws + OFF_W);
    float* qg_ws = (float*)(ws + OFF_QG);
    float* at_ws = (float*)(ws + OFF_AT);
    float* Ct    = (float*)(ws + OFF_CT);
    unsigned short* Tn = (unsigned short*)(ws + OFF_TN);
    float* s_ws  = (float*)(ws + OFF_S);
    unsigned short* obf = (unsigned short*)(ws + OFF_OBF);
    float* opart = (float*)(ws + OFF_OPART);

    cast_f32_bf16<<<4096, 256, 0, stream>>>(X, Xbf, 2048 * 2048);
    dim3 tb(64, 4);
    transpose_cast<<<dim3(1536 / 64, 2048 / 64), tb, 0, stream>>>(Wq, WallT, 2048, 1536);
    transpose_cast<<<dim3(1536 / 64, 2048 / 64), tb, 0, stream>>>(Wk, WallT + (size_t)1536 * 2048, 2048, 1536);
    transpose_cast<<<dim3(3072 / 64, 2048 / 64), tb, 0, stream>>>(Wv, WallT + (size_t)3072 * 2048, 2048, 3072);
    transpose_cast<<<dim3(3072 / 64, 2048 / 64), tb, 0, stream>>>(Wg, WallT + (size_t)6144 * 2048, 2048, 3072);
    transpose_cast<<<dim3(2048 / 64, 3072 / 64), tb, 0, stream>>>(Wo, WoT, 3072, 2048);

    // fused QKV (f32) + gate (bf16) projection, 2-phase pipelined
    gemm_bt2<<<dim3(9216 / 128, 2048 / 128), 256, 0, stream>>>(Xbf, WallT,
                                                               Cqkv, QKVD, QKVD / 128,
                                                               Cgate, VDIMN, 2048, 2048);

    conv_silu_all<<<dim3(QKVD / 256, T_LEN), 256, 0, stream>>>(Cqkv, cq, ck, cv, qkvpost);
    beta_g<<<T_LEN, 256, 0, stream>>>(X, Wb, Wa, Alog, dtb, bvec, gvec);

    phase1_mfma<<<dim3(NCHUNK, HVN), 256, 0, stream>>>(qkvpost, gvec, bvec,
                                                       u_ws, w_ws, qg_ws, at_ws, gl_ws, Ct, Tn);
    mscan<<<dim3(4, HVN), 128, 0, stream>>>(Ct, Tn, s_ws);
    phase2b_mfma<<<dim3(NCHUNK, HVN), 256, 0, stream>>>(s_ws, w_ws, qg_ws, at_ws, u_ws,
                                                        Cgate, nw, obf);

    // output GEMM split-K=3 (2-phase pipelined) + deterministic fixup
    gemm_btk<<<dim3(2048 / 128, 2048 / 128, 3), 256, 0, stream>>>(obf, WoT, (float*)d_out, opart,
                                                                  2048, 2048, 3072);
    addk<<<4096, 256, 0, stream>>>((float*)d_out, opart, 2048 * 2048);
}

// Round 12
// 413.514 us; speedup vs baseline: 1.9435x; 1.1218x over previous
//
#include <hip/hip_runtime.h>
#include <math.h>

#define T_LEN 2048
#define HIDN  2048
#define HKN   16
#define DKN   96
#define HVN   16
#define DVN   192
#define KDIMN 1536
#define VDIMN 3072
#define QKVD  6144   // q(1536)+k(1536)+v(3072)
#define CHUNKN 64
#define NCHUNK 32
#define EPSF 1e-6f
#define TN_STRIDE 10240   // ushorts per (chunk,head) Tn record

typedef __attribute__((ext_vector_type(8))) short short8;
typedef __attribute__((ext_vector_type(4))) float f32x4;

__device__ __forceinline__ unsigned short f2bf(float f) {
    unsigned int u = __float_as_uint(f);
    unsigned int r = (u + 0x7FFFu + ((u >> 16) & 1u)) >> 16;
    return (unsigned short)r;
}
__device__ __forceinline__ float bf2f(unsigned short u) {
    return __uint_as_float(((unsigned int)u) << 16);
}
__device__ __forceinline__ float siluf(float x) { return x / (1.f + expf(-x)); }

__device__ __forceinline__ void gld_lds16(const void* g, void* l) {
    __builtin_amdgcn_global_load_lds((const __attribute__((address_space(1))) unsigned int*)g,
                                     (__attribute__((address_space(3))) unsigned int*)l, 16, 0, 0);
}

// ---------------- cast f32 -> bf16 (4/thread) ----------------
__global__ void cast_f32_bf16(const float* __restrict__ in, unsigned short* __restrict__ out, int n) {
    int i = (blockIdx.x * blockDim.x + threadIdx.x) * 4;
    if (i >= n) return;
    float4 v = *(const float4*)(in + i);
    ushort4 o;
    o.x = f2bf(v.x); o.y = f2bf(v.y); o.z = f2bf(v.z); o.w = f2bf(v.w);
    *(ushort4*)(out + i) = o;
}

// ---------------- fused weight transposes: 5 weights, one dispatch ----------------
// tiles: Wq 768 | Wk 768 | Wv 1536 | Wg 1536 | Wo 1536  (64x64 tiles, block=(64,4))
__global__ void prep_weights(const float* __restrict__ Wq, const float* __restrict__ Wk,
                             const float* __restrict__ Wv, const float* __restrict__ Wg,
                             const float* __restrict__ Wo,
                             unsigned short* __restrict__ WallT, unsigned short* __restrict__ WoT) {
    __shared__ float tile[64][65];
    int bid = blockIdx.x;
    const float* W; unsigned short* Wt; int K, N, l;
    if (bid < 768)       { W = Wq; Wt = WallT;                          K = 2048; N = 1536; l = bid; }
    else if (bid < 1536) { W = Wk; Wt = WallT + (size_t)1536 * 2048;    K = 2048; N = 1536; l = bid - 768; }
    else if (bid < 3072) { W = Wv; Wt = WallT + (size_t)3072 * 2048;    K = 2048; N = 3072; l = bid - 1536; }
    else if (bid < 4608) { W = Wg; Wt = WallT + (size_t)6144 * 2048;    K = 2048; N = 3072; l = bid - 3072; }
    else                 { W = Wo; Wt = WoT;                            K = 3072; N = 2048; l = bid - 4608; }
    int nbx = N >> 6;
    int n0 = (l % nbx) * 64, k0 = (l / nbx) * 64;
    int tx = threadIdx.x, ty = threadIdx.y;
    for (int r = ty; r < 64; r += 4) tile[r][tx] = W[(size_t)(k0 + r) * N + n0 + tx];
    __syncthreads();
    for (int r = ty; r < 64; r += 4) Wt[(size_t)(n0 + r) * K + k0 + tx] = f2bf(tile[tx][r]);
}

// ---------------- fused projection GEMM, 2-phase double-buffered LDS ----------------
__global__ __launch_bounds__(256) void gemm_bt2(const unsigned short* __restrict__ A,
                                                const unsigned short* __restrict__ Bt,
                                                float* __restrict__ C1, int ld1, int nblk1,
                                                unsigned short* __restrict__ C2, int ld2,
                                                int M, int K) {
    __shared__ __align__(16) unsigned short As[2][128 * 32];
    __shared__ __align__(16) unsigned short Bs[2][128 * 32];
    int tid = threadIdx.x;
    int wave = tid >> 6, lane = tid & 63;
    int bm = blockIdx.y, bn = blockIdx.x;
    f32x4 acc[4][4] = {};
    int wr = wave >> 1, wc = wave & 1;
    int rstage = wave * 32 + (lane >> 2);
    int cstage = (lane & 3) * 8;
    const size_t a_row0 = (size_t)bm * 128;
    const size_t b_row0 = (size_t)bn * 128;
    const unsigned short* gaBase = A + (a_row0 + rstage) * (size_t)K + cstage;
    const unsigned short* gbBase = Bt + (b_row0 + rstage) * (size_t)K + cstage;
    int row_a[4], row_b[4];
#pragma unroll
    for (int i = 0; i < 4; ++i) {
        row_a[i] = wr * 64 + i * 16 + (lane & 15);
        row_b[i] = wc * 64 + i * 16 + (lane & 15);
    }
    int koff = (lane >> 4) * 8;
    int niter = K >> 5;
    {
        unsigned short* ab = &As[0][wave * 1024];
        unsigned short* bb = &Bs[0][wave * 1024];
        gld_lds16(gaBase, ab);
        gld_lds16(gaBase + (size_t)16 * K, ab + 512);
        gld_lds16(gbBase, bb);
        gld_lds16(gbBase + (size_t)16 * K, bb + 512);
    }
    __syncthreads();
    for (int i = 0; i < niter; ++i) {
        int cur = i & 1;
        if (i + 1 < niter) {
            int k0 = (i + 1) * 32;
            unsigned short* ab = &As[cur ^ 1][wave * 1024];
            unsigned short* bb = &Bs[cur ^ 1][wave * 1024];
            gld_lds16(gaBase + k0, ab);
            gld_lds16(gaBase + k0 + (size_t)16 * K, ab + 512);
            gld_lds16(gbBase + k0, bb);
            gld_lds16(gbBase + k0 + (size_t)16 * K, bb + 512);
        }
        short8 af[4], bfr[4];
#pragma unroll
        for (int mi = 0; mi < 4; ++mi) af[mi] = *(const short8*)&As[cur][row_a[mi] * 32 + koff];
#pragma unroll
        for (int ni = 0; ni < 4; ++ni) bfr[ni] = *(const short8*)&Bs[cur][row_b[ni] * 32 + koff];
#pragma unroll
        for (int mi = 0; mi < 4; ++mi)
#pragma unroll
            for (int ni = 0; ni < 4; ++ni)
                acc[mi][ni] = __builtin_amdgcn_mfma_f32_16x16x32_bf16(af[mi], bfr[ni], acc[mi][ni], 0, 0, 0);
        __syncthreads();
    }
    if (bn < nblk1) {
        int colb = bn * 128;
#pragma unroll
        for (int mi = 0; mi < 4; ++mi) {
            int rbase = bm * 128 + wr * 64 + mi * 16 + (lane >> 4) * 4;
#pragma unroll
            for (int ni = 0; ni < 4; ++ni) {
                int col = colb + wc * 64 + ni * 16 + (lane & 15);
#pragma unroll
                for (int j = 0; j < 4; ++j)
                    C1[(size_t)(rbase + j) * ld1 + col] = acc[mi][ni][j];
            }
        }
    } else {
        int colb = (bn - nblk1) * 128;
#pragma unroll
        for (int mi = 0; mi < 4; ++mi) {
            int rbase = bm * 128 + wr * 64 + mi * 16 + (lane >> 4) * 4;
#pragma unroll
            for (int ni = 0; ni < 4; ++ni) {
                int col = colb + wc * 64 + ni * 16 + (lane & 15);
#pragma unroll
                for (int j = 0; j < 4; ++j)
                    C2[(size_t)(rbase + j) * ld2 + col] = f2bf(acc[mi][ni][j]);
            }
        }
    }
}

// ---------------- split-K GEMM (SPLIT=3), 2-phase double-buffered LDS ----------------
__global__ __launch_bounds__(256) void gemm_btk(const unsigned short* __restrict__ A,
                                                const unsigned short* __restrict__ Bt,
                                                float* __restrict__ C, float* __restrict__ Cp,
                                                int M, int N, int K) {
    __shared__ __align__(16) unsigned short As[2][128 * 32];
    __shared__ __align__(16) unsigned short Bs[2][128 * 32];
    int tid = threadIdx.x;
    int wave = tid >> 6, lane = tid & 63;
    int bm = blockIdx.y, bn = blockIdx.x, kz = blockIdx.z;
    int kchunk = K / 3;
    int kbeg = kz * kchunk;
    f32x4 acc[4][4] = {};
    int wr = wave >> 1, wc = wave & 1;
    int rstage = wave * 32 + (lane >> 2);
    int cstage = (lane & 3) * 8;
    const size_t a_row0 = (size_t)bm * 128;
    const size_t b_row0 = (size_t)bn * 128;
    const unsigned short* gaBase = A + (a_row0 + rstage) * (size_t)K + kbeg + cstage;
    const unsigned short* gbBase = Bt + (b_row0 + rstage) * (size_t)K + kbeg + cstage;
    int row_a[4], row_b[4];
#pragma unroll
    for (int i = 0; i < 4; ++i) {
        row_a[i] = wr * 64 + i * 16 + (lane & 15);
        row_b[i] = wc * 64 + i * 16 + (lane & 15);
    }
    int koff = (lane >> 4) * 8;
    int niter = kchunk >> 5;
    {
        unsigned short* ab = &As[0][wave * 1024];
        unsigned short* bb = &Bs[0][wave * 1024];
        gld_lds16(gaBase, ab);
        gld_lds16(gaBase + (size_t)16 * K, ab + 512);
        gld_lds16(gbBase, bb);
        gld_lds16(gbBase + (size_t)16 * K, bb + 512);
    }
    __syncthreads();
    for (int i = 0; i < niter; ++i) {
        int cur = i & 1;
        if (i + 1 < niter) {
            int k0 = (i + 1) * 32;
            unsigned short* ab = &As[cur ^ 1][wave * 1024];
            unsigned short* bb = &Bs[cur ^ 1][wave * 1024];
            gld_lds16(gaBase + k0, ab);
            gld_lds16(gaBase + k0 + (size_t)16 * K, ab + 512);
            gld_lds16(gbBase + k0, bb);
            gld_lds16(gbBase + k0 + (size_t)16 * K, bb + 512);
        }
        short8 af[4], bfr[4];
#pragma unroll
        for (int mi = 0; mi < 4; ++mi) af[mi] = *(const short8*)&As[cur][row_a[mi] * 32 + koff];
#pragma unroll
        for (int ni = 0; ni < 4; ++ni) bfr[ni] = *(const short8*)&Bs[cur][row_b[ni] * 32 + koff];
#pragma unroll
        for (int mi = 0; mi < 4; ++mi)
#pragma unroll
            for (int ni = 0; ni < 4; ++ni)
                acc[mi][ni] = __builtin_amdgcn_mfma_f32_16x16x32_bf16(af[mi], bfr[ni], acc[mi][ni], 0, 0, 0);
        __syncthreads();
    }
    float* Cout = (kz == 0) ? C : (Cp + (size_t)(kz - 1) * M * N);
#pragma unroll
    for (int mi = 0; mi < 4; ++mi) {
        int rbase = bm * 128 + wr * 64 + mi * 16 + (lane >> 4) * 4;
#pragma unroll
        for (int ni = 0; ni < 4; ++ni) {
            int col = bn * 128 + wc * 64 + ni * 16 + (lane & 15);
#pragma unroll
            for (int j = 0; j < 4; ++j)
                Cout[(size_t)(rbase + j) * N + col] = acc[mi][ni][j];
        }
    }
}

// ---------------- addk: out += p0 + p1 ----------------
__global__ void addk(float* __restrict__ out, const float* __restrict__ p, int n) {
    int i = (blockIdx.x * blockDim.x + threadIdx.x) * 4;
    if (i >= n) return;
    float4 a = *(const float4*)(out + i);
    float4 b = *(const float4*)(p + i);
    float4 c = *(const float4*)(p + n + i);
    a.x += b.x + c.x; a.y += b.y + c.y; a.z += b.z + c.z; a.w += b.w + c.w;
    *(float4*)(out + i) = a;
}

// ---------------- beta / g projections (f32, vectorized) ----------------
__global__ __launch_bounds__(256) void beta_g(const float* __restrict__ X,
                                              const float* __restrict__ Wb, const float* __restrict__ Wa,
                                              const float* __restrict__ A_log, const float* __restrict__ dtb,
                                              float* __restrict__ bvec, float* __restrict__ gvec) {
    int t = blockIdx.x;
    int tid = threadIdx.x;
    int cg = tid & 7, ks = tid >> 3;
    int wave = tid >> 6, lane = tid & 63;
    const float* xr = X + (size_t)t * HIDN;
    const float* Wsel = (cg < 4) ? Wb : Wa;
    int cc = (cg & 3) * 4;
    float ax = 0.f, ay = 0.f, az = 0.f, aw = 0.f;
#pragma unroll 4
    for (int i = 0; i < 16; ++i) {
        int k = (ks + 32 * i) * 4;
        float4 xv = *(const float4*)(xr + k);
        float4 w0 = *(const float4*)(Wsel + (size_t)(k + 0) * 16 + cc);
        float4 w1 = *(const float4*)(Wsel + (size_t)(k + 1) * 16 + cc);
        float4 w2 = *(const float4*)(Wsel + (size_t)(k + 2) * 16 + cc);
        float4 w3 = *(const float4*)(Wsel + (size_t)(k + 3) * 16 + cc);
        ax += xv.x * w0.x + xv.y * w1.x + xv.z * w2.x + xv.w * w3.x;
        ay += xv.x * w0.y + xv.y * w1.y + xv.z * w2.y + xv.w * w3.y;
        az += xv.x * w0.z + xv.y * w1.z + xv.z * w2.z + xv.w * w3.z;
        aw += xv.x * w0.w + xv.y * w1.w + xv.z * w2.w + xv.w * w3.w;
    }
#pragma unroll
    for (int off = 8; off <= 32; off <<= 1) {
        ax += __shfl_xor(ax, off, 64);
        ay += __shfl_xor(ay, off, 64);
        az += __shfl_xor(az, off, 64);
        aw += __shfl_xor(aw, off, 64);
    }
    __shared__ float red[4][8][4];
    if ((lane >> 3) == 0) {
        red[wave][cg][0] = ax; red[wave][cg][1] = ay;
        red[wave][cg][2] = az; red[wave][cg][3] = aw;
    }
    __syncthreads();
    if (tid < 8) {
        float tot[4];
#pragma unroll
        for (int j = 0; j < 4; ++j)
            tot[j] = red[0][tid][j] + red[1][tid][j] + red[2][tid][j] + red[3][tid][j];
        int c0 = (tid & 3) * 4;
        if (tid < 4) {
#pragma unroll
            for (int j = 0; j < 4; ++j)
                bvec[(size_t)t * 16 + c0 + j] = 2.f / (1.f + expf(-tot[j]));
        } else {
#pragma unroll
            for (int j = 0; j < 4; ++j) {
                float a = tot[j] + dtb[c0 + j];
                float sp = (a > 20.f) ? a : log1pf(expf(a));
                gvec[(size_t)t * 16 + c0 + j] = -expf(A_log[c0 + j]) * sp;
            }
        }
    }
}

// ---------------- phase 1 (MFMA): fused conv+SiLU + WY-prep + tprep ----------------
__global__ __launch_bounds__(256) void phase1_mfma(
    const float* __restrict__ Cqkv,
    const float* __restrict__ cq, const float* __restrict__ ck, const float* __restrict__ cv,
    const float* __restrict__ gvec, const float* __restrict__ bvec,
    float* __restrict__ u_ws, float* __restrict__ w_ws,
    float* __restrict__ qg_ws, float* __restrict__ at_ws,
    float* __restrict__ gl_ws, float* __restrict__ Ct,
    unsigned short* __restrict__ Tn) {
    int n = blockIdx.x, h = blockIdx.y;
    int t0 = n * CHUNKN;
    int tid = threadIdx.x;
    int wave = tid >> 6, lane = tid & 63;
    size_t base = (size_t)(h * NCHUNK + n);

    __shared__ __align__(16) char LB1[139776];
    unsigned short* QKb  = (unsigned short*)(LB1 + 0);        // 128*104
    unsigned short* Pb   = (unsigned short*)(LB1 + 26624);    // 64*104
    unsigned short* RHSw = (unsigned short*)(LB1 + 39936);    // 96*72
    unsigned short* RHSv = (unsigned short*)(LB1 + 53760);    // 192*72
    unsigned short* Ab   = (unsigned short*)(LB1 + 81408);    // 64*104
    unsigned short* Atb  = (unsigned short*)(LB1 + 94720);    // 64*104
    unsigned short* Ptb  = (unsigned short*)(LB1 + 108032);   // 64*104
    float*          Pf   = (float*)(LB1 + 121344);            // 64*68 -> 138752
    unsigned short* kdT  = (unsigned short*)(LB1 + 81408);    // overlay
    unsigned short* wT   = (unsigned short*)(LB1 + 95232);    // overlay
    unsigned short* uT   = (unsigned short*)(LB1 + 109056);   // overlay
    float* gr_s = (float*)(LB1 + 138752);
    float* gc_s = gr_s + 64;
    float* be_s = gc_s + 64;
    float* egc  = be_s + 64;
    __shared__ __align__(16) float cwS[384 * 4];  // conv weights for this head: q|k|v

    // stage conv weights + gate scalars
    for (int f = tid; f < 384; f += 256) {
        const float* src = (f < 96)  ? (cq + (size_t)(h * 96 + f) * 4)
                         : (f < 192) ? (ck + (size_t)(h * 96 + f - 96) * 4)
                                     : (cv + (size_t)(h * 192 + f - 192) * 4);
        *(float4*)&cwS[f * 4] = *(const float4*)src;
    }
    if (tid < 64) {
        gr_s[tid] = gvec[(size_t)(t0 + tid) * HVN + h];
        be_s[tid] = bvec[(size_t)(t0 + tid) * HVN + h];
    }
    __syncthreads();
    if (tid < 64) {
        float sacc = 0.f;
        for (int j = 0; j <= tid; ++j) sacc += gr_s[j];
        gc_s[tid] = sacc;
    }
    __syncthreads();
    float gl = gc_s[63];
    if (tid < 64) egc[tid] = expf(gl - gc_s[tid]);

    int r = tid >> 2, sub = tid & 3;
    int trow = t0 + r;
    // ---- k: conv+silu, l2norm, write Kn(bf16), RHSw ----
    {
        int gc0 = 1536 + h * DKN + sub * 24;  // global channel base
        int lc0 = 96 + sub * 24;              // cwS base
        float kreg[24];
        float ss = 0.f;
#pragma unroll
        for (int i = 0; i < 6; ++i) {
            float4 x0 = (trow >= 3) ? *(const float4*)(Cqkv + (size_t)(trow - 3) * QKVD + gc0 + i * 4) : make_float4(0, 0, 0, 0);
            float4 x1 = (trow >= 2) ? *(const float4*)(Cqkv + (size_t)(trow - 2) * QKVD + gc0 + i * 4) : make_float4(0, 0, 0, 0);
            float4 x2 = (trow >= 1) ? *(const float4*)(Cqkv + (size_t)(trow - 1) * QKVD + gc0 + i * 4) : make_float4(0, 0, 0, 0);
            float4 x3 = *(const float4*)(Cqkv + (size_t)trow * QKVD + gc0 + i * 4);
#pragma unroll
            for (int c = 0; c < 4; ++c) {
                float4 w = *(const float4*)&cwS[(lc0 + i * 4 + c) * 4];
                float xv = ((const float*)&x0)[c] * w.x + ((const float*)&x1)[c] * w.y
                         + ((const float*)&x2)[c] * w.z + ((const float*)&x3)[c] * w.w;
                xv = siluf(xv);
                kreg[i * 4 + c] = xv;
                ss += xv * xv;
            }
        }
        ss += __shfl_xor(ss, 1, 64);
        ss += __shfl_xor(ss, 2, 64);
        float nrm = rsqrtf(ss + EPSF);
        float ebg = be_s[r] * expf(gc_s[r]);
#pragma unroll
        for (int i = 0; i < 24; ++i) {
            float kn = kreg[i] * nrm;
            QKb[r * 104 + sub * 24 + i] = f2bf(kn);
            RHSw[(sub * 24 + i) * 72 + r] = f2bf(kn * ebg);
        }
    }
    // ---- q: conv+silu, l2norm*dk^-0.5, write Qn(bf16), qg_ws ----
    {
        int gc0 = h * DKN + sub * 24;
        int lc0 = sub * 24;
        float qreg[24];
        float ss = 0.f;
#pragma unroll
        for (int i = 0; i < 6; ++i) {
            float4 x0 = (trow >= 3) ? *(const float4*)(Cqkv + (size_t)(trow - 3) * QKVD + gc0 + i * 4) : make_float4(0, 0, 0, 0);
            float4 x1 = (trow >= 2) ? *(const float4*)(Cqkv + (size_t)(trow - 2) * QKVD + gc0 + i * 4) : make_float4(0, 0, 0, 0);
            float4 x2 = (trow >= 1) ? *(const float4*)(Cqkv + (size_t)(trow - 1) * QKVD + gc0 + i * 4) : make_float4(0, 0, 0, 0);
            float4 x3 = *(const float4*)(Cqkv + (size_t)trow * QKVD + gc0 + i * 4);
#pragma unroll
            for (int c = 0; c < 4; ++c) {
                float4 w = *(const float4*)&cwS[(lc0 + i * 4 + c) * 4];
                float xv = ((const float*)&x0)[c] * w.x + ((const float*)&x1)[c] * w.y
                         + ((const float*)&x2)[c] * w.z + ((const float*)&x3)[c] * w.w;
                xv = siluf(xv);
                qreg[i * 4 + c] = xv;
                ss += xv * xv;
            }
        }
        ss += __shfl_xor(ss, 1, 64);
        ss += __shfl_xor(ss, 2, 64);
        float nrm = rsqrtf(ss + EPSF) * 0.10206207261596577f;
        float eg = expf(gc_s[r]);
        float* qgp = qg_ws + base * (64 * 96) + r * 96 + sub * 24;
#pragma unroll
        for (int i = 0; i < 24; ++i) {
            float qn = qreg[i] * nrm;
            QKb[(64 + r) * 104 + sub * 24 + i] = f2bf(qn);
            qgp[i] = qn * eg;
        }
    }
    // ---- v: conv+silu, stage RHSv = (v*beta)^T bf16 ----
    {
        int gc0 = 3072 + h * DVN + sub * 48;
        int lc0 = 192 + sub * 48;
        float ber = be_s[r];
#pragma unroll
        for (int i = 0; i < 12; ++i) {
            float4 x0 = (trow >= 3) ? *(const float4*)(Cqkv + (size_t)(trow - 3) * QKVD + gc0 + i * 4) : make_float4(0, 0, 0, 0);
            float4 x1 = (trow >= 2) ? *(const float4*)(Cqkv + (size_t)(trow - 2) * QKVD + gc0 + i * 4) : make_float4(0, 0, 0, 0);
            float4 x2 = (trow >= 1) ? *(const float4*)(Cqkv + (size_t)(trow - 1) * QKVD + gc0 + i * 4) : make_float4(0, 0, 0, 0);
            float4 x3 = *(const float4*)(Cqkv + (size_t)trow * QKVD + gc0 + i * 4);
#pragma unroll
            for (int c = 0; c < 4; ++c) {
                float4 w = *(const float4*)&cwS[(lc0 + i * 4 + c) * 4];
                float xv = ((const float*)&x0)[c] * w.x + ((const float*)&x1)[c] * w.y
                         + ((const float*)&x2)[c] * w.z + ((const float*)&x3)[c] * w.w;
                RHSv[(sub * 48 + i * 4 + c) * 72 + r] = f2bf(siluf(xv) * ber);
            }
        }
    }
    __syncthreads();

    // MFMA1: [Kn;Qn] @ Kn^T -> A (rows<64) and attn (rows>=64)
    {
        f32x4 acc1[2][4] = {};
#pragma unroll
        for (int ks = 0; ks < 3; ++ks) {
            int ko = ks * 32 + (lane >> 4) * 8;
            short8 af[2], bfv[4];
#pragma unroll
            for (int rt2 = 0; rt2 < 2; ++rt2)
                af[rt2] = *(const short8*)&QKb[(wave * 32 + rt2 * 16 + (lane & 15)) * 104 + ko];
#pragma unroll
            for (int ct = 0; ct < 4; ++ct)
                bfv[ct] = *(const short8*)&QKb[(ct * 16 + (lane & 15)) * 104 + ko];
#pragma unroll
            for (int rt2 = 0; rt2 < 2; ++rt2)
#pragma unroll
                for (int ct = 0; ct < 4; ++ct)
                    acc1[rt2][ct] = __builtin_amdgcn_mfma_f32_16x16x32_bf16(af[rt2], bfv[ct], acc1[rt2][ct], 0, 0, 0);
        }
#pragma unroll
        for (int rt2 = 0; rt2 < 2; ++rt2)
#pragma unroll
            for (int ct = 0; ct < 4; ++ct)
#pragma unroll
                for (int j = 0; j < 4; ++j) {
                    int rr = wave * 32 + rt2 * 16 + (lane >> 4) * 4 + j;
                    int cc = ct * 16 + (lane & 15);
                    float val = acc1[rt2][ct][j];
                    if (rr < 64) {
                        float av = (rr > cc) ? -be_s[rr] * expf(gc_s[rr] - gc_s[cc]) * val : 0.f;
                        unsigned short ab = f2bf(av);
                        Ab[rr * 104 + cc] = ab;
                        Atb[cc * 104 + rr] = ab;
                        float pv = (rr == cc) ? 1.f : av;
                        Pf[rr * 68 + cc] = pv;
                        unsigned short pb = f2bf(pv);
                        Pb[rr * 104 + cc] = pb;
                        Ptb[cc * 104 + rr] = pb;
                    } else {
                        int ar = rr - 64;
                        float av = (ar >= cc) ? expf(gc_s[ar] - gc_s[cc]) * val : 0.f;
                        at_ws[base * (64 * 64) + ar * 64 + cc] = av;
                    }
                }
    }
    __syncthreads();

    // doubling: T = (I+A)(I+A^2)(I+A^4)(I+A^8)(I+A^16)(I+A^32)
#pragma unroll 1
    for (int lev = 0; lev < 5; ++lev) {
        f32x4 d[4] = {};
#pragma unroll
        for (int ks = 0; ks < 2; ++ks) {
            int ko = ks * 32 + (lane >> 4) * 8;
            short8 a0 = *(const short8*)&Ab[(wave * 16 + (lane & 15)) * 104 + ko];
#pragma unroll
            for (int ct = 0; ct < 4; ++ct) {
                short8 b0 = *(const short8*)&Atb[(ct * 16 + (lane & 15)) * 104 + ko];
                d[ct] = __builtin_amdgcn_mfma_f32_16x16x32_bf16(a0, b0, d[ct], 0, 0, 0);
            }
        }
        __syncthreads();
#pragma unroll
        for (int ct = 0; ct < 4; ++ct)
#pragma unroll
            for (int j = 0; j < 4; ++j) {
                int rr = wave * 16 + (lane >> 4) * 4 + j;
                int cc = ct * 16 + (lane & 15);
                unsigned short hb = f2bf(d[ct][j]);
                Ab[rr * 104 + cc] = hb;
                Atb[cc * 104 + rr] = hb;
            }
        __syncthreads();
        f32x4 e[4];
#pragma unroll
        for (int ct = 0; ct < 4; ++ct)
#pragma unroll
            for (int j = 0; j < 4; ++j)
                e[ct][j] = Pf[(wave * 16 + (lane >> 4) * 4 + j) * 68 + ct * 16 + (lane & 15)];
#pragma unroll
        for (int ks = 0; ks < 2; ++ks) {
            int ko = ks * 32 + (lane >> 4) * 8;
            short8 a0 = *(const short8*)&Ab[(wave * 16 + (lane & 15)) * 104 + ko];
#pragma unroll
            for (int ct = 0; ct < 4; ++ct) {
                short8 b0 = *(const short8*)&Ptb[(ct * 16 + (lane & 15)) * 104 + ko];
                e[ct] = __builtin_amdgcn_mfma_f32_16x16x32_bf16(a0, b0, e[ct], 0, 0, 0);
            }
        }
        __syncthreads();
#pragma unroll
        for (int ct = 0; ct < 4; ++ct)
#pragma unroll
            for (int j = 0; j < 4; ++j) {
                int rr = wave * 16 + (lane >> 4) * 4 + j;
                int cc = ct * 16 + (lane & 15);
                float pv = e[ct][j];
                Pf[rr * 68 + cc] = pv;
                unsigned short pb = f2bf(pv);
                Pb[rr * 104 + cc] = pb;
                Ptb[cc * 104 + rr] = pb;
            }
        __syncthreads();
    }
    // --- Ab/Atb/Ptb/Pf dead; overlay kdT/wT/uT ---

    for (int f = tid; f < 6144; f += 256) {
        int d = f >> 6, tt = f & 63;
        kdT[d * 72 + tt] = f2bf(bf2f(QKb[tt * 104 + d]) * egc[tt]);
    }

#pragma unroll 1
    for (int i = 0; i < 18; ++i) {
        int id = wave * 18 + i;
        int rt = id & 3, ct = id >> 2;
        f32x4 o4 = {};
#pragma unroll
        for (int ks = 0; ks < 2; ++ks) {
            int ko = ks * 32 + (lane >> 4) * 8;
            short8 a0 = *(const short8*)&Pb[(rt * 16 + (lane & 15)) * 104 + ko];
            short8 b0 = (ct < 12)
                ? *(const short8*)&RHSv[(ct * 16 + (lane & 15)) * 72 + ko]
                : *(const short8*)&RHSw[((ct - 12) * 16 + (lane & 15)) * 72 + ko];
            o4 = __builtin_amdgcn_mfma_f32_16x16x32_bf16(a0, b0, o4, 0, 0, 0);
        }
#pragma unroll
        for (int j = 0; j < 4; ++j) {
            int rr = rt * 16 + (lane >> 4) * 4 + j;
            int nn = ct * 16 + (lane & 15);
            if (ct < 12) {
                u_ws[base * (64 * 192) + rr * 192 + nn] = o4[j];
                uT[nn * 72 + rr] = f2bf(o4[j]);
            } else {
                w_ws[base * (64 * 96) + rr * 96 + (nn - 192)] = o4[j];
                wT[(nn - 192) * 72 + rr] = f2bf(o4[j]);
            }
        }
    }
    __syncthreads();

    // fused tprep: Tn = e^gl I - kd^T w (bf16, stride-104), Ct = u^T kd (f32)
    float eglv = expf(gl);
#pragma unroll 1
    for (int q = 0; q < 27; ++q) {
        int id = wave * 27 + q;
        f32x4 acc = {};
        if (id < 36) {
            int jt = id / 6, kt = id % 6;
#pragma unroll
            for (int ks = 0; ks < 2; ++ks) {
                int ko = ks * 32 + (lane >> 4) * 8;
                short8 a0 = *(const short8*)&kdT[(jt * 16 + (lane & 15)) * 72 + ko];
                short8 b0 = *(const short8*)&wT[(kt * 16 + (lane & 15)) * 72 + ko];
                acc = __builtin_amdgcn_mfma_f32_16x16x32_bf16(a0, b0, acc, 0, 0, 0);
            }
#pragma unroll
            for (int rr = 0; rr < 4; ++rr) {
                int j = jt * 16 + (lane >> 4) * 4 + rr;
                int k = kt * 16 + (lane & 15);
                float val = -acc[rr];
                if (j == k) val += eglv;
                Tn[base * TN_STRIDE + j * 104 + k] = f2bf(val);
            }
        } else {
            int cid = id - 36;
            int it = cid / 6, jt = cid % 6;
#pragma unroll
            for (int ks = 0; ks < 2; ++ks) {
                int ko = ks * 32 + (lane >> 4) * 8;
                short8 a0 = *(const short8*)&uT[(it * 16 + (lane & 15)) * 72 + ko];
                short8 b0 = *(const short8*)&kdT[(jt * 16 + (lane & 15)) * 72 + ko];
                acc = __builtin_amdgcn_mfma_f32_16x16x32_bf16(a0, b0, acc, 0, 0, 0);
            }
#pragma unroll
            for (int rr = 0; rr < 4; ++rr)
                Ct[base * 18432 + (size_t)(it * 16 + (lane >> 4) * 4 + rr) * 96 + jt * 16 + (lane & 15)] = acc[rr];
        }
    }
    if (tid == 0) gl_ws[base] = gl;
}

// ---------------- mscan: St_{n+1} = St_n @ T_n^T + Ct_n ----------------
__global__ __launch_bounds__(128) void mscan(const float* __restrict__ Ct, const unsigned short* __restrict__ Tn,
                                             float* __restrict__ s_ws) {
    int rg = blockIdx.x, h = blockIdx.y;
    int tid = threadIdx.x, wave = tid >> 6, lane = tid & 63;
    __shared__ __align__(16) unsigned short St[48 * 104];
    __shared__ __align__(16) unsigned short TnB[2][TN_STRIDE];
    __shared__ __align__(16) float CtB[2][48 * 96];
    for (int i = tid; i < 48 * 104; i += 128) St[i] = 0;

    {
        const float* cp = Ct + (size_t)(h * NCHUNK) * 18432 + rg * (48 * 96);
        const unsigned short* tp = Tn + (size_t)(h * NCHUNK) * TN_STRIDE;
#pragma unroll
        for (int q = 0; q < 9; ++q) {
            size_t o = (size_t)(wave * 9 + q) * 1024 + lane * 16;
            gld_lds16((const char*)cp + o, (char*)&CtB[0][0] + (size_t)(wave * 9 + q) * 1024);
        }
#pragma unroll
        for (int q = 0; q < 10; ++q) {
            size_t o = (size_t)(wave * 10 + q) * 1024 + lane * 16;
            gld_lds16((const char*)tp + o, (char*)&TnB[0][0] + (size_t)(wave * 10 + q) * 1024);
        }
    }
    f32x4 acc[3][3] = {};
    int colw = wave * 48;
    __syncthreads();

#pragma unroll 1
    for (int n = 0; n < NCHUNK; ++n) {
        size_t base = (size_t)(h * NCHUNK + n);
        int cur = n & 1;
        if (n + 1 < NCHUNK) {
            const float* cp = Ct + (base + 1) * 18432 + rg * (48 * 96);
            const unsigned short* tp = Tn + (base + 1) * TN_STRIDE;
#pragma unroll
            for (int q = 0; q < 9; ++q) {
                size_t o = (size_t)(wave * 9 + q) * 1024 + lane * 16;
                gld_lds16((const char*)cp + o, (char*)&CtB[cur ^ 1][0] + (size_t)(wave * 9 + q) * 1024);
            }
#pragma unroll
            for (int q = 0; q < 10; ++q) {
                size_t o = (size_t)(wave * 10 + q) * 1024 + lane * 16;
                gld_lds16((const char*)tp + o, (char*)&TnB[cur ^ 1][0] + (size_t)(wave * 10 + q) * 1024);
            }
        }
        float* sp = s_ws + base * 18432 + rg * (48 * 96);
#pragma unroll
        for (int it = 0; it < 3; ++it)
#pragma unroll
            for (int jt = 0; jt < 3; ++jt) {
                int irow = it * 16 + (lane >> 4) * 4;
                int col = colw + jt * 16 + (lane & 15);
#pragma unroll
                for (int r = 0; r < 4; ++r) {
                    sp[(size_t)(irow + r) * 96 + col] = acc[it][jt][r];
                    acc[it][jt][r] = CtB[cur][(irow + r) * 96 + col];
                }
            }
#pragma unroll
        for (int ks = 0; ks < 3; ++ks) {
            int ko = ks * 32 + (lane >> 4) * 8;
            short8 af[3], bfv[3];
#pragma unroll
            for (int it = 0; it < 3; ++it)
                af[it] = *(const short8*)&St[(it * 16 + (lane & 15)) * 104 + ko];
#pragma unroll
            for (int jt = 0; jt < 3; ++jt)
                bfv[jt] = *(const short8*)&TnB[cur][(colw + jt * 16 + (lane & 15)) * 104 + ko];
#pragma unroll
            for (int it = 0; it < 3; ++it)
#pragma unroll
                for (int jt = 0; jt < 3; ++jt)
                    acc[it][jt] = __builtin_amdgcn_mfma_f32_16x16x32_bf16(af[it], bfv[jt], acc[it][jt], 0, 0, 0);
        }
        __syncthreads();
#pragma unroll
        for (int it = 0; it < 3; ++it)
#pragma unroll
            for (int jt = 0; jt < 3; ++jt)
#pragma unroll
                for (int r = 0; r < 4; ++r)
                    St[(it * 16 + (lane >> 4) * 4 + r) * 104 + colw + jt * 16 + (lane & 15)] = f2bf(acc[it][jt][r]);
        __syncthreads();
    }
}

// ---------------- phase2b (MFMA) + fused gate/RMSNorm -> obf ----------------
#define P2_ST 0
#define P2_W  39936
#define P2_QG 53248
#define P2_AT 66560
#define P2_U  75776
#define P2_VN 125952
__global__ __launch_bounds__(256) void phase2b_mfma(const float* __restrict__ s_ws, const float* __restrict__ w_ws,
                                                    const float* __restrict__ qg_ws, const float* __restrict__ at_ws,
                                                    const float* __restrict__ u_ws,
                                                    const unsigned short* __restrict__ Cgate,
                                                    const float* __restrict__ nw,
                                                    unsigned short* __restrict__ obf) {
    __shared__ __align__(16) char LB[153600];
    unsigned short* StB = (unsigned short*)(LB + P2_ST);
    unsigned short* wB  = (unsigned short*)(LB + P2_W);
    unsigned short* qgB = (unsigned short*)(LB + P2_QG);
    unsigned short* atB = (unsigned short*)(LB + P2_AT);
    float* uF           = (float*)(LB + P2_U);
    unsigned short* vnB = (unsigned short*)(LB + P2_VN);
    int n = blockIdx.x, h = blockIdx.y;
    size_t base = (size_t)(h * NCHUNK + n);
    int tid = threadIdx.x, wave = tid >> 6, lane = tid & 63;
    int i0w = wave * 48;
    {
        const float* sp = s_ws + base * 18432;
        for (int f = tid; f < 4608; f += 256) {
            int i = f / 24, c4 = (f % 24) * 4;
            float4 v = *(const float4*)(sp + i * 96 + c4);
            ushort4 o4; o4.x = f2bf(v.x); o4.y = f2bf(v.y); o4.z = f2bf(v.z); o4.w = f2bf(v.w);
            *(ushort4*)&StB[i * 104 + c4] = o4;
        }
    }
    {
        const float* wp = w_ws + base * 6144;
        const float* qp = qg_ws + base * 6144;
        for (int f = tid; f < 1536; f += 256) {
            int t = f / 24, c4 = (f % 24) * 4;
            float4 wv = *(const float4*)(wp + t * 96 + c4);
            float4 qv = *(const float4*)(qp + t * 96 + c4);
            ushort4 ow; ow.x = f2bf(-wv.x); ow.y = f2bf(-wv.y); ow.z = f2bf(-wv.z); ow.w = f2bf(-wv.w);
            ushort4 oq; oq.x = f2bf(qv.x); oq.y = f2bf(qv.y); oq.z = f2bf(qv.z); oq.w = f2bf(qv.w);
            *(ushort4*)&wB[t * 104 + c4] = ow;
            *(ushort4*)&qgB[t * 104 + c4] = oq;
        }
    }
    {
        const float* ap = at_ws + base * 4096;
        for (int f = tid; f < 1024; f += 256) {
            int t = f / 16, c4 = (f % 16) * 4;
            float4 av = *(const float4*)(ap + t * 64 + c4);
            ushort4 oa; oa.x = f2bf(av.x); oa.y = f2bf(av.y); oa.z = f2bf(av.z); oa.w = f2bf(av.w);
            *(ushort4*)&atB[t * 72 + c4] = oa;
        }
    }
    {
        const float* up = u_ws + base * 12288;
        for (int f = tid; f < 3072; f += 256) {
            int t = f / 48, c4 = (f % 48) * 4;
            *(float4*)&uF[t * 196 + c4] = *(const float4*)(up + t * 192 + c4);
        }
    }
    __syncthreads();
    {
        f32x4 acc[3][4];
#pragma unroll
        for (int it = 0; it < 3; ++it)
#pragma unroll
            for (int jt = 0; jt < 4; ++jt)
#pragma unroll
                for (int r = 0; r < 4; ++r)
                    acc[it][jt][r] = uF[(jt * 16 + (lane & 15)) * 196 + i0w + it * 16 + (lane >> 4) * 4 + r];
#pragma unroll
        for (int ks = 0; ks < 3; ++ks) {
            int ko = ks * 32 + (lane >> 4) * 8;
            short8 af[3], bfv[4];
#pragma unroll
            for (int it = 0; it < 3; ++it)
                af[it] = *(const short8*)&StB[(i0w + it * 16 + (lane & 15)) * 104 + ko];
#pragma unroll
            for (int jt = 0; jt < 4; ++jt)
                bfv[jt] = *(const short8*)&wB[(jt * 16 + (lane & 15)) * 104 + ko];
#pragma unroll
            for (int it = 0; it < 3; ++it)
#pragma unroll
                for (int jt = 0; jt < 4; ++jt)
                    acc[it][jt] = __builtin_amdgcn_mfma_f32_16x16x32_bf16(af[it], bfv[jt], acc[it][jt], 0, 0, 0);
        }
#pragma unroll
        for (int it = 0; it < 3; ++it)
#pragma unroll
            for (int jt = 0; jt < 4; ++jt)
#pragma unroll
                for (int r = 0; r < 4; ++r)
                    vnB[(i0w + it * 16 + (lane >> 4) * 4 + r) * 72 + jt * 16 + (lane & 15)] = f2bf(acc[it][jt][r]);
    }
    f32x4 acc2[3][4] = {};
#pragma unroll
    for (int ks = 0; ks < 3; ++ks) {
        int ko = ks * 32 + (lane >> 4) * 8;
        short8 af[3], bfv[4];
#pragma unroll
        for (int it = 0; it < 3; ++it)
            af[it] = *(const short8*)&StB[(i0w + it * 16 + (lane & 15)) * 104 + ko];
#pragma unroll
        for (int jt = 0; jt < 4; ++jt)
            bfv[jt] = *(const short8*)&qgB[(jt * 16 + (lane & 15)) * 104 + ko];
#pragma unroll
        for (int it = 0; it < 3; ++it)
#pragma unroll
            for (int jt = 0; jt < 4; ++jt)
                acc2[it][jt] = __builtin_amdgcn_mfma_f32_16x16x32_bf16(af[it], bfv[jt], acc2[it][jt], 0, 0, 0);
    }
#pragma unroll
    for (int ks = 0; ks < 2; ++ks) {
        int ko = ks * 32 + (lane >> 4) * 8;
        short8 af[3], bfv[4];
#pragma unroll
        for (int it = 0; it < 3; ++it)
            af[it] = *(const short8*)&vnB[(i0w + it * 16 + (lane & 15)) * 72 + ko];
#pragma unroll
        for (int jt = 0; jt < 4; ++jt)
            bfv[jt] = *(const short8*)&atB[(jt * 16 + (lane & 15)) * 72 + ko];
#pragma unroll
        for (int it = 0; it < 3; ++it)
#pragma unroll
            for (int jt = 0; jt < 4; ++jt)
                acc2[it][jt] = __builtin_amdgcn_mfma_f32_16x16x32_bf16(af[it], bfv[jt], acc2[it][jt], 0, 0, 0);
    }
    __syncthreads();
    float* oF = (float*)(LB + 0); // [192][68]
#pragma unroll
    for (int it = 0; it < 3; ++it)
#pragma unroll
        for (int jt = 0; jt < 4; ++jt)
#pragma unroll
            for (int r = 0; r < 4; ++r)
                oF[(i0w + it * 16 + (lane >> 4) * 4 + r) * 68 + jt * 16 + (lane & 15)] = acc2[it][jt][r];
    __syncthreads();

    float* ssq = (float*)(LB + 131072);
    float* rno = (float*)(LB + 132096);
    int jj = tid >> 2, qq = tid & 3;
    int t0 = n * CHUNKN;
    {
        const unsigned short* gp = Cgate + (size_t)(t0 + jj) * VDIMN + h * DVN + qq * 48;
        float ss = 0.f;
#pragma unroll 4
        for (int m = 0; m < 48; ++m) {
            int i = qq * 48 + m;
            float x = oF[i * 68 + jj];
            float g = bf2f(gp[m]);
            float xv = x * siluf(g);
            oF[i * 68 + jj] = xv;
            ss += xv * xv;
        }
        ssq[jj * 4 + qq] = ss;
    }
    __syncthreads();
    if (tid < 64) {
        float tot = ssq[tid * 4] + ssq[tid * 4 + 1] + ssq[tid * 4 + 2] + ssq[tid * 4 + 3];
        rno[tid] = rsqrtf(tot * (1.f / 192.f) + EPSF);
    }
    __syncthreads();
    {
        float rr2 = rno[jj];
        unsigned short* op = obf + (size_t)(t0 + jj) * VDIMN + h * DVN + qq * 48;
#pragma unroll 4
        for (int m = 0; m < 48; ++m) {
            int i = qq * 48 + m;
            op[m] = f2bf(oF[i * 68 + jj] * rr2 * nw[i]);
        }
    }
}

extern "C" void kernel_launch(void* const* d_in, const int* in_sizes, int n_in,
                              void* d_out, int out_size, void* d_ws, size_t ws_size,
                              hipStream_t stream) {
    (void)in_sizes; (void)n_in; (void)out_size;
    const float* X    = (const float*)d_in[0];
    const float* Wq   = (const float*)d_in[1];
    const float* Wk   = (const float*)d_in[2];
    const float* Wv   = (const float*)d_in[3];
    const float* Wb   = (const float*)d_in[4];
    const float* Wa   = (const float*)d_in[5];
    const float* Wg   = (const float*)d_in[6];
    const float* Wo   = (const float*)d_in[7];
    const float* cq   = (const float*)d_in[8];
    const float* ck   = (const float*)d_in[9];
    const float* cv   = (const float*)d_in[10];
    const float* Alog = (const float*)d_in[11];
    const float* dtb  = (const float*)d_in[12];
    const float* nw   = (const float*)d_in[13];

    // workspace layout
    const size_t OFF_XBF   = 0;                     // Xbf 8.39 MB -> at_ws after gemm
    const size_t OFF_WALLT = 8388608;               // WallT 37.7 MB -> obf at +25.2 after gemms
    const size_t OFF_WOT   = 46137344;              // WoT 12.6 MB (live to end)
    const size_t OFF_CQKV  = 58720256;              // Cqkv f32 50.3 MB (live thru phase1) -> s_ws -> opart
    const size_t OFF_CGATE = 109051904;             // Cgate bf16 12.6 MB
    const size_t OFF_CT    = 134217728;             // Ct 37.7 MB (phase1 writes)
    const size_t OFF_TN    = OFF_CT + 37748736;     // Tn 10.5 MB -> ends 182.5 MB
    const size_t OFF_GVEC  = 184549376;
    const size_t OFF_BVEC  = 184680448;
    const size_t OFF_GL    = 184811520;
    const size_t OFF_U     = 184819712;             // u 25.2 MB
    const size_t OFF_W     = 209985536;             // w 12.6 MB
    const size_t OFF_QG    = 222568448;             // qg 12.6 MB -> ends 235.2 MB
    const size_t OFF_AT    = OFF_XBF;
    const size_t OFF_S     = OFF_CQKV;              // s_ws 37.7 MB (after phase1)
    const size_t OFF_OBF   = OFF_WALLT + 25165824;
    const size_t OFF_OPART = OFF_CQKV;              // opart 33.6 MB (after phase2b)
    const size_t NEEDED    = 235151360;
    if (ws_size < NEEDED) return;

    char* ws = (char*)d_ws;
    unsigned short* Xbf   = (unsigned short*)(ws + OFF_XBF);
    unsigned short* WallT = (unsigned short*)(ws + OFF_WALLT);
    unsigned short* WoT   = (unsigned short*)(ws + OFF_WOT);
    float* Cqkv  = (float*)(ws + OFF_CQKV);
    unsigned short* Cgate = (unsigned short*)(ws + OFF_CGATE);
    float* gvec  = (float*)(ws + OFF_GVEC);
    float* bvec  = (float*)(ws + OFF_BVEC);
    float* gl_ws = (float*)(ws + OFF_GL);
    float* u_ws  = (float*)(ws + OFF_U);
    float* w_ws  = (float*)(ws + OFF_W);
    float* qg_ws = (float*)(ws + OFF_QG);
    float* at_ws = (float*)(ws + OFF_AT);
    float* Ct    = (float*)(ws + OFF_CT);
    unsigned short* Tn = (unsigned short*)(ws + OFF_TN);
    float* s_ws  = (float*)(ws + OFF_S);
    unsigned short* obf = (unsigned short*)(ws + OFF_OBF);
    float* opart = (float*)(ws + OFF_OPART);

    cast_f32_bf16<<<4096, 256, 0, stream>>>(X, Xbf, 2048 * 2048);
    prep_weights<<<6144, dim3(64, 4), 0, stream>>>(Wq, Wk, Wv, Wg, Wo, WallT, WoT);

    // fused QKV (f32) + gate (bf16) projection, 2-phase pipelined
    gemm_bt2<<<dim3(9216 / 128, 2048 / 128), 256, 0, stream>>>(Xbf, WallT,
                                                               Cqkv, QKVD, QKVD / 128,
                                                               Cgate, VDIMN, 2048, 2048);

    beta_g<<<T_LEN, 256, 0, stream>>>(X, Wb, Wa, Alog, dtb, bvec, gvec);

    // phase1: conv+SiLU fused (reads Cqkv with causal halo), WY-prep, tprep
    phase1_mfma<<<dim3(NCHUNK, HVN), 256, 0, stream>>>(Cqkv, cq, ck, cv, gvec, bvec,
                                                       u_ws, w_ws, qg_ws, at_ws, gl_ws, Ct, Tn);
    mscan<<<dim3(4, HVN), 128, 0, stream>>>(Ct, Tn, s_ws);
    phase2b_mfma<<<dim3(NCHUNK, HVN), 256, 0, stream>>>(s_ws, w_ws, qg_ws, at_ws, u_ws,
                                                        Cgate, nw, obf);

    // output GEMM split-K=3 (2-phase pipelined) + deterministic fixup
    gemm_btk<<<dim3(2048 / 128, 2048 / 128, 3), 256, 0, stream>>>(obf, WoT, (float*)d_out, opart,
                                                                  2048, 2048, 3072);
    addk<<<4096, 256, 0, stream>>>((float*)d_out, opart, 2048 * 2048);
}

// Round 13
// 402.721 us; speedup vs baseline: 1.9956x; 1.0268x over previous
//
#include <hip/hip_runtime.h>
#include <math.h>

#define T_LEN 2048
#define HIDN  2048
#define HKN   16
#define DKN   96
#define HVN   16
#define DVN   192
#define KDIMN 1536
#define VDIMN 3072
#define QKVD  6144   // q(1536)+k(1536)+v(3072)
#define CHUNKN 64
#define NCHUNK 32
#define EPSF 1e-6f
#define TN_STRIDE 10240   // ushorts per record: 96*104 + pad -> 20480 B
#define WQG_ST 6656       // ushorts per record: 64*104 -> 13312 B
#define AT_ST  4608       // ushorts per record: 64*72  -> 9216 B
#define CT_ST  18432      // ushorts per record: 192*96 -> 36864 B
#define S_ST   19968      // ushorts per record: 192*104 -> 39936 B
#define U_ST   12288      // floats per record: 64*192

typedef __attribute__((ext_vector_type(8))) short short8;
typedef __attribute__((ext_vector_type(4))) float f32x4;

__device__ __forceinline__ unsigned short f2bf(float f) {
    unsigned int u = __float_as_uint(f);
    unsigned int r = (u + 0x7FFFu + ((u >> 16) & 1u)) >> 16;
    return (unsigned short)r;
}
__device__ __forceinline__ float bf2f(unsigned short u) {
    return __uint_as_float(((unsigned int)u) << 16);
}
__device__ __forceinline__ float siluf(float x) { return x / (1.f + expf(-x)); }

__device__ __forceinline__ void gld_lds16(const void* g, void* l) {
    __builtin_amdgcn_global_load_lds((const __attribute__((address_space(1))) unsigned int*)g,
                                     (__attribute__((address_space(3))) unsigned int*)l, 16, 0, 0);
}

// ---------------- fused weight transposes: 5 weights, one dispatch ----------------
__global__ void prep_weights(const float* __restrict__ Wq, const float* __restrict__ Wk,
                             const float* __restrict__ Wv, const float* __restrict__ Wg,
                             const float* __restrict__ Wo,
                             unsigned short* __restrict__ WallT, unsigned short* __restrict__ WoT) {
    __shared__ float tile[64][65];
    int bid = blockIdx.x;
    const float* W; unsigned short* Wt; int K, N, l;
    if (bid < 768)       { W = Wq; Wt = WallT;                          K = 2048; N = 1536; l = bid; }
    else if (bid < 1536) { W = Wk; Wt = WallT + (size_t)1536 * 2048;    K = 2048; N = 1536; l = bid - 768; }
    else if (bid < 3072) { W = Wv; Wt = WallT + (size_t)3072 * 2048;    K = 2048; N = 3072; l = bid - 1536; }
    else if (bid < 4608) { W = Wg; Wt = WallT + (size_t)6144 * 2048;    K = 2048; N = 3072; l = bid - 3072; }
    else                 { W = Wo; Wt = WoT;                            K = 3072; N = 2048; l = bid - 4608; }
    int nbx = N >> 6;
    int n0 = (l % nbx) * 64, k0 = (l / nbx) * 64;
    int tx = threadIdx.x, ty = threadIdx.y;
    for (int r = ty; r < 64; r += 4) tile[r][tx] = W[(size_t)(k0 + r) * N + n0 + tx];
    __syncthreads();
    for (int r = ty; r < 64; r += 4) Wt[(size_t)(n0 + r) * K + k0 + tx] = f2bf(tile[tx][r]);
}

// ---------------- fused projection GEMM, 2-phase double-buffered LDS ----------------
__global__ __launch_bounds__(256) void gemm_bt2(const unsigned short* __restrict__ A,
                                                const unsigned short* __restrict__ Bt,
                                                float* __restrict__ C1, int ld1, int nblk1,
                                                unsigned short* __restrict__ C2, int ld2,
                                                int M, int K) {
    __shared__ __align__(16) unsigned short As[2][128 * 32];
    __shared__ __align__(16) unsigned short Bs[2][128 * 32];
    int tid = threadIdx.x;
    int wave = tid >> 6, lane = tid & 63;
    int bm = blockIdx.y, bn = blockIdx.x;
    f32x4 acc[4][4] = {};
    int wr = wave >> 1, wc = wave & 1;
    int rstage = wave * 32 + (lane >> 2);
    int cstage = (lane & 3) * 8;
    const size_t a_row0 = (size_t)bm * 128;
    const size_t b_row0 = (size_t)bn * 128;
    const unsigned short* gaBase = A + (a_row0 + rstage) * (size_t)K + cstage;
    const unsigned short* gbBase = Bt + (b_row0 + rstage) * (size_t)K + cstage;
    int row_a[4], row_b[4];
#pragma unroll
    for (int i = 0; i < 4; ++i) {
        row_a[i] = wr * 64 + i * 16 + (lane & 15);
        row_b[i] = wc * 64 + i * 16 + (lane & 15);
    }
    int koff = (lane >> 4) * 8;
    int niter = K >> 5;
    {
        unsigned short* ab = &As[0][wave * 1024];
        unsigned short* bb = &Bs[0][wave * 1024];
        gld_lds16(gaBase, ab);
        gld_lds16(gaBase + (size_t)16 * K, ab + 512);
        gld_lds16(gbBase, bb);
        gld_lds16(gbBase + (size_t)16 * K, bb + 512);
    }
    __syncthreads();
    for (int i = 0; i < niter; ++i) {
        int cur = i & 1;
        if (i + 1 < niter) {
            int k0 = (i + 1) * 32;
            unsigned short* ab = &As[cur ^ 1][wave * 1024];
            unsigned short* bb = &Bs[cur ^ 1][wave * 1024];
            gld_lds16(gaBase + k0, ab);
            gld_lds16(gaBase + k0 + (size_t)16 * K, ab + 512);
            gld_lds16(gbBase + k0, bb);
            gld_lds16(gbBase + k0 + (size_t)16 * K, bb + 512);
        }
        short8 af[4], bfr[4];
#pragma unroll
        for (int mi = 0; mi < 4; ++mi) af[mi] = *(const short8*)&As[cur][row_a[mi] * 32 + koff];
#pragma unroll
        for (int ni = 0; ni < 4; ++ni) bfr[ni] = *(const short8*)&Bs[cur][row_b[ni] * 32 + koff];
#pragma unroll
        for (int mi = 0; mi < 4; ++mi)
#pragma unroll
            for (int ni = 0; ni < 4; ++ni)
                acc[mi][ni] = __builtin_amdgcn_mfma_f32_16x16x32_bf16(af[mi], bfr[ni], acc[mi][ni], 0, 0, 0);
        __syncthreads();
    }
    if (bn < nblk1) {
        int colb = bn * 128;
#pragma unroll
        for (int mi = 0; mi < 4; ++mi) {
            int rbase = bm * 128 + wr * 64 + mi * 16 + (lane >> 4) * 4;
#pragma unroll
            for (int ni = 0; ni < 4; ++ni) {
                int col = colb + wc * 64 + ni * 16 + (lane & 15);
#pragma unroll
                for (int j = 0; j < 4; ++j)
                    C1[(size_t)(rbase + j) * ld1 + col] = acc[mi][ni][j];
            }
        }
    } else {
        int colb = (bn - nblk1) * 128;
#pragma unroll
        for (int mi = 0; mi < 4; ++mi) {
            int rbase = bm * 128 + wr * 64 + mi * 16 + (lane >> 4) * 4;
#pragma unroll
            for (int ni = 0; ni < 4; ++ni) {
                int col = colb + wc * 64 + ni * 16 + (lane & 15);
#pragma unroll
                for (int j = 0; j < 4; ++j)
                    C2[(size_t)(rbase + j) * ld2 + col] = f2bf(acc[mi][ni][j]);
            }
        }
    }
}

// ---------------- split-K GEMM (SPLIT=3), 2-phase double-buffered LDS ----------------
__global__ __launch_bounds__(256) void gemm_btk(const unsigned short* __restrict__ A,
                                                const unsigned short* __restrict__ Bt,
                                                float* __restrict__ C, float* __restrict__ Cp,
                                                int M, int N, int K) {
    __shared__ __align__(16) unsigned short As[2][128 * 32];
    __shared__ __align__(16) unsigned short Bs[2][128 * 32];
    int tid = threadIdx.x;
    int wave = tid >> 6, lane = tid & 63;
    int bm = blockIdx.y, bn = blockIdx.x, kz = blockIdx.z;
    int kchunk = K / 3;
    int kbeg = kz * kchunk;
    f32x4 acc[4][4] = {};
    int wr = wave >> 1, wc = wave & 1;
    int rstage = wave * 32 + (lane >> 2);
    int cstage = (lane & 3) * 8;
    const size_t a_row0 = (size_t)bm * 128;
    const size_t b_row0 = (size_t)bn * 128;
    const unsigned short* gaBase = A + (a_row0 + rstage) * (size_t)K + kbeg + cstage;
    const unsigned short* gbBase = Bt + (b_row0 + rstage) * (size_t)K + kbeg + cstage;
    int row_a[4], row_b[4];
#pragma unroll
    for (int i = 0; i < 4; ++i) {
        row_a[i] = wr * 64 + i * 16 + (lane & 15);
        row_b[i] = wc * 64 + i * 16 + (lane & 15);
    }
    int koff = (lane >> 4) * 8;
    int niter = kchunk >> 5;
    {
        unsigned short* ab = &As[0][wave * 1024];
        unsigned short* bb = &Bs[0][wave * 1024];
        gld_lds16(gaBase, ab);
        gld_lds16(gaBase + (size_t)16 * K, ab + 512);
        gld_lds16(gbBase, bb);
        gld_lds16(gbBase + (size_t)16 * K, bb + 512);
    }
    __syncthreads();
    for (int i = 0; i < niter; ++i) {
        int cur = i & 1;
        if (i + 1 < niter) {
            int k0 = (i + 1) * 32;
            unsigned short* ab = &As[cur ^ 1][wave * 1024];
            unsigned short* bb = &Bs[cur ^ 1][wave * 1024];
            gld_lds16(gaBase + k0, ab);
            gld_lds16(gaBase + k0 + (size_t)16 * K, ab + 512);
            gld_lds16(gbBase + k0, bb);
            gld_lds16(gbBase + k0 + (size_t)16 * K, bb + 512);
        }
        short8 af[4], bfr[4];
#pragma unroll
        for (int mi = 0; mi < 4; ++mi) af[mi] = *(const short8*)&As[cur][row_a[mi] * 32 + koff];
#pragma unroll
        for (int ni = 0; ni < 4; ++ni) bfr[ni] = *(const short8*)&Bs[cur][row_b[ni] * 32 + koff];
#pragma unroll
        for (int mi = 0; mi < 4; ++mi)
#pragma unroll
            for (int ni = 0; ni < 4; ++ni)
                acc[mi][ni] = __builtin_amdgcn_mfma_f32_16x16x32_bf16(af[mi], bfr[ni], acc[mi][ni], 0, 0, 0);
        __syncthreads();
    }
    float* Cout = (kz == 0) ? C : (Cp + (size_t)(kz - 1) * M * N);
#pragma unroll
    for (int mi = 0; mi < 4; ++mi) {
        int rbase = bm * 128 + wr * 64 + mi * 16 + (lane >> 4) * 4;
#pragma unroll
        for (int ni = 0; ni < 4; ++ni) {
            int col = bn * 128 + wc * 64 + ni * 16 + (lane & 15);
#pragma unroll
            for (int j = 0; j < 4; ++j)
                Cout[(size_t)(rbase + j) * N + col] = acc[mi][ni][j];
        }
    }
}

// ---------------- addk: out += p0 + p1 ----------------
__global__ void addk(float* __restrict__ out, const float* __restrict__ p, int n) {
    int i = (blockIdx.x * blockDim.x + threadIdx.x) * 4;
    if (i >= n) return;
    float4 a = *(const float4*)(out + i);
    float4 b = *(const float4*)(p + i);
    float4 c = *(const float4*)(p + n + i);
    a.x += b.x + c.x; a.y += b.y + c.y; a.z += b.z + c.z; a.w += b.w + c.w;
    *(float4*)(out + i) = a;
}

// ---------------- beta / g projections (f32) + fused X->bf16 cast ----------------
__global__ __launch_bounds__(256) void beta_g(const float* __restrict__ X,
                                              const float* __restrict__ Wb, const float* __restrict__ Wa,
                                              const float* __restrict__ A_log, const float* __restrict__ dtb,
                                              float* __restrict__ bvec, float* __restrict__ gvec,
                                              unsigned short* __restrict__ Xbf) {
    int t = blockIdx.x;
    int tid = threadIdx.x;
    int cg = tid & 7, ks = tid >> 3;
    int wave = tid >> 6, lane = tid & 63;
    const float* xr = X + (size_t)t * HIDN;
    const float* Wsel = (cg < 4) ? Wb : Wa;
    int cc = (cg & 3) * 4;
    float ax = 0.f, ay = 0.f, az = 0.f, aw = 0.f;
#pragma unroll 4
    for (int i = 0; i < 16; ++i) {
        int k = (ks + 32 * i) * 4;
        float4 xv = *(const float4*)(xr + k);
        if (cg == 0) {
            ushort4 xo;
            xo.x = f2bf(xv.x); xo.y = f2bf(xv.y); xo.z = f2bf(xv.z); xo.w = f2bf(xv.w);
            *(ushort4*)(Xbf + (size_t)t * HIDN + k) = xo;
        }
        float4 w0 = *(const float4*)(Wsel + (size_t)(k + 0) * 16 + cc);
        float4 w1 = *(const float4*)(Wsel + (size_t)(k + 1) * 16 + cc);
        float4 w2 = *(const float4*)(Wsel + (size_t)(k + 2) * 16 + cc);
        float4 w3 = *(const float4*)(Wsel + (size_t)(k + 3) * 16 + cc);
        ax += xv.x * w0.x + xv.y * w1.x + xv.z * w2.x + xv.w * w3.x;
        ay += xv.x * w0.y + xv.y * w1.y + xv.z * w2.y + xv.w * w3.y;
        az += xv.x * w0.z + xv.y * w1.z + xv.z * w2.z + xv.w * w3.z;
        aw += xv.x * w0.w + xv.y * w1.w + xv.z * w2.w + xv.w * w3.w;
    }
#pragma unroll
    for (int off = 8; off <= 32; off <<= 1) {
        ax += __shfl_xor(ax, off, 64);
        ay += __shfl_xor(ay, off, 64);
        az += __shfl_xor(az, off, 64);
        aw += __shfl_xor(aw, off, 64);
    }
    __shared__ float red[4][8][4];
    if ((lane >> 3) == 0) {
        red[wave][cg][0] = ax; red[wave][cg][1] = ay;
        red[wave][cg][2] = az; red[wave][cg][3] = aw;
    }
    __syncthreads();
    if (tid < 8) {
        float tot[4];
#pragma unroll
        for (int j = 0; j < 4; ++j)
            tot[j] = red[0][tid][j] + red[1][tid][j] + red[2][tid][j] + red[3][tid][j];
        int c0 = (tid & 3) * 4;
        if (tid < 4) {
#pragma unroll
            for (int j = 0; j < 4; ++j)
                bvec[(size_t)t * 16 + c0 + j] = 2.f / (1.f + expf(-tot[j]));
        } else {
#pragma unroll
            for (int j = 0; j < 4; ++j) {
                float a = tot[j] + dtb[c0 + j];
                float sp = (a > 20.f) ? a : log1pf(expf(a));
                gvec[(size_t)t * 16 + c0 + j] = -expf(A_log[c0 + j]) * sp;
            }
        }
    }
}

// ---------------- phase 1 (MFMA): fused conv+SiLU + WY-prep + tprep ----------------
__global__ __launch_bounds__(256) void phase1_mfma(
    const float* __restrict__ Cqkv,
    const float* __restrict__ cq, const float* __restrict__ ck, const float* __restrict__ cv,
    const float* __restrict__ gvec, const float* __restrict__ bvec,
    float* __restrict__ u_ws, unsigned short* __restrict__ w_bf,
    unsigned short* __restrict__ qg_bf, unsigned short* __restrict__ at_bf,
    unsigned short* __restrict__ Ct, unsigned short* __restrict__ Tn) {
    int n = blockIdx.x, h = blockIdx.y;
    int t0 = n * CHUNKN;
    int tid = threadIdx.x;
    int wave = tid >> 6, lane = tid & 63;
    size_t base = (size_t)(h * NCHUNK + n);

    __shared__ __align__(16) char LB1[139776];
    unsigned short* QKb  = (unsigned short*)(LB1 + 0);        // 128*104
    unsigned short* Pb   = (unsigned short*)(LB1 + 26624);    // 64*104
    unsigned short* RHSw = (unsigned short*)(LB1 + 39936);    // 96*72
    unsigned short* RHSv = (unsigned short*)(LB1 + 53760);    // 192*72
    unsigned short* Ab   = (unsigned short*)(LB1 + 81408);    // 64*104
    unsigned short* Atb  = (unsigned short*)(LB1 + 94720);    // 64*104
    unsigned short* Ptb  = (unsigned short*)(LB1 + 108032);   // 64*104
    float*          Pf   = (float*)(LB1 + 121344);            // 64*68 -> 138752
    unsigned short* kdT  = (unsigned short*)(LB1 + 81408);    // overlay
    unsigned short* wT   = (unsigned short*)(LB1 + 95232);    // overlay
    unsigned short* uT   = (unsigned short*)(LB1 + 109056);   // overlay
    float* gr_s = (float*)(LB1 + 138752);
    float* gc_s = gr_s + 64;
    float* be_s = gc_s + 64;
    float* egc  = be_s + 64;
    __shared__ __align__(16) float cwS[384 * 4];

    for (int f = tid; f < 384; f += 256) {
        const float* src = (f < 96)  ? (cq + (size_t)(h * 96 + f) * 4)
                         : (f < 192) ? (ck + (size_t)(h * 96 + f - 96) * 4)
                                     : (cv + (size_t)(h * 192 + f - 192) * 4);
        *(float4*)&cwS[f * 4] = *(const float4*)src;
    }
    if (tid < 64) {
        gr_s[tid] = gvec[(size_t)(t0 + tid) * HVN + h];
        be_s[tid] = bvec[(size_t)(t0 + tid) * HVN + h];
    }
    __syncthreads();
    if (tid < 64) {
        float sacc = 0.f;
        for (int j = 0; j <= tid; ++j) sacc += gr_s[j];
        gc_s[tid] = sacc;
    }
    __syncthreads();
    float gl = gc_s[63];
    if (tid < 64) egc[tid] = expf(gl - gc_s[tid]);

    int r = tid >> 2, sub = tid & 3;
    int trow = t0 + r;
    // ---- k ----
    {
        int gc0 = 1536 + h * DKN + sub * 24;
        int lc0 = 96 + sub * 24;
        float kreg[24];
        float ss = 0.f;
#pragma unroll
        for (int i = 0; i < 6; ++i) {
            float4 x0 = (trow >= 3) ? *(const float4*)(Cqkv + (size_t)(trow - 3) * QKVD + gc0 + i * 4) : make_float4(0, 0, 0, 0);
            float4 x1 = (trow >= 2) ? *(const float4*)(Cqkv + (size_t)(trow - 2) * QKVD + gc0 + i * 4) : make_float4(0, 0, 0, 0);
            float4 x2 = (trow >= 1) ? *(const float4*)(Cqkv + (size_t)(trow - 1) * QKVD + gc0 + i * 4) : make_float4(0, 0, 0, 0);
            float4 x3 = *(const float4*)(Cqkv + (size_t)trow * QKVD + gc0 + i * 4);
#pragma unroll
            for (int c = 0; c < 4; ++c) {
                float4 w = *(const float4*)&cwS[(lc0 + i * 4 + c) * 4];
                float xv = ((const float*)&x0)[c] * w.x + ((const float*)&x1)[c] * w.y
                         + ((const float*)&x2)[c] * w.z + ((const float*)&x3)[c] * w.w;
                xv = siluf(xv);
                kreg[i * 4 + c] = xv;
                ss += xv * xv;
            }
        }
        ss += __shfl_xor(ss, 1, 64);
        ss += __shfl_xor(ss, 2, 64);
        float nrm = rsqrtf(ss + EPSF);
        float ebg = be_s[r] * expf(gc_s[r]);
#pragma unroll
        for (int i = 0; i < 24; ++i) {
            float kn = kreg[i] * nrm;
            QKb[r * 104 + sub * 24 + i] = f2bf(kn);
            RHSw[(sub * 24 + i) * 72 + r] = f2bf(kn * ebg);
        }
    }
    // ---- q ----
    {
        int gc0 = h * DKN + sub * 24;
        int lc0 = sub * 24;
        float qreg[24];
        float ss = 0.f;
#pragma unroll
        for (int i = 0; i < 6; ++i) {
            float4 x0 = (trow >= 3) ? *(const float4*)(Cqkv + (size_t)(trow - 3) * QKVD + gc0 + i * 4) : make_float4(0, 0, 0, 0);
            float4 x1 = (trow >= 2) ? *(const float4*)(Cqkv + (size_t)(trow - 2) * QKVD + gc0 + i * 4) : make_float4(0, 0, 0, 0);
            float4 x2 = (trow >= 1) ? *(const float4*)(Cqkv + (size_t)(trow - 1) * QKVD + gc0 + i * 4) : make_float4(0, 0, 0, 0);
            float4 x3 = *(const float4*)(Cqkv + (size_t)trow * QKVD + gc0 + i * 4);
#pragma unroll
            for (int c = 0; c < 4; ++c) {
                float4 w = *(const float4*)&cwS[(lc0 + i * 4 + c) * 4];
                float xv = ((const float*)&x0)[c] * w.x + ((const float*)&x1)[c] * w.y
                         + ((const float*)&x2)[c] * w.z + ((const float*)&x3)[c] * w.w;
                xv = siluf(xv);
                qreg[i * 4 + c] = xv;
                ss += xv * xv;
            }
        }
        ss += __shfl_xor(ss, 1, 64);
        ss += __shfl_xor(ss, 2, 64);
        float nrm = rsqrtf(ss + EPSF) * 0.10206207261596577f;
        float eg = expf(gc_s[r]);
        unsigned short* qgp = qg_bf + base * WQG_ST + r * 104 + sub * 24;
#pragma unroll
        for (int i = 0; i < 24; ++i) {
            float qn = qreg[i] * nrm;
            QKb[(64 + r) * 104 + sub * 24 + i] = f2bf(qn);
            qgp[i] = f2bf(qn * eg);
        }
    }
    // ---- v ----
    {
        int gc0 = 3072 + h * DVN + sub * 48;
        int lc0 = 192 + sub * 48;
        float ber = be_s[r];
#pragma unroll
        for (int i = 0; i < 12; ++i) {
            float4 x0 = (trow >= 3) ? *(const float4*)(Cqkv + (size_t)(trow - 3) * QKVD + gc0 + i * 4) : make_float4(0, 0, 0, 0);
            float4 x1 = (trow >= 2) ? *(const float4*)(Cqkv + (size_t)(trow - 2) * QKVD + gc0 + i * 4) : make_float4(0, 0, 0, 0);
            float4 x2 = (trow >= 1) ? *(const float4*)(Cqkv + (size_t)(trow - 1) * QKVD + gc0 + i * 4) : make_float4(0, 0, 0, 0);
            float4 x3 = *(const float4*)(Cqkv + (size_t)trow * QKVD + gc0 + i * 4);
#pragma unroll
            for (int c = 0; c < 4; ++c) {
                float4 w = *(const float4*)&cwS[(lc0 + i * 4 + c) * 4];
                float xv = ((const float*)&x0)[c] * w.x + ((const float*)&x1)[c] * w.y
                         + ((const float*)&x2)[c] * w.z + ((const float*)&x3)[c] * w.w;
                RHSv[(sub * 48 + i * 4 + c) * 72 + r] = f2bf(siluf(xv) * ber);
            }
        }
    }
    __syncthreads();

    // MFMA1: [Kn;Qn] @ Kn^T
    {
        f32x4 acc1[2][4] = {};
#pragma unroll
        for (int ks = 0; ks < 3; ++ks) {
            int ko = ks * 32 + (lane >> 4) * 8;
            short8 af[2], bfv[4];
#pragma unroll
            for (int rt2 = 0; rt2 < 2; ++rt2)
                af[rt2] = *(const short8*)&QKb[(wave * 32 + rt2 * 16 + (lane & 15)) * 104 + ko];
#pragma unroll
            for (int ct = 0; ct < 4; ++ct)
                bfv[ct] = *(const short8*)&QKb[(ct * 16 + (lane & 15)) * 104 + ko];
#pragma unroll
            for (int rt2 = 0; rt2 < 2; ++rt2)
#pragma unroll
                for (int ct = 0; ct < 4; ++ct)
                    acc1[rt2][ct] = __builtin_amdgcn_mfma_f32_16x16x32_bf16(af[rt2], bfv[ct], acc1[rt2][ct], 0, 0, 0);
        }
#pragma unroll
        for (int rt2 = 0; rt2 < 2; ++rt2)
#pragma unroll
            for (int ct = 0; ct < 4; ++ct)
#pragma unroll
                for (int j = 0; j < 4; ++j) {
                    int rr = wave * 32 + rt2 * 16 + (lane >> 4) * 4 + j;
                    int cc = ct * 16 + (lane & 15);
                    float val = acc1[rt2][ct][j];
                    if (rr < 64) {
                        float av = (rr > cc) ? -be_s[rr] * expf(gc_s[rr] - gc_s[cc]) * val : 0.f;
                        unsigned short ab = f2bf(av);
                        Ab[rr * 104 + cc] = ab;
                        Atb[cc * 104 + rr] = ab;
                        float pv = (rr == cc) ? 1.f : av;
                        Pf[rr * 68 + cc] = pv;
                        unsigned short pb = f2bf(pv);
                        Pb[rr * 104 + cc] = pb;
                        Ptb[cc * 104 + rr] = pb;
                    } else {
                        int ar = rr - 64;
                        float av = (ar >= cc) ? expf(gc_s[ar] - gc_s[cc]) * val : 0.f;
                        at_bf[base * AT_ST + ar * 72 + cc] = f2bf(av);
                    }
                }
    }
    __syncthreads();

    // doubling
#pragma unroll 1
    for (int lev = 0; lev < 5; ++lev) {
        f32x4 d[4] = {};
#pragma unroll
        for (int ks = 0; ks < 2; ++ks) {
            int ko = ks * 32 + (lane >> 4) * 8;
            short8 a0 = *(const short8*)&Ab[(wave * 16 + (lane & 15)) * 104 + ko];
#pragma unroll
            for (int ct = 0; ct < 4; ++ct) {
                short8 b0 = *(const short8*)&Atb[(ct * 16 + (lane & 15)) * 104 + ko];
                d[ct] = __builtin_amdgcn_mfma_f32_16x16x32_bf16(a0, b0, d[ct], 0, 0, 0);
            }
        }
        __syncthreads();
#pragma unroll
        for (int ct = 0; ct < 4; ++ct)
#pragma unroll
            for (int j = 0; j < 4; ++j) {
                int rr = wave * 16 + (lane >> 4) * 4 + j;
                int cc = ct * 16 + (lane & 15);
                unsigned short hb = f2bf(d[ct][j]);
                Ab[rr * 104 + cc] = hb;
                Atb[cc * 104 + rr] = hb;
            }
        __syncthreads();
        f32x4 e[4];
#pragma unroll
        for (int ct = 0; ct < 4; ++ct)
#pragma unroll
            for (int j = 0; j < 4; ++j)
                e[ct][j] = Pf[(wave * 16 + (lane >> 4) * 4 + j) * 68 + ct * 16 + (lane & 15)];
#pragma unroll
        for (int ks = 0; ks < 2; ++ks) {
            int ko = ks * 32 + (lane >> 4) * 8;
            short8 a0 = *(const short8*)&Ab[(wave * 16 + (lane & 15)) * 104 + ko];
#pragma unroll
            for (int ct = 0; ct < 4; ++ct) {
                short8 b0 = *(const short8*)&Ptb[(ct * 16 + (lane & 15)) * 104 + ko];
                e[ct] = __builtin_amdgcn_mfma_f32_16x16x32_bf16(a0, b0, e[ct], 0, 0, 0);
            }
        }
        __syncthreads();
#pragma unroll
        for (int ct = 0; ct < 4; ++ct)
#pragma unroll
            for (int j = 0; j < 4; ++j) {
                int rr = wave * 16 + (lane >> 4) * 4 + j;
                int cc = ct * 16 + (lane & 15);
                float pv = e[ct][j];
                Pf[rr * 68 + cc] = pv;
                unsigned short pb = f2bf(pv);
                Pb[rr * 104 + cc] = pb;
                Ptb[cc * 104 + rr] = pb;
            }
        __syncthreads();
    }
    // overlay kdT/wT/uT
    for (int f = tid; f < 6144; f += 256) {
        int d = f >> 6, tt = f & 63;
        kdT[d * 72 + tt] = f2bf(bf2f(QKb[tt * 104 + d]) * egc[tt]);
    }

#pragma unroll 1
    for (int i = 0; i < 18; ++i) {
        int id = wave * 18 + i;
        int rt = id & 3, ct = id >> 2;
        f32x4 o4 = {};
#pragma unroll
        for (int ks = 0; ks < 2; ++ks) {
            int ko = ks * 32 + (lane >> 4) * 8;
            short8 a0 = *(const short8*)&Pb[(rt * 16 + (lane & 15)) * 104 + ko];
            short8 b0 = (ct < 12)
                ? *(const short8*)&RHSv[(ct * 16 + (lane & 15)) * 72 + ko]
                : *(const short8*)&RHSw[((ct - 12) * 16 + (lane & 15)) * 72 + ko];
            o4 = __builtin_amdgcn_mfma_f32_16x16x32_bf16(a0, b0, o4, 0, 0, 0);
        }
#pragma unroll
        for (int j = 0; j < 4; ++j) {
            int rr = rt * 16 + (lane >> 4) * 4 + j;
            int nn = ct * 16 + (lane & 15);
            if (ct < 12) {
                u_ws[base * U_ST + rr * 192 + nn] = o4[j];
                uT[nn * 72 + rr] = f2bf(o4[j]);
            } else {
                w_bf[base * WQG_ST + rr * 104 + (nn - 192)] = f2bf(-o4[j]);
                wT[(nn - 192) * 72 + rr] = f2bf(o4[j]);
            }
        }
    }
    __syncthreads();

    // fused tprep: Tn = e^gl I - kd^T w (bf16, stride-104), Ct = u^T kd (bf16)
    float eglv = expf(gl);
#pragma unroll 1
    for (int q = 0; q < 27; ++q) {
        int id = wave * 27 + q;
        f32x4 acc = {};
        if (id < 36) {
            int jt = id / 6, kt = id % 6;
#pragma unroll
            for (int ks = 0; ks < 2; ++ks) {
                int ko = ks * 32 + (lane >> 4) * 8;
                short8 a0 = *(const short8*)&kdT[(jt * 16 + (lane & 15)) * 72 + ko];
                short8 b0 = *(const short8*)&wT[(kt * 16 + (lane & 15)) * 72 + ko];
                acc = __builtin_amdgcn_mfma_f32_16x16x32_bf16(a0, b0, acc, 0, 0, 0);
            }
#pragma unroll
            for (int rr = 0; rr < 4; ++rr) {
                int j = jt * 16 + (lane >> 4) * 4 + rr;
                int k = kt * 16 + (lane & 15);
                float val = -acc[rr];
                if (j == k) val += eglv;
                Tn[base * TN_STRIDE + j * 104 + k] = f2bf(val);
            }
        } else {
            int cid = id - 36;
            int it = cid / 6, jt = cid % 6;
#pragma unroll
            for (int ks = 0; ks < 2; ++ks) {
                int ko = ks * 32 + (lane >> 4) * 8;
                short8 a0 = *(const short8*)&uT[(it * 16 + (lane & 15)) * 72 + ko];
                short8 b0 = *(const short8*)&kdT[(jt * 16 + (lane & 15)) * 72 + ko];
                acc = __builtin_amdgcn_mfma_f32_16x16x32_bf16(a0, b0, acc, 0, 0, 0);
            }
#pragma unroll
            for (int rr = 0; rr < 4; ++rr)
                Ct[base * CT_ST + (size_t)(it * 16 + (lane >> 4) * 4 + rr) * 96 + jt * 16 + (lane & 15)] = f2bf(acc[rr]);
        }
    }
}

// ---------------- mscan: St_{n+1} = St_n @ T_n^T + Ct_n; stores S_pre bf16 ----------------
__global__ __launch_bounds__(128) void mscan(const unsigned short* __restrict__ Ct,
                                             const unsigned short* __restrict__ Tn,
                                             unsigned short* __restrict__ s_bf) {
    int rg = blockIdx.x, h = blockIdx.y;
    int tid = threadIdx.x, wave = tid >> 6, lane = tid & 63;
    __shared__ __align__(16) unsigned short St[48 * 104];
    __shared__ __align__(16) unsigned short TnB[2][TN_STRIDE];
    __shared__ __align__(16) unsigned short CtB[2][48 * 96];
    for (int i = tid; i < 48 * 104; i += 128) St[i] = 0;

    {
        const char* cp = (const char*)(Ct + (size_t)(h * NCHUNK) * CT_ST + rg * (48 * 96));
        const char* tp = (const char*)(Tn + (size_t)(h * NCHUNK) * TN_STRIDE);
        for (int q = wave; q < 9; q += 2)
            gld_lds16(cp + (size_t)q * 1024 + lane * 16, (char*)&CtB[0][0] + (size_t)q * 1024);
#pragma unroll
        for (int q = 0; q < 10; ++q) {
            size_t o = (size_t)(wave * 10 + q) * 1024 + lane * 16;
            gld_lds16(tp + o, (char*)&TnB[0][0] + (size_t)(wave * 10 + q) * 1024);
        }
    }
    f32x4 acc[3][3];
    int colw = wave * 48;
    __syncthreads();

#pragma unroll 1
    for (int n = 0; n < NCHUNK; ++n) {
        size_t base = (size_t)(h * NCHUNK + n);
        int cur = n & 1;
        if (n + 1 < NCHUNK) {
            const char* cp = (const char*)(Ct + (base + 1) * CT_ST + rg * (48 * 96));
            const char* tp = (const char*)(Tn + (base + 1) * TN_STRIDE);
            for (int q = wave; q < 9; q += 2)
                gld_lds16(cp + (size_t)q * 1024 + lane * 16, (char*)&CtB[cur ^ 1][0] + (size_t)q * 1024);
#pragma unroll
            for (int q = 0; q < 10; ++q) {
                size_t o = (size_t)(wave * 10 + q) * 1024 + lane * 16;
                gld_lds16(tp + o, (char*)&TnB[cur ^ 1][0] + (size_t)(wave * 10 + q) * 1024);
            }
        }
        // store S_pre (= current St, bf16) to s_bf
        {
            unsigned short* sp = s_bf + base * S_ST + rg * 4992;
            for (int f = tid; f < 624; f += 128)
                *(short8*)(sp + f * 8) = *(const short8*)&St[f * 8];
        }
        // re-init acc from Ct
#pragma unroll
        for (int it = 0; it < 3; ++it)
#pragma unroll
            for (int jt = 0; jt < 3; ++jt) {
                int irow = it * 16 + (lane >> 4) * 4;
                int col = colw + jt * 16 + (lane & 15);
#pragma unroll
                for (int r = 0; r < 4; ++r)
                    acc[it][jt][r] = bf2f(CtB[cur][(irow + r) * 96 + col]);
            }
#pragma unroll
        for (int ks = 0; ks < 3; ++ks) {
            int ko = ks * 32 + (lane >> 4) * 8;
            short8 af[3], bfv[3];
#pragma unroll
            for (int it = 0; it < 3; ++it)
                af[it] = *(const short8*)&St[(it * 16 + (lane & 15)) * 104 + ko];
#pragma unroll
            for (int jt = 0; jt < 3; ++jt)
                bfv[jt] = *(const short8*)&TnB[cur][(colw + jt * 16 + (lane & 15)) * 104 + ko];
#pragma unroll
            for (int it = 0; it < 3; ++it)
#pragma unroll
                for (int jt = 0; jt < 3; ++jt)
                    acc[it][jt] = __builtin_amdgcn_mfma_f32_16x16x32_bf16(af[it], bfv[jt], acc[it][jt], 0, 0, 0);
        }
        __syncthreads();
#pragma unroll
        for (int it = 0; it < 3; ++it)
#pragma unroll
            for (int jt = 0; jt < 3; ++jt)
#pragma unroll
                for (int r = 0; r < 4; ++r)
                    St[(it * 16 + (lane >> 4) * 4 + r) * 104 + colw + jt * 16 + (lane & 15)] = f2bf(acc[it][jt][r]);
        __syncthreads();
    }
}

// ---------------- phase2b (MFMA) + fused gate/RMSNorm -> obf ----------------
#define P2_ST 0
#define P2_W  39936
#define P2_QG 53248
#define P2_AT 66560
#define P2_U  75776
#define P2_VN 125952
__global__ __launch_bounds__(256) void phase2b_mfma(const unsigned short* __restrict__ s_bf,
                                                    const unsigned short* __restrict__ w_bf,
                                                    const unsigned short* __restrict__ qg_bf,
                                                    const unsigned short* __restrict__ at_bf,
                                                    const float* __restrict__ u_ws,
                                                    const unsigned short* __restrict__ Cgate,
                                                    const float* __restrict__ nw,
                                                    unsigned short* __restrict__ obf) {
    __shared__ __align__(16) char LB[153600];
    unsigned short* StB = (unsigned short*)(LB + P2_ST);   // [192][104]
    unsigned short* wB  = (unsigned short*)(LB + P2_W);    // [64][104], pre-negated
    unsigned short* qgB = (unsigned short*)(LB + P2_QG);   // [64][104]
    unsigned short* atB = (unsigned short*)(LB + P2_AT);   // [64][72]
    float* uF           = (float*)(LB + P2_U);             // [64][196]
    unsigned short* vnB = (unsigned short*)(LB + P2_VN);   // [192][72]
    int n = blockIdx.x, h = blockIdx.y;
    size_t base = (size_t)(h * NCHUNK + n);
    int tid = threadIdx.x, wave = tid >> 6, lane = tid & 63;
    int i0w = wave * 48;
    // direct gld_lds staging (all layouts linear, bf16 from global)
    {
        const char* sp = (const char*)(s_bf + base * S_ST);
        const char* wp = (const char*)(w_bf + base * WQG_ST);
        const char* qp = (const char*)(qg_bf + base * WQG_ST);
        const char* ap = (const char*)(at_bf + base * AT_ST);
        for (int q = wave; q < 39; q += 4)
            gld_lds16(sp + (size_t)q * 1024 + lane * 16, LB + P2_ST + (size_t)q * 1024);
        for (int q = wave; q < 13; q += 4)
            gld_lds16(wp + (size_t)q * 1024 + lane * 16, LB + P2_W + (size_t)q * 1024);
        for (int q = wave; q < 13; q += 4)
            gld_lds16(qp + (size_t)q * 1024 + lane * 16, LB + P2_QG + (size_t)q * 1024);
        for (int q = wave; q < 9; q += 4)
            gld_lds16(ap + (size_t)q * 1024 + lane * 16, LB + P2_AT + (size_t)q * 1024);
    }
    {
        const float* up = u_ws + base * U_ST;
        for (int f = tid; f < 3072; f += 256) {
            int t = f / 48, c4 = (f % 48) * 4;
            *(float4*)&uF[t * 196 + c4] = *(const float4*)(up + t * 192 + c4);
        }
    }
    __syncthreads();
    {
        f32x4 acc[3][4];
#pragma unroll
        for (int it = 0; it < 3; ++it)
#pragma unroll
            for (int jt = 0; jt < 4; ++jt)
#pragma unroll
                for (int r = 0; r < 4; ++r)
                    acc[it][jt][r] = uF[(jt * 16 + (lane & 15)) * 196 + i0w + it * 16 + (lane >> 4) * 4 + r];
#pragma unroll
        for (int ks = 0; ks < 3; ++ks) {
            int ko = ks * 32 + (lane >> 4) * 8;
            short8 af[3], bfv[4];
#pragma unroll
            for (int it = 0; it < 3; ++it)
                af[it] = *(const short8*)&StB[(i0w + it * 16 + (lane & 15)) * 104 + ko];
#pragma unroll
            for (int jt = 0; jt < 4; ++jt)
                bfv[jt] = *(const short8*)&wB[(jt * 16 + (lane & 15)) * 104 + ko];
#pragma unroll
            for (int it = 0; it < 3; ++it)
#pragma unroll
                for (int jt = 0; jt < 4; ++jt)
                    acc[it][jt] = __builtin_amdgcn_mfma_f32_16x16x32_bf16(af[it], bfv[jt], acc[it][jt], 0, 0, 0);
        }
#pragma unroll
        for (int it = 0; it < 3; ++it)
#pragma unroll
            for (int jt = 0; jt < 4; ++jt)
#pragma unroll
                for (int r = 0; r < 4; ++r)
                    vnB[(i0w + it * 16 + (lane >> 4) * 4 + r) * 72 + jt * 16 + (lane & 15)] = f2bf(acc[it][jt][r]);
    }
    f32x4 acc2[3][4] = {};
#pragma unroll
    for (int ks = 0; ks < 3; ++ks) {
        int ko = ks * 32 + (lane >> 4) * 8;
        short8 af[3], bfv[4];
#pragma unroll
        for (int it = 0; it < 3; ++it)
            af[it] = *(const short8*)&StB[(i0w + it * 16 + (lane & 15)) * 104 + ko];
#pragma unroll
        for (int jt = 0; jt < 4; ++jt)
            bfv[jt] = *(const short8*)&qgB[(jt * 16 + (lane & 15)) * 104 + ko];
#pragma unroll
        for (int it = 0; it < 3; ++it)
#pragma unroll
            for (int jt = 0; jt < 4; ++jt)
                acc2[it][jt] = __builtin_amdgcn_mfma_f32_16x16x32_bf16(af[it], bfv[jt], acc2[it][jt], 0, 0, 0);
    }
#pragma unroll
    for (int ks = 0; ks < 2; ++ks) {
        int ko = ks * 32 + (lane >> 4) * 8;
        short8 af[3], bfv[4];
#pragma unroll
        for (int it = 0; it < 3; ++it)
            af[it] = *(const short8*)&vnB[(i0w + it * 16 + (lane & 15)) * 72 + ko];
#pragma unroll
        for (int jt = 0; jt < 4; ++jt)
            bfv[jt] = *(const short8*)&atB[(jt * 16 + (lane & 15)) * 72 + ko];
#pragma unroll
        for (int it = 0; it < 3; ++it)
#pragma unroll
            for (int jt = 0; jt < 4; ++jt)
                acc2[it][jt] = __builtin_amdgcn_mfma_f32_16x16x32_bf16(af[it], bfv[jt], acc2[it][jt], 0, 0, 0);
    }
    __syncthreads();
    float* oF = (float*)(LB + 0); // [192][68]
#pragma unroll
    for (int it = 0; it < 3; ++it)
#pragma unroll
        for (int jt = 0; jt < 4; ++jt)
#pragma unroll
            for (int r = 0; r < 4; ++r)
                oF[(i0w + it * 16 + (lane >> 4) * 4 + r) * 68 + jt * 16 + (lane & 15)] = acc2[it][jt][r];
    __syncthreads();

    float* ssq = (float*)(LB + 131072);
    float* rno = (float*)(LB + 132096);
    int jj = tid >> 2, qq = tid & 3;
    int t0 = n * CHUNKN;
    {
        const unsigned short* gp = Cgate + (size_t)(t0 + jj) * VDIMN + h * DVN + qq * 48;
        float ss = 0.f;
#pragma unroll 4
        for (int m = 0; m < 48; ++m) {
            int i = qq * 48 + m;
            float x = oF[i * 68 + jj];
            float g = bf2f(gp[m]);
            float xv = x * siluf(g);
            oF[i * 68 + jj] = xv;
            ss += xv * xv;
        }
        ssq[jj * 4 + qq] = ss;
    }
    __syncthreads();
    if (tid < 64) {
        float tot = ssq[tid * 4] + ssq[tid * 4 + 1] + ssq[tid * 4 + 2] + ssq[tid * 4 + 3];
        rno[tid] = rsqrtf(tot * (1.f / 192.f) + EPSF);
    }
    __syncthreads();
    {
        float rr2 = rno[jj];
        unsigned short* op = obf + (size_t)(t0 + jj) * VDIMN + h * DVN + qq * 48;
#pragma unroll 4
        for (int m = 0; m < 48; ++m) {
            int i = qq * 48 + m;
            op[m] = f2bf(oF[i * 68 + jj] * rr2 * nw[i]);
        }
    }
}

extern "C" void kernel_launch(void* const* d_in, const int* in_sizes, int n_in,
                              void* d_out, int out_size, void* d_ws, size_t ws_size,
                              hipStream_t stream) {
    (void)in_sizes; (void)n_in; (void)out_size;
    const float* X    = (const float*)d_in[0];
    const float* Wq   = (const float*)d_in[1];
    const float* Wk   = (const float*)d_in[2];
    const float* Wv   = (const float*)d_in[3];
    const float* Wb   = (const float*)d_in[4];
    const float* Wa   = (const float*)d_in[5];
    const float* Wg   = (const float*)d_in[6];
    const float* Wo   = (const float*)d_in[7];
    const float* cq   = (const float*)d_in[8];
    const float* ck   = (const float*)d_in[9];
    const float* cv   = (const float*)d_in[10];
    const float* Alog = (const float*)d_in[11];
    const float* dtb  = (const float*)d_in[12];
    const float* nw   = (const float*)d_in[13];

    const size_t OFF_XBF   = 0;                     // Xbf 8.39 MB -> at_bf after gemm
    const size_t OFF_WALLT = 8388608;               // WallT 37.7 MB -> obf at +25.2 after gemms
    const size_t OFF_WOT   = 46137344;              // WoT 12.6 MB (live to end)
    const size_t OFF_CQKV  = 58720256;              // Cqkv f32 50.3 MB -> s_bf -> opart
    const size_t OFF_CGATE = 109051904;             // Cgate bf16 12.6 MB
    const size_t OFF_CT    = 134217728;             // Ct bf16 18.9 MB
    const size_t OFF_TN    = OFF_CT + 37748736;     // Tn 10.5 MB
    const size_t OFF_GVEC  = 184549376;
    const size_t OFF_BVEC  = 184680448;
    const size_t OFF_U     = 184819712;             // u f32 25.2 MB
    const size_t OFF_W     = 209985536;             // w_bf 6.8 MB
    const size_t OFF_QG    = 222568448;             // qg_bf 6.8 MB
    const size_t OFF_AT    = OFF_XBF;               // at_bf 4.7 MB (after proj gemm)
    const size_t OFF_S     = OFF_CQKV;              // s_bf 20.4 MB (after phase1)
    const size_t OFF_OBF   = OFF_WALLT + 25165824;
    const size_t OFF_OPART = OFF_CQKV;              // opart (after phase2b reads done? used by gemm_btk)
    const size_t NEEDED    = 235151360;
    if (ws_size < NEEDED) return;

    char* ws = (char*)d_ws;
    unsigned short* Xbf   = (unsigned short*)(ws + OFF_XBF);
    unsigned short* WallT = (unsigned short*)(ws + OFF_WALLT);
    unsigned short* WoT   = (unsigned short*)(ws + OFF_WOT);
    float* Cqkv  = (float*)(ws + OFF_CQKV);
    unsigned short* Cgate = (unsigned short*)(ws + OFF_CGATE);
    float* gvec  = (float*)(ws + OFF_GVEC);
    float* bvec  = (float*)(ws + OFF_BVEC);
    float* u_ws  = (float*)(ws + OFF_U);
    unsigned short* w_bf  = (unsigned short*)(ws + OFF_W);
    unsigned short* qg_bf = (unsigned short*)(ws + OFF_QG);
    unsigned short* at_bf = (unsigned short*)(ws + OFF_AT);
    unsigned short* Ct    = (unsigned short*)(ws + OFF_CT);
    unsigned short* Tn    = (unsigned short*)(ws + OFF_TN);
    unsigned short* s_bf  = (unsigned short*)(ws + OFF_S);
    unsigned short* obf   = (unsigned short*)(ws + OFF_OBF);
    float* opart = (float*)(ws + OFF_OPART);

    // beta/g projection (f32 exact) + fused X->bf16 cast
    beta_g<<<T_LEN, 256, 0, stream>>>(X, Wb, Wa, Alog, dtb, bvec, gvec, Xbf);
    prep_weights<<<6144, dim3(64, 4), 0, stream>>>(Wq, Wk, Wv, Wg, Wo, WallT, WoT);

    // fused QKV (f32) + gate (bf16) projection, 2-phase pipelined
    gemm_bt2<<<dim3(9216 / 128, 2048 / 128), 256, 0, stream>>>(Xbf, WallT,
                                                               Cqkv, QKVD, QKVD / 128,
                                                               Cgate, VDIMN, 2048, 2048);

    // phase1: conv+SiLU fused, WY-prep, tprep -> bf16 intermediates
    phase1_mfma<<<dim3(NCHUNK, HVN), 256, 0, stream>>>(Cqkv, cq, ck, cv, gvec, bvec,
                                                       u_ws, w_bf, qg_bf, at_bf, Ct, Tn);
    mscan<<<dim3(4, HVN), 128, 0, stream>>>(Ct, Tn, s_bf);
    phase2b_mfma<<<dim3(NCHUNK, HVN), 256, 0, stream>>>(s_bf, w_bf, qg_bf, at_bf, u_ws,
                                                        Cgate, nw, obf);

    // output GEMM split-K=3 (2-phase pipelined) + deterministic fixup
    gemm_btk<<<dim3(2048 / 128, 2048 / 128, 3), 256, 0, stream>>>(obf, WoT, (float*)d_out, opart,
                                                                  2048, 2048, 3072);
    addk<<<4096, 256, 0, stream>>>((float*)d_out, opart, 2048 * 2048);
}